// Round 2
// baseline (3268.789 us; speedup 1.0000x reference)
//
#include <hip/hip_runtime.h>
#include <hip/hip_bf16.h>
#include <math.h>

#define LQ 5440
#define CDIM 256
#define BATCH 2
#define FFDIM 1024

// ---------------------------------------------------------------------------
// Generic tiled fp32 GEMM: C[M,N] = act(A @ W^T + bias)
// A: [M,K] row-major (ATRANS=false) or [K,M] row-major (ATRANS=true)
// W: [N,K] row-major. M,N multiples of 64; K multiple of 16.
// ---------------------------------------------------------------------------
template <bool ATRANS, bool RELU>
__global__ __launch_bounds__(256) void gemm_kernel(
    const float* __restrict__ A, const float* __restrict__ W,
    const float* __restrict__ bias, float* __restrict__ C,
    int M, int N, int K, long bsA, long bsC) {
  __shared__ __align__(16) float As[16][72];
  __shared__ __align__(16) float Ws[16][72];
  const int tid = threadIdx.x;
  const int bm = blockIdx.y * 64, bn = blockIdx.x * 64;
  A += (size_t)blockIdx.z * bsA;
  C += (size_t)blockIdx.z * bsC;
  const int tx = tid & 15, ty = tid >> 4;
  float acc[4][4] = {};
  for (int k0 = 0; k0 < K; k0 += 16) {
#pragma unroll
    for (int i = 0; i < 4; ++i) {
      int idx = tid + i * 256;
      if (ATRANS) {
        int k = idx >> 6, m = idx & 63;
        As[k][m] = A[(size_t)(k0 + k) * M + bm + m];
      } else {
        int m = idx >> 4, k = idx & 15;
        As[k][m] = A[(size_t)(bm + m) * K + k0 + k];
      }
      int n = idx >> 4, k2 = idx & 15;
      Ws[k2][n] = W[(size_t)(bn + n) * K + k0 + k2];
    }
    __syncthreads();
#pragma unroll
    for (int k = 0; k < 16; ++k) {
      const float4 av = *(const float4*)&As[k][ty * 4];
      const float4 bv = *(const float4*)&Ws[k][tx * 4];
      const float a4[4] = {av.x, av.y, av.z, av.w};
      const float b4[4] = {bv.x, bv.y, bv.z, bv.w};
#pragma unroll
      for (int i = 0; i < 4; ++i)
#pragma unroll
        for (int j = 0; j < 4; ++j) acc[i][j] = fmaf(a4[i], b4[j], acc[i][j]);
    }
    __syncthreads();
  }
  const float4 bv4 = *(const float4*)&bias[bn + tx * 4];
  const float bb[4] = {bv4.x, bv4.y, bv4.z, bv4.w};
#pragma unroll
  for (int i = 0; i < 4; ++i) {
    float4 o;
    float* op = (float*)&o;
#pragma unroll
    for (int j = 0; j < 4; ++j) {
      float v = acc[i][j] + bb[j];
      if (RELU) v = fmaxf(v, 0.f);
      op[j] = v;
    }
    *(float4*)&C[(size_t)(bm + ty * 4 + i) * N + bn + tx * 4] = o;
  }
}

static inline void gemm(const float* A, const float* W, const float* bias, float* C,
                        int M, int N, int K, bool atrans, bool relu, int bz,
                        long bsA, long bsC, hipStream_t s) {
  dim3 grid(N / 64, M / 64, bz), blk(256);
  if (atrans)
    gemm_kernel<true, false><<<grid, blk, 0, s>>>(A, W, bias, C, M, N, K, bsA, bsC);
  else if (relu)
    gemm_kernel<false, true><<<grid, blk, 0, s>>>(A, W, bias, C, M, N, K, bsA, bsC);
  else
    gemm_kernel<false, false><<<grid, blk, 0, s>>>(A, W, bias, C, M, N, K, bsA, bsC);
}

// ---------------------------------------------------------------------------
__device__ __forceinline__ void get_level(int t, int& l, int& hw, int& Hl, int& Wl) {
  if (t < 4096)      { l = 0; hw = t;        Hl = 64; Wl = 64; }
  else if (t < 5120) { l = 1; hw = t - 4096; Hl = 32; Wl = 32; }
  else if (t < 5376) { l = 2; hw = t - 5120; Hl = 16; Wl = 16; }
  else               { l = 3; hw = t - 5376; Hl = 8;  Wl = 8;  }
}

// GroupNorm stats: one block per (group, level, batch)
__global__ __launch_bounds__(256) void gn_stats_kernel(const float* __restrict__ x,
                                                       float2* __restrict__ stats) {
  const int HWs[4] = {4096, 1024, 256, 64};
  const int STs[4] = {0, 4096, 5120, 5376};
  int g = blockIdx.x, l = blockIdx.y, b = blockIdx.z;
  int HW = HWs[l];
  size_t base = ((size_t)b * LQ + STs[l]) * CDIM + g * 8;
  float s = 0.f, ss = 0.f;
  for (int i = threadIdx.x; i < HW * 8; i += 256) {
    int hw = i >> 3, ci = i & 7;
    float v = x[base + (size_t)hw * CDIM + ci];
    s += v; ss += v * v;
  }
#pragma unroll
  for (int o = 32; o; o >>= 1) { s += __shfl_down(s, o); ss += __shfl_down(ss, o); }
  __shared__ float rs[4], rss[4];
  int lane = threadIdx.x & 63, wid = threadIdx.x >> 6;
  if (lane == 0) { rs[wid] = s; rss[wid] = ss; }
  __syncthreads();
  if (threadIdx.x == 0) {
    s = rs[0] + rs[1] + rs[2] + rs[3];
    ss = rss[0] + rss[1] + rss[2] + rss[3];
    float n = (float)(HW * 8);
    float mu = s / n;
    float var = ss / n - mu * mu;
    stats[(b * 4 + l) * 32 + g] = make_float2(mu, rsqrtf(var + 1e-5f));
  }
}

__global__ void gn_apply_kernel(float* __restrict__ x, const float2* __restrict__ stats,
                                const float* __restrict__ gw, const float* __restrict__ gb) {
  int idx = blockIdx.x * 256 + threadIdx.x;
  if (idx >= BATCH * LQ * CDIM) return;
  int c = idx & 255;
  int tok = idx >> 8;
  int b = tok / LQ, t = tok % LQ;
  int l, hw, Hl, Wl;
  get_level(t, l, hw, Hl, Wl);
  float2 st = stats[(b * 4 + l) * 32 + (c >> 3)];
  x[idx] = (x[idx] - st.x) * st.y * gw[l * CDIM + c] + gb[l * CDIM + c];
}

// Sine positional embedding + level embed: pos[t, c]
__global__ void pos_embed_kernel(const float* __restrict__ level_embed,
                                 float* __restrict__ pos) {
  int idx = blockIdx.x * 256 + threadIdx.x;
  if (idx >= LQ * CDIM) return;
  int t = idx >> 8, c = idx & 255;
  int l, hw, Hl, Wl;
  get_level(t, l, hw, Hl, Wl);
  int y = hw / Wl, xx = hw % Wl;
  const float twopi = 6.28318530717958647692f;
  float v; int cc;
  if (c < 128) { v = (float)(y + 1) * twopi / ((float)Hl + 1e-6f); cc = c; }
  else         { v = (float)(xx + 1) * twopi / ((float)Wl + 1e-6f); cc = c - 128; }
  int k = cc >> 1;
  float dim_t = expf((float)k * (logf(10000.0f) / 64.0f));
  float p = v / dim_t;
  float e = (cc & 1) ? cosf(p) : sinf(p);
  pos[idx] = e + level_embed[l * CDIM + c];
}

__global__ void ref_kernel(float* __restrict__ ref) {
  int t = blockIdx.x * 256 + threadIdx.x;
  if (t >= LQ) return;
  int l, hw, Hl, Wl;
  get_level(t, l, hw, Hl, Wl);
  int y = hw / Wl, xx = hw % Wl;
  ref[t * 2]     = ((float)xx + 0.5f) / (float)Wl;
  ref[t * 2 + 1] = ((float)y + 0.5f) / (float)Hl;
}

__global__ void add_pos_kernel(const float* __restrict__ x, const float* __restrict__ pos,
                               float* __restrict__ q) {
  int i = blockIdx.x * 256 + threadIdx.x;  // float4 index
  if (i >= BATCH * LQ * 64) return;
  int r = i % (LQ * 64);
  float4 a = ((const float4*)x)[i];
  float4 p = ((const float4*)pos)[r];
  a.x += p.x; a.y += p.y; a.z += p.z; a.w += p.w;
  ((float4*)q)[i] = a;
}

// Deformable attention core: block=(32,8) per (q, b)
__global__ __launch_bounds__(256) void deform_attn_kernel(
    const float* __restrict__ value, const float* __restrict__ off,
    const float* __restrict__ aw, const float* __restrict__ ref,
    float* __restrict__ out) {
  const int Wl_[4] = {64, 32, 16, 8};
  const int st_[4] = {0, 4096, 5120, 5376};
  int qi = blockIdx.x, b = blockIdx.y;
  int dh = threadIdx.x, h = threadIdx.y;
  size_t tok = (size_t)b * LQ + qi;
  const float* offp = off + tok * CDIM + h * 32;
  const float* awp = aw + tok * 128 + h * 16;
  float logit[16];
  float mx = -1e30f;
#pragma unroll
  for (int i = 0; i < 16; ++i) { logit[i] = awp[i]; mx = fmaxf(mx, logit[i]); }
  float ssum = 0.f;
#pragma unroll
  for (int i = 0; i < 16; ++i) { logit[i] = expf(logit[i] - mx); ssum += logit[i]; }
  float inv = 1.0f / ssum;
  float rx = ref[qi * 2], ry = ref[qi * 2 + 1];
  float acc = 0.f;
#pragma unroll
  for (int l = 0; l < 4; ++l) {
    int Wl = Wl_[l], Hl = Wl_[l];
    const float* vbase = value + ((size_t)b * LQ + st_[l]) * CDIM + h * 32 + dh;
#pragma unroll
    for (int p = 0; p < 4; ++p) {
      float ox = offp[(l * 4 + p) * 2];
      float oy = offp[(l * 4 + p) * 2 + 1];
      float px = (rx + ox / (float)Wl) * (float)Wl - 0.5f;
      float py = (ry + oy / (float)Hl) * (float)Hl - 0.5f;
      float wgt = logit[l * 4 + p] * inv;
      float fpx = floorf(px), fpy = floorf(py);
      int x0 = (int)fpx, y0 = (int)fpy;
      float fx = px - fpx, fy = py - fpy;
#pragma unroll
      for (int dy = 0; dy < 2; ++dy) {
#pragma unroll
        for (int dx = 0; dx < 2; ++dx) {
          int xi = x0 + dx, yi = y0 + dy;
          if (xi >= 0 && xi < Wl && yi >= 0 && yi < Hl) {
            float wc = (dx ? fx : 1.f - fx) * (dy ? fy : 1.f - fy);
            acc += wgt * wc * vbase[(size_t)(yi * Wl + xi) * CDIM];
          }
        }
      }
    }
  }
  out[tok * CDIM + h * 32 + dh] = acc;
}

// x = LayerNorm(x + r); one wave per token
__global__ __launch_bounds__(256) void add_ln_kernel(float* __restrict__ x,
                                                     const float* __restrict__ r,
                                                     const float* __restrict__ w,
                                                     const float* __restrict__ b) {
  int wid = threadIdx.x >> 6, lane = threadIdx.x & 63;
  size_t tok = (size_t)blockIdx.x * 4 + wid;
  size_t base = tok * CDIM + lane * 4;
  float4 xv = *(const float4*)&x[base];
  float4 rv = *(const float4*)&r[base];
  float v[4] = {xv.x + rv.x, xv.y + rv.y, xv.z + rv.z, xv.w + rv.w};
  float s = v[0] + v[1] + v[2] + v[3];
  float ss = v[0] * v[0] + v[1] * v[1] + v[2] * v[2] + v[3] * v[3];
#pragma unroll
  for (int o = 1; o < 64; o <<= 1) { s += __shfl_xor(s, o); ss += __shfl_xor(ss, o); }
  float mu = s * (1.0f / 256.0f);
  float var = ss * (1.0f / 256.0f) - mu * mu;
  float rsig = rsqrtf(var + 1e-5f);
  int c = lane * 4;
  float4 wv = *(const float4*)&w[c];
  float4 bv = *(const float4*)&b[c];
  float4 o4;
  o4.x = (v[0] - mu) * rsig * wv.x + bv.x;
  o4.y = (v[1] - mu) * rsig * wv.y + bv.y;
  o4.z = (v[2] - mu) * rsig * wv.z + bv.z;
  o4.w = (v[3] - mu) * rsig * wv.w + bv.w;
  *(float4*)&x[base] = o4;
}

// tokens (first 4096) -> image [B, C, 64, 64]
__global__ void tok2img_kernel(const float* __restrict__ x, float* __restrict__ img) {
  int i = blockIdx.x * 256 + threadIdx.x;
  if (i >= BATCH * 4096 * CDIM) return;
  int b = i / (4096 * CDIM);
  int rr = i % (4096 * CDIM);
  int hw = rr >> 8, c = rr & 255;
  img[((size_t)b * CDIM + c) * 4096 + hw] = x[((size_t)b * LQ + hw) * CDIM + c];
}

// conv3x3 256->64 + ReLU. grid (16 tiles, 4 ocb, B), block 256
__global__ __launch_bounds__(256) void conv1_kernel(const float* __restrict__ img,
                                                    const float* __restrict__ w,
                                                    const float* __restrict__ bias,
                                                    float* __restrict__ out) {
  int tile_id = blockIdx.x;
  int ty0 = (tile_id >> 2) * 16, tx0 = (tile_id & 3) * 16;
  int ocb = blockIdx.y * 16;
  int b = blockIdx.z;
  int sx = threadIdx.x & 15, sy = threadIdx.x >> 4;
  __shared__ float tile[18][18];
  float acc[16] = {};
  for (int ic = 0; ic < 256; ++ic) {
    const float* ip = img + ((size_t)b * CDIM + ic) * 4096;
    for (int i = threadIdx.x; i < 324; i += 256) {
      int rr = i / 18, cc = i % 18;
      int gy = ty0 + rr - 1, gx = tx0 + cc - 1;
      tile[rr][cc] = (gy >= 0 && gy < 64 && gx >= 0 && gx < 64) ? ip[gy * 64 + gx] : 0.f;
    }
    __syncthreads();
    float t9[9];
#pragma unroll
    for (int ky = 0; ky < 3; ++ky)
#pragma unroll
      for (int kx = 0; kx < 3; ++kx) t9[ky * 3 + kx] = tile[sy + ky][sx + kx];
    const float* wp = w + ((size_t)ocb * 256 + ic) * 9;
#pragma unroll
    for (int oc = 0; oc < 16; ++oc)
#pragma unroll
      for (int k = 0; k < 9; ++k) acc[oc] = fmaf(wp[oc * 2304 + k], t9[k], acc[oc]);
    __syncthreads();
  }
#pragma unroll
  for (int oc = 0; oc < 16; ++oc)
    out[((size_t)b * 64 + ocb + oc) * 4096 + (ty0 + sy) * 64 + tx0 + sx] =
        fmaxf(acc[oc] + bias[ocb + oc], 0.f);
}

// conv3x3 64->2. grid (16, 1, B), block 256
__global__ __launch_bounds__(256) void conv2_kernel(const float* __restrict__ in,
                                                    const float* __restrict__ w,
                                                    const float* __restrict__ bias,
                                                    float* __restrict__ out) {
  int tile_id = blockIdx.x;
  int ty0 = (tile_id >> 2) * 16, tx0 = (tile_id & 3) * 16;
  int b = blockIdx.z;
  int sx = threadIdx.x & 15, sy = threadIdx.x >> 4;
  __shared__ float tile[18][18];
  float acc[2] = {};
  for (int ic = 0; ic < 64; ++ic) {
    const float* ip = in + ((size_t)b * 64 + ic) * 4096;
    for (int i = threadIdx.x; i < 324; i += 256) {
      int rr = i / 18, cc = i % 18;
      int gy = ty0 + rr - 1, gx = tx0 + cc - 1;
      tile[rr][cc] = (gy >= 0 && gy < 64 && gx >= 0 && gx < 64) ? ip[gy * 64 + gx] : 0.f;
    }
    __syncthreads();
    float t9[9];
#pragma unroll
    for (int ky = 0; ky < 3; ++ky)
#pragma unroll
      for (int kx = 0; kx < 3; ++kx) t9[ky * 3 + kx] = tile[sy + ky][sx + kx];
    const float* wp = w + (size_t)ic * 9;
#pragma unroll
    for (int oc = 0; oc < 2; ++oc)
#pragma unroll
      for (int k = 0; k < 9; ++k) acc[oc] = fmaf(wp[oc * 576 + k], t9[k], acc[oc]);
    __syncthreads();
  }
#pragma unroll
  for (int oc = 0; oc < 2; ++oc)
    out[((size_t)b * 2 + oc) * 4096 + (ty0 + sy) * 64 + tx0 + sx] = acc[oc] + bias[oc];
}

// 4x bilinear upsample 64->256, half-pixel, edge clamp
__global__ void upsample_kernel(const float* __restrict__ in, float* __restrict__ out) {
  int idx = blockIdx.x * 256 + threadIdx.x;
  if (idx >= BATCH * 2 * 256 * 256) return;
  int X = idx & 255, Y = (idx >> 8) & 255, p = idx >> 16;
  float tx = ((float)X + 0.5f) * 0.25f - 0.5f;
  float ty = ((float)Y + 0.5f) * 0.25f - 0.5f;
  float fxf = floorf(tx), fyf = floorf(ty);
  int x0 = (int)fxf, y0 = (int)fyf;
  float fx = tx - fxf, fy = ty - fyf;
  int x0c = min(max(x0, 0), 63), x1c = min(max(x0 + 1, 0), 63);
  int y0c = min(max(y0, 0), 63), y1c = min(max(y0 + 1, 0), 63);
  const float* ip = in + (size_t)p * 4096;
  float v = (1.f - fy) * ((1.f - fx) * ip[y0c * 64 + x0c] + fx * ip[y0c * 64 + x1c]) +
            fy * ((1.f - fx) * ip[y1c * 64 + x0c] + fx * ip[y1c * 64 + x1c]);
  out[idx] = v;
}

// ---------------------------------------------------------------------------
extern "C" void kernel_launch(void* const* d_in, const int* in_sizes, int n_in,
                              void* d_out, int out_size, void* d_ws, size_t ws_size,
                              hipStream_t stream) {
  const float* f[4] = {(const float*)d_in[0], (const float*)d_in[1],
                       (const float*)d_in[2], (const float*)d_in[3]};
  const float* proj_w = (const float*)d_in[4];
  const float* proj_b = (const float*)d_in[5];
  const float* gn_w = (const float*)d_in[6];
  const float* gn_b = (const float*)d_in[7];
  const float* level_embed = (const float*)d_in[8];
  const float* so_w = (const float*)d_in[9];
  const float* so_b = (const float*)d_in[10];
  const float* aw_w = (const float*)d_in[11];
  const float* aw_b = (const float*)d_in[12];
  const float* vp_w = (const float*)d_in[13];
  const float* vp_b = (const float*)d_in[14];
  const float* op_w = (const float*)d_in[15];
  const float* op_b = (const float*)d_in[16];
  const float* n1_w = (const float*)d_in[17];
  const float* n1_b = (const float*)d_in[18];
  const float* l1_w = (const float*)d_in[19];
  const float* l1_b = (const float*)d_in[20];
  const float* l2_w = (const float*)d_in[21];
  const float* l2_b = (const float*)d_in[22];
  const float* n2_w = (const float*)d_in[23];
  const float* n2_b = (const float*)d_in[24];
  const float* c1_w = (const float*)d_in[25];
  const float* c1_b = (const float*)d_in[26];
  const float* c2_w = (const float*)d_in[27];
  const float* c2_b = (const float*)d_in[28];
  (void)in_sizes; (void)n_in; (void)out_size; (void)ws_size;

  float* ws = (float*)d_ws;
  const size_t TOK = (size_t)BATCH * LQ * CDIM;  // 2785280
  size_t o = 0;
  float* x = ws + o;    o += TOK;
  float* q = ws + o;    o += TOK;
  float* val = ws + o;  o += TOK;
  float* offb = ws + o; o += TOK;
  float* attn = ws + o; o += TOK;
  float* tmp = ws + o;  o += TOK;
  float* awb = ws + o;  o += (size_t)BATCH * LQ * 128;
  float* pos = ws + o;  o += (size_t)LQ * CDIM;
  float* refb = ws + o; o += 10944;
  float2* stats = (float2*)(ws + o); o += 512;
  float* ff1 = ws + o;  o += (size_t)BATCH * LQ * FFDIM;
  float* img = ff1;                 // head reuses ff1 region
  float* c1o = ff1 + (size_t)BATCH * CDIM * 4096;
  float* c2o = c1o + (size_t)BATCH * 64 * 4096;

  const int HWs[4] = {4096, 1024, 256, 64};
  const int STs[4] = {0, 4096, 5120, 5376};

  // 1) input proj (1x1 conv as GEMM, A = f[l][b] is [K=256, M=HW]) -> x tokens
  for (int l = 0; l < 4; ++l) {
    gemm(f[l], proj_w + (size_t)l * CDIM * CDIM, proj_b + l * CDIM,
         x + (size_t)STs[l] * CDIM, HWs[l], CDIM, CDIM, /*atrans=*/true,
         /*relu=*/false, /*bz=*/BATCH, (long)CDIM * HWs[l], (long)LQ * CDIM, stream);
  }
  // 2) GroupNorm
  gn_stats_kernel<<<dim3(32, 4, BATCH), 256, 0, stream>>>(x, stats);
  {
    int n = BATCH * LQ * CDIM;
    gn_apply_kernel<<<(n + 255) / 256, 256, 0, stream>>>(x, stats, gn_w, gn_b);
  }
  // 3) pos embed + reference points
  pos_embed_kernel<<<(LQ * CDIM + 255) / 256, 256, 0, stream>>>(level_embed, pos);
  ref_kernel<<<(LQ + 255) / 256, 256, 0, stream>>>(refb);

  const int M = BATCH * LQ;  // 10880
  for (int i = 0; i < 6; ++i) {
    const float* sw = so_w + (size_t)i * CDIM * CDIM;
    const float* sb = so_b + (size_t)i * CDIM;
    const float* aww = aw_w + (size_t)i * 128 * CDIM;
    const float* awbias = aw_b + (size_t)i * 128;
    const float* vw = vp_w + (size_t)i * CDIM * CDIM;
    const float* vb = vp_b + (size_t)i * CDIM;
    const float* ow = op_w + (size_t)i * CDIM * CDIM;
    const float* ob = op_b + (size_t)i * CDIM;
    const float* w1 = l1_w + (size_t)i * FFDIM * CDIM;
    const float* b1 = l1_b + (size_t)i * FFDIM;
    const float* w2 = l2_w + (size_t)i * CDIM * FFDIM;
    const float* b2 = l2_b + (size_t)i * CDIM;

    add_pos_kernel<<<(M * 64 + 255) / 256, 256, 0, stream>>>(x, pos, q);
    gemm(x, vw, vb, val, M, CDIM, CDIM, false, false, 1, 0, 0, stream);
    gemm(q, sw, sb, offb, M, CDIM, CDIM, false, false, 1, 0, 0, stream);
    gemm(q, aww, awbias, awb, M, 128, CDIM, false, false, 1, 0, 0, stream);
    deform_attn_kernel<<<dim3(LQ, BATCH), dim3(32, 8), 0, stream>>>(val, offb, awb,
                                                                    refb, attn);
    gemm(attn, ow, ob, tmp, M, CDIM, CDIM, false, false, 1, 0, 0, stream);
    add_ln_kernel<<<M / 4, 256, 0, stream>>>(x, tmp, n1_w + (size_t)i * CDIM,
                                             n1_b + (size_t)i * CDIM);
    gemm(x, w1, b1, ff1, M, FFDIM, CDIM, false, true, 1, 0, 0, stream);
    gemm(ff1, w2, b2, tmp, M, CDIM, FFDIM, false, false, 1, 0, 0, stream);
    add_ln_kernel<<<M / 4, 256, 0, stream>>>(x, tmp, n2_w + (size_t)i * CDIM,
                                             n2_b + (size_t)i * CDIM);
  }

  // head
  {
    int n = BATCH * 4096 * CDIM;
    tok2img_kernel<<<(n + 255) / 256, 256, 0, stream>>>(x, img);
  }
  conv1_kernel<<<dim3(16, 4, BATCH), 256, 0, stream>>>(img, c1_w, c1_b, c1o);
  conv2_kernel<<<dim3(16, 1, BATCH), 256, 0, stream>>>(c1o, c2_w, c2_b, c2o);
  {
    int n = BATCH * 2 * 256 * 256;
    upsample_kernel<<<(n + 255) / 256, 256, 0, stream>>>(c2o, (float*)d_out);
  }
}

// Round 3
// 3268.491 us; speedup vs baseline: 1.0001x; 1.0001x over previous
//
#include <hip/hip_runtime.h>
#include <hip/hip_bf16.h>
#include <math.h>

#define LQ 5440
#define CDIM 256
#define BATCH 2
#define FFDIM 1024

// ---------------------------------------------------------------------------
// Generic tiled fp32 GEMM: C[M,N] = act(A @ W^T + bias)
// A: [M,K] row-major (ATRANS=false) or [K,M] row-major (ATRANS=true)
// W: [N,K] row-major. M,N multiples of 64; K multiple of 16.
// ---------------------------------------------------------------------------
template <bool ATRANS, bool RELU>
__global__ __launch_bounds__(256) void gemm_kernel(
    const float* __restrict__ A, const float* __restrict__ W,
    const float* __restrict__ bias, float* __restrict__ C,
    int M, int N, int K, long bsA, long bsC) {
  __shared__ __align__(16) float As[16][72];
  __shared__ __align__(16) float Ws[16][72];
  const int tid = threadIdx.x;
  const int bm = blockIdx.y * 64, bn = blockIdx.x * 64;
  A += (size_t)blockIdx.z * bsA;
  C += (size_t)blockIdx.z * bsC;
  const int tx = tid & 15, ty = tid >> 4;
  float acc[4][4] = {};
  for (int k0 = 0; k0 < K; k0 += 16) {
#pragma unroll
    for (int i = 0; i < 4; ++i) {
      int idx = tid + i * 256;
      if (ATRANS) {
        int k = idx >> 6, m = idx & 63;
        As[k][m] = A[(size_t)(k0 + k) * M + bm + m];
      } else {
        int m = idx >> 4, k = idx & 15;
        As[k][m] = A[(size_t)(bm + m) * K + k0 + k];
      }
      int n = idx >> 4, k2 = idx & 15;
      Ws[k2][n] = W[(size_t)(bn + n) * K + k0 + k2];
    }
    __syncthreads();
#pragma unroll
    for (int k = 0; k < 16; ++k) {
      const float4 av = *(const float4*)&As[k][ty * 4];
      const float4 bv = *(const float4*)&Ws[k][tx * 4];
      const float a4[4] = {av.x, av.y, av.z, av.w};
      const float b4[4] = {bv.x, bv.y, bv.z, bv.w};
#pragma unroll
      for (int i = 0; i < 4; ++i)
#pragma unroll
        for (int j = 0; j < 4; ++j) acc[i][j] = fmaf(a4[i], b4[j], acc[i][j]);
    }
    __syncthreads();
  }
  const float4 bv4 = *(const float4*)&bias[bn + tx * 4];
  const float bb[4] = {bv4.x, bv4.y, bv4.z, bv4.w};
#pragma unroll
  for (int i = 0; i < 4; ++i) {
    float4 o;
    float* op = (float*)&o;
#pragma unroll
    for (int j = 0; j < 4; ++j) {
      float v = acc[i][j] + bb[j];
      if (RELU) v = fmaxf(v, 0.f);
      op[j] = v;
    }
    *(float4*)&C[(size_t)(bm + ty * 4 + i) * N + bn + tx * 4] = o;
  }
}

static inline void gemm(const float* A, const float* W, const float* bias, float* C,
                        int M, int N, int K, bool atrans, bool relu, int bz,
                        long bsA, long bsC, hipStream_t s) {
  dim3 grid(N / 64, M / 64, bz), blk(256);
  if (atrans)
    gemm_kernel<true, false><<<grid, blk, 0, s>>>(A, W, bias, C, M, N, K, bsA, bsC);
  else if (relu)
    gemm_kernel<false, true><<<grid, blk, 0, s>>>(A, W, bias, C, M, N, K, bsA, bsC);
  else
    gemm_kernel<false, false><<<grid, blk, 0, s>>>(A, W, bias, C, M, N, K, bsA, bsC);
}

// ---------------------------------------------------------------------------
__device__ __forceinline__ void get_level(int t, int& l, int& hw, int& Hl, int& Wl) {
  if (t < 4096)      { l = 0; hw = t;        Hl = 64; Wl = 64; }
  else if (t < 5120) { l = 1; hw = t - 4096; Hl = 32; Wl = 32; }
  else if (t < 5376) { l = 2; hw = t - 5120; Hl = 16; Wl = 16; }
  else               { l = 3; hw = t - 5376; Hl = 8;  Wl = 8;  }
}

// GroupNorm stats: one block per (group, level, batch)
__global__ __launch_bounds__(256) void gn_stats_kernel(const float* __restrict__ x,
                                                       float2* __restrict__ stats) {
  const int HWs[4] = {4096, 1024, 256, 64};
  const int STs[4] = {0, 4096, 5120, 5376};
  int g = blockIdx.x, l = blockIdx.y, b = blockIdx.z;
  int HW = HWs[l];
  size_t base = ((size_t)b * LQ + STs[l]) * CDIM + g * 8;
  float s = 0.f, ss = 0.f;
  for (int i = threadIdx.x; i < HW * 8; i += 256) {
    int hw = i >> 3, ci = i & 7;
    float v = x[base + (size_t)hw * CDIM + ci];
    s += v; ss += v * v;
  }
#pragma unroll
  for (int o = 32; o; o >>= 1) { s += __shfl_down(s, o); ss += __shfl_down(ss, o); }
  __shared__ float rs[4], rss[4];
  int lane = threadIdx.x & 63, wid = threadIdx.x >> 6;
  if (lane == 0) { rs[wid] = s; rss[wid] = ss; }
  __syncthreads();
  if (threadIdx.x == 0) {
    s = rs[0] + rs[1] + rs[2] + rs[3];
    ss = rss[0] + rss[1] + rss[2] + rss[3];
    float n = (float)(HW * 8);
    float mu = s / n;
    float var = ss / n - mu * mu;
    stats[(b * 4 + l) * 32 + g] = make_float2(mu, rsqrtf(var + 1e-5f));
  }
}

__global__ void gn_apply_kernel(float* __restrict__ x, const float2* __restrict__ stats,
                                const float* __restrict__ gw, const float* __restrict__ gb) {
  int idx = blockIdx.x * 256 + threadIdx.x;
  if (idx >= BATCH * LQ * CDIM) return;
  int c = idx & 255;
  int tok = idx >> 8;
  int b = tok / LQ, t = tok % LQ;
  int l, hw, Hl, Wl;
  get_level(t, l, hw, Hl, Wl);
  float2 st = stats[(b * 4 + l) * 32 + (c >> 3)];
  x[idx] = (x[idx] - st.x) * st.y * gw[l * CDIM + c] + gb[l * CDIM + c];
}

// Sine positional embedding + level embed: pos[t, c]
__global__ void pos_embed_kernel(const float* __restrict__ level_embed,
                                 float* __restrict__ pos) {
  int idx = blockIdx.x * 256 + threadIdx.x;
  if (idx >= LQ * CDIM) return;
  int t = idx >> 8, c = idx & 255;
  int l, hw, Hl, Wl;
  get_level(t, l, hw, Hl, Wl);
  int y = hw / Wl, xx = hw % Wl;
  const float twopi = 6.28318530717958647692f;
  float v; int cc;
  if (c < 128) { v = (float)(y + 1) * twopi / ((float)Hl + 1e-6f); cc = c; }
  else         { v = (float)(xx + 1) * twopi / ((float)Wl + 1e-6f); cc = c - 128; }
  int k = cc >> 1;
  float dim_t = expf((float)k * (logf(10000.0f) / 64.0f));
  float p = v / dim_t;
  float e = (cc & 1) ? cosf(p) : sinf(p);
  pos[idx] = e + level_embed[l * CDIM + c];
}

__global__ void ref_kernel(float* __restrict__ ref) {
  int t = blockIdx.x * 256 + threadIdx.x;
  if (t >= LQ) return;
  int l, hw, Hl, Wl;
  get_level(t, l, hw, Hl, Wl);
  int y = hw / Wl, xx = hw % Wl;
  ref[t * 2]     = ((float)xx + 0.5f) / (float)Wl;
  ref[t * 2 + 1] = ((float)y + 0.5f) / (float)Hl;
}

__global__ void add_pos_kernel(const float* __restrict__ x, const float* __restrict__ pos,
                               float* __restrict__ q) {
  int i = blockIdx.x * 256 + threadIdx.x;  // float4 index
  if (i >= BATCH * LQ * 64) return;
  int r = i % (LQ * 64);
  float4 a = ((const float4*)x)[i];
  float4 p = ((const float4*)pos)[r];
  a.x += p.x; a.y += p.y; a.z += p.z; a.w += p.w;
  ((float4*)q)[i] = a;
}

// Deformable attention core: block=(32,8) per (q, b)
__global__ __launch_bounds__(256) void deform_attn_kernel(
    const float* __restrict__ value, const float* __restrict__ off,
    const float* __restrict__ aw, const float* __restrict__ ref,
    float* __restrict__ out) {
  const int Wl_[4] = {64, 32, 16, 8};
  const int st_[4] = {0, 4096, 5120, 5376};
  int qi = blockIdx.x, b = blockIdx.y;
  int dh = threadIdx.x, h = threadIdx.y;
  size_t tok = (size_t)b * LQ + qi;
  const float* offp = off + tok * CDIM + h * 32;
  const float* awp = aw + tok * 128 + h * 16;
  float logit[16];
  float mx = -1e30f;
#pragma unroll
  for (int i = 0; i < 16; ++i) { logit[i] = awp[i]; mx = fmaxf(mx, logit[i]); }
  float ssum = 0.f;
#pragma unroll
  for (int i = 0; i < 16; ++i) { logit[i] = expf(logit[i] - mx); ssum += logit[i]; }
  float inv = 1.0f / ssum;
  float rx = ref[qi * 2], ry = ref[qi * 2 + 1];
  float acc = 0.f;
#pragma unroll
  for (int l = 0; l < 4; ++l) {
    int Wl = Wl_[l], Hl = Wl_[l];
    const float* vbase = value + ((size_t)b * LQ + st_[l]) * CDIM + h * 32 + dh;
#pragma unroll
    for (int p = 0; p < 4; ++p) {
      float ox = offp[(l * 4 + p) * 2];
      float oy = offp[(l * 4 + p) * 2 + 1];
      float px = (rx + ox / (float)Wl) * (float)Wl - 0.5f;
      float py = (ry + oy / (float)Hl) * (float)Hl - 0.5f;
      float wgt = logit[l * 4 + p] * inv;
      float fpx = floorf(px), fpy = floorf(py);
      int x0 = (int)fpx, y0 = (int)fpy;
      float fx = px - fpx, fy = py - fpy;
#pragma unroll
      for (int dy = 0; dy < 2; ++dy) {
#pragma unroll
        for (int dx = 0; dx < 2; ++dx) {
          int xi = x0 + dx, yi = y0 + dy;
          if (xi >= 0 && xi < Wl && yi >= 0 && yi < Hl) {
            float wc = (dx ? fx : 1.f - fx) * (dy ? fy : 1.f - fy);
            acc += wgt * wc * vbase[(size_t)(yi * Wl + xi) * CDIM];
          }
        }
      }
    }
  }
  out[tok * CDIM + h * 32 + dh] = acc;
}

// x = LayerNorm(x + r); one wave per token
__global__ __launch_bounds__(256) void add_ln_kernel(float* __restrict__ x,
                                                     const float* __restrict__ r,
                                                     const float* __restrict__ w,
                                                     const float* __restrict__ b) {
  int wid = threadIdx.x >> 6, lane = threadIdx.x & 63;
  size_t tok = (size_t)blockIdx.x * 4 + wid;
  size_t base = tok * CDIM + lane * 4;
  float4 xv = *(const float4*)&x[base];
  float4 rv = *(const float4*)&r[base];
  float v[4] = {xv.x + rv.x, xv.y + rv.y, xv.z + rv.z, xv.w + rv.w};
  float s = v[0] + v[1] + v[2] + v[3];
  float ss = v[0] * v[0] + v[1] * v[1] + v[2] * v[2] + v[3] * v[3];
#pragma unroll
  for (int o = 1; o < 64; o <<= 1) { s += __shfl_xor(s, o); ss += __shfl_xor(ss, o); }
  float mu = s * (1.0f / 256.0f);
  float var = ss * (1.0f / 256.0f) - mu * mu;
  float rsig = rsqrtf(var + 1e-5f);
  int c = lane * 4;
  float4 wv = *(const float4*)&w[c];
  float4 bv = *(const float4*)&b[c];
  float4 o4;
  o4.x = (v[0] - mu) * rsig * wv.x + bv.x;
  o4.y = (v[1] - mu) * rsig * wv.y + bv.y;
  o4.z = (v[2] - mu) * rsig * wv.z + bv.z;
  o4.w = (v[3] - mu) * rsig * wv.w + bv.w;
  *(float4*)&x[base] = o4;
}

// tokens (first 4096) -> image [B, C, 64, 64]
__global__ void tok2img_kernel(const float* __restrict__ x, float* __restrict__ img) {
  int i = blockIdx.x * 256 + threadIdx.x;
  if (i >= BATCH * 4096 * CDIM) return;
  int b = i / (4096 * CDIM);
  int rr = i % (4096 * CDIM);
  int hw = rr >> 8, c = rr & 255;
  img[((size_t)b * CDIM + c) * 4096 + hw] = x[((size_t)b * LQ + hw) * CDIM + c];
}

// conv3x3 256->64 + ReLU. grid (16 tiles, 4 ocb, B), block 256
__global__ __launch_bounds__(256) void conv1_kernel(const float* __restrict__ img,
                                                    const float* __restrict__ w,
                                                    const float* __restrict__ bias,
                                                    float* __restrict__ out) {
  int tile_id = blockIdx.x;
  int ty0 = (tile_id >> 2) * 16, tx0 = (tile_id & 3) * 16;
  int ocb = blockIdx.y * 16;
  int b = blockIdx.z;
  int sx = threadIdx.x & 15, sy = threadIdx.x >> 4;
  __shared__ float tile[18][18];
  float acc[16] = {};
  for (int ic = 0; ic < 256; ++ic) {
    const float* ip = img + ((size_t)b * CDIM + ic) * 4096;
    for (int i = threadIdx.x; i < 324; i += 256) {
      int rr = i / 18, cc = i % 18;
      int gy = ty0 + rr - 1, gx = tx0 + cc - 1;
      tile[rr][cc] = (gy >= 0 && gy < 64 && gx >= 0 && gx < 64) ? ip[gy * 64 + gx] : 0.f;
    }
    __syncthreads();
    float t9[9];
#pragma unroll
    for (int ky = 0; ky < 3; ++ky)
#pragma unroll
      for (int kx = 0; kx < 3; ++kx) t9[ky * 3 + kx] = tile[sy + ky][sx + kx];
    const float* wp = w + ((size_t)ocb * 256 + ic) * 9;
#pragma unroll
    for (int oc = 0; oc < 16; ++oc)
#pragma unroll
      for (int k = 0; k < 9; ++k) acc[oc] = fmaf(wp[oc * 2304 + k], t9[k], acc[oc]);
    __syncthreads();
  }
#pragma unroll
  for (int oc = 0; oc < 16; ++oc)
    out[((size_t)b * 64 + ocb + oc) * 4096 + (ty0 + sy) * 64 + tx0 + sx] =
        fmaxf(acc[oc] + bias[ocb + oc], 0.f);
}

// conv3x3 64->2. grid (16, 1, B), block 256
__global__ __launch_bounds__(256) void conv2_kernel(const float* __restrict__ in,
                                                    const float* __restrict__ w,
                                                    const float* __restrict__ bias,
                                                    float* __restrict__ out) {
  int tile_id = blockIdx.x;
  int ty0 = (tile_id >> 2) * 16, tx0 = (tile_id & 3) * 16;
  int b = blockIdx.z;
  int sx = threadIdx.x & 15, sy = threadIdx.x >> 4;
  __shared__ float tile[18][18];
  float acc[2] = {};
  for (int ic = 0; ic < 64; ++ic) {
    const float* ip = in + ((size_t)b * 64 + ic) * 4096;
    for (int i = threadIdx.x; i < 324; i += 256) {
      int rr = i / 18, cc = i % 18;
      int gy = ty0 + rr - 1, gx = tx0 + cc - 1;
      tile[rr][cc] = (gy >= 0 && gy < 64 && gx >= 0 && gx < 64) ? ip[gy * 64 + gx] : 0.f;
    }
    __syncthreads();
    float t9[9];
#pragma unroll
    for (int ky = 0; ky < 3; ++ky)
#pragma unroll
      for (int kx = 0; kx < 3; ++kx) t9[ky * 3 + kx] = tile[sy + ky][sx + kx];
    const float* wp = w + (size_t)ic * 9;
#pragma unroll
    for (int oc = 0; oc < 2; ++oc)
#pragma unroll
      for (int k = 0; k < 9; ++k) acc[oc] = fmaf(wp[oc * 576 + k], t9[k], acc[oc]);
    __syncthreads();
  }
#pragma unroll
  for (int oc = 0; oc < 2; ++oc)
    out[((size_t)b * 2 + oc) * 4096 + (ty0 + sy) * 64 + tx0 + sx] = acc[oc] + bias[oc];
}

// 4x bilinear upsample 64->256, half-pixel, edge clamp
__global__ void upsample_kernel(const float* __restrict__ in, float* __restrict__ out) {
  int idx = blockIdx.x * 256 + threadIdx.x;
  if (idx >= BATCH * 2 * 256 * 256) return;
  int X = idx & 255, Y = (idx >> 8) & 255, p = idx >> 16;
  float tx = ((float)X + 0.5f) * 0.25f - 0.5f;
  float ty = ((float)Y + 0.5f) * 0.25f - 0.5f;
  float fxf = floorf(tx), fyf = floorf(ty);
  int x0 = (int)fxf, y0 = (int)fyf;
  float fx = tx - fxf, fy = ty - fyf;
  int x0c = min(max(x0, 0), 63), x1c = min(max(x0 + 1, 0), 63);
  int y0c = min(max(y0, 0), 63), y1c = min(max(y0 + 1, 0), 63);
  const float* ip = in + (size_t)p * 4096;
  float v = (1.f - fy) * ((1.f - fx) * ip[y0c * 64 + x0c] + fx * ip[y0c * 64 + x1c]) +
            fy * ((1.f - fx) * ip[y1c * 64 + x0c] + fx * ip[y1c * 64 + x1c]);
  out[idx] = v;
}

// ---------------------------------------------------------------------------
extern "C" void kernel_launch(void* const* d_in, const int* in_sizes, int n_in,
                              void* d_out, int out_size, void* d_ws, size_t ws_size,
                              hipStream_t stream) {
  const float* f[4] = {(const float*)d_in[0], (const float*)d_in[1],
                       (const float*)d_in[2], (const float*)d_in[3]};
  const float* proj_w = (const float*)d_in[4];
  const float* proj_b = (const float*)d_in[5];
  const float* gn_w = (const float*)d_in[6];
  const float* gn_b = (const float*)d_in[7];
  const float* level_embed = (const float*)d_in[8];
  const float* so_w = (const float*)d_in[9];
  const float* so_b = (const float*)d_in[10];
  const float* aw_w = (const float*)d_in[11];
  const float* aw_b = (const float*)d_in[12];
  const float* vp_w = (const float*)d_in[13];
  const float* vp_b = (const float*)d_in[14];
  const float* op_w = (const float*)d_in[15];
  const float* op_b = (const float*)d_in[16];
  const float* n1_w = (const float*)d_in[17];
  const float* n1_b = (const float*)d_in[18];
  const float* l1_w = (const float*)d_in[19];
  const float* l1_b = (const float*)d_in[20];
  const float* l2_w = (const float*)d_in[21];
  const float* l2_b = (const float*)d_in[22];
  const float* n2_w = (const float*)d_in[23];
  const float* n2_b = (const float*)d_in[24];
  const float* c1_w = (const float*)d_in[25];
  const float* c1_b = (const float*)d_in[26];
  const float* c2_w = (const float*)d_in[27];
  const float* c2_b = (const float*)d_in[28];
  (void)in_sizes; (void)n_in; (void)out_size; (void)ws_size;

  float* ws = (float*)d_ws;
  const size_t TOK = (size_t)BATCH * LQ * CDIM;  // 2785280
  size_t o = 0;
  float* x = ws + o;    o += TOK;
  float* q = ws + o;    o += TOK;
  float* val = ws + o;  o += TOK;
  float* offb = ws + o; o += TOK;
  float* attn = ws + o; o += TOK;
  float* tmp = ws + o;  o += TOK;
  float* awb = ws + o;  o += (size_t)BATCH * LQ * 128;
  float* pos = ws + o;  o += (size_t)LQ * CDIM;
  float* refb = ws + o; o += 10944;
  float2* stats = (float2*)(ws + o); o += 512;
  float* ff1 = ws + o;  o += (size_t)BATCH * LQ * FFDIM;
  float* img = ff1;                 // head reuses ff1 region
  float* c1o = ff1 + (size_t)BATCH * CDIM * 4096;
  float* c2o = c1o + (size_t)BATCH * 64 * 4096;

  const int HWs[4] = {4096, 1024, 256, 64};
  const int STs[4] = {0, 4096, 5120, 5376};

  // 1) input proj (1x1 conv as GEMM, A = f[l][b] is [K=256, M=HW]) -> x tokens
  for (int l = 0; l < 4; ++l) {
    gemm(f[l], proj_w + (size_t)l * CDIM * CDIM, proj_b + l * CDIM,
         x + (size_t)STs[l] * CDIM, HWs[l], CDIM, CDIM, /*atrans=*/true,
         /*relu=*/false, /*bz=*/BATCH, (long)CDIM * HWs[l], (long)LQ * CDIM, stream);
  }
  // 2) GroupNorm
  gn_stats_kernel<<<dim3(32, 4, BATCH), 256, 0, stream>>>(x, stats);
  {
    int n = BATCH * LQ * CDIM;
    gn_apply_kernel<<<(n + 255) / 256, 256, 0, stream>>>(x, stats, gn_w, gn_b);
  }
  // 3) pos embed + reference points
  pos_embed_kernel<<<(LQ * CDIM + 255) / 256, 256, 0, stream>>>(level_embed, pos);
  ref_kernel<<<(LQ + 255) / 256, 256, 0, stream>>>(refb);

  const int M = BATCH * LQ;  // 10880
  for (int i = 0; i < 6; ++i) {
    const float* sw = so_w + (size_t)i * CDIM * CDIM;
    const float* sb = so_b + (size_t)i * CDIM;
    const float* aww = aw_w + (size_t)i * 128 * CDIM;
    const float* awbias = aw_b + (size_t)i * 128;
    const float* vw = vp_w + (size_t)i * CDIM * CDIM;
    const float* vb = vp_b + (size_t)i * CDIM;
    const float* ow = op_w + (size_t)i * CDIM * CDIM;
    const float* ob = op_b + (size_t)i * CDIM;
    const float* w1 = l1_w + (size_t)i * FFDIM * CDIM;
    const float* b1 = l1_b + (size_t)i * FFDIM;
    const float* w2 = l2_w + (size_t)i * CDIM * FFDIM;
    const float* b2 = l2_b + (size_t)i * CDIM;

    add_pos_kernel<<<(M * 64 + 255) / 256, 256, 0, stream>>>(x, pos, q);
    gemm(x, vw, vb, val, M, CDIM, CDIM, false, false, 1, 0, 0, stream);
    gemm(q, sw, sb, offb, M, CDIM, CDIM, false, false, 1, 0, 0, stream);
    gemm(q, aww, awbias, awb, M, 128, CDIM, false, false, 1, 0, 0, stream);
    deform_attn_kernel<<<dim3(LQ, BATCH), dim3(32, 8), 0, stream>>>(val, offb, awb,
                                                                    refb, attn);
    gemm(attn, ow, ob, tmp, M, CDIM, CDIM, false, false, 1, 0, 0, stream);
    add_ln_kernel<<<M / 4, 256, 0, stream>>>(x, tmp, n1_w + (size_t)i * CDIM,
                                             n1_b + (size_t)i * CDIM);
    gemm(x, w1, b1, ff1, M, FFDIM, CDIM, false, true, 1, 0, 0, stream);
    gemm(ff1, w2, b2, tmp, M, CDIM, FFDIM, false, false, 1, 0, 0, stream);
    add_ln_kernel<<<M / 4, 256, 0, stream>>>(x, tmp, n2_w + (size_t)i * CDIM,
                                             n2_b + (size_t)i * CDIM);
  }

  // head
  {
    int n = BATCH * 4096 * CDIM;
    tok2img_kernel<<<(n + 255) / 256, 256, 0, stream>>>(x, img);
  }
  conv1_kernel<<<dim3(16, 4, BATCH), 256, 0, stream>>>(img, c1_w, c1_b, c1o);
  conv2_kernel<<<dim3(16, 1, BATCH), 256, 0, stream>>>(c1o, c2_w, c2_b, c2o);
  {
    int n = BATCH * 2 * 256 * 256;
    upsample_kernel<<<(n + 255) / 256, 256, 0, stream>>>(c2o, (float*)d_out);
  }
}

// Round 4
// 1661.604 us; speedup vs baseline: 1.9672x; 1.9671x over previous
//
#include <hip/hip_runtime.h>
#include <hip/hip_bf16.h>
#include <math.h>

#define LQ 5440
#define CDIM 256
#define BATCH 2
#define FFDIM 1024

typedef __attribute__((ext_vector_type(8))) short bf16x8;
typedef __attribute__((ext_vector_type(4))) float f32x4;

typedef __attribute__((address_space(1))) void* gas1_t;
typedef __attribute__((address_space(3))) void* las3_t;

__device__ __forceinline__ void async16(const void* g, void* l) {
  __builtin_amdgcn_global_load_lds((gas1_t)g, (las3_t)l, 16, 0, 0);
}

// ---------------------------------------------------------------------------
// bf16 MFMA GEMM: C[M,N] = act(A @ Wt^T + bias), A:[M,K] bf16, Wt:[N,K] bf16.
// M % 128 == 0, N % 128 == 0, K % 32 == 0. 128x128 tile, 4 waves (2x2), each
// wave 64x64 = 4x4 fragments of 16x16x32 MFMA. m97-style 2-barrier loop.
// ---------------------------------------------------------------------------
template <bool RELU, bool OUT_F32, bool OUT_B16>
__global__ __launch_bounds__(256, 2) void gemm_bf16_kernel(
    const __hip_bfloat16* __restrict__ A, const __hip_bfloat16* __restrict__ Wt,
    const float* __restrict__ bias, float* __restrict__ C,
    __hip_bfloat16* __restrict__ Cb, int M, int N, int K) {
  __shared__ __hip_bfloat16 As[128 * 32];
  __shared__ __hip_bfloat16 Bs[128 * 32];
  const int tid = threadIdx.x;
  const int bm = blockIdx.y * 128, bn = blockIdx.x * 128;
  const int lane = tid & 63, wave = tid >> 6;
  const int wr = wave >> 1, wc = wave & 1;
  // staging: thread t -> tile row t>>2 (0..63; +64 second issue), col (t&3)*8
  const int srow = tid >> 2;
  const int scol = (tid & 3) * 8;
  const __hip_bfloat16* ga0 = A + (size_t)(bm + srow) * K + scol;
  const __hip_bfloat16* ga1 = A + (size_t)(bm + 64 + srow) * K + scol;
  const __hip_bfloat16* gb0 = Wt + (size_t)(bn + srow) * K + scol;
  const __hip_bfloat16* gb1 = Wt + (size_t)(bn + 64 + srow) * K + scol;
  __hip_bfloat16* la0 = &As[srow * 32 + scol];
  __hip_bfloat16* la1 = &As[(64 + srow) * 32 + scol];
  __hip_bfloat16* lb0 = &Bs[srow * 32 + scol];
  __hip_bfloat16* lb1 = &Bs[(64 + srow) * 32 + scol];

  f32x4 acc[4][4] = {};
  const int fr = lane & 15;          // fragment row within 16
  const int ksub = (lane >> 4) * 8;  // k sub-offset (bf16 elems)

  for (int k0 = 0; k0 < K; k0 += 32) {
    async16(ga0 + k0, la0);
    async16(ga1 + k0, la1);
    async16(gb0 + k0, lb0);
    async16(gb1 + k0, lb1);
    __syncthreads();
    bf16x8 af[4], bfv[4];
#pragma unroll
    for (int mi = 0; mi < 4; ++mi)
      af[mi] = *(const bf16x8*)&As[(wr * 64 + mi * 16 + fr) * 32 + ksub];
#pragma unroll
    for (int nj = 0; nj < 4; ++nj)
      bfv[nj] = *(const bf16x8*)&Bs[(wc * 64 + nj * 16 + fr) * 32 + ksub];
#pragma unroll
    for (int mi = 0; mi < 4; ++mi)
#pragma unroll
      for (int nj = 0; nj < 4; ++nj)
        acc[mi][nj] = __builtin_amdgcn_mfma_f32_16x16x32_bf16(af[mi], bfv[nj],
                                                              acc[mi][nj], 0, 0, 0);
    __syncthreads();
  }

  const int cc = lane & 15;
  const int rbase = (lane >> 4) * 4;
  float bcol[4];
#pragma unroll
  for (int nj = 0; nj < 4; ++nj) bcol[nj] = bias[bn + wc * 64 + nj * 16 + cc];
#pragma unroll
  for (int mi = 0; mi < 4; ++mi)
#pragma unroll
    for (int nj = 0; nj < 4; ++nj) {
      int col = bn + wc * 64 + nj * 16 + cc;
#pragma unroll
      for (int r = 0; r < 4; ++r) {
        int row = bm + wr * 64 + mi * 16 + rbase + r;
        float v = acc[mi][nj][r] + bcol[nj];
        if (RELU) v = fmaxf(v, 0.f);
        if (OUT_F32) C[(size_t)row * N + col] = v;
        if (OUT_B16) Cb[(size_t)row * N + col] = __float2bfloat16(v);
      }
    }
}

// fp32 -> bf16 bulk convert (n % 4 == 0)
__global__ void f2b4_kernel(const float* __restrict__ in,
                            __hip_bfloat16* __restrict__ out, int n4) {
  int i = blockIdx.x * 256 + threadIdx.x;
  if (i >= n4) return;
  float4 v = ((const float4*)in)[i];
  union { ushort4 u; __hip_bfloat16 h[4]; } p;
  p.h[0] = __float2bfloat16(v.x);
  p.h[1] = __float2bfloat16(v.y);
  p.h[2] = __float2bfloat16(v.z);
  p.h[3] = __float2bfloat16(v.w);
  ((ushort4*)out)[i] = p.u;
}

// ---------------------------------------------------------------------------
// fp32 tiled GEMM (kept for input_proj only): C = A^T-layout @ W^T + bias
// A: [K, M] row-major. M,N multiples of 64 (M>=64), K multiple of 16.
// ---------------------------------------------------------------------------
__global__ __launch_bounds__(256) void gemm_f32_at_kernel(
    const float* __restrict__ A, const float* __restrict__ W,
    const float* __restrict__ bias, float* __restrict__ C,
    int M, int N, int K, long bsA, long bsC) {
  __shared__ __align__(16) float As[16][72];
  __shared__ __align__(16) float Ws[16][72];
  const int tid = threadIdx.x;
  const int bm = blockIdx.y * 64, bn = blockIdx.x * 64;
  A += (size_t)blockIdx.z * bsA;
  C += (size_t)blockIdx.z * bsC;
  const int tx = tid & 15, ty = tid >> 4;
  float acc[4][4] = {};
  for (int k0 = 0; k0 < K; k0 += 16) {
#pragma unroll
    for (int i = 0; i < 4; ++i) {
      int idx = tid + i * 256;
      int k = idx >> 6, m = idx & 63;
      As[k][m] = A[(size_t)(k0 + k) * M + bm + m];
      int n = idx >> 4, k2 = idx & 15;
      Ws[k2][n] = W[(size_t)(bn + n) * K + k0 + k2];
    }
    __syncthreads();
#pragma unroll
    for (int k = 0; k < 16; ++k) {
      const float4 av = *(const float4*)&As[k][ty * 4];
      const float4 bv = *(const float4*)&Ws[k][tx * 4];
      const float a4[4] = {av.x, av.y, av.z, av.w};
      const float b4[4] = {bv.x, bv.y, bv.z, bv.w};
#pragma unroll
      for (int i = 0; i < 4; ++i)
#pragma unroll
        for (int j = 0; j < 4; ++j) acc[i][j] = fmaf(a4[i], b4[j], acc[i][j]);
    }
    __syncthreads();
  }
  const float4 bv4 = *(const float4*)&bias[bn + tx * 4];
  const float bb[4] = {bv4.x, bv4.y, bv4.z, bv4.w};
#pragma unroll
  for (int i = 0; i < 4; ++i) {
    float4 o;
    float* op = (float*)&o;
#pragma unroll
    for (int j = 0; j < 4; ++j) op[j] = acc[i][j] + bb[j];
    *(float4*)&C[(size_t)(bm + ty * 4 + i) * N + bn + tx * 4] = o;
  }
}

// ---------------------------------------------------------------------------
__device__ __forceinline__ void get_level(int t, int& l, int& hw, int& Hl, int& Wl) {
  if (t < 4096)      { l = 0; hw = t;        Hl = 64; Wl = 64; }
  else if (t < 5120) { l = 1; hw = t - 4096; Hl = 32; Wl = 32; }
  else if (t < 5376) { l = 2; hw = t - 5120; Hl = 16; Wl = 16; }
  else               { l = 3; hw = t - 5376; Hl = 8;  Wl = 8;  }
}

__global__ __launch_bounds__(256) void gn_stats_kernel(const float* __restrict__ x,
                                                       float2* __restrict__ stats) {
  const int HWs[4] = {4096, 1024, 256, 64};
  const int STs[4] = {0, 4096, 5120, 5376};
  int g = blockIdx.x, l = blockIdx.y, b = blockIdx.z;
  int HW = HWs[l];
  size_t base = ((size_t)b * LQ + STs[l]) * CDIM + g * 8;
  float s = 0.f, ss = 0.f;
  for (int i = threadIdx.x; i < HW * 8; i += 256) {
    int hw = i >> 3, ci = i & 7;
    float v = x[base + (size_t)hw * CDIM + ci];
    s += v; ss += v * v;
  }
#pragma unroll
  for (int o = 32; o; o >>= 1) { s += __shfl_down(s, o); ss += __shfl_down(ss, o); }
  __shared__ float rs[4], rss[4];
  int lane = threadIdx.x & 63, wid = threadIdx.x >> 6;
  if (lane == 0) { rs[wid] = s; rss[wid] = ss; }
  __syncthreads();
  if (threadIdx.x == 0) {
    s = rs[0] + rs[1] + rs[2] + rs[3];
    ss = rss[0] + rss[1] + rss[2] + rss[3];
    float n = (float)(HW * 8);
    float mu = s / n;
    float var = ss / n - mu * mu;
    stats[(b * 4 + l) * 32 + g] = make_float2(mu, rsqrtf(var + 1e-5f));
  }
}

__global__ void gn_apply_kernel(float* __restrict__ x, __hip_bfloat16* __restrict__ xb,
                                const float2* __restrict__ stats,
                                const float* __restrict__ gw, const float* __restrict__ gb) {
  int idx = blockIdx.x * 256 + threadIdx.x;
  if (idx >= BATCH * LQ * CDIM) return;
  int c = idx & 255;
  int tok = idx >> 8;
  int b = tok / LQ, t = tok % LQ;
  int l, hw, Hl, Wl;
  get_level(t, l, hw, Hl, Wl);
  float2 st = stats[(b * 4 + l) * 32 + (c >> 3)];
  float v = (x[idx] - st.x) * st.y * gw[l * CDIM + c] + gb[l * CDIM + c];
  x[idx] = v;
  xb[idx] = __float2bfloat16(v);
}

__global__ void pos_embed_kernel(const float* __restrict__ level_embed,
                                 float* __restrict__ pos) {
  int idx = blockIdx.x * 256 + threadIdx.x;
  if (idx >= LQ * CDIM) return;
  int t = idx >> 8, c = idx & 255;
  int l, hw, Hl, Wl;
  get_level(t, l, hw, Hl, Wl);
  int y = hw / Wl, xx = hw % Wl;
  const float twopi = 6.28318530717958647692f;
  float v; int cc;
  if (c < 128) { v = (float)(y + 1) * twopi / ((float)Hl + 1e-6f); cc = c; }
  else         { v = (float)(xx + 1) * twopi / ((float)Wl + 1e-6f); cc = c - 128; }
  int k = cc >> 1;
  float dim_t = expf((float)k * (logf(10000.0f) / 64.0f));
  float p = v / dim_t;
  float e = (cc & 1) ? cosf(p) : sinf(p);
  pos[idx] = e + level_embed[l * CDIM + c];
}

__global__ void ref_kernel(float* __restrict__ ref) {
  int t = blockIdx.x * 256 + threadIdx.x;
  if (t >= LQ) return;
  int l, hw, Hl, Wl;
  get_level(t, l, hw, Hl, Wl);
  int y = hw / Wl, xx = hw % Wl;
  ref[t * 2]     = ((float)xx + 0.5f) / (float)Wl;
  ref[t * 2 + 1] = ((float)y + 0.5f) / (float)Hl;
}

// q_b16 = bf16(x + pos)
__global__ void add_pos_kernel(const float* __restrict__ x, const float* __restrict__ pos,
                               __hip_bfloat16* __restrict__ qb) {
  int i = blockIdx.x * 256 + threadIdx.x;  // float4 index
  if (i >= BATCH * LQ * 64) return;
  int r = i % (LQ * 64);
  float4 a = ((const float4*)x)[i];
  float4 p = ((const float4*)pos)[r];
  union { ushort4 u; __hip_bfloat16 h[4]; } pk;
  pk.h[0] = __float2bfloat16(a.x + p.x);
  pk.h[1] = __float2bfloat16(a.y + p.y);
  pk.h[2] = __float2bfloat16(a.z + p.z);
  pk.h[3] = __float2bfloat16(a.w + p.w);
  ((ushort4*)qb)[i] = pk.u;
}

// Deformable attention core: block=(32,8) per (q, b); writes bf16
__global__ __launch_bounds__(256) void deform_attn_kernel(
    const float* __restrict__ value, const float* __restrict__ off,
    const float* __restrict__ aw, const float* __restrict__ ref,
    __hip_bfloat16* __restrict__ out) {
  const int Wl_[4] = {64, 32, 16, 8};
  const int st_[4] = {0, 4096, 5120, 5376};
  int qi = blockIdx.x, b = blockIdx.y;
  int dh = threadIdx.x, h = threadIdx.y;
  size_t tok = (size_t)b * LQ + qi;
  const float* offp = off + tok * CDIM + h * 32;
  const float* awp = aw + tok * 128 + h * 16;
  float logit[16];
  float mx = -1e30f;
#pragma unroll
  for (int i = 0; i < 16; ++i) { logit[i] = awp[i]; mx = fmaxf(mx, logit[i]); }
  float ssum = 0.f;
#pragma unroll
  for (int i = 0; i < 16; ++i) { logit[i] = expf(logit[i] - mx); ssum += logit[i]; }
  float inv = 1.0f / ssum;
  float rx = ref[qi * 2], ry = ref[qi * 2 + 1];
  float acc = 0.f;
#pragma unroll
  for (int l = 0; l < 4; ++l) {
    int Wl = Wl_[l], Hl = Wl_[l];
    const float* vbase = value + ((size_t)b * LQ + st_[l]) * CDIM + h * 32 + dh;
#pragma unroll
    for (int p = 0; p < 4; ++p) {
      float ox = offp[(l * 4 + p) * 2];
      float oy = offp[(l * 4 + p) * 2 + 1];
      float px = (rx + ox / (float)Wl) * (float)Wl - 0.5f;
      float py = (ry + oy / (float)Hl) * (float)Hl - 0.5f;
      float wgt = logit[l * 4 + p] * inv;
      float fpx = floorf(px), fpy = floorf(py);
      int x0 = (int)fpx, y0 = (int)fpy;
      float fx = px - fpx, fy = py - fpy;
#pragma unroll
      for (int dy = 0; dy < 2; ++dy) {
#pragma unroll
        for (int dx = 0; dx < 2; ++dx) {
          int xi = x0 + dx, yi = y0 + dy;
          if (xi >= 0 && xi < Wl && yi >= 0 && yi < Hl) {
            float wc = (dx ? fx : 1.f - fx) * (dy ? fy : 1.f - fy);
            acc += wgt * wc * vbase[(size_t)(yi * Wl + xi) * CDIM];
          }
        }
      }
    }
  }
  out[tok * CDIM + h * 32 + dh] = __float2bfloat16(acc);
}

// x = LayerNorm(x + r); writes fp32 x and bf16 shadow xb. One wave per token.
__global__ __launch_bounds__(256) void add_ln_kernel(float* __restrict__ x,
                                                     __hip_bfloat16* __restrict__ xb,
                                                     const float* __restrict__ r,
                                                     const float* __restrict__ w,
                                                     const float* __restrict__ b) {
  int wid = threadIdx.x >> 6, lane = threadIdx.x & 63;
  size_t tok = (size_t)blockIdx.x * 4 + wid;
  size_t base = tok * CDIM + lane * 4;
  float4 xv = *(const float4*)&x[base];
  float4 rv = *(const float4*)&r[base];
  float v[4] = {xv.x + rv.x, xv.y + rv.y, xv.z + rv.z, xv.w + rv.w};
  float s = v[0] + v[1] + v[2] + v[3];
  float ss = v[0] * v[0] + v[1] * v[1] + v[2] * v[2] + v[3] * v[3];
#pragma unroll
  for (int o = 1; o < 64; o <<= 1) { s += __shfl_xor(s, o); ss += __shfl_xor(ss, o); }
  float mu = s * (1.0f / 256.0f);
  float var = ss * (1.0f / 256.0f) - mu * mu;
  float rsig = rsqrtf(var + 1e-5f);
  int c = lane * 4;
  float4 wv = *(const float4*)&w[c];
  float4 bv = *(const float4*)&b[c];
  float4 o4;
  o4.x = (v[0] - mu) * rsig * wv.x + bv.x;
  o4.y = (v[1] - mu) * rsig * wv.y + bv.y;
  o4.z = (v[2] - mu) * rsig * wv.z + bv.z;
  o4.w = (v[3] - mu) * rsig * wv.w + bv.w;
  *(float4*)&x[base] = o4;
  union { ushort4 u; __hip_bfloat16 h[4]; } pk;
  pk.h[0] = __float2bfloat16(o4.x);
  pk.h[1] = __float2bfloat16(o4.y);
  pk.h[2] = __float2bfloat16(o4.z);
  pk.h[3] = __float2bfloat16(o4.w);
  *(ushort4*)&xb[base] = pk.u;
}

__global__ void tok2img_kernel(const float* __restrict__ x, float* __restrict__ img) {
  int i = blockIdx.x * 256 + threadIdx.x;
  if (i >= BATCH * 4096 * CDIM) return;
  int b = i / (4096 * CDIM);
  int rr = i % (4096 * CDIM);
  int hw = rr >> 8, c = rr & 255;
  img[((size_t)b * CDIM + c) * 4096 + hw] = x[((size_t)b * LQ + hw) * CDIM + c];
}

// conv3x3 256->64 + ReLU. One thread per (pixel, 8-oc group).
// grid (16 pixel-blocks, 8 oc-groups, B), block 256.
__global__ __launch_bounds__(256) void conv1_kernel(const float* __restrict__ img,
                                                    const float* __restrict__ w,
                                                    const float* __restrict__ bias,
                                                    float* __restrict__ out) {
  int pix = blockIdx.x * 256 + threadIdx.x;
  int ocg = blockIdx.y, b = blockIdx.z;
  int y = pix >> 6, x = pix & 63;
  const float* ip = img + (size_t)b * 256 * 4096;
  int offs[9];
  float msk[9];
#pragma unroll
  for (int dy = 0; dy < 3; ++dy)
#pragma unroll
    for (int dx = 0; dx < 3; ++dx) {
      int yy = y + dy - 1, xx = x + dx - 1;
      bool ok = (yy >= 0 && yy < 64 && xx >= 0 && xx < 64);
      offs[dy * 3 + dx] = ok ? yy * 64 + xx : 0;
      msk[dy * 3 + dx] = ok ? 1.f : 0.f;
    }
  float acc[8] = {};
  const float* wp0 = w + (size_t)(ocg * 8) * 2304;
  for (int ic = 0; ic < 256; ++ic) {
    const float* pl = ip + (size_t)ic * 4096;
    float t9[9];
#pragma unroll
    for (int k = 0; k < 9; ++k) t9[k] = pl[offs[k]] * msk[k];
    const float* wp = wp0 + ic * 9;  // uniform across block -> scalar loads
#pragma unroll
    for (int oc = 0; oc < 8; ++oc)
#pragma unroll
      for (int k = 0; k < 9; ++k) acc[oc] = fmaf(wp[oc * 2304 + k], t9[k], acc[oc]);
  }
#pragma unroll
  for (int oc = 0; oc < 8; ++oc)
    out[(size_t)(b * 64 + ocg * 8 + oc) * 4096 + pix] =
        fmaxf(acc[oc] + bias[ocg * 8 + oc], 0.f);
}

// conv3x3 64->2. One thread per pixel (both ocs). grid (16, 1, B), block 256.
__global__ __launch_bounds__(256) void conv2_kernel(const float* __restrict__ in,
                                                    const float* __restrict__ w,
                                                    const float* __restrict__ bias,
                                                    float* __restrict__ out) {
  int pix = blockIdx.x * 256 + threadIdx.x;
  int b = blockIdx.z;
  int y = pix >> 6, x = pix & 63;
  const float* ip = in + (size_t)b * 64 * 4096;
  int offs[9];
  float msk[9];
#pragma unroll
  for (int dy = 0; dy < 3; ++dy)
#pragma unroll
    for (int dx = 0; dx < 3; ++dx) {
      int yy = y + dy - 1, xx = x + dx - 1;
      bool ok = (yy >= 0 && yy < 64 && xx >= 0 && xx < 64);
      offs[dy * 3 + dx] = ok ? yy * 64 + xx : 0;
      msk[dy * 3 + dx] = ok ? 1.f : 0.f;
    }
  float acc[2] = {};
  for (int ic = 0; ic < 64; ++ic) {
    const float* pl = ip + (size_t)ic * 4096;
    float t9[9];
#pragma unroll
    for (int k = 0; k < 9; ++k) t9[k] = pl[offs[k]] * msk[k];
    const float* wp = w + ic * 9;
#pragma unroll
    for (int oc = 0; oc < 2; ++oc)
#pragma unroll
      for (int k = 0; k < 9; ++k) acc[oc] = fmaf(wp[oc * 576 + k], t9[k], acc[oc]);
  }
#pragma unroll
  for (int oc = 0; oc < 2; ++oc)
    out[(size_t)(b * 2 + oc) * 4096 + pix] = acc[oc] + bias[oc];
}

// 4x bilinear upsample 64->256, half-pixel, edge clamp
__global__ void upsample_kernel(const float* __restrict__ in, float* __restrict__ out) {
  int idx = blockIdx.x * 256 + threadIdx.x;
  if (idx >= BATCH * 2 * 256 * 256) return;
  int X = idx & 255, Y = (idx >> 8) & 255, p = idx >> 16;
  float tx = ((float)X + 0.5f) * 0.25f - 0.5f;
  float ty = ((float)Y + 0.5f) * 0.25f - 0.5f;
  float fxf = floorf(tx), fyf = floorf(ty);
  int x0 = (int)fxf, y0 = (int)fyf;
  float fx = tx - fxf, fy = ty - fyf;
  int x0c = min(max(x0, 0), 63), x1c = min(max(x0 + 1, 0), 63);
  int y0c = min(max(y0, 0), 63), y1c = min(max(y0 + 1, 0), 63);
  const float* ip = in + (size_t)p * 4096;
  float v = (1.f - fy) * ((1.f - fx) * ip[y0c * 64 + x0c] + fx * ip[y0c * 64 + x1c]) +
            fy * ((1.f - fx) * ip[y1c * 64 + x0c] + fx * ip[y1c * 64 + x1c]);
  out[idx] = v;
}

// ---------------------------------------------------------------------------
extern "C" void kernel_launch(void* const* d_in, const int* in_sizes, int n_in,
                              void* d_out, int out_size, void* d_ws, size_t ws_size,
                              hipStream_t stream) {
  const float* f[4] = {(const float*)d_in[0], (const float*)d_in[1],
                       (const float*)d_in[2], (const float*)d_in[3]};
  const float* proj_w = (const float*)d_in[4];
  const float* proj_b = (const float*)d_in[5];
  const float* gn_w = (const float*)d_in[6];
  const float* gn_b = (const float*)d_in[7];
  const float* level_embed = (const float*)d_in[8];
  const float* so_w = (const float*)d_in[9];
  const float* so_b = (const float*)d_in[10];
  const float* aw_w = (const float*)d_in[11];
  const float* aw_b = (const float*)d_in[12];
  const float* vp_w = (const float*)d_in[13];
  const float* vp_b = (const float*)d_in[14];
  const float* op_w = (const float*)d_in[15];
  const float* op_b = (const float*)d_in[16];
  const float* n1_w = (const float*)d_in[17];
  const float* n1_b = (const float*)d_in[18];
  const float* l1_w = (const float*)d_in[19];
  const float* l1_b = (const float*)d_in[20];
  const float* l2_w = (const float*)d_in[21];
  const float* l2_b = (const float*)d_in[22];
  const float* n2_w = (const float*)d_in[23];
  const float* n2_b = (const float*)d_in[24];
  const float* c1_w = (const float*)d_in[25];
  const float* c1_b = (const float*)d_in[26];
  const float* c2_w = (const float*)d_in[27];
  const float* c2_b = (const float*)d_in[28];
  (void)in_sizes; (void)n_in; (void)out_size; (void)ws_size;

  float* ws = (float*)d_ws;
  const size_t TOK = (size_t)BATCH * LQ * CDIM;  // 2785280
  size_t o = 0;
  float* x = ws + o;    o += TOK;
  float* tmp = ws + o;  o += TOK;                 // also img for head
  float* val = ws + o;  o += TOK;                 // also c1o for head
  float* offb = ws + o; o += TOK;                 // also c2o for head
  float* awb = ws + o;  o += (size_t)BATCH * LQ * 128;
  float* pos = ws + o;  o += (size_t)LQ * CDIM;
  float* refb = ws + o; o += 11008;
  float2* stats = (float2*)(ws + o); o += 512;
  __hip_bfloat16* xb = (__hip_bfloat16*)(ws + o);    o += TOK / 2;
  __hip_bfloat16* qb = (__hip_bfloat16*)(ws + o);    o += TOK / 2;
  __hip_bfloat16* attnb = (__hip_bfloat16*)(ws + o); o += TOK / 2;
  __hip_bfloat16* ff1b = (__hip_bfloat16*)(ws + o);  o += (size_t)BATCH * LQ * FFDIM / 2;
  __hip_bfloat16* so_wb = (__hip_bfloat16*)(ws + o); o += 196608;
  __hip_bfloat16* aw_wb = (__hip_bfloat16*)(ws + o); o += 98304;
  __hip_bfloat16* vp_wb = (__hip_bfloat16*)(ws + o); o += 196608;
  __hip_bfloat16* op_wb = (__hip_bfloat16*)(ws + o); o += 196608;
  __hip_bfloat16* l1_wb = (__hip_bfloat16*)(ws + o); o += 786432;
  __hip_bfloat16* l2_wb = (__hip_bfloat16*)(ws + o); o += 786432;
  float* img = tmp;
  float* c1o = val;
  float* c2o = offb;

  const int HWs[4] = {4096, 1024, 256, 64};
  const int STs[4] = {0, 4096, 5120, 5376};

  // 0) weights -> bf16 (every call; no caching allowed)
  f2b4_kernel<<<(393216 / 4 + 255) / 256, 256, 0, stream>>>(so_w, so_wb, 393216 / 4);
  f2b4_kernel<<<(196608 / 4 + 255) / 256, 256, 0, stream>>>(aw_w, aw_wb, 196608 / 4);
  f2b4_kernel<<<(393216 / 4 + 255) / 256, 256, 0, stream>>>(vp_w, vp_wb, 393216 / 4);
  f2b4_kernel<<<(393216 / 4 + 255) / 256, 256, 0, stream>>>(op_w, op_wb, 393216 / 4);
  f2b4_kernel<<<(1572864 / 4 + 255) / 256, 256, 0, stream>>>(l1_w, l1_wb, 1572864 / 4);
  f2b4_kernel<<<(1572864 / 4 + 255) / 256, 256, 0, stream>>>(l2_w, l2_wb, 1572864 / 4);

  // 1) input proj (1x1 conv as GEMM, A = f[l][b] is [K=256, M=HW])
  for (int l = 0; l < 4; ++l) {
    dim3 grid(CDIM / 64, HWs[l] / 64 > 0 ? HWs[l] / 64 : 1, BATCH);
    gemm_f32_at_kernel<<<grid, 256, 0, stream>>>(
        f[l], proj_w + (size_t)l * CDIM * CDIM, proj_b + l * CDIM,
        x + (size_t)STs[l] * CDIM, HWs[l], CDIM, CDIM,
        (long)CDIM * HWs[l], (long)LQ * CDIM);
  }
  // 2) GroupNorm (+ bf16 shadow)
  gn_stats_kernel<<<dim3(32, 4, BATCH), 256, 0, stream>>>(x, stats);
  {
    int n = BATCH * LQ * CDIM;
    gn_apply_kernel<<<(n + 255) / 256, 256, 0, stream>>>(x, xb, stats, gn_w, gn_b);
  }
  // 3) pos embed + reference points
  pos_embed_kernel<<<(LQ * CDIM + 255) / 256, 256, 0, stream>>>(level_embed, pos);
  ref_kernel<<<(LQ + 255) / 256, 256, 0, stream>>>(refb);

  const int M = BATCH * LQ;  // 10880 = 85 * 128
  for (int i = 0; i < 6; ++i) {
    const __hip_bfloat16* sw = so_wb + (size_t)i * 65536;
    const __hip_bfloat16* aww = aw_wb + (size_t)i * 32768;
    const __hip_bfloat16* vw = vp_wb + (size_t)i * 65536;
    const __hip_bfloat16* ow = op_wb + (size_t)i * 65536;
    const __hip_bfloat16* w1 = l1_wb + (size_t)i * 262144;
    const __hip_bfloat16* w2 = l2_wb + (size_t)i * 262144;
    const float* sb = so_b + (size_t)i * CDIM;
    const float* awbias = aw_b + (size_t)i * 128;
    const float* vb = vp_b + (size_t)i * CDIM;
    const float* ob = op_b + (size_t)i * CDIM;
    const float* b1 = l1_b + (size_t)i * FFDIM;
    const float* b2 = l2_b + (size_t)i * CDIM;

    add_pos_kernel<<<(M * 64 + 255) / 256, 256, 0, stream>>>(x, pos, qb);
    // value proj: val(fp32) = xb @ vw^T
    gemm_bf16_kernel<false, true, false><<<dim3(2, 85), 256, 0, stream>>>(
        xb, vw, vb, val, nullptr, M, CDIM, CDIM);
    // sampling offsets: offb(fp32) = qb @ sw^T
    gemm_bf16_kernel<false, true, false><<<dim3(2, 85), 256, 0, stream>>>(
        qb, sw, sb, offb, nullptr, M, CDIM, CDIM);
    // attention weights: awb(fp32) = qb @ aww^T
    gemm_bf16_kernel<false, true, false><<<dim3(1, 85), 256, 0, stream>>>(
        qb, aww, awbias, awb, nullptr, M, 128, CDIM);
    deform_attn_kernel<<<dim3(LQ, BATCH), dim3(32, 8), 0, stream>>>(val, offb, awb,
                                                                    refb, attnb);
    // output proj: tmp(fp32) = attnb @ ow^T
    gemm_bf16_kernel<false, true, false><<<dim3(2, 85), 256, 0, stream>>>(
        attnb, ow, ob, tmp, nullptr, M, CDIM, CDIM);
    add_ln_kernel<<<M / 4, 256, 0, stream>>>(x, xb, tmp, n1_w + (size_t)i * CDIM,
                                             n1_b + (size_t)i * CDIM);
    // ffn1: ff1b(bf16) = relu(xb @ w1^T)
    gemm_bf16_kernel<true, false, true><<<dim3(8, 85), 256, 0, stream>>>(
        xb, w1, b1, nullptr, ff1b, M, FFDIM, CDIM);
    // ffn2: tmp(fp32) = ff1b @ w2^T
    gemm_bf16_kernel<false, true, false><<<dim3(2, 85), 256, 0, stream>>>(
        ff1b, w2, b2, tmp, nullptr, M, CDIM, FFDIM);
    add_ln_kernel<<<M / 4, 256, 0, stream>>>(x, xb, tmp, n2_w + (size_t)i * CDIM,
                                             n2_b + (size_t)i * CDIM);
  }

  // head
  {
    int n = BATCH * 4096 * CDIM;
    tok2img_kernel<<<(n + 255) / 256, 256, 0, stream>>>(x, img);
  }
  conv1_kernel<<<dim3(16, 8, BATCH), 256, 0, stream>>>(img, c1_w, c1_b, c1o);
  conv2_kernel<<<dim3(16, 1, BATCH), 256, 0, stream>>>(c1o, c2_w, c2_b, c2o);
  {
    int n = BATCH * 2 * 256 * 256;
    upsample_kernel<<<(n + 255) / 256, 256, 0, stream>>>(c2o, (float*)d_out);
  }
}

// Round 5
// 1057.671 us; speedup vs baseline: 3.0906x; 1.5710x over previous
//
#include <hip/hip_runtime.h>
#include <hip/hip_bf16.h>
#include <math.h>

#define LQ 5440
#define CDIM 256
#define BATCH 2
#define FFDIM 1024

typedef __attribute__((ext_vector_type(8))) short bf16x8;
typedef __attribute__((ext_vector_type(4))) float f32x4;

typedef __attribute__((address_space(1))) void* gas1_t;
typedef __attribute__((address_space(3))) void* las3_t;

__device__ __forceinline__ void async16(const void* g, void* l) {
  __builtin_amdgcn_global_load_lds((gas1_t)g, (las3_t)l, 16, 0, 0);
}

// ---------------------------------------------------------------------------
// bf16 MFMA GEMM: C[M,N] = act(A @ Wt^T + bias), A:[M,K] bf16, Wt:[N,K] bf16.
// M % 128 == 0, N % 128 == 0, K % 32 == 0. 128x128 tile, 4 waves (2x2).
// ---------------------------------------------------------------------------
template <bool RELU, bool OUT_F32, bool OUT_B16>
__global__ __launch_bounds__(256, 2) void gemm_bf16_kernel(
    const __hip_bfloat16* __restrict__ A, const __hip_bfloat16* __restrict__ Wt,
    const float* __restrict__ bias, float* __restrict__ C,
    __hip_bfloat16* __restrict__ Cb, int M, int N, int K) {
  __shared__ __hip_bfloat16 As[128 * 32];
  __shared__ __hip_bfloat16 Bs[128 * 32];
  const int tid = threadIdx.x;
  const int bm = blockIdx.y * 128, bn = blockIdx.x * 128;
  const int lane = tid & 63, wave = tid >> 6;
  const int wr = wave >> 1, wc = wave & 1;
  const int srow = tid >> 2;
  const int scol = (tid & 3) * 8;
  const __hip_bfloat16* ga0 = A + (size_t)(bm + srow) * K + scol;
  const __hip_bfloat16* ga1 = A + (size_t)(bm + 64 + srow) * K + scol;
  const __hip_bfloat16* gb0 = Wt + (size_t)(bn + srow) * K + scol;
  const __hip_bfloat16* gb1 = Wt + (size_t)(bn + 64 + srow) * K + scol;
  __hip_bfloat16* la0 = &As[srow * 32 + scol];
  __hip_bfloat16* la1 = &As[(64 + srow) * 32 + scol];
  __hip_bfloat16* lb0 = &Bs[srow * 32 + scol];
  __hip_bfloat16* lb1 = &Bs[(64 + srow) * 32 + scol];

  f32x4 acc[4][4] = {};
  const int fr = lane & 15;
  const int ksub = (lane >> 4) * 8;

  for (int k0 = 0; k0 < K; k0 += 32) {
    async16(ga0 + k0, la0);
    async16(ga1 + k0, la1);
    async16(gb0 + k0, lb0);
    async16(gb1 + k0, lb1);
    __syncthreads();
    bf16x8 af[4], bfv[4];
#pragma unroll
    for (int mi = 0; mi < 4; ++mi)
      af[mi] = *(const bf16x8*)&As[(wr * 64 + mi * 16 + fr) * 32 + ksub];
#pragma unroll
    for (int nj = 0; nj < 4; ++nj)
      bfv[nj] = *(const bf16x8*)&Bs[(wc * 64 + nj * 16 + fr) * 32 + ksub];
#pragma unroll
    for (int mi = 0; mi < 4; ++mi)
#pragma unroll
      for (int nj = 0; nj < 4; ++nj)
        acc[mi][nj] = __builtin_amdgcn_mfma_f32_16x16x32_bf16(af[mi], bfv[nj],
                                                              acc[mi][nj], 0, 0, 0);
    __syncthreads();
  }

  const int cc = lane & 15;
  const int rbase = (lane >> 4) * 4;
  float bcol[4];
#pragma unroll
  for (int nj = 0; nj < 4; ++nj) bcol[nj] = bias[bn + wc * 64 + nj * 16 + cc];
#pragma unroll
  for (int mi = 0; mi < 4; ++mi)
#pragma unroll
    for (int nj = 0; nj < 4; ++nj) {
      int col = bn + wc * 64 + nj * 16 + cc;
#pragma unroll
      for (int r = 0; r < 4; ++r) {
        int row = bm + wr * 64 + mi * 16 + rbase + r;
        float v = acc[mi][nj][r] + bcol[nj];
        if (RELU) v = fmaxf(v, 0.f);
        if (OUT_F32) C[(size_t)row * N + col] = v;
        if (OUT_B16) Cb[(size_t)row * N + col] = __float2bfloat16(v);
      }
    }
}

// fp32 -> bf16 bulk convert (n % 4 == 0)
__global__ void f2b4_kernel(const float* __restrict__ in,
                            __hip_bfloat16* __restrict__ out, int n4) {
  int i = blockIdx.x * 256 + threadIdx.x;
  if (i >= n4) return;
  float4 v = ((const float4*)in)[i];
  union { ushort4 u; __hip_bfloat16 h[4]; } p;
  p.h[0] = __float2bfloat16(v.x);
  p.h[1] = __float2bfloat16(v.y);
  p.h[2] = __float2bfloat16(v.z);
  p.h[3] = __float2bfloat16(v.w);
  ((ushort4*)out)[i] = p.u;
}

// ---------------------------------------------------------------------------
// fp32 tiled GEMM (input_proj only): A:[K,M] row-major, W:[N,K].
// ---------------------------------------------------------------------------
__global__ __launch_bounds__(256) void gemm_f32_at_kernel(
    const float* __restrict__ A, const float* __restrict__ W,
    const float* __restrict__ bias, float* __restrict__ C,
    int M, int N, int K, long bsA, long bsC) {
  __shared__ __align__(16) float As[16][72];
  __shared__ __align__(16) float Ws[16][72];
  const int tid = threadIdx.x;
  const int bm = blockIdx.y * 64, bn = blockIdx.x * 64;
  A += (size_t)blockIdx.z * bsA;
  C += (size_t)blockIdx.z * bsC;
  const int tx = tid & 15, ty = tid >> 4;
  float acc[4][4] = {};
  for (int k0 = 0; k0 < K; k0 += 16) {
#pragma unroll
    for (int i = 0; i < 4; ++i) {
      int idx = tid + i * 256;
      int k = idx >> 6, m = idx & 63;
      As[k][m] = A[(size_t)(k0 + k) * M + bm + m];
      int n = idx >> 4, k2 = idx & 15;
      Ws[k2][n] = W[(size_t)(bn + n) * K + k0 + k2];
    }
    __syncthreads();
#pragma unroll
    for (int k = 0; k < 16; ++k) {
      const float4 av = *(const float4*)&As[k][ty * 4];
      const float4 bv = *(const float4*)&Ws[k][tx * 4];
      const float a4[4] = {av.x, av.y, av.z, av.w};
      const float b4[4] = {bv.x, bv.y, bv.z, bv.w};
#pragma unroll
      for (int i = 0; i < 4; ++i)
#pragma unroll
        for (int j = 0; j < 4; ++j) acc[i][j] = fmaf(a4[i], b4[j], acc[i][j]);
    }
    __syncthreads();
  }
  const float4 bv4 = *(const float4*)&bias[bn + tx * 4];
  const float bb[4] = {bv4.x, bv4.y, bv4.z, bv4.w};
#pragma unroll
  for (int i = 0; i < 4; ++i) {
    float4 o;
    float* op = (float*)&o;
#pragma unroll
    for (int j = 0; j < 4; ++j) op[j] = acc[i][j] + bb[j];
    *(float4*)&C[(size_t)(bm + ty * 4 + i) * N + bn + tx * 4] = o;
  }
}

// ---------------------------------------------------------------------------
__device__ __forceinline__ void get_level(int t, int& l, int& hw, int& Hl, int& Wl) {
  if (t < 4096)      { l = 0; hw = t;        Hl = 64; Wl = 64; }
  else if (t < 5120) { l = 1; hw = t - 4096; Hl = 32; Wl = 32; }
  else if (t < 5376) { l = 2; hw = t - 5120; Hl = 16; Wl = 16; }
  else               { l = 3; hw = t - 5376; Hl = 8;  Wl = 8;  }
}

__global__ __launch_bounds__(256) void gn_stats_kernel(const float* __restrict__ x,
                                                       float2* __restrict__ stats) {
  const int HWs[4] = {4096, 1024, 256, 64};
  const int STs[4] = {0, 4096, 5120, 5376};
  int g = blockIdx.x, l = blockIdx.y, b = blockIdx.z;
  int HW = HWs[l];
  size_t base = ((size_t)b * LQ + STs[l]) * CDIM + g * 8;
  float s = 0.f, ss = 0.f;
  for (int i = threadIdx.x; i < HW * 8; i += 256) {
    int hw = i >> 3, ci = i & 7;
    float v = x[base + (size_t)hw * CDIM + ci];
    s += v; ss += v * v;
  }
#pragma unroll
  for (int o = 32; o; o >>= 1) { s += __shfl_down(s, o); ss += __shfl_down(ss, o); }
  __shared__ float rs[4], rss[4];
  int lane = threadIdx.x & 63, wid = threadIdx.x >> 6;
  if (lane == 0) { rs[wid] = s; rss[wid] = ss; }
  __syncthreads();
  if (threadIdx.x == 0) {
    s = rs[0] + rs[1] + rs[2] + rs[3];
    ss = rss[0] + rss[1] + rss[2] + rss[3];
    float n = (float)(HW * 8);
    float mu = s / n;
    float var = ss / n - mu * mu;
    stats[(b * 4 + l) * 32 + g] = make_float2(mu, rsqrtf(var + 1e-5f));
  }
}

__global__ void gn_apply_kernel(float* __restrict__ x, __hip_bfloat16* __restrict__ xb,
                                const float2* __restrict__ stats,
                                const float* __restrict__ gw, const float* __restrict__ gb) {
  int idx = blockIdx.x * 256 + threadIdx.x;
  if (idx >= BATCH * LQ * CDIM) return;
  int c = idx & 255;
  int tok = idx >> 8;
  int b = tok / LQ, t = tok % LQ;
  int l, hw, Hl, Wl;
  get_level(t, l, hw, Hl, Wl);
  float2 st = stats[(b * 4 + l) * 32 + (c >> 3)];
  float v = (x[idx] - st.x) * st.y * gw[l * CDIM + c] + gb[l * CDIM + c];
  x[idx] = v;
  xb[idx] = __float2bfloat16(v);
}

__global__ void pos_embed_kernel(const float* __restrict__ level_embed,
                                 float* __restrict__ pos) {
  int idx = blockIdx.x * 256 + threadIdx.x;
  if (idx >= LQ * CDIM) return;
  int t = idx >> 8, c = idx & 255;
  int l, hw, Hl, Wl;
  get_level(t, l, hw, Hl, Wl);
  int y = hw / Wl, xx = hw % Wl;
  const float twopi = 6.28318530717958647692f;
  float v; int cc;
  if (c < 128) { v = (float)(y + 1) * twopi / ((float)Hl + 1e-6f); cc = c; }
  else         { v = (float)(xx + 1) * twopi / ((float)Wl + 1e-6f); cc = c - 128; }
  int k = cc >> 1;
  float dim_t = expf((float)k * (logf(10000.0f) / 64.0f));
  float p = v / dim_t;
  float e = (cc & 1) ? cosf(p) : sinf(p);
  pos[idx] = e + level_embed[l * CDIM + c];
}

__global__ void ref_kernel(float* __restrict__ ref) {
  int t = blockIdx.x * 256 + threadIdx.x;
  if (t >= LQ) return;
  int l, hw, Hl, Wl;
  get_level(t, l, hw, Hl, Wl);
  int y = hw / Wl, xx = hw % Wl;
  ref[t * 2]     = ((float)xx + 0.5f) / (float)Wl;
  ref[t * 2 + 1] = ((float)y + 0.5f) / (float)Hl;
}

__global__ void add_pos_kernel(const float* __restrict__ x, const float* __restrict__ pos,
                               __hip_bfloat16* __restrict__ qb) {
  int i = blockIdx.x * 256 + threadIdx.x;
  if (i >= BATCH * LQ * 64) return;
  int r = i % (LQ * 64);
  float4 a = ((const float4*)x)[i];
  float4 p = ((const float4*)pos)[r];
  union { ushort4 u; __hip_bfloat16 h[4]; } pk;
  pk.h[0] = __float2bfloat16(a.x + p.x);
  pk.h[1] = __float2bfloat16(a.y + p.y);
  pk.h[2] = __float2bfloat16(a.z + p.z);
  pk.h[3] = __float2bfloat16(a.w + p.w);
  ((ushort4*)qb)[i] = pk.u;
}

// ---------------------------------------------------------------------------
// Deformable attention: 8-lane group per (token, head), 4 channels per lane.
// value is bf16 [B*LQ, C]; gathers are ushort4 (8B/lane, 64B/group).
// ---------------------------------------------------------------------------
__global__ __launch_bounds__(256) void deform_attn_kernel(
    const __hip_bfloat16* __restrict__ value, const float* __restrict__ off,
    const float* __restrict__ aw, const float* __restrict__ ref,
    __hip_bfloat16* __restrict__ out) {
  const int Wl_[4] = {64, 32, 16, 8};
  const int st_[4] = {0, 4096, 5120, 5376};
  int gid = blockIdx.x * 32 + (threadIdx.x >> 3);
  int lane8 = threadIdx.x & 7;
  int h = gid & 7;
  int tok = gid >> 3;
  int b = tok / LQ;
  int qi = tok - b * LQ;

  const float4* awv = (const float4*)(aw + (size_t)tok * 128 + h * 16);
  float4 q0 = awv[0], q1 = awv[1], q2 = awv[2], q3 = awv[3];
  float logit[16] = {q0.x, q0.y, q0.z, q0.w, q1.x, q1.y, q1.z, q1.w,
                     q2.x, q2.y, q2.z, q2.w, q3.x, q3.y, q3.z, q3.w};
  float mx = -1e30f;
#pragma unroll
  for (int i = 0; i < 16; ++i) mx = fmaxf(mx, logit[i]);
  float ssum = 0.f;
#pragma unroll
  for (int i = 0; i < 16; ++i) { logit[i] = expf(logit[i] - mx); ssum += logit[i]; }
  float inv = 1.0f / ssum;

  float rx = ref[qi * 2], ry = ref[qi * 2 + 1];
  const float4* offv = (const float4*)(off + (size_t)tok * 256 + h * 32);
  float acc0 = 0.f, acc1 = 0.f, acc2 = 0.f, acc3 = 0.f;

#pragma unroll
  for (int l = 0; l < 4; ++l) {
    const int Wl = Wl_[l];
    const float fW = (float)Wl;
    const __hip_bfloat16* vbase =
        value + ((size_t)b * LQ + st_[l]) * CDIM + h * 32 + lane8 * 4;
    float bx = fmaf(rx, fW, -0.5f);
    float by = fmaf(ry, fW, -0.5f);
    float4 oa = offv[l * 2], ob = offv[l * 2 + 1];
    float oxs[4] = {oa.x, oa.z, ob.x, ob.z};
    float oys[4] = {oa.y, oa.w, ob.y, ob.w};
#pragma unroll
    for (int p = 0; p < 4; ++p) {
      float px = bx + oxs[p], py = by + oys[p];
      float wgt = logit[l * 4 + p] * inv;
      float fpx = floorf(px), fpy = floorf(py);
      int x0 = (int)fpx, y0 = (int)fpy;
      float fx = px - fpx, fy = py - fpy;
#pragma unroll
      for (int dy = 0; dy < 2; ++dy)
#pragma unroll
        for (int dx = 0; dx < 2; ++dx) {
          int xi = x0 + dx, yi = y0 + dy;
          if (xi >= 0 && xi < Wl && yi >= 0 && yi < Wl) {
            float wc = wgt * (dx ? fx : 1.f - fx) * (dy ? fy : 1.f - fy);
            ushort4 u = *(const ushort4*)(vbase + (size_t)(yi * Wl + xi) * CDIM);
            acc0 = fmaf(wc, __uint_as_float((unsigned)u.x << 16), acc0);
            acc1 = fmaf(wc, __uint_as_float((unsigned)u.y << 16), acc1);
            acc2 = fmaf(wc, __uint_as_float((unsigned)u.z << 16), acc2);
            acc3 = fmaf(wc, __uint_as_float((unsigned)u.w << 16), acc3);
          }
        }
    }
  }
  union { ushort4 u; __hip_bfloat16 hh[4]; } pk;
  pk.hh[0] = __float2bfloat16(acc0);
  pk.hh[1] = __float2bfloat16(acc1);
  pk.hh[2] = __float2bfloat16(acc2);
  pk.hh[3] = __float2bfloat16(acc3);
  *(ushort4*)(out + (size_t)tok * CDIM + h * 32 + lane8 * 4) = pk.u;
}

// x = LayerNorm(x + r); writes fp32 x and bf16 shadow xb. One wave per token.
__global__ __launch_bounds__(256) void add_ln_kernel(float* __restrict__ x,
                                                     __hip_bfloat16* __restrict__ xb,
                                                     const float* __restrict__ r,
                                                     const float* __restrict__ w,
                                                     const float* __restrict__ b) {
  int wid = threadIdx.x >> 6, lane = threadIdx.x & 63;
  size_t tok = (size_t)blockIdx.x * 4 + wid;
  size_t base = tok * CDIM + lane * 4;
  float4 xv = *(const float4*)&x[base];
  float4 rv = *(const float4*)&r[base];
  float v[4] = {xv.x + rv.x, xv.y + rv.y, xv.z + rv.z, xv.w + rv.w};
  float s = v[0] + v[1] + v[2] + v[3];
  float ss = v[0] * v[0] + v[1] * v[1] + v[2] * v[2] + v[3] * v[3];
#pragma unroll
  for (int o = 1; o < 64; o <<= 1) { s += __shfl_xor(s, o); ss += __shfl_xor(ss, o); }
  float mu = s * (1.0f / 256.0f);
  float var = ss * (1.0f / 256.0f) - mu * mu;
  float rsig = rsqrtf(var + 1e-5f);
  int c = lane * 4;
  float4 wv = *(const float4*)&w[c];
  float4 bv = *(const float4*)&b[c];
  float4 o4;
  o4.x = (v[0] - mu) * rsig * wv.x + bv.x;
  o4.y = (v[1] - mu) * rsig * wv.y + bv.y;
  o4.z = (v[2] - mu) * rsig * wv.z + bv.z;
  o4.w = (v[3] - mu) * rsig * wv.w + bv.w;
  *(float4*)&x[base] = o4;
  union { ushort4 u; __hip_bfloat16 h[4]; } pk;
  pk.h[0] = __float2bfloat16(o4.x);
  pk.h[1] = __float2bfloat16(o4.y);
  pk.h[2] = __float2bfloat16(o4.z);
  pk.h[3] = __float2bfloat16(o4.w);
  *(ushort4*)&xb[base] = pk.u;
}

__global__ void tok2img_kernel(const float* __restrict__ x, float* __restrict__ img) {
  int i = blockIdx.x * 256 + threadIdx.x;
  if (i >= BATCH * 4096 * CDIM) return;
  int b = i / (4096 * CDIM);
  int rr = i % (4096 * CDIM);
  int hw = rr >> 8, c = rr & 255;
  img[((size_t)b * CDIM + c) * 4096 + hw] = x[((size_t)b * LQ + hw) * CDIM + c];
}

// conv1 split-K partials: grid (16 pixblocks, 8 ocg, B*4 chunks), block 256.
// part layout: [(b*4+chunk)][64 oc][4096]
__global__ __launch_bounds__(256) void conv1_part_kernel(const float* __restrict__ img,
                                                         const float* __restrict__ w,
                                                         float* __restrict__ part) {
  int pix = blockIdx.x * 256 + threadIdx.x;
  int ocg = blockIdx.y;
  int bz = blockIdx.z;
  int b = bz >> 2, chunk = bz & 3;
  int y = pix >> 6, x = pix & 63;
  int offs[9];
  float msk[9];
#pragma unroll
  for (int dy = 0; dy < 3; ++dy)
#pragma unroll
    for (int dx = 0; dx < 3; ++dx) {
      int yy = y + dy - 1, xx = x + dx - 1;
      bool ok = (yy >= 0 && yy < 64 && xx >= 0 && xx < 64);
      offs[dy * 3 + dx] = ok ? yy * 64 + xx : 0;
      msk[dy * 3 + dx] = ok ? 1.f : 0.f;
    }
  float acc[8] = {};
  const float* ip = img + ((size_t)b * 256 + chunk * 64) * 4096;
  const float* wp0 = w + ((size_t)(ocg * 8)) * 2304 + chunk * 64 * 9;
  for (int ic = 0; ic < 64; ++ic) {
    const float* pl = ip + (size_t)ic * 4096;
    float t9[9];
#pragma unroll
    for (int k = 0; k < 9; ++k) t9[k] = pl[offs[k]] * msk[k];
    const float* wp = wp0 + ic * 9;
#pragma unroll
    for (int oc = 0; oc < 8; ++oc)
#pragma unroll
      for (int k = 0; k < 9; ++k) acc[oc] = fmaf(wp[oc * 2304 + k], t9[k], acc[oc]);
  }
#pragma unroll
  for (int oc = 0; oc < 8; ++oc)
    part[((size_t)bz * 64 + ocg * 8 + oc) * 4096 + pix] = acc[oc];
}

// sum 4 chunks + bias + relu -> c1o [B][64][4096]
__global__ void conv1_reduce_kernel(const float* __restrict__ part,
                                    const float* __restrict__ bias,
                                    float* __restrict__ out) {
  int i = blockIdx.x * 256 + threadIdx.x;  // float4 index
  if (i >= BATCH * 64 * 1024) return;
  int flat = i * 4;
  int pix = flat & 4095;
  int boc = flat >> 12;
  int b = boc >> 6, oc = boc & 63;
  float4 s = make_float4(0.f, 0.f, 0.f, 0.f);
#pragma unroll
  for (int ch = 0; ch < 4; ++ch) {
    float4 v = *(const float4*)&part[(((size_t)(b * 4 + ch) * 64 + oc) << 12) + pix];
    s.x += v.x; s.y += v.y; s.z += v.z; s.w += v.w;
  }
  float bb = bias[oc];
  float4 o;
  o.x = fmaxf(s.x + bb, 0.f);
  o.y = fmaxf(s.y + bb, 0.f);
  o.z = fmaxf(s.z + bb, 0.f);
  o.w = fmaxf(s.w + bb, 0.f);
  *(float4*)&out[((size_t)boc << 12) + pix] = o;
}

// conv2 split-K partials: grid (16, 8 chunks, B). part2: [(chunk*2+b)*2+oc][4096]
__global__ __launch_bounds__(256) void conv2_part_kernel(const float* __restrict__ in,
                                                         const float* __restrict__ w,
                                                         float* __restrict__ part) {
  int pix = blockIdx.x * 256 + threadIdx.x;
  int chunk = blockIdx.y, b = blockIdx.z;
  int y = pix >> 6, x = pix & 63;
  int offs[9];
  float msk[9];
#pragma unroll
  for (int dy = 0; dy < 3; ++dy)
#pragma unroll
    for (int dx = 0; dx < 3; ++dx) {
      int yy = y + dy - 1, xx = x + dx - 1;
      bool ok = (yy >= 0 && yy < 64 && xx >= 0 && xx < 64);
      offs[dy * 3 + dx] = ok ? yy * 64 + xx : 0;
      msk[dy * 3 + dx] = ok ? 1.f : 0.f;
    }
  float acc[2] = {};
  const float* ip = in + ((size_t)b * 64 + chunk * 8) * 4096;
  const float* wp0 = w + chunk * 8 * 9;
  for (int ic = 0; ic < 8; ++ic) {
    const float* pl = ip + (size_t)ic * 4096;
    float t9[9];
#pragma unroll
    for (int k = 0; k < 9; ++k) t9[k] = pl[offs[k]] * msk[k];
    const float* wp = wp0 + ic * 9;
#pragma unroll
    for (int oc = 0; oc < 2; ++oc)
#pragma unroll
      for (int k = 0; k < 9; ++k) acc[oc] = fmaf(wp[oc * 576 + k], t9[k], acc[oc]);
  }
#pragma unroll
  for (int oc = 0; oc < 2; ++oc)
    part[((size_t)(chunk * 2 + b) * 2 + oc) * 4096 + pix] = acc[oc];
}

// sum 8 chunks + bias -> c2o [B*2][4096]
__global__ void conv2_reduce_kernel(const float* __restrict__ part,
                                    const float* __restrict__ bias,
                                    float* __restrict__ out) {
  int i = blockIdx.x * 256 + threadIdx.x;  // float4 index over 4096
  if (i >= BATCH * 2 * 1024) return;
  int flat = i * 4;
  int pix = flat & 4095;
  int boc = flat >> 12;  // b*2+oc
  int b = boc >> 1, oc = boc & 1;
  float4 s = make_float4(0.f, 0.f, 0.f, 0.f);
#pragma unroll
  for (int ch = 0; ch < 8; ++ch) {
    float4 v = *(const float4*)&part[(((size_t)(ch * 2 + b) * 2 + oc) << 12) + pix];
    s.x += v.x; s.y += v.y; s.z += v.z; s.w += v.w;
  }
  float bb = bias[oc];
  float4 o = make_float4(s.x + bb, s.y + bb, s.z + bb, s.w + bb);
  *(float4*)&out[((size_t)boc << 12) + pix] = o;
}

// 4x bilinear upsample 64->256, half-pixel, edge clamp
__global__ void upsample_kernel(const float* __restrict__ in, float* __restrict__ out) {
  int idx = blockIdx.x * 256 + threadIdx.x;
  if (idx >= BATCH * 2 * 256 * 256) return;
  int X = idx & 255, Y = (idx >> 8) & 255, p = idx >> 16;
  float tx = ((float)X + 0.5f) * 0.25f - 0.5f;
  float ty = ((float)Y + 0.5f) * 0.25f - 0.5f;
  float fxf = floorf(tx), fyf = floorf(ty);
  int x0 = (int)fxf, y0 = (int)fyf;
  float fx = tx - fxf, fy = ty - fyf;
  int x0c = min(max(x0, 0), 63), x1c = min(max(x0 + 1, 0), 63);
  int y0c = min(max(y0, 0), 63), y1c = min(max(y0 + 1, 0), 63);
  const float* ip = in + (size_t)p * 4096;
  float v = (1.f - fy) * ((1.f - fx) * ip[y0c * 64 + x0c] + fx * ip[y0c * 64 + x1c]) +
            fy * ((1.f - fx) * ip[y1c * 64 + x0c] + fx * ip[y1c * 64 + x1c]);
  out[idx] = v;
}

// ---------------------------------------------------------------------------
extern "C" void kernel_launch(void* const* d_in, const int* in_sizes, int n_in,
                              void* d_out, int out_size, void* d_ws, size_t ws_size,
                              hipStream_t stream) {
  const float* f[4] = {(const float*)d_in[0], (const float*)d_in[1],
                       (const float*)d_in[2], (const float*)d_in[3]};
  const float* proj_w = (const float*)d_in[4];
  const float* proj_b = (const float*)d_in[5];
  const float* gn_w = (const float*)d_in[6];
  const float* gn_b = (const float*)d_in[7];
  const float* level_embed = (const float*)d_in[8];
  const float* so_w = (const float*)d_in[9];
  const float* so_b = (const float*)d_in[10];
  const float* aw_w = (const float*)d_in[11];
  const float* aw_b = (const float*)d_in[12];
  const float* vp_w = (const float*)d_in[13];
  const float* vp_b = (const float*)d_in[14];
  const float* op_w = (const float*)d_in[15];
  const float* op_b = (const float*)d_in[16];
  const float* n1_w = (const float*)d_in[17];
  const float* n1_b = (const float*)d_in[18];
  const float* l1_w = (const float*)d_in[19];
  const float* l1_b = (const float*)d_in[20];
  const float* l2_w = (const float*)d_in[21];
  const float* l2_b = (const float*)d_in[22];
  const float* n2_w = (const float*)d_in[23];
  const float* n2_b = (const float*)d_in[24];
  const float* c1_w = (const float*)d_in[25];
  const float* c1_b = (const float*)d_in[26];
  const float* c2_w = (const float*)d_in[27];
  const float* c2_b = (const float*)d_in[28];
  (void)in_sizes; (void)n_in; (void)out_size; (void)ws_size;

  float* ws = (float*)d_ws;
  const size_t TOK = (size_t)BATCH * LQ * CDIM;  // 2785280
  size_t o = 0;
  float* x = ws + o;    o += TOK;
  float* tmp = ws + o;  o += TOK;                 // alias: img
  float* offb = ws + o; o += TOK;                 // alias: conv1 partials (2.1M)
  float* awb = ws + o;  o += (size_t)BATCH * LQ * 128;  // alias: c1o (0.52M)
  float* pos = ws + o;  o += (size_t)LQ * CDIM;   // alias: conv2 partials + c2o
  float* refb = ws + o; o += 11008;
  float2* stats = (float2*)(ws + o); o += 512;
  __hip_bfloat16* xb = (__hip_bfloat16*)(ws + o);    o += TOK / 2;
  __hip_bfloat16* qb = (__hip_bfloat16*)(ws + o);    o += TOK / 2;
  __hip_bfloat16* valb = (__hip_bfloat16*)(ws + o);  o += TOK / 2;
  __hip_bfloat16* attnb = (__hip_bfloat16*)(ws + o); o += TOK / 2;
  __hip_bfloat16* ff1b = (__hip_bfloat16*)(ws + o);  o += (size_t)BATCH * LQ * FFDIM / 2;
  __hip_bfloat16* so_wb = (__hip_bfloat16*)(ws + o); o += 196608;
  __hip_bfloat16* aw_wb = (__hip_bfloat16*)(ws + o); o += 98304;
  __hip_bfloat16* vp_wb = (__hip_bfloat16*)(ws + o); o += 196608;
  __hip_bfloat16* op_wb = (__hip_bfloat16*)(ws + o); o += 196608;
  __hip_bfloat16* l1_wb = (__hip_bfloat16*)(ws + o); o += 786432;
  __hip_bfloat16* l2_wb = (__hip_bfloat16*)(ws + o); o += 786432;
  float* img = tmp;
  float* part1 = offb;
  float* c1o = awb;
  float* part2 = pos;
  float* c2o = pos + 262144;

  const int HWs[4] = {4096, 1024, 256, 64};
  const int STs[4] = {0, 4096, 5120, 5376};

  // 0) weights -> bf16
  f2b4_kernel<<<(393216 / 4 + 255) / 256, 256, 0, stream>>>(so_w, so_wb, 393216 / 4);
  f2b4_kernel<<<(196608 / 4 + 255) / 256, 256, 0, stream>>>(aw_w, aw_wb, 196608 / 4);
  f2b4_kernel<<<(393216 / 4 + 255) / 256, 256, 0, stream>>>(vp_w, vp_wb, 393216 / 4);
  f2b4_kernel<<<(393216 / 4 + 255) / 256, 256, 0, stream>>>(op_w, op_wb, 393216 / 4);
  f2b4_kernel<<<(1572864 / 4 + 255) / 256, 256, 0, stream>>>(l1_w, l1_wb, 1572864 / 4);
  f2b4_kernel<<<(1572864 / 4 + 255) / 256, 256, 0, stream>>>(l2_w, l2_wb, 1572864 / 4);

  // 1) input proj
  for (int l = 0; l < 4; ++l) {
    dim3 grid(CDIM / 64, HWs[l] / 64 > 0 ? HWs[l] / 64 : 1, BATCH);
    gemm_f32_at_kernel<<<grid, 256, 0, stream>>>(
        f[l], proj_w + (size_t)l * CDIM * CDIM, proj_b + l * CDIM,
        x + (size_t)STs[l] * CDIM, HWs[l], CDIM, CDIM,
        (long)CDIM * HWs[l], (long)LQ * CDIM);
  }
  // 2) GroupNorm (+ bf16 shadow)
  gn_stats_kernel<<<dim3(32, 4, BATCH), 256, 0, stream>>>(x, stats);
  {
    int n = BATCH * LQ * CDIM;
    gn_apply_kernel<<<(n + 255) / 256, 256, 0, stream>>>(x, xb, stats, gn_w, gn_b);
  }
  // 3) pos embed + reference points
  pos_embed_kernel<<<(LQ * CDIM + 255) / 256, 256, 0, stream>>>(level_embed, pos);
  ref_kernel<<<(LQ + 255) / 256, 256, 0, stream>>>(refb);

  const int M = BATCH * LQ;  // 10880 = 85 * 128
  for (int i = 0; i < 6; ++i) {
    const __hip_bfloat16* sw = so_wb + (size_t)i * 65536;
    const __hip_bfloat16* aww = aw_wb + (size_t)i * 32768;
    const __hip_bfloat16* vw = vp_wb + (size_t)i * 65536;
    const __hip_bfloat16* ow = op_wb + (size_t)i * 65536;
    const __hip_bfloat16* w1 = l1_wb + (size_t)i * 262144;
    const __hip_bfloat16* w2 = l2_wb + (size_t)i * 262144;
    const float* sb = so_b + (size_t)i * CDIM;
    const float* awbias = aw_b + (size_t)i * 128;
    const float* vb = vp_b + (size_t)i * CDIM;
    const float* ob = op_b + (size_t)i * CDIM;
    const float* b1 = l1_b + (size_t)i * FFDIM;
    const float* b2 = l2_b + (size_t)i * CDIM;

    add_pos_kernel<<<(M * 64 + 255) / 256, 256, 0, stream>>>(x, pos, qb);
    // value proj -> bf16 directly
    gemm_bf16_kernel<false, false, true><<<dim3(2, 85), 256, 0, stream>>>(
        xb, vw, vb, nullptr, valb, M, CDIM, CDIM);
    gemm_bf16_kernel<false, true, false><<<dim3(2, 85), 256, 0, stream>>>(
        qb, sw, sb, offb, nullptr, M, CDIM, CDIM);
    gemm_bf16_kernel<false, true, false><<<dim3(1, 85), 256, 0, stream>>>(
        qb, aww, awbias, awb, nullptr, M, 128, CDIM);
    deform_attn_kernel<<<BATCH * LQ * 8 / 32, 256, 0, stream>>>(valb, offb, awb,
                                                                refb, attnb);
    gemm_bf16_kernel<false, true, false><<<dim3(2, 85), 256, 0, stream>>>(
        attnb, ow, ob, tmp, nullptr, M, CDIM, CDIM);
    add_ln_kernel<<<M / 4, 256, 0, stream>>>(x, xb, tmp, n1_w + (size_t)i * CDIM,
                                             n1_b + (size_t)i * CDIM);
    gemm_bf16_kernel<true, false, true><<<dim3(8, 85), 256, 0, stream>>>(
        xb, w1, b1, nullptr, ff1b, M, FFDIM, CDIM);
    gemm_bf16_kernel<false, true, false><<<dim3(2, 85), 256, 0, stream>>>(
        ff1b, w2, b2, tmp, nullptr, M, CDIM, FFDIM);
    add_ln_kernel<<<M / 4, 256, 0, stream>>>(x, xb, tmp, n2_w + (size_t)i * CDIM,
                                             n2_b + (size_t)i * CDIM);
  }

  // head
  {
    int n = BATCH * 4096 * CDIM;
    tok2img_kernel<<<(n + 255) / 256, 256, 0, stream>>>(x, img);
  }
  conv1_part_kernel<<<dim3(16, 8, BATCH * 4), 256, 0, stream>>>(img, c1_w, part1);
  conv1_reduce_kernel<<<(BATCH * 64 * 1024 + 255) / 256, 256, 0, stream>>>(part1, c1_b,
                                                                           c1o);
  conv2_part_kernel<<<dim3(16, 8, BATCH), 256, 0, stream>>>(c1o, c2_w, part2);
  conv2_reduce_kernel<<<(BATCH * 2 * 1024 + 255) / 256, 256, 0, stream>>>(part2, c2_b,
                                                                          c2o);
  {
    int n = BATCH * 2 * 256 * 256;
    upsample_kernel<<<(n + 255) / 256, 256, 0, stream>>>(c2o, (float*)d_out);
  }
}

// Round 6
// 956.281 us; speedup vs baseline: 3.4182x; 1.1060x over previous
//
#include <hip/hip_runtime.h>
#include <hip/hip_bf16.h>
#include <math.h>

#define LQ 5440
#define CDIM 256
#define BATCH 2
#define FFDIM 1024

typedef __attribute__((ext_vector_type(8))) short bf16x8;
typedef __attribute__((ext_vector_type(4))) float f32x4;

typedef __attribute__((address_space(1))) void* gas1_t;
typedef __attribute__((address_space(3))) void* las3_t;

__device__ __forceinline__ void async16(const void* g, void* l) {
  __builtin_amdgcn_global_load_lds((gas1_t)g, (las3_t)l, 16, 0, 0);
}

// ---------------------------------------------------------------------------
// bf16 MFMA GEMM: C[M,N] = act(A @ Wt^T + bias), A:[M,K] bf16, Wt:[N,K] bf16.
// ---------------------------------------------------------------------------
template <bool RELU, bool OUT_F32, bool OUT_B16>
__global__ __launch_bounds__(256, 2) void gemm_bf16_kernel(
    const __hip_bfloat16* __restrict__ A, const __hip_bfloat16* __restrict__ Wt,
    const float* __restrict__ bias, float* __restrict__ C,
    __hip_bfloat16* __restrict__ Cb, int M, int N, int K) {
  __shared__ __hip_bfloat16 As[128 * 32];
  __shared__ __hip_bfloat16 Bs[128 * 32];
  const int tid = threadIdx.x;
  const int bm = blockIdx.y * 128, bn = blockIdx.x * 128;
  const int lane = tid & 63, wave = tid >> 6;
  const int wr = wave >> 1, wc = wave & 1;
  const int srow = tid >> 2;
  const int scol = (tid & 3) * 8;
  const __hip_bfloat16* ga0 = A + (size_t)(bm + srow) * K + scol;
  const __hip_bfloat16* ga1 = A + (size_t)(bm + 64 + srow) * K + scol;
  const __hip_bfloat16* gb0 = Wt + (size_t)(bn + srow) * K + scol;
  const __hip_bfloat16* gb1 = Wt + (size_t)(bn + 64 + srow) * K + scol;
  __hip_bfloat16* la0 = &As[srow * 32 + scol];
  __hip_bfloat16* la1 = &As[(64 + srow) * 32 + scol];
  __hip_bfloat16* lb0 = &Bs[srow * 32 + scol];
  __hip_bfloat16* lb1 = &Bs[(64 + srow) * 32 + scol];

  f32x4 acc[4][4] = {};
  const int fr = lane & 15;
  const int ksub = (lane >> 4) * 8;

  for (int k0 = 0; k0 < K; k0 += 32) {
    async16(ga0 + k0, la0);
    async16(ga1 + k0, la1);
    async16(gb0 + k0, lb0);
    async16(gb1 + k0, lb1);
    __syncthreads();
    bf16x8 af[4], bfv[4];
#pragma unroll
    for (int mi = 0; mi < 4; ++mi)
      af[mi] = *(const bf16x8*)&As[(wr * 64 + mi * 16 + fr) * 32 + ksub];
#pragma unroll
    for (int nj = 0; nj < 4; ++nj)
      bfv[nj] = *(const bf16x8*)&Bs[(wc * 64 + nj * 16 + fr) * 32 + ksub];
#pragma unroll
    for (int mi = 0; mi < 4; ++mi)
#pragma unroll
      for (int nj = 0; nj < 4; ++nj)
        acc[mi][nj] = __builtin_amdgcn_mfma_f32_16x16x32_bf16(af[mi], bfv[nj],
                                                              acc[mi][nj], 0, 0, 0);
    __syncthreads();
  }

  const int cc = lane & 15;
  const int rbase = (lane >> 4) * 4;
  float bcol[4];
#pragma unroll
  for (int nj = 0; nj < 4; ++nj) bcol[nj] = bias[bn + wc * 64 + nj * 16 + cc];
#pragma unroll
  for (int mi = 0; mi < 4; ++mi)
#pragma unroll
    for (int nj = 0; nj < 4; ++nj) {
      int col = bn + wc * 64 + nj * 16 + cc;
#pragma unroll
      for (int r = 0; r < 4; ++r) {
        int row = bm + wr * 64 + mi * 16 + rbase + r;
        float v = acc[mi][nj][r] + bcol[nj];
        if (RELU) v = fmaxf(v, 0.f);
        if (OUT_F32) C[(size_t)row * N + col] = v;
        if (OUT_B16) Cb[(size_t)row * N + col] = __float2bfloat16(v);
      }
    }
}

// ---------------------------------------------------------------------------
// conv1 as implicit GEMM (NHWC): out[pix, oc] = relu(sum_k A[pix,k] W[oc,k] + b)
// A rows = shifted token rows of xb (level 0), k = tap*256+ic. 128px x 64oc tile.
// ---------------------------------------------------------------------------
__global__ __launch_bounds__(256, 2) void conv1_mfma_kernel(
    const __hip_bfloat16* __restrict__ xb, const __hip_bfloat16* __restrict__ wc1,
    const float* __restrict__ bias, const __hip_bfloat16* __restrict__ zerob,
    __hip_bfloat16* __restrict__ c1o) {
  __shared__ __hip_bfloat16 As[128 * 32];
  __shared__ __hip_bfloat16 Bs[64 * 32];
  const int tid = threadIdx.x;
  const int b = blockIdx.x >> 5;
  const int pm = (blockIdx.x & 31) * 128;
  const int lane = tid & 63, wave = tid >> 6;
  const int sr = tid >> 2;
  const int sc = (tid & 3) * 8;
  __hip_bfloat16* la0 = &As[sr * 32 + sc];
  __hip_bfloat16* la1 = &As[(64 + sr) * 32 + sc];
  __hip_bfloat16* lb = &Bs[sr * 32 + sc];
  f32x4 acc[2][4] = {};
  const int fr = lane & 15, ksub = (lane >> 4) * 8;

  for (int tap = 0; tap < 9; ++tap) {
    const int dy = tap / 3 - 1, dx = tap % 3 - 1;
    int hw0 = pm + sr;
    int y0 = (hw0 >> 6) + dy, x0 = (hw0 & 63) + dx;
    bool ok0 = (y0 >= 0 && y0 < 64 && x0 >= 0 && x0 < 64);
    const __hip_bfloat16* s0 =
        xb + ((size_t)(b * LQ) + y0 * 64 + x0) * 256 + sc;
    int hw1 = pm + 64 + sr;
    int y1 = (hw1 >> 6) + dy, x1 = (hw1 & 63) + dx;
    bool ok1 = (y1 >= 0 && y1 < 64 && x1 >= 0 && x1 < 64);
    const __hip_bfloat16* s1 =
        xb + ((size_t)(b * LQ) + y1 * 64 + x1) * 256 + sc;
    const __hip_bfloat16* wsrc = wc1 + (size_t)sr * 2304 + tap * 256 + sc;
    for (int kk = 0; kk < 256; kk += 32) {
      async16(ok0 ? s0 + kk : zerob, la0);
      async16(ok1 ? s1 + kk : zerob, la1);
      async16(wsrc + kk, lb);
      __syncthreads();
      bf16x8 af[2], bfv[4];
#pragma unroll
      for (int mi = 0; mi < 2; ++mi)
        af[mi] = *(const bf16x8*)&As[(wave * 32 + mi * 16 + fr) * 32 + ksub];
#pragma unroll
      for (int nj = 0; nj < 4; ++nj)
        bfv[nj] = *(const bf16x8*)&Bs[(nj * 16 + fr) * 32 + ksub];
#pragma unroll
      for (int mi = 0; mi < 2; ++mi)
#pragma unroll
        for (int nj = 0; nj < 4; ++nj)
          acc[mi][nj] = __builtin_amdgcn_mfma_f32_16x16x32_bf16(
              af[mi], bfv[nj], acc[mi][nj], 0, 0, 0);
      __syncthreads();
    }
  }
  const int cc = lane & 15;
  const int rbase = (lane >> 4) * 4;
#pragma unroll
  for (int mi = 0; mi < 2; ++mi)
#pragma unroll
    for (int nj = 0; nj < 4; ++nj) {
      int col = nj * 16 + cc;
      float bb = bias[col];
#pragma unroll
      for (int r = 0; r < 4; ++r) {
        int row = wave * 32 + mi * 16 + rbase + r;
        float v = fmaxf(acc[mi][nj][r] + bb, 0.f);
        c1o[(size_t)(b * 4096 + pm + row) * 64 + col] = __float2bfloat16(v);
      }
    }
}

// fp32 -> bf16 bulk convert (n % 4 == 0)
__global__ void f2b4_kernel(const float* __restrict__ in,
                            __hip_bfloat16* __restrict__ out, int n4) {
  int i = blockIdx.x * 256 + threadIdx.x;
  if (i >= n4) return;
  float4 v = ((const float4*)in)[i];
  union { ushort4 u; __hip_bfloat16 h[4]; } p;
  p.h[0] = __float2bfloat16(v.x);
  p.h[1] = __float2bfloat16(v.y);
  p.h[2] = __float2bfloat16(v.z);
  p.h[3] = __float2bfloat16(v.w);
  ((ushort4*)out)[i] = p.u;
}

// combined so+aw weight staging: [6][384][256] bf16
__global__ void sowa_prep_kernel(const float* __restrict__ so_w,
                                 const float* __restrict__ aw_w,
                                 __hip_bfloat16* __restrict__ out) {
  int i = blockIdx.x * 256 + threadIdx.x;
  if (i >= 6 * 384 * 256) return;
  int il = i / (384 * 256);
  int rem = i - il * 384 * 256;
  int n = rem >> 8, k = rem & 255;
  float v = (n < 256) ? so_w[(size_t)il * 65536 + n * 256 + k]
                      : aw_w[(size_t)il * 32768 + (n - 256) * 256 + k];
  out[i] = __float2bfloat16(v);
}

__global__ void sowa_bias_prep_kernel(const float* __restrict__ so_b,
                                      const float* __restrict__ aw_b,
                                      float* __restrict__ out) {
  int i = blockIdx.x * 256 + threadIdx.x;
  if (i >= 6 * 384) return;
  int il = i / 384, n = i % 384;
  out[i] = (n < 256) ? so_b[il * 256 + n] : aw_b[il * 128 + n - 256];
}

// conv1 weight staging: wc1[oc][tap*256+ic] = bf16(c1_w[oc][ic][tap])
__global__ void wc1_prep_kernel(const float* __restrict__ w,
                                __hip_bfloat16* __restrict__ out) {
  int i = blockIdx.x * 256 + threadIdx.x;
  if (i >= 64 * 2304) return;
  int oc = i / 2304, r = i % 2304;
  int tap = r >> 8, ic = r & 255;
  out[i] = __float2bfloat16(w[(size_t)oc * 2304 + ic * 9 + tap]);
}

// ---------------------------------------------------------------------------
// fp32 tiled GEMM (input_proj only): A:[K,M] row-major, W:[N,K].
// ---------------------------------------------------------------------------
__global__ __launch_bounds__(256) void gemm_f32_at_kernel(
    const float* __restrict__ A, const float* __restrict__ W,
    const float* __restrict__ bias, float* __restrict__ C,
    int M, int N, int K, long bsA, long bsC) {
  __shared__ __align__(16) float As[16][72];
  __shared__ __align__(16) float Ws[16][72];
  const int tid = threadIdx.x;
  const int bm = blockIdx.y * 64, bn = blockIdx.x * 64;
  A += (size_t)blockIdx.z * bsA;
  C += (size_t)blockIdx.z * bsC;
  const int tx = tid & 15, ty = tid >> 4;
  float acc[4][4] = {};
  for (int k0 = 0; k0 < K; k0 += 16) {
#pragma unroll
    for (int i = 0; i < 4; ++i) {
      int idx = tid + i * 256;
      int k = idx >> 6, m = idx & 63;
      As[k][m] = A[(size_t)(k0 + k) * M + bm + m];
      int n = idx >> 4, k2 = idx & 15;
      Ws[k2][n] = W[(size_t)(bn + n) * K + k0 + k2];
    }
    __syncthreads();
#pragma unroll
    for (int k = 0; k < 16; ++k) {
      const float4 av = *(const float4*)&As[k][ty * 4];
      const float4 bv = *(const float4*)&Ws[k][tx * 4];
      const float a4[4] = {av.x, av.y, av.z, av.w};
      const float b4[4] = {bv.x, bv.y, bv.z, bv.w};
#pragma unroll
      for (int i = 0; i < 4; ++i)
#pragma unroll
        for (int j = 0; j < 4; ++j) acc[i][j] = fmaf(a4[i], b4[j], acc[i][j]);
    }
    __syncthreads();
  }
  const float4 bv4 = *(const float4*)&bias[bn + tx * 4];
  const float bb[4] = {bv4.x, bv4.y, bv4.z, bv4.w};
#pragma unroll
  for (int i = 0; i < 4; ++i) {
    float4 o;
    float* op = (float*)&o;
#pragma unroll
    for (int j = 0; j < 4; ++j) op[j] = acc[i][j] + bb[j];
    *(float4*)&C[(size_t)(bm + ty * 4 + i) * N + bn + tx * 4] = o;
  }
}

// ---------------------------------------------------------------------------
__device__ __forceinline__ void get_level(int t, int& l, int& hw, int& Hl, int& Wl) {
  if (t < 4096)      { l = 0; hw = t;        Hl = 64; Wl = 64; }
  else if (t < 5120) { l = 1; hw = t - 4096; Hl = 32; Wl = 32; }
  else if (t < 5376) { l = 2; hw = t - 5120; Hl = 16; Wl = 16; }
  else               { l = 3; hw = t - 5376; Hl = 8;  Wl = 8;  }
}

__global__ __launch_bounds__(256) void gn_stats_kernel(const float* __restrict__ x,
                                                       float2* __restrict__ stats) {
  const int HWs[4] = {4096, 1024, 256, 64};
  const int STs[4] = {0, 4096, 5120, 5376};
  int g = blockIdx.x, l = blockIdx.y, b = blockIdx.z;
  int HW = HWs[l];
  size_t base = ((size_t)b * LQ + STs[l]) * CDIM + g * 8;
  float s = 0.f, ss = 0.f;
  for (int i = threadIdx.x; i < HW * 8; i += 256) {
    int hw = i >> 3, ci = i & 7;
    float v = x[base + (size_t)hw * CDIM + ci];
    s += v; ss += v * v;
  }
#pragma unroll
  for (int o = 32; o; o >>= 1) { s += __shfl_down(s, o); ss += __shfl_down(ss, o); }
  __shared__ float rs[4], rss[4];
  int lane = threadIdx.x & 63, wid = threadIdx.x >> 6;
  if (lane == 0) { rs[wid] = s; rss[wid] = ss; }
  __syncthreads();
  if (threadIdx.x == 0) {
    s = rs[0] + rs[1] + rs[2] + rs[3];
    ss = rss[0] + rss[1] + rss[2] + rss[3];
    float n = (float)(HW * 8);
    float mu = s / n;
    float var = ss / n - mu * mu;
    stats[(b * 4 + l) * 32 + g] = make_float2(mu, rsqrtf(var + 1e-5f));
  }
}

// GN apply + bf16 shadow + qb = bf16(x + pos)
__global__ void gn_apply_kernel(float* __restrict__ x, __hip_bfloat16* __restrict__ xb,
                                __hip_bfloat16* __restrict__ qb,
                                const float* __restrict__ pos,
                                const float2* __restrict__ stats,
                                const float* __restrict__ gw, const float* __restrict__ gb) {
  int idx = blockIdx.x * 256 + threadIdx.x;
  if (idx >= BATCH * LQ * CDIM) return;
  int c = idx & 255;
  int tok = idx >> 8;
  int b = tok / LQ, t = tok % LQ;
  int l, hw, Hl, Wl;
  get_level(t, l, hw, Hl, Wl);
  float2 st = stats[(b * 4 + l) * 32 + (c >> 3)];
  float v = (x[idx] - st.x) * st.y * gw[l * CDIM + c] + gb[l * CDIM + c];
  x[idx] = v;
  xb[idx] = __float2bfloat16(v);
  qb[idx] = __float2bfloat16(v + pos[t * 256 + c]);
}

__global__ void pos_embed_kernel(const float* __restrict__ level_embed,
                                 float* __restrict__ pos) {
  int idx = blockIdx.x * 256 + threadIdx.x;
  if (idx >= LQ * CDIM) return;
  int t = idx >> 8, c = idx & 255;
  int l, hw, Hl, Wl;
  get_level(t, l, hw, Hl, Wl);
  int y = hw / Wl, xx = hw % Wl;
  const float twopi = 6.28318530717958647692f;
  float v; int cc;
  if (c < 128) { v = (float)(y + 1) * twopi / ((float)Hl + 1e-6f); cc = c; }
  else         { v = (float)(xx + 1) * twopi / ((float)Wl + 1e-6f); cc = c - 128; }
  int k = cc >> 1;
  float dim_t = expf((float)k * (logf(10000.0f) / 64.0f));
  float p = v / dim_t;
  float e = (cc & 1) ? cosf(p) : sinf(p);
  pos[idx] = e + level_embed[l * CDIM + c];
}

__global__ void ref_kernel(float* __restrict__ ref) {
  int t = blockIdx.x * 256 + threadIdx.x;
  if (t >= LQ) return;
  int l, hw, Hl, Wl;
  get_level(t, l, hw, Hl, Wl);
  int y = hw / Wl, xx = hw % Wl;
  ref[t * 2]     = ((float)xx + 0.5f) / (float)Wl;
  ref[t * 2 + 1] = ((float)y + 0.5f) / (float)Hl;
}

// ---------------------------------------------------------------------------
// Deformable attention: 8-lane group per (token, head); off/aw from combined
// projection buffer with row stride 384 (cols 0..255 = offsets, 256.. = aw).
// ---------------------------------------------------------------------------
__global__ __launch_bounds__(256) void deform_attn_kernel(
    const __hip_bfloat16* __restrict__ value, const float* __restrict__ comb,
    const float* __restrict__ ref, __hip_bfloat16* __restrict__ out) {
  const int Wl_[4] = {64, 32, 16, 8};
  const int st_[4] = {0, 4096, 5120, 5376};
  int gid = blockIdx.x * 32 + (threadIdx.x >> 3);
  int lane8 = threadIdx.x & 7;
  int h = gid & 7;
  int tok = gid >> 3;
  int b = tok / LQ;
  int qi = tok - b * LQ;

  const float4* awv = (const float4*)(comb + (size_t)tok * 384 + 256 + h * 16);
  float4 q0 = awv[0], q1 = awv[1], q2 = awv[2], q3 = awv[3];
  float logit[16] = {q0.x, q0.y, q0.z, q0.w, q1.x, q1.y, q1.z, q1.w,
                     q2.x, q2.y, q2.z, q2.w, q3.x, q3.y, q3.z, q3.w};
  float mx = -1e30f;
#pragma unroll
  for (int i = 0; i < 16; ++i) mx = fmaxf(mx, logit[i]);
  float ssum = 0.f;
#pragma unroll
  for (int i = 0; i < 16; ++i) { logit[i] = expf(logit[i] - mx); ssum += logit[i]; }
  float inv = 1.0f / ssum;

  float rx = ref[qi * 2], ry = ref[qi * 2 + 1];
  const float4* offv = (const float4*)(comb + (size_t)tok * 384 + h * 32);
  float acc0 = 0.f, acc1 = 0.f, acc2 = 0.f, acc3 = 0.f;

#pragma unroll
  for (int l = 0; l < 4; ++l) {
    const int Wl = Wl_[l];
    const float fW = (float)Wl;
    const __hip_bfloat16* vbase =
        value + ((size_t)b * LQ + st_[l]) * CDIM + h * 32 + lane8 * 4;
    float bx = fmaf(rx, fW, -0.5f);
    float by = fmaf(ry, fW, -0.5f);
    float4 oa = offv[l * 2], ob = offv[l * 2 + 1];
    float oxs[4] = {oa.x, oa.z, ob.x, ob.z};
    float oys[4] = {oa.y, oa.w, ob.y, ob.w};
#pragma unroll
    for (int p = 0; p < 4; ++p) {
      float px = bx + oxs[p], py = by + oys[p];
      float wgt = logit[l * 4 + p] * inv;
      float fpx = floorf(px), fpy = floorf(py);
      int x0 = (int)fpx, y0 = (int)fpy;
      float fx = px - fpx, fy = py - fpy;
#pragma unroll
      for (int dy = 0; dy < 2; ++dy)
#pragma unroll
        for (int dx = 0; dx < 2; ++dx) {
          int xi = x0 + dx, yi = y0 + dy;
          if (xi >= 0 && xi < Wl && yi >= 0 && yi < Wl) {
            float wc = wgt * (dx ? fx : 1.f - fx) * (dy ? fy : 1.f - fy);
            ushort4 u = *(const ushort4*)(vbase + (size_t)(yi * Wl + xi) * CDIM);
            acc0 = fmaf(wc, __uint_as_float((unsigned)u.x << 16), acc0);
            acc1 = fmaf(wc, __uint_as_float((unsigned)u.y << 16), acc1);
            acc2 = fmaf(wc, __uint_as_float((unsigned)u.z << 16), acc2);
            acc3 = fmaf(wc, __uint_as_float((unsigned)u.w << 16), acc3);
          }
        }
    }
  }
  union { ushort4 u; __hip_bfloat16 hh[4]; } pk;
  pk.hh[0] = __float2bfloat16(acc0);
  pk.hh[1] = __float2bfloat16(acc1);
  pk.hh[2] = __float2bfloat16(acc2);
  pk.hh[3] = __float2bfloat16(acc3);
  *(ushort4*)(out + (size_t)tok * CDIM + h * 32 + lane8 * 4) = pk.u;
}

// x = LayerNorm(x + r); writes fp32 x, bf16 xb, optionally qb = bf16(x+pos).
template <bool EMIT_Q>
__global__ __launch_bounds__(256) void add_ln_kernel(
    float* __restrict__ x, __hip_bfloat16* __restrict__ xb,
    __hip_bfloat16* __restrict__ qb, const float* __restrict__ pos,
    const float* __restrict__ r, const float* __restrict__ w,
    const float* __restrict__ b) {
  int wid = threadIdx.x >> 6, lane = threadIdx.x & 63;
  size_t tok = (size_t)blockIdx.x * 4 + wid;
  size_t base = tok * CDIM + lane * 4;
  float4 xv = *(const float4*)&x[base];
  float4 rv = *(const float4*)&r[base];
  float v[4] = {xv.x + rv.x, xv.y + rv.y, xv.z + rv.z, xv.w + rv.w};
  float s = v[0] + v[1] + v[2] + v[3];
  float ss = v[0] * v[0] + v[1] * v[1] + v[2] * v[2] + v[3] * v[3];
#pragma unroll
  for (int o = 1; o < 64; o <<= 1) { s += __shfl_xor(s, o); ss += __shfl_xor(ss, o); }
  float mu = s * (1.0f / 256.0f);
  float var = ss * (1.0f / 256.0f) - mu * mu;
  float rsig = rsqrtf(var + 1e-5f);
  int c = lane * 4;
  float4 wv = *(const float4*)&w[c];
  float4 bv = *(const float4*)&b[c];
  float4 o4;
  o4.x = (v[0] - mu) * rsig * wv.x + bv.x;
  o4.y = (v[1] - mu) * rsig * wv.y + bv.y;
  o4.z = (v[2] - mu) * rsig * wv.z + bv.z;
  o4.w = (v[3] - mu) * rsig * wv.w + bv.w;
  *(float4*)&x[base] = o4;
  union { ushort4 u; __hip_bfloat16 h[4]; } pk;
  pk.h[0] = __float2bfloat16(o4.x);
  pk.h[1] = __float2bfloat16(o4.y);
  pk.h[2] = __float2bfloat16(o4.z);
  pk.h[3] = __float2bfloat16(o4.w);
  *(ushort4*)&xb[base] = pk.u;
  if (EMIT_Q) {
    int t = (int)(tok >= LQ ? tok - LQ : tok);
    float4 pv = *(const float4*)&pos[(size_t)t * CDIM + c];
    union { ushort4 u; __hip_bfloat16 h[4]; } pq;
    pq.h[0] = __float2bfloat16(o4.x + pv.x);
    pq.h[1] = __float2bfloat16(o4.y + pv.y);
    pq.h[2] = __float2bfloat16(o4.z + pv.z);
    pq.h[3] = __float2bfloat16(o4.w + pv.w);
    *(ushort4*)&qb[base] = pq.u;
  }
}

// conv2 NHWC split over taps: part[tap][b][pix][2]
__global__ __launch_bounds__(256) void conv2_part_kernel(
    const __hip_bfloat16* __restrict__ c1o, const float* __restrict__ w,
    float* __restrict__ part) {
  int pix = blockIdx.x * 256 + threadIdx.x;
  int tap = blockIdx.y, b = blockIdx.z;
  int y = pix >> 6, x = pix & 63;
  int dy = tap / 3 - 1, dx = tap % 3 - 1;
  int yy = y + dy, xx = x + dx;
  bool ok = (yy >= 0 && yy < 64 && xx >= 0 && xx < 64);
  float a0 = 0.f, a1 = 0.f;
  if (ok) {
    const __hip_bfloat16* row = c1o + (size_t)(b * 4096 + yy * 64 + xx) * 64;
#pragma unroll
    for (int ic4 = 0; ic4 < 16; ++ic4) {
      ushort4 u = *(const ushort4*)(row + ic4 * 4);
      float f0 = __uint_as_float((unsigned)u.x << 16);
      float f1 = __uint_as_float((unsigned)u.y << 16);
      float f2 = __uint_as_float((unsigned)u.z << 16);
      float f3 = __uint_as_float((unsigned)u.w << 16);
      int ic = ic4 * 4;
      a0 = fmaf(w[(ic + 0) * 9 + tap], f0, a0);
      a0 = fmaf(w[(ic + 1) * 9 + tap], f1, a0);
      a0 = fmaf(w[(ic + 2) * 9 + tap], f2, a0);
      a0 = fmaf(w[(ic + 3) * 9 + tap], f3, a0);
      a1 = fmaf(w[576 + (ic + 0) * 9 + tap], f0, a1);
      a1 = fmaf(w[576 + (ic + 1) * 9 + tap], f1, a1);
      a1 = fmaf(w[576 + (ic + 2) * 9 + tap], f2, a1);
      a1 = fmaf(w[576 + (ic + 3) * 9 + tap], f3, a1);
    }
  }
  float2 o = make_float2(a0, a1);
  *(float2*)&part[((size_t)(tap * BATCH + b) * 4096 + pix) * 2] = o;
}

// sum 9 taps + bias -> c2o [b][pix][2]
__global__ void conv2_reduce_kernel(const float* __restrict__ part,
                                    const float* __restrict__ bias,
                                    float* __restrict__ out) {
  int i = blockIdx.x * 256 + threadIdx.x;
  if (i >= BATCH * 4096) return;
  int b = i >> 12, pix = i & 4095;
  float s0 = bias[0], s1 = bias[1];
#pragma unroll
  for (int tap = 0; tap < 9; ++tap) {
    float2 v = *(const float2*)&part[((size_t)(tap * BATCH + b) * 4096 + pix) * 2];
    s0 += v.x; s1 += v.y;
  }
  *(float2*)&out[(size_t)i * 2] = make_float2(s0, s1);
}

// 4x bilinear upsample 64->256; input layout [b][pix][2]
__global__ void upsample_kernel(const float* __restrict__ in, float* __restrict__ out) {
  int idx = blockIdx.x * 256 + threadIdx.x;
  if (idx >= BATCH * 2 * 256 * 256) return;
  int X = idx & 255, Y = (idx >> 8) & 255, p = idx >> 16;
  int b = p >> 1, oc = p & 1;
  float tx = ((float)X + 0.5f) * 0.25f - 0.5f;
  float ty = ((float)Y + 0.5f) * 0.25f - 0.5f;
  float fxf = floorf(tx), fyf = floorf(ty);
  int x0 = (int)fxf, y0 = (int)fyf;
  float fx = tx - fxf, fy = ty - fyf;
  int x0c = min(max(x0, 0), 63), x1c = min(max(x0 + 1, 0), 63);
  int y0c = min(max(y0, 0), 63), y1c = min(max(y0 + 1, 0), 63);
  const float* ip = in + (size_t)b * 4096 * 2 + oc;
  float v = (1.f - fy) * ((1.f - fx) * ip[(y0c * 64 + x0c) * 2] + fx * ip[(y0c * 64 + x1c) * 2]) +
            fy * ((1.f - fx) * ip[(y1c * 64 + x0c) * 2] + fx * ip[(y1c * 64 + x1c) * 2]);
  out[idx] = v;
}

// ---------------------------------------------------------------------------
extern "C" void kernel_launch(void* const* d_in, const int* in_sizes, int n_in,
                              void* d_out, int out_size, void* d_ws, size_t ws_size,
                              hipStream_t stream) {
  const float* f[4] = {(const float*)d_in[0], (const float*)d_in[1],
                       (const float*)d_in[2], (const float*)d_in[3]};
  const float* proj_w = (const float*)d_in[4];
  const float* proj_b = (const float*)d_in[5];
  const float* gn_w = (const float*)d_in[6];
  const float* gn_b = (const float*)d_in[7];
  const float* level_embed = (const float*)d_in[8];
  const float* so_w = (const float*)d_in[9];
  const float* so_b = (const float*)d_in[10];
  const float* aw_w = (const float*)d_in[11];
  const float* aw_b = (const float*)d_in[12];
  const float* vp_w = (const float*)d_in[13];
  const float* vp_b = (const float*)d_in[14];
  const float* op_w = (const float*)d_in[15];
  const float* op_b = (const float*)d_in[16];
  const float* n1_w = (const float*)d_in[17];
  const float* n1_b = (const float*)d_in[18];
  const float* l1_w = (const float*)d_in[19];
  const float* l1_b = (const float*)d_in[20];
  const float* l2_w = (const float*)d_in[21];
  const float* l2_b = (const float*)d_in[22];
  const float* n2_w = (const float*)d_in[23];
  const float* n2_b = (const float*)d_in[24];
  const float* c1_w = (const float*)d_in[25];
  const float* c1_b = (const float*)d_in[26];
  const float* c2_w = (const float*)d_in[27];
  const float* c2_b = (const float*)d_in[28];
  (void)in_sizes; (void)n_in; (void)out_size; (void)ws_size;

  float* ws = (float*)d_ws;
  const size_t TOK = (size_t)BATCH * LQ * CDIM;  // 2785280
  size_t o = 0;
  float* x = ws + o;     o += TOK;
  float* tmp = ws + o;   o += TOK;
  float* comb = ws + o;  o += (size_t)BATCH * LQ * 384;  // so+aw outputs
  float* pos = ws + o;   o += (size_t)LQ * CDIM;
  float* refb = ws + o;  o += 11008;
  float2* stats = (float2*)(ws + o); o += 512;
  float* zerof = ws + o; o += 256;   // 1KB zero page (bf16 view)
  float* sowa_bias = ws + o; o += 2304;
  __hip_bfloat16* xb = (__hip_bfloat16*)(ws + o);    o += TOK / 2;
  __hip_bfloat16* qb = (__hip_bfloat16*)(ws + o);    o += TOK / 2;
  __hip_bfloat16* valb = (__hip_bfloat16*)(ws + o);  o += TOK / 2;
  __hip_bfloat16* attnb = (__hip_bfloat16*)(ws + o); o += TOK / 2;
  __hip_bfloat16* ff1b = (__hip_bfloat16*)(ws + o);  o += (size_t)BATCH * LQ * FFDIM / 2;
  __hip_bfloat16* sowa_wb = (__hip_bfloat16*)(ws + o); o += 294912;
  __hip_bfloat16* vp_wb = (__hip_bfloat16*)(ws + o); o += 196608;
  __hip_bfloat16* op_wb = (__hip_bfloat16*)(ws + o); o += 196608;
  __hip_bfloat16* l1_wb = (__hip_bfloat16*)(ws + o); o += 786432;
  __hip_bfloat16* l2_wb = (__hip_bfloat16*)(ws + o); o += 786432;
  __hip_bfloat16* wc1b = (__hip_bfloat16*)(ws + o);  o += 73728;
  // head scratch aliases ff1b region (free after encoder)
  __hip_bfloat16* c1ob = ff1b;                                   // 512K bf16
  float* part2 = (float*)(ff1b + 524288);                        // 147456 f32
  float* c2o = part2 + 147456;                                   // 16384 f32

  const int HWs[4] = {4096, 1024, 256, 64};
  const int STs[4] = {0, 4096, 5120, 5376};

  // 0) staging: zero page, bf16 weights, combined so+aw
  hipMemsetAsync(zerof, 0, 1024, stream);
  sowa_prep_kernel<<<(589824 + 255) / 256, 256, 0, stream>>>(so_w, aw_w, sowa_wb);
  sowa_bias_prep_kernel<<<9, 256, 0, stream>>>(so_b, aw_b, sowa_bias);
  wc1_prep_kernel<<<(147456 + 255) / 256, 256, 0, stream>>>(c1_w, wc1b);
  f2b4_kernel<<<(393216 / 4 + 255) / 256, 256, 0, stream>>>(vp_w, vp_wb, 393216 / 4);
  f2b4_kernel<<<(393216 / 4 + 255) / 256, 256, 0, stream>>>(op_w, op_wb, 393216 / 4);
  f2b4_kernel<<<(1572864 / 4 + 255) / 256, 256, 0, stream>>>(l1_w, l1_wb, 1572864 / 4);
  f2b4_kernel<<<(1572864 / 4 + 255) / 256, 256, 0, stream>>>(l2_w, l2_wb, 1572864 / 4);

  // 1) input proj
  for (int l = 0; l < 4; ++l) {
    dim3 grid(CDIM / 64, HWs[l] / 64 > 0 ? HWs[l] / 64 : 1, BATCH);
    gemm_f32_at_kernel<<<grid, 256, 0, stream>>>(
        f[l], proj_w + (size_t)l * CDIM * CDIM, proj_b + l * CDIM,
        x + (size_t)STs[l] * CDIM, HWs[l], CDIM, CDIM,
        (long)CDIM * HWs[l], (long)LQ * CDIM);
  }
  // 2) pos embed + ref (before gn_apply, which consumes pos)
  pos_embed_kernel<<<(LQ * CDIM + 255) / 256, 256, 0, stream>>>(level_embed, pos);
  ref_kernel<<<(LQ + 255) / 256, 256, 0, stream>>>(refb);
  // 3) GroupNorm (+ bf16 shadow + qb)
  gn_stats_kernel<<<dim3(32, 4, BATCH), 256, 0, stream>>>(x, stats);
  {
    int n = BATCH * LQ * CDIM;
    gn_apply_kernel<<<(n + 255) / 256, 256, 0, stream>>>(x, xb, qb, pos, stats,
                                                         gn_w, gn_b);
  }

  const int M = BATCH * LQ;  // 10880 = 85 * 128
  for (int i = 0; i < 6; ++i) {
    const __hip_bfloat16* sowa = sowa_wb + (size_t)i * 98304;
    const __hip_bfloat16* vw = vp_wb + (size_t)i * 65536;
    const __hip_bfloat16* ow = op_wb + (size_t)i * 65536;
    const __hip_bfloat16* w1 = l1_wb + (size_t)i * 262144;
    const __hip_bfloat16* w2 = l2_wb + (size_t)i * 262144;
    const float* vb = vp_b + (size_t)i * CDIM;
    const float* ob = op_b + (size_t)i * CDIM;
    const float* b1 = l1_b + (size_t)i * FFDIM;
    const float* b2 = l2_b + (size_t)i * CDIM;

    gemm_bf16_kernel<false, false, true><<<dim3(2, 85), 256, 0, stream>>>(
        xb, vw, vb, nullptr, valb, M, CDIM, CDIM);
    gemm_bf16_kernel<false, true, false><<<dim3(3, 85), 256, 0, stream>>>(
        qb, sowa, sowa_bias + i * 384, comb, nullptr, M, 384, CDIM);
    deform_attn_kernel<<<BATCH * LQ * 8 / 32, 256, 0, stream>>>(valb, comb, refb,
                                                                attnb);
    gemm_bf16_kernel<false, true, false><<<dim3(2, 85), 256, 0, stream>>>(
        attnb, ow, ob, tmp, nullptr, M, CDIM, CDIM);
    add_ln_kernel<false><<<M / 4, 256, 0, stream>>>(
        x, xb, nullptr, nullptr, tmp, n1_w + (size_t)i * CDIM, n1_b + (size_t)i * CDIM);
    gemm_bf16_kernel<true, false, true><<<dim3(8, 85), 256, 0, stream>>>(
        xb, w1, b1, nullptr, ff1b, M, FFDIM, CDIM);
    gemm_bf16_kernel<false, true, false><<<dim3(2, 85), 256, 0, stream>>>(
        ff1b, w2, b2, tmp, nullptr, M, CDIM, FFDIM);
    add_ln_kernel<true><<<M / 4, 256, 0, stream>>>(
        x, xb, qb, pos, tmp, n2_w + (size_t)i * CDIM, n2_b + (size_t)i * CDIM);
  }

  // head: conv1 (implicit MFMA GEMM from xb), conv2 NHWC, upsample
  conv1_mfma_kernel<<<64, 256, 0, stream>>>(xb, wc1b, c1_b,
                                            (const __hip_bfloat16*)zerof, c1ob);
  conv2_part_kernel<<<dim3(16, 9, BATCH), 256, 0, stream>>>(c1ob, c2_w, part2);
  conv2_reduce_kernel<<<(BATCH * 4096 + 255) / 256, 256, 0, stream>>>(part2, c2_b,
                                                                      c2o);
  {
    int n = BATCH * 2 * 256 * 256;
    upsample_kernel<<<(n + 255) / 256, 256, 0, stream>>>(c2o, (float*)d_out);
  }
}

// Round 7
// 782.729 us; speedup vs baseline: 4.1761x; 1.2217x over previous
//
#include <hip/hip_runtime.h>
#include <hip/hip_bf16.h>
#include <math.h>

#define LQ 5440
#define CDIM 256
#define BATCH 2
#define FFDIM 1024

typedef __attribute__((ext_vector_type(8))) short bf16x8;
typedef __attribute__((ext_vector_type(4))) float f32x4;

typedef __attribute__((address_space(1))) void* gas1_t;
typedef __attribute__((address_space(3))) void* las3_t;

__device__ __forceinline__ void async16(const void* g, void* l) {
  __builtin_amdgcn_global_load_lds((gas1_t)g, (las3_t)l, 16, 0, 0);
}

#define WAIT_VM4() asm volatile("s_waitcnt vmcnt(4)" ::: "memory")
#define WAIT_VM0() asm volatile("s_waitcnt vmcnt(0)" ::: "memory")

// ---------------------------------------------------------------------------
// bf16 MFMA GEMM, 3-buffer depth-2 pipelined (counted vmcnt, 1 barrier/iter).
// C[M,N] = act(A @ Wt^T + bias), A:[M,K] bf16, Wt:[N,K] bf16.
// M % 128 == 0, N % 128 == 0, K % 32 == 0, K >= 64.
// ---------------------------------------------------------------------------
template <bool RELU, bool OUT_F32, bool OUT_B16>
__global__ __launch_bounds__(256, 2) void gemm_bf16_kernel(
    const __hip_bfloat16* __restrict__ A, const __hip_bfloat16* __restrict__ Wt,
    const float* __restrict__ bias, float* __restrict__ C,
    __hip_bfloat16* __restrict__ Cb, int M, int N, int K) {
  __shared__ __hip_bfloat16 As[3][128 * 32];
  __shared__ __hip_bfloat16 Bs[3][128 * 32];
  const int tid = threadIdx.x;
  const int bm = blockIdx.y * 128, bn = blockIdx.x * 128;
  const int lane = tid & 63, wave = tid >> 6;
  const int wr = wave >> 1, wc = wave & 1;
  const int srow = tid >> 2;
  const int scol = (tid & 3) * 8;
  const int lo0 = srow * 32 + scol;
  const int lo1 = (64 + srow) * 32 + scol;
  const __hip_bfloat16* ga0 = A + (size_t)(bm + srow) * K + scol;
  const __hip_bfloat16* ga1 = A + (size_t)(bm + 64 + srow) * K + scol;
  const __hip_bfloat16* gb0 = Wt + (size_t)(bn + srow) * K + scol;
  const __hip_bfloat16* gb1 = Wt + (size_t)(bn + 64 + srow) * K + scol;

  const int nt = K >> 5;
  // prologue: stage tiles 0 and 1
  async16(ga0, &As[0][lo0]);
  async16(ga1, &As[0][lo1]);
  async16(gb0, &Bs[0][lo0]);
  async16(gb1, &Bs[0][lo1]);
  async16(ga0 + 32, &As[1][lo0]);
  async16(ga1 + 32, &As[1][lo1]);
  async16(gb0 + 32, &Bs[1][lo0]);
  async16(gb1 + 32, &Bs[1][lo1]);

  f32x4 acc[4][4] = {};
  const int fr = lane & 15;
  const int ksub = (lane >> 4) * 8;

  int cur = 0, nxt = 2;
  for (int t = 0; t < nt; ++t) {
    if (t == nt - 1) WAIT_VM0(); else WAIT_VM4();
    __builtin_amdgcn_s_barrier();
    asm volatile("" ::: "memory");
    bf16x8 af[4], bfv[4];
    const __hip_bfloat16* as = As[cur];
    const __hip_bfloat16* bs = Bs[cur];
#pragma unroll
    for (int mi = 0; mi < 4; ++mi)
      af[mi] = *(const bf16x8*)&as[(wr * 64 + mi * 16 + fr) * 32 + ksub];
#pragma unroll
    for (int nj = 0; nj < 4; ++nj)
      bfv[nj] = *(const bf16x8*)&bs[(wc * 64 + nj * 16 + fr) * 32 + ksub];
    if (t + 2 < nt) {
      const int ko = (t + 2) * 32;
      async16(ga0 + ko, &As[nxt][lo0]);
      async16(ga1 + ko, &As[nxt][lo1]);
      async16(gb0 + ko, &Bs[nxt][lo0]);
      async16(gb1 + ko, &Bs[nxt][lo1]);
    }
#pragma unroll
    for (int mi = 0; mi < 4; ++mi)
#pragma unroll
      for (int nj = 0; nj < 4; ++nj)
        acc[mi][nj] = __builtin_amdgcn_mfma_f32_16x16x32_bf16(af[mi], bfv[nj],
                                                              acc[mi][nj], 0, 0, 0);
    cur = (cur == 2) ? 0 : cur + 1;
    nxt = (nxt == 2) ? 0 : nxt + 1;
  }

  const int cc = lane & 15;
  const int rbase = (lane >> 4) * 4;
  float bcol[4];
#pragma unroll
  for (int nj = 0; nj < 4; ++nj) bcol[nj] = bias[bn + wc * 64 + nj * 16 + cc];
#pragma unroll
  for (int mi = 0; mi < 4; ++mi)
#pragma unroll
    for (int nj = 0; nj < 4; ++nj) {
      int col = bn + wc * 64 + nj * 16 + cc;
#pragma unroll
      for (int r = 0; r < 4; ++r) {
        int row = bm + wr * 64 + mi * 16 + rbase + r;
        float v = acc[mi][nj][r] + bcol[nj];
        if (RELU) v = fmaxf(v, 0.f);
        if (OUT_F32) C[(size_t)row * N + col] = v;
        if (OUT_B16) Cb[(size_t)row * N + col] = __float2bfloat16(v);
      }
    }
}

// ---------------------------------------------------------------------------
// conv1 as implicit GEMM (NHWC): out[pix, oc] = relu(sum_k A[pix,k] W[oc,k] + b)
// ---------------------------------------------------------------------------
__global__ __launch_bounds__(256, 2) void conv1_mfma_kernel(
    const __hip_bfloat16* __restrict__ xb, const __hip_bfloat16* __restrict__ wc1,
    const float* __restrict__ bias, const __hip_bfloat16* __restrict__ zerob,
    __hip_bfloat16* __restrict__ c1o) {
  __shared__ __hip_bfloat16 As[128 * 32];
  __shared__ __hip_bfloat16 Bs[64 * 32];
  const int tid = threadIdx.x;
  const int b = blockIdx.x >> 5;
  const int pm = (blockIdx.x & 31) * 128;
  const int lane = tid & 63, wave = tid >> 6;
  const int sr = tid >> 2;
  const int sc = (tid & 3) * 8;
  __hip_bfloat16* la0 = &As[sr * 32 + sc];
  __hip_bfloat16* la1 = &As[(64 + sr) * 32 + sc];
  __hip_bfloat16* lb = &Bs[sr * 32 + sc];
  f32x4 acc[2][4] = {};
  const int fr = lane & 15, ksub = (lane >> 4) * 8;

  for (int tap = 0; tap < 9; ++tap) {
    const int dy = tap / 3 - 1, dx = tap % 3 - 1;
    int hw0 = pm + sr;
    int y0 = (hw0 >> 6) + dy, x0 = (hw0 & 63) + dx;
    bool ok0 = (y0 >= 0 && y0 < 64 && x0 >= 0 && x0 < 64);
    const __hip_bfloat16* s0 = xb + ((size_t)(b * LQ) + y0 * 64 + x0) * 256 + sc;
    int hw1 = pm + 64 + sr;
    int y1 = (hw1 >> 6) + dy, x1 = (hw1 & 63) + dx;
    bool ok1 = (y1 >= 0 && y1 < 64 && x1 >= 0 && x1 < 64);
    const __hip_bfloat16* s1 = xb + ((size_t)(b * LQ) + y1 * 64 + x1) * 256 + sc;
    const __hip_bfloat16* wsrc = wc1 + (size_t)sr * 2304 + tap * 256 + sc;
    for (int kk = 0; kk < 256; kk += 32) {
      async16(ok0 ? s0 + kk : zerob, la0);
      async16(ok1 ? s1 + kk : zerob, la1);
      async16(wsrc + kk, lb);
      __syncthreads();
      bf16x8 af[2], bfv[4];
#pragma unroll
      for (int mi = 0; mi < 2; ++mi)
        af[mi] = *(const bf16x8*)&As[(wave * 32 + mi * 16 + fr) * 32 + ksub];
#pragma unroll
      for (int nj = 0; nj < 4; ++nj)
        bfv[nj] = *(const bf16x8*)&Bs[(nj * 16 + fr) * 32 + ksub];
#pragma unroll
      for (int mi = 0; mi < 2; ++mi)
#pragma unroll
        for (int nj = 0; nj < 4; ++nj)
          acc[mi][nj] = __builtin_amdgcn_mfma_f32_16x16x32_bf16(
              af[mi], bfv[nj], acc[mi][nj], 0, 0, 0);
      __syncthreads();
    }
  }
  const int cc = lane & 15;
  const int rbase = (lane >> 4) * 4;
#pragma unroll
  for (int mi = 0; mi < 2; ++mi)
#pragma unroll
    for (int nj = 0; nj < 4; ++nj) {
      int col = nj * 16 + cc;
      float bb = bias[col];
#pragma unroll
      for (int r = 0; r < 4; ++r) {
        int row = wave * 32 + mi * 16 + rbase + r;
        float v = fmaxf(acc[mi][nj][r] + bb, 0.f);
        c1o[(size_t)(b * 4096 + pm + row) * 64 + col] = __float2bfloat16(v);
      }
    }
}

// fp32 -> bf16 bulk convert (n % 4 == 0)
__global__ void f2b4_kernel(const float* __restrict__ in,
                            __hip_bfloat16* __restrict__ out, int n4) {
  int i = blockIdx.x * 256 + threadIdx.x;
  if (i >= n4) return;
  float4 v = ((const float4*)in)[i];
  union { ushort4 u; __hip_bfloat16 h[4]; } p;
  p.h[0] = __float2bfloat16(v.x);
  p.h[1] = __float2bfloat16(v.y);
  p.h[2] = __float2bfloat16(v.z);
  p.h[3] = __float2bfloat16(v.w);
  ((ushort4*)out)[i] = p.u;
}

// combined so+aw weight staging: [6][384][256] bf16
__global__ void sowa_prep_kernel(const float* __restrict__ so_w,
                                 const float* __restrict__ aw_w,
                                 __hip_bfloat16* __restrict__ out) {
  int i = blockIdx.x * 256 + threadIdx.x;
  if (i >= 6 * 384 * 256) return;
  int il = i / (384 * 256);
  int rem = i - il * 384 * 256;
  int n = rem >> 8, k = rem & 255;
  float v = (n < 256) ? so_w[(size_t)il * 65536 + n * 256 + k]
                      : aw_w[(size_t)il * 32768 + (n - 256) * 256 + k];
  out[i] = __float2bfloat16(v);
}

__global__ void sowa_bias_prep_kernel(const float* __restrict__ so_b,
                                      const float* __restrict__ aw_b,
                                      float* __restrict__ out) {
  int i = blockIdx.x * 256 + threadIdx.x;
  if (i >= 6 * 384) return;
  int il = i / 384, n = i % 384;
  out[i] = (n < 256) ? so_b[il * 256 + n] : aw_b[il * 128 + n - 256];
}

// conv1 weight staging: wc1[oc][tap*256+ic] = bf16(c1_w[oc][ic][tap])
__global__ void wc1_prep_kernel(const float* __restrict__ w,
                                __hip_bfloat16* __restrict__ out) {
  int i = blockIdx.x * 256 + threadIdx.x;
  if (i >= 64 * 2304) return;
  int oc = i / 2304, r = i % 2304;
  int tap = r >> 8, ic = r & 255;
  out[i] = __float2bfloat16(w[(size_t)oc * 2304 + ic * 9 + tap]);
}

// ---------------------------------------------------------------------------
// fp32 tiled GEMM (input_proj only): A:[K,M] row-major, W:[N,K].
// ---------------------------------------------------------------------------
__global__ __launch_bounds__(256) void gemm_f32_at_kernel(
    const float* __restrict__ A, const float* __restrict__ W,
    const float* __restrict__ bias, float* __restrict__ C,
    int M, int N, int K, long bsA, long bsC) {
  __shared__ __align__(16) float As[16][72];
  __shared__ __align__(16) float Ws[16][72];
  const int tid = threadIdx.x;
  const int bm = blockIdx.y * 64, bn = blockIdx.x * 64;
  A += (size_t)blockIdx.z * bsA;
  C += (size_t)blockIdx.z * bsC;
  const int tx = tid & 15, ty = tid >> 4;
  float acc[4][4] = {};
  for (int k0 = 0; k0 < K; k0 += 16) {
#pragma unroll
    for (int i = 0; i < 4; ++i) {
      int idx = tid + i * 256;
      int k = idx >> 6, m = idx & 63;
      As[k][m] = A[(size_t)(k0 + k) * M + bm + m];
      int n = idx >> 4, k2 = idx & 15;
      Ws[k2][n] = W[(size_t)(bn + n) * K + k0 + k2];
    }
    __syncthreads();
#pragma unroll
    for (int k = 0; k < 16; ++k) {
      const float4 av = *(const float4*)&As[k][ty * 4];
      const float4 bv = *(const float4*)&Ws[k][tx * 4];
      const float a4[4] = {av.x, av.y, av.z, av.w};
      const float b4[4] = {bv.x, bv.y, bv.z, bv.w};
#pragma unroll
      for (int i = 0; i < 4; ++i)
#pragma unroll
        for (int j = 0; j < 4; ++j) acc[i][j] = fmaf(a4[i], b4[j], acc[i][j]);
    }
    __syncthreads();
  }
  const float4 bv4 = *(const float4*)&bias[bn + tx * 4];
  const float bb[4] = {bv4.x, bv4.y, bv4.z, bv4.w};
#pragma unroll
  for (int i = 0; i < 4; ++i) {
    float4 o;
    float* op = (float*)&o;
#pragma unroll
    for (int j = 0; j < 4; ++j) op[j] = acc[i][j] + bb[j];
    *(float4*)&C[(size_t)(bm + ty * 4 + i) * N + bn + tx * 4] = o;
  }
}

// ---------------------------------------------------------------------------
__device__ __forceinline__ void get_level(int t, int& l, int& hw, int& Hl, int& Wl) {
  if (t < 4096)      { l = 0; hw = t;        Hl = 64; Wl = 64; }
  else if (t < 5120) { l = 1; hw = t - 4096; Hl = 32; Wl = 32; }
  else if (t < 5376) { l = 2; hw = t - 5120; Hl = 16; Wl = 16; }
  else               { l = 3; hw = t - 5376; Hl = 8;  Wl = 8;  }
}

__global__ __launch_bounds__(256) void gn_stats_kernel(const float* __restrict__ x,
                                                       float2* __restrict__ stats) {
  const int HWs[4] = {4096, 1024, 256, 64};
  const int STs[4] = {0, 4096, 5120, 5376};
  int g = blockIdx.x, l = blockIdx.y, b = blockIdx.z;
  int HW = HWs[l];
  size_t base = ((size_t)b * LQ + STs[l]) * CDIM + g * 8;
  float s = 0.f, ss = 0.f;
  for (int i = threadIdx.x; i < HW * 8; i += 256) {
    int hw = i >> 3, ci = i & 7;
    float v = x[base + (size_t)hw * CDIM + ci];
    s += v; ss += v * v;
  }
#pragma unroll
  for (int o = 32; o; o >>= 1) { s += __shfl_down(s, o); ss += __shfl_down(ss, o); }
  __shared__ float rs[4], rss[4];
  int lane = threadIdx.x & 63, wid = threadIdx.x >> 6;
  if (lane == 0) { rs[wid] = s; rss[wid] = ss; }
  __syncthreads();
  if (threadIdx.x == 0) {
    s = rs[0] + rs[1] + rs[2] + rs[3];
    ss = rss[0] + rss[1] + rss[2] + rss[3];
    float n = (float)(HW * 8);
    float mu = s / n;
    float var = ss / n - mu * mu;
    stats[(b * 4 + l) * 32 + g] = make_float2(mu, rsqrtf(var + 1e-5f));
  }
}

// GN apply + bf16 shadow + qb = bf16(x + pos)
__global__ void gn_apply_kernel(float* __restrict__ x, __hip_bfloat16* __restrict__ xb,
                                __hip_bfloat16* __restrict__ qb,
                                const float* __restrict__ pos,
                                const float2* __restrict__ stats,
                                const float* __restrict__ gw, const float* __restrict__ gb) {
  int idx = blockIdx.x * 256 + threadIdx.x;
  if (idx >= BATCH * LQ * CDIM) return;
  int c = idx & 255;
  int tok = idx >> 8;
  int b = tok / LQ, t = tok % LQ;
  int l, hw, Hl, Wl;
  get_level(t, l, hw, Hl, Wl);
  float2 st = stats[(b * 4 + l) * 32 + (c >> 3)];
  float v = (x[idx] - st.x) * st.y * gw[l * CDIM + c] + gb[l * CDIM + c];
  x[idx] = v;
  xb[idx] = __float2bfloat16(v);
  qb[idx] = __float2bfloat16(v + pos[t * 256 + c]);
}

__global__ void pos_embed_kernel(const float* __restrict__ level_embed,
                                 float* __restrict__ pos) {
  int idx = blockIdx.x * 256 + threadIdx.x;
  if (idx >= LQ * CDIM) return;
  int t = idx >> 8, c = idx & 255;
  int l, hw, Hl, Wl;
  get_level(t, l, hw, Hl, Wl);
  int y = hw / Wl, xx = hw % Wl;
  const float twopi = 6.28318530717958647692f;
  float v; int cc;
  if (c < 128) { v = (float)(y + 1) * twopi / ((float)Hl + 1e-6f); cc = c; }
  else         { v = (float)(xx + 1) * twopi / ((float)Wl + 1e-6f); cc = c - 128; }
  int k = cc >> 1;
  float dim_t = expf((float)k * (logf(10000.0f) / 64.0f));
  float p = v / dim_t;
  float e = (cc & 1) ? cosf(p) : sinf(p);
  pos[idx] = e + level_embed[l * CDIM + c];
}

__global__ void ref_kernel(float* __restrict__ ref) {
  int t = blockIdx.x * 256 + threadIdx.x;
  if (t >= LQ) return;
  int l, hw, Hl, Wl;
  get_level(t, l, hw, Hl, Wl);
  int y = hw / Wl, xx = hw % Wl;
  ref[t * 2]     = ((float)xx + 0.5f) / (float)Wl;
  ref[t * 2 + 1] = ((float)y + 0.5f) / (float)Hl;
}

// ---------------------------------------------------------------------------
// Deformable attention: 8-lane group per (token, head); branchless bilinear,
// 4 corner loads issued unconditionally (clamped addr, validity in weights).
// ---------------------------------------------------------------------------
__global__ __launch_bounds__(256) void deform_attn_kernel(
    const __hip_bfloat16* __restrict__ value, const float* __restrict__ comb,
    const float* __restrict__ ref, __hip_bfloat16* __restrict__ out) {
  const int Wl_[4] = {64, 32, 16, 8};
  const int st_[4] = {0, 4096, 5120, 5376};
  int gid = blockIdx.x * 32 + (threadIdx.x >> 3);
  int lane8 = threadIdx.x & 7;
  int h = gid & 7;
  int tok = gid >> 3;
  int b = tok / LQ;
  int qi = tok - b * LQ;

  const float4* awv = (const float4*)(comb + (size_t)tok * 384 + 256 + h * 16);
  float4 q0 = awv[0], q1 = awv[1], q2 = awv[2], q3 = awv[3];
  float logit[16] = {q0.x, q0.y, q0.z, q0.w, q1.x, q1.y, q1.z, q1.w,
                     q2.x, q2.y, q2.z, q2.w, q3.x, q3.y, q3.z, q3.w};
  float mx = -1e30f;
#pragma unroll
  for (int i = 0; i < 16; ++i) mx = fmaxf(mx, logit[i]);
  const float LOG2E = 1.4426950408889634f;
  float ssum = 0.f;
#pragma unroll
  for (int i = 0; i < 16; ++i) {
    logit[i] = exp2f((logit[i] - mx) * LOG2E);
    ssum += logit[i];
  }
  float inv = 1.0f / ssum;

  float rx = ref[qi * 2], ry = ref[qi * 2 + 1];
  const float4* offv = (const float4*)(comb + (size_t)tok * 384 + h * 32);
  float acc0 = 0.f, acc1 = 0.f, acc2 = 0.f, acc3 = 0.f;

#pragma unroll
  for (int l = 0; l < 4; ++l) {
    const int Wl = Wl_[l];
    const float fW = (float)Wl;
    const __hip_bfloat16* vbase =
        value + ((size_t)b * LQ + st_[l]) * CDIM + h * 32 + lane8 * 4;
    float bx = fmaf(rx, fW, -0.5f);
    float by = fmaf(ry, fW, -0.5f);
    float4 oa = offv[l * 2], ob = offv[l * 2 + 1];
    float oxs[4] = {oa.x, oa.z, ob.x, ob.z};
    float oys[4] = {oa.y, oa.w, ob.y, ob.w};
#pragma unroll
    for (int p = 0; p < 4; ++p) {
      float px = bx + oxs[p], py = by + oys[p];
      float wgt = logit[l * 4 + p] * inv;
      float fpx = floorf(px), fpy = floorf(py);
      int x0 = (int)fpx, y0 = (int)fpy;
      float fx = px - fpx, fy = py - fpy;
      // validity folded into per-axis weights; addresses clamped
      float wx0 = (x0 >= 0 && x0 < Wl) ? (1.f - fx) : 0.f;
      float wx1 = (x0 >= -1 && x0 < Wl - 1) ? fx : 0.f;
      float wy0 = (y0 >= 0 && y0 < Wl) ? (wgt * (1.f - fy)) : 0.f;
      float wy1 = (y0 >= -1 && y0 < Wl - 1) ? (wgt * fy) : 0.f;
      int xc0 = min(max(x0, 0), Wl - 1);
      int xc1 = min(max(x0 + 1, 0), Wl - 1);
      int yc0 = min(max(y0, 0), Wl - 1);
      int yc1 = min(max(y0 + 1, 0), Wl - 1);
      const __hip_bfloat16* r0 = vbase + (size_t)(yc0 * Wl) * CDIM;
      const __hip_bfloat16* r1 = vbase + (size_t)(yc1 * Wl) * CDIM;
      ushort4 u00 = *(const ushort4*)(r0 + (size_t)xc0 * CDIM);
      ushort4 u01 = *(const ushort4*)(r0 + (size_t)xc1 * CDIM);
      ushort4 u10 = *(const ushort4*)(r1 + (size_t)xc0 * CDIM);
      ushort4 u11 = *(const ushort4*)(r1 + (size_t)xc1 * CDIM);
      float w00 = wy0 * wx0, w01 = wy0 * wx1, w10 = wy1 * wx0, w11 = wy1 * wx1;
      acc0 = fmaf(w00, __uint_as_float((unsigned)u00.x << 16), acc0);
      acc1 = fmaf(w00, __uint_as_float((unsigned)u00.y << 16), acc1);
      acc2 = fmaf(w00, __uint_as_float((unsigned)u00.z << 16), acc2);
      acc3 = fmaf(w00, __uint_as_float((unsigned)u00.w << 16), acc3);
      acc0 = fmaf(w01, __uint_as_float((unsigned)u01.x << 16), acc0);
      acc1 = fmaf(w01, __uint_as_float((unsigned)u01.y << 16), acc1);
      acc2 = fmaf(w01, __uint_as_float((unsigned)u01.z << 16), acc2);
      acc3 = fmaf(w01, __uint_as_float((unsigned)u01.w << 16), acc3);
      acc0 = fmaf(w10, __uint_as_float((unsigned)u10.x << 16), acc0);
      acc1 = fmaf(w10, __uint_as_float((unsigned)u10.y << 16), acc1);
      acc2 = fmaf(w10, __uint_as_float((unsigned)u10.z << 16), acc2);
      acc3 = fmaf(w10, __uint_as_float((unsigned)u10.w << 16), acc3);
      acc0 = fmaf(w11, __uint_as_float((unsigned)u11.x << 16), acc0);
      acc1 = fmaf(w11, __uint_as_float((unsigned)u11.y << 16), acc1);
      acc2 = fmaf(w11, __uint_as_float((unsigned)u11.z << 16), acc2);
      acc3 = fmaf(w11, __uint_as_float((unsigned)u11.w << 16), acc3);
    }
  }
  union { ushort4 u; __hip_bfloat16 hh[4]; } pk;
  pk.hh[0] = __float2bfloat16(acc0);
  pk.hh[1] = __float2bfloat16(acc1);
  pk.hh[2] = __float2bfloat16(acc2);
  pk.hh[3] = __float2bfloat16(acc3);
  *(ushort4*)(out + (size_t)tok * CDIM + h * 32 + lane8 * 4) = pk.u;
}

// x = LayerNorm(x + r); writes fp32 x, bf16 xb, optionally qb = bf16(x+pos).
template <bool EMIT_Q>
__global__ __launch_bounds__(256) void add_ln_kernel(
    float* __restrict__ x, __hip_bfloat16* __restrict__ xb,
    __hip_bfloat16* __restrict__ qb, const float* __restrict__ pos,
    const float* __restrict__ r, const float* __restrict__ w,
    const float* __restrict__ b) {
  int wid = threadIdx.x >> 6, lane = threadIdx.x & 63;
  size_t tok = (size_t)blockIdx.x * 4 + wid;
  size_t base = tok * CDIM + lane * 4;
  float4 xv = *(const float4*)&x[base];
  float4 rv = *(const float4*)&r[base];
  float v[4] = {xv.x + rv.x, xv.y + rv.y, xv.z + rv.z, xv.w + rv.w};
  float s = v[0] + v[1] + v[2] + v[3];
  float ss = v[0] * v[0] + v[1] * v[1] + v[2] * v[2] + v[3] * v[3];
#pragma unroll
  for (int o = 1; o < 64; o <<= 1) { s += __shfl_xor(s, o); ss += __shfl_xor(ss, o); }
  float mu = s * (1.0f / 256.0f);
  float var = ss * (1.0f / 256.0f) - mu * mu;
  float rsig = rsqrtf(var + 1e-5f);
  int c = lane * 4;
  float4 wv = *(const float4*)&w[c];
  float4 bv = *(const float4*)&b[c];
  float4 o4;
  o4.x = (v[0] - mu) * rsig * wv.x + bv.x;
  o4.y = (v[1] - mu) * rsig * wv.y + bv.y;
  o4.z = (v[2] - mu) * rsig * wv.z + bv.z;
  o4.w = (v[3] - mu) * rsig * wv.w + bv.w;
  *(float4*)&x[base] = o4;
  union { ushort4 u; __hip_bfloat16 h[4]; } pk;
  pk.h[0] = __float2bfloat16(o4.x);
  pk.h[1] = __float2bfloat16(o4.y);
  pk.h[2] = __float2bfloat16(o4.z);
  pk.h[3] = __float2bfloat16(o4.w);
  *(ushort4*)&xb[base] = pk.u;
  if (EMIT_Q) {
    int t = (int)(tok >= LQ ? tok - LQ : tok);
    float4 pv = *(const float4*)&pos[(size_t)t * CDIM + c];
    union { ushort4 u; __hip_bfloat16 h[4]; } pq;
    pq.h[0] = __float2bfloat16(o4.x + pv.x);
    pq.h[1] = __float2bfloat16(o4.y + pv.y);
    pq.h[2] = __float2bfloat16(o4.z + pv.z);
    pq.h[3] = __float2bfloat16(o4.w + pv.w);
    *(ushort4*)&qb[base] = pq.u;
  }
}

// conv2 NHWC split over taps: part[tap][b][pix][2]
__global__ __launch_bounds__(256) void conv2_part_kernel(
    const __hip_bfloat16* __restrict__ c1o, const float* __restrict__ w,
    float* __restrict__ part) {
  int pix = blockIdx.x * 256 + threadIdx.x;
  int tap = blockIdx.y, b = blockIdx.z;
  int y = pix >> 6, x = pix & 63;
  int dy = tap / 3 - 1, dx = tap % 3 - 1;
  int yy = y + dy, xx = x + dx;
  bool ok = (yy >= 0 && yy < 64 && xx >= 0 && xx < 64);
  float a0 = 0.f, a1 = 0.f;
  if (ok) {
    const __hip_bfloat16* row = c1o + (size_t)(b * 4096 + yy * 64 + xx) * 64;
#pragma unroll
    for (int ic4 = 0; ic4 < 16; ++ic4) {
      ushort4 u = *(const ushort4*)(row + ic4 * 4);
      float f0 = __uint_as_float((unsigned)u.x << 16);
      float f1 = __uint_as_float((unsigned)u.y << 16);
      float f2 = __uint_as_float((unsigned)u.z << 16);
      float f3 = __uint_as_float((unsigned)u.w << 16);
      int ic = ic4 * 4;
      a0 = fmaf(w[(ic + 0) * 9 + tap], f0, a0);
      a0 = fmaf(w[(ic + 1) * 9 + tap], f1, a0);
      a0 = fmaf(w[(ic + 2) * 9 + tap], f2, a0);
      a0 = fmaf(w[(ic + 3) * 9 + tap], f3, a0);
      a1 = fmaf(w[576 + (ic + 0) * 9 + tap], f0, a1);
      a1 = fmaf(w[576 + (ic + 1) * 9 + tap], f1, a1);
      a1 = fmaf(w[576 + (ic + 2) * 9 + tap], f2, a1);
      a1 = fmaf(w[576 + (ic + 3) * 9 + tap], f3, a1);
    }
  }
  float2 o = make_float2(a0, a1);
  *(float2*)&part[((size_t)(tap * BATCH + b) * 4096 + pix) * 2] = o;
}

// sum 9 taps + bias -> c2o [b][pix][2]
__global__ void conv2_reduce_kernel(const float* __restrict__ part,
                                    const float* __restrict__ bias,
                                    float* __restrict__ out) {
  int i = blockIdx.x * 256 + threadIdx.x;
  if (i >= BATCH * 4096) return;
  int b = i >> 12, pix = i & 4095;
  float s0 = bias[0], s1 = bias[1];
#pragma unroll
  for (int tap = 0; tap < 9; ++tap) {
    float2 v = *(const float2*)&part[((size_t)(tap * BATCH + b) * 4096 + pix) * 2];
    s0 += v.x; s1 += v.y;
  }
  *(float2*)&out[(size_t)i * 2] = make_float2(s0, s1);
}

// 4x bilinear upsample 64->256; input layout [b][pix][2]
__global__ void upsample_kernel(const float* __restrict__ in, float* __restrict__ out) {
  int idx = blockIdx.x * 256 + threadIdx.x;
  if (idx >= BATCH * 2 * 256 * 256) return;
  int X = idx & 255, Y = (idx >> 8) & 255, p = idx >> 16;
  int b = p >> 1, oc = p & 1;
  float tx = ((float)X + 0.5f) * 0.25f - 0.5f;
  float ty = ((float)Y + 0.5f) * 0.25f - 0.5f;
  float fxf = floorf(tx), fyf = floorf(ty);
  int x0 = (int)fxf, y0 = (int)fyf;
  float fx = tx - fxf, fy = ty - fyf;
  int x0c = min(max(x0, 0), 63), x1c = min(max(x0 + 1, 0), 63);
  int y0c = min(max(y0, 0), 63), y1c = min(max(y0 + 1, 0), 63);
  const float* ip = in + (size_t)b * 4096 * 2 + oc;
  float v = (1.f - fy) * ((1.f - fx) * ip[(y0c * 64 + x0c) * 2] + fx * ip[(y0c * 64 + x1c) * 2]) +
            fy * ((1.f - fx) * ip[(y1c * 64 + x0c) * 2] + fx * ip[(y1c * 64 + x1c) * 2]);
  out[idx] = v;
}

// ---------------------------------------------------------------------------
extern "C" void kernel_launch(void* const* d_in, const int* in_sizes, int n_in,
                              void* d_out, int out_size, void* d_ws, size_t ws_size,
                              hipStream_t stream) {
  const float* f[4] = {(const float*)d_in[0], (const float*)d_in[1],
                       (const float*)d_in[2], (const float*)d_in[3]};
  const float* proj_w = (const float*)d_in[4];
  const float* proj_b = (const float*)d_in[5];
  const float* gn_w = (const float*)d_in[6];
  const float* gn_b = (const float*)d_in[7];
  const float* level_embed = (const float*)d_in[8];
  const float* so_w = (const float*)d_in[9];
  const float* so_b = (const float*)d_in[10];
  const float* aw_w = (const float*)d_in[11];
  const float* aw_b = (const float*)d_in[12];
  const float* vp_w = (const float*)d_in[13];
  const float* vp_b = (const float*)d_in[14];
  const float* op_w = (const float*)d_in[15];
  const float* op_b = (const float*)d_in[16];
  const float* n1_w = (const float*)d_in[17];
  const float* n1_b = (const float*)d_in[18];
  const float* l1_w = (const float*)d_in[19];
  const float* l1_b = (const float*)d_in[20];
  const float* l2_w = (const float*)d_in[21];
  const float* l2_b = (const float*)d_in[22];
  const float* n2_w = (const float*)d_in[23];
  const float* n2_b = (const float*)d_in[24];
  const float* c1_w = (const float*)d_in[25];
  const float* c1_b = (const float*)d_in[26];
  const float* c2_w = (const float*)d_in[27];
  const float* c2_b = (const float*)d_in[28];
  (void)in_sizes; (void)n_in; (void)out_size; (void)ws_size;

  float* ws = (float*)d_ws;
  const size_t TOK = (size_t)BATCH * LQ * CDIM;  // 2785280
  size_t o = 0;
  float* x = ws + o;     o += TOK;
  float* tmp = ws + o;   o += TOK;
  float* comb = ws + o;  o += (size_t)BATCH * LQ * 384;  // so+aw outputs
  float* pos = ws + o;   o += (size_t)LQ * CDIM;
  float* refb = ws + o;  o += 11008;
  float2* stats = (float2*)(ws + o); o += 512;
  float* zerof = ws + o; o += 256;   // 1KB zero page (bf16 view)
  float* sowa_bias = ws + o; o += 2304;
  __hip_bfloat16* xb = (__hip_bfloat16*)(ws + o);    o += TOK / 2;
  __hip_bfloat16* qb = (__hip_bfloat16*)(ws + o);    o += TOK / 2;
  __hip_bfloat16* valb = (__hip_bfloat16*)(ws + o);  o += TOK / 2;
  __hip_bfloat16* attnb = (__hip_bfloat16*)(ws + o); o += TOK / 2;
  __hip_bfloat16* ff1b = (__hip_bfloat16*)(ws + o);  o += (size_t)BATCH * LQ * FFDIM / 2;
  __hip_bfloat16* sowa_wb = (__hip_bfloat16*)(ws + o); o += 294912;
  __hip_bfloat16* vp_wb = (__hip_bfloat16*)(ws + o); o += 196608;
  __hip_bfloat16* op_wb = (__hip_bfloat16*)(ws + o); o += 196608;
  __hip_bfloat16* l1_wb = (__hip_bfloat16*)(ws + o); o += 786432;
  __hip_bfloat16* l2_wb = (__hip_bfloat16*)(ws + o); o += 786432;
  __hip_bfloat16* wc1b = (__hip_bfloat16*)(ws + o);  o += 73728;
  // head scratch aliases ff1b region (free after encoder)
  __hip_bfloat16* c1ob = ff1b;                                   // 512K bf16
  float* part2 = (float*)(ff1b + 524288);                        // 147456 f32
  float* c2o = part2 + 147456;                                   // 16384 f32

  const int HWs[4] = {4096, 1024, 256, 64};
  const int STs[4] = {0, 4096, 5120, 5376};

  // 0) staging: zero page, bf16 weights, combined so+aw
  hipMemsetAsync(zerof, 0, 1024, stream);
  sowa_prep_kernel<<<(589824 + 255) / 256, 256, 0, stream>>>(so_w, aw_w, sowa_wb);
  sowa_bias_prep_kernel<<<9, 256, 0, stream>>>(so_b, aw_b, sowa_bias);
  wc1_prep_kernel<<<(147456 + 255) / 256, 256, 0, stream>>>(c1_w, wc1b);
  f2b4_kernel<<<(393216 / 4 + 255) / 256, 256, 0, stream>>>(vp_w, vp_wb, 393216 / 4);
  f2b4_kernel<<<(393216 / 4 + 255) / 256, 256, 0, stream>>>(op_w, op_wb, 393216 / 4);
  f2b4_kernel<<<(1572864 / 4 + 255) / 256, 256, 0, stream>>>(l1_w, l1_wb, 1572864 / 4);
  f2b4_kernel<<<(1572864 / 4 + 255) / 256, 256, 0, stream>>>(l2_w, l2_wb, 1572864 / 4);

  // 1) input proj
  for (int l = 0; l < 4; ++l) {
    dim3 grid(CDIM / 64, HWs[l] / 64 > 0 ? HWs[l] / 64 : 1, BATCH);
    gemm_f32_at_kernel<<<grid, 256, 0, stream>>>(
        f[l], proj_w + (size_t)l * CDIM * CDIM, proj_b + l * CDIM,
        x + (size_t)STs[l] * CDIM, HWs[l], CDIM, CDIM,
        (long)CDIM * HWs[l], (long)LQ * CDIM);
  }
  // 2) pos embed + ref (before gn_apply, which consumes pos)
  pos_embed_kernel<<<(LQ * CDIM + 255) / 256, 256, 0, stream>>>(level_embed, pos);
  ref_kernel<<<(LQ + 255) / 256, 256, 0, stream>>>(refb);
  // 3) GroupNorm (+ bf16 shadow + qb)
  gn_stats_kernel<<<dim3(32, 4, BATCH), 256, 0, stream>>>(x, stats);
  {
    int n = BATCH * LQ * CDIM;
    gn_apply_kernel<<<(n + 255) / 256, 256, 0, stream>>>(x, xb, qb, pos, stats,
                                                         gn_w, gn_b);
  }

  const int M = BATCH * LQ;  // 10880 = 85 * 128
  for (int i = 0; i < 6; ++i) {
    const __hip_bfloat16* sowa = sowa_wb + (size_t)i * 98304;
    const __hip_bfloat16* vw = vp_wb + (size_t)i * 65536;
    const __hip_bfloat16* ow = op_wb + (size_t)i * 65536;
    const __hip_bfloat16* w1 = l1_wb + (size_t)i * 262144;
    const __hip_bfloat16* w2 = l2_wb + (size_t)i * 262144;
    const float* vb = vp_b + (size_t)i * CDIM;
    const float* ob = op_b + (size_t)i * CDIM;
    const float* b1 = l1_b + (size_t)i * FFDIM;
    const float* b2 = l2_b + (size_t)i * CDIM;

    gemm_bf16_kernel<false, false, true><<<dim3(2, 85), 256, 0, stream>>>(
        xb, vw, vb, nullptr, valb, M, CDIM, CDIM);
    gemm_bf16_kernel<false, true, false><<<dim3(3, 85), 256, 0, stream>>>(
        qb, sowa, sowa_bias + i * 384, comb, nullptr, M, 384, CDIM);
    deform_attn_kernel<<<BATCH * LQ * 8 / 32, 256, 0, stream>>>(valb, comb, refb,
                                                                attnb);
    gemm_bf16_kernel<false, true, false><<<dim3(2, 85), 256, 0, stream>>>(
        attnb, ow, ob, tmp, nullptr, M, CDIM, CDIM);
    add_ln_kernel<false><<<M / 4, 256, 0, stream>>>(
        x, xb, nullptr, nullptr, tmp, n1_w + (size_t)i * CDIM, n1_b + (size_t)i * CDIM);
    gemm_bf16_kernel<true, false, true><<<dim3(8, 85), 256, 0, stream>>>(
        xb, w1, b1, nullptr, ff1b, M, FFDIM, CDIM);
    gemm_bf16_kernel<false, true, false><<<dim3(2, 85), 256, 0, stream>>>(
        ff1b, w2, b2, tmp, nullptr, M, CDIM, FFDIM);
    add_ln_kernel<true><<<M / 4, 256, 0, stream>>>(
        x, xb, qb, pos, tmp, n2_w + (size_t)i * CDIM, n2_b + (size_t)i * CDIM);
  }

  // head: conv1 (implicit MFMA GEMM from xb), conv2 NHWC, upsample
  conv1_mfma_kernel<<<64, 256, 0, stream>>>(xb, wc1b, c1_b,
                                            (const __hip_bfloat16*)zerof, c1ob);
  conv2_part_kernel<<<dim3(16, 9, BATCH), 256, 0, stream>>>(c1ob, c2_w, part2);
  conv2_reduce_kernel<<<(BATCH * 4096 + 255) / 256, 256, 0, stream>>>(part2, c2_b,
                                                                      c2o);
  {
    int n = BATCH * 2 * 256 * 256;
    upsample_kernel<<<(n + 255) / 256, 256, 0, stream>>>(c2o, (float*)d_out);
  }
}

// Round 8
// 731.968 us; speedup vs baseline: 4.4658x; 1.0693x over previous
//
#include <hip/hip_runtime.h>
#include <hip/hip_bf16.h>
#include <math.h>

#define LQ 5440
#define CDIM 256
#define BATCH 2
#define FFDIM 1024

typedef __attribute__((ext_vector_type(8))) short bf16x8;
typedef __attribute__((ext_vector_type(4))) float f32x4;

typedef __attribute__((address_space(1))) void* gas1_t;
typedef __attribute__((address_space(3))) void* las3_t;

__device__ __forceinline__ void async16(const void* g, void* l) {
  __builtin_amdgcn_global_load_lds((gas1_t)g, (las3_t)l, 16, 0, 0);
}

#define WAIT_VM4() asm volatile("s_waitcnt vmcnt(4)" ::: "memory")
#define WAIT_VM3() asm volatile("s_waitcnt vmcnt(3)" ::: "memory")
#define WAIT_VM0() asm volatile("s_waitcnt vmcnt(0)" ::: "memory")

// chunk (0..84) -> level, row0 (64-row chunks across the 4 levels)
__device__ __forceinline__ void get_chunk(int chunk, int& l, int& row0) {
  if (chunk < 64)      { l = 0; row0 = chunk * 64; }
  else if (chunk < 80) { l = 1; row0 = (chunk - 64) * 64; }
  else if (chunk < 84) { l = 2; row0 = (chunk - 80) * 64; }
  else                 { l = 3; row0 = 0; }
}

// ---------------------------------------------------------------------------
// bf16 MFMA GEMM, 3-buffer depth-2 pipelined (counted vmcnt, 1 barrier/iter).
// C[M,N] = act(A @ Wt^T + bias). REMAP: output row r -> token-major x with
// per-batch stride (input-proj path, M = 2*HW).
// ---------------------------------------------------------------------------
template <bool RELU, bool OUT_F32, bool OUT_B16, bool REMAP>
__global__ __launch_bounds__(256, 2) void gemm_bf16_kernel(
    const __hip_bfloat16* __restrict__ A, const __hip_bfloat16* __restrict__ Wt,
    const float* __restrict__ bias, float* __restrict__ C,
    __hip_bfloat16* __restrict__ Cb, int M, int N, int K,
    int mrows, long obase, long obstride) {
  __shared__ __hip_bfloat16 As[3][128 * 32];
  __shared__ __hip_bfloat16 Bs[3][128 * 32];
  const int tid = threadIdx.x;
  const int bm = blockIdx.y * 128, bn = blockIdx.x * 128;
  const int lane = tid & 63, wave = tid >> 6;
  const int wr = wave >> 1, wc = wave & 1;
  const int srow = tid >> 2;
  const int scol = (tid & 3) * 8;
  const int lo0 = srow * 32 + scol;
  const int lo1 = (64 + srow) * 32 + scol;
  const __hip_bfloat16* ga0 = A + (size_t)(bm + srow) * K + scol;
  const __hip_bfloat16* ga1 = A + (size_t)(bm + 64 + srow) * K + scol;
  const __hip_bfloat16* gb0 = Wt + (size_t)(bn + srow) * K + scol;
  const __hip_bfloat16* gb1 = Wt + (size_t)(bn + 64 + srow) * K + scol;

  const int nt = K >> 5;
  async16(ga0, &As[0][lo0]);
  async16(ga1, &As[0][lo1]);
  async16(gb0, &Bs[0][lo0]);
  async16(gb1, &Bs[0][lo1]);
  async16(ga0 + 32, &As[1][lo0]);
  async16(ga1 + 32, &As[1][lo1]);
  async16(gb0 + 32, &Bs[1][lo0]);
  async16(gb1 + 32, &Bs[1][lo1]);

  f32x4 acc[4][4] = {};
  const int fr = lane & 15;
  const int ksub = (lane >> 4) * 8;

  int cur = 0, nxt = 2;
  for (int t = 0; t < nt; ++t) {
    if (t == nt - 1) WAIT_VM0(); else WAIT_VM4();
    __builtin_amdgcn_s_barrier();
    asm volatile("" ::: "memory");
    bf16x8 af[4], bfv[4];
    const __hip_bfloat16* as = As[cur];
    const __hip_bfloat16* bs = Bs[cur];
#pragma unroll
    for (int mi = 0; mi < 4; ++mi)
      af[mi] = *(const bf16x8*)&as[(wr * 64 + mi * 16 + fr) * 32 + ksub];
#pragma unroll
    for (int nj = 0; nj < 4; ++nj)
      bfv[nj] = *(const bf16x8*)&bs[(wc * 64 + nj * 16 + fr) * 32 + ksub];
    if (t + 2 < nt) {
      const int ko = (t + 2) * 32;
      async16(ga0 + ko, &As[nxt][lo0]);
      async16(ga1 + ko, &As[nxt][lo1]);
      async16(gb0 + ko, &Bs[nxt][lo0]);
      async16(gb1 + ko, &Bs[nxt][lo1]);
    }
#pragma unroll
    for (int mi = 0; mi < 4; ++mi)
#pragma unroll
      for (int nj = 0; nj < 4; ++nj)
        acc[mi][nj] = __builtin_amdgcn_mfma_f32_16x16x32_bf16(af[mi], bfv[nj],
                                                              acc[mi][nj], 0, 0, 0);
    cur = (cur == 2) ? 0 : cur + 1;
    nxt = (nxt == 2) ? 0 : nxt + 1;
  }

  const int cc = lane & 15;
  const int rbase = (lane >> 4) * 4;
  float bcol[4];
#pragma unroll
  for (int nj = 0; nj < 4; ++nj) bcol[nj] = bias[bn + wc * 64 + nj * 16 + cc];
#pragma unroll
  for (int mi = 0; mi < 4; ++mi)
#pragma unroll
    for (int nj = 0; nj < 4; ++nj) {
      int col = bn + wc * 64 + nj * 16 + cc;
#pragma unroll
      for (int r = 0; r < 4; ++r) {
        int row = bm + wr * 64 + mi * 16 + rbase + r;
        float v = acc[mi][nj][r] + bcol[nj];
        if (RELU) v = fmaxf(v, 0.f);
        if (OUT_F32) {
          size_t oaddr;
          if (REMAP)
            oaddr = (size_t)obase +
                    (row < mrows ? (size_t)row * N
                                 : (size_t)obstride + (size_t)(row - mrows) * N) +
                    col;
          else
            oaddr = (size_t)row * N + col;
          C[oaddr] = v;
        }
        if (OUT_B16) Cb[(size_t)row * N + col] = __float2bfloat16(v);
      }
    }
}

// ---------------------------------------------------------------------------
// conv1 implicit GEMM (NHWC), flattened 72-step pipelined K-loop.
// ---------------------------------------------------------------------------
__global__ __launch_bounds__(256, 2) void conv1_mfma_kernel(
    const __hip_bfloat16* __restrict__ xb, const __hip_bfloat16* __restrict__ wc1,
    const float* __restrict__ bias, const __hip_bfloat16* __restrict__ zerob,
    __hip_bfloat16* __restrict__ c1o) {
  __shared__ __hip_bfloat16 As[3][128 * 32];
  __shared__ __hip_bfloat16 Bs[3][64 * 32];
  const int tid = threadIdx.x;
  const int b = blockIdx.x >> 5;
  const int pm = (blockIdx.x & 31) * 128;
  const int lane = tid & 63, wave = tid >> 6;
  const int sr = tid >> 2;
  const int sc = (tid & 3) * 8;
  const int loA0 = sr * 32 + sc, loA1 = (64 + sr) * 32 + sc;
  f32x4 acc[2][4] = {};
  const int fr = lane & 15, ksub = (lane >> 4) * 8;

  auto stage = [&](int kt, int buf) {
    int tap = kt >> 3;
    int kk = (kt & 7) * 32;
    int dy = tap / 3 - 1, dx = tap % 3 - 1;
    int hw0 = pm + sr;
    int y0 = (hw0 >> 6) + dy, x0 = (hw0 & 63) + dx;
    bool ok0 = (y0 >= 0 && y0 < 64 && x0 >= 0 && x0 < 64);
    const __hip_bfloat16* s0 =
        xb + ((size_t)(b * LQ) + y0 * 64 + x0) * 256 + kk + sc;
    int hw1 = pm + 64 + sr;
    int y1 = (hw1 >> 6) + dy, x1 = (hw1 & 63) + dx;
    bool ok1 = (y1 >= 0 && y1 < 64 && x1 >= 0 && x1 < 64);
    const __hip_bfloat16* s1 =
        xb + ((size_t)(b * LQ) + y1 * 64 + x1) * 256 + kk + sc;
    const __hip_bfloat16* wsrc = wc1 + (size_t)sr * 2304 + tap * 256 + kk + sc;
    async16(ok0 ? s0 : zerob, &As[buf][loA0]);
    async16(ok1 ? s1 : zerob, &As[buf][loA1]);
    async16(wsrc, &Bs[buf][loA0]);
  };
  stage(0, 0);
  stage(1, 1);
  int cur = 0, nxt = 2;
  for (int kt = 0; kt < 72; ++kt) {
    if (kt == 71) WAIT_VM0(); else WAIT_VM3();
    __builtin_amdgcn_s_barrier();
    asm volatile("" ::: "memory");
    bf16x8 af[2], bfv[4];
#pragma unroll
    for (int mi = 0; mi < 2; ++mi)
      af[mi] = *(const bf16x8*)&As[cur][(wave * 32 + mi * 16 + fr) * 32 + ksub];
#pragma unroll
    for (int nj = 0; nj < 4; ++nj)
      bfv[nj] = *(const bf16x8*)&Bs[cur][(nj * 16 + fr) * 32 + ksub];
    if (kt + 2 < 72) stage(kt + 2, nxt);
#pragma unroll
    for (int mi = 0; mi < 2; ++mi)
#pragma unroll
      for (int nj = 0; nj < 4; ++nj)
        acc[mi][nj] = __builtin_amdgcn_mfma_f32_16x16x32_bf16(
            af[mi], bfv[nj], acc[mi][nj], 0, 0, 0);
    cur = (cur == 2) ? 0 : cur + 1;
    nxt = (nxt == 2) ? 0 : nxt + 1;
  }
  const int cc = lane & 15;
  const int rbase = (lane >> 4) * 4;
#pragma unroll
  for (int mi = 0; mi < 2; ++mi)
#pragma unroll
    for (int nj = 0; nj < 4; ++nj) {
      int col = nj * 16 + cc;
      float bb = bias[col];
#pragma unroll
      for (int r = 0; r < 4; ++r) {
        int row = wave * 32 + mi * 16 + rbase + r;
        float v = fmaxf(acc[mi][nj][r] + bb, 0.f);
        c1o[(size_t)(b * 4096 + pm + row) * 64 + col] = __float2bfloat16(v);
      }
    }
}

// fp32 -> bf16 bulk convert (n % 4 == 0)
__global__ void f2b4_kernel(const float* __restrict__ in,
                            __hip_bfloat16* __restrict__ out, int n4) {
  int i = blockIdx.x * 256 + threadIdx.x;
  if (i >= n4) return;
  float4 v = ((const float4*)in)[i];
  union { ushort4 u; __hip_bfloat16 h[4]; } p;
  p.h[0] = __float2bfloat16(v.x);
  p.h[1] = __float2bfloat16(v.y);
  p.h[2] = __float2bfloat16(v.z);
  p.h[3] = __float2bfloat16(v.w);
  ((ushort4*)out)[i] = p.u;
}

// combined so+aw weight staging: [6][384][256] bf16
__global__ void sowa_prep_kernel(const float* __restrict__ so_w,
                                 const float* __restrict__ aw_w,
                                 __hip_bfloat16* __restrict__ out) {
  int i = blockIdx.x * 256 + threadIdx.x;
  if (i >= 6 * 384 * 256) return;
  int il = i / (384 * 256);
  int rem = i - il * 384 * 256;
  int n = rem >> 8, k = rem & 255;
  float v = (n < 256) ? so_w[(size_t)il * 65536 + n * 256 + k]
                      : aw_w[(size_t)il * 32768 + (n - 256) * 256 + k];
  out[i] = __float2bfloat16(v);
}

__global__ void sowa_bias_prep_kernel(const float* __restrict__ so_b,
                                      const float* __restrict__ aw_b,
                                      float* __restrict__ out) {
  int i = blockIdx.x * 256 + threadIdx.x;
  if (i >= 6 * 384) return;
  int il = i / 384, n = i % 384;
  out[i] = (n < 256) ? so_b[il * 256 + n] : aw_b[il * 128 + n - 256];
}

// conv1 weight staging: wc1[oc][tap*256+ic] = bf16(c1_w[oc][ic][tap])
__global__ void wc1_prep_kernel(const float* __restrict__ w,
                                __hip_bfloat16* __restrict__ out) {
  int i = blockIdx.x * 256 + threadIdx.x;
  if (i >= 64 * 2304) return;
  int oc = i / 2304, r = i % 2304;
  int tap = r >> 8, ic = r & 255;
  out[i] = __float2bfloat16(w[(size_t)oc * 2304 + ic * 9 + tap]);
}

// ---------------------------------------------------------------------------
// transpose+convert: f[l][b][c][hw] fp32 -> ft (level-major) [l][b][hw][c] bf16
// ---------------------------------------------------------------------------
__global__ __launch_bounds__(256) void transpose_f_kernel(
    const float* __restrict__ f0, const float* __restrict__ f1,
    const float* __restrict__ f2, const float* __restrict__ f3,
    __hip_bfloat16* __restrict__ ft) {
  __shared__ float tile[64][65];
  const int HWs[4] = {4096, 1024, 256, 64};
  const int STs[4] = {0, 4096, 5120, 5376};
  int chunk = blockIdx.x, c0 = blockIdx.y * 64, b = blockIdx.z;
  int l, row0;
  get_chunk(chunk, l, row0);
  const float* fin = (l == 0) ? f0 : (l == 1) ? f1 : (l == 2) ? f2 : f3;
  const int HW = HWs[l];
  int t = threadIdx.x;
  int cr = t >> 4, hc4 = (t & 15) * 4;
#pragma unroll
  for (int p = 0; p < 4; ++p) {
    int c = c0 + p * 16 + cr;
    float4 v = *(const float4*)&fin[(size_t)(b * 256 + c) * HW + row0 + hc4];
    tile[p * 16 + cr][hc4 + 0] = v.x;
    tile[p * 16 + cr][hc4 + 1] = v.y;
    tile[p * 16 + cr][hc4 + 2] = v.z;
    tile[p * 16 + cr][hc4 + 3] = v.w;
  }
  __syncthreads();
  size_t obase = (size_t)2 * STs[l] * 256 + ((size_t)b * HW + row0) * 256 + c0;
#pragma unroll
  for (int p = 0; p < 4; ++p) {
    int r = p * 16 + cr;
    union { ushort4 u; __hip_bfloat16 h[4]; } pk;
    pk.h[0] = __float2bfloat16(tile[hc4 + 0][r]);
    pk.h[1] = __float2bfloat16(tile[hc4 + 1][r]);
    pk.h[2] = __float2bfloat16(tile[hc4 + 2][r]);
    pk.h[3] = __float2bfloat16(tile[hc4 + 3][r]);
    *(ushort4*)&ft[obase + (size_t)r * 256 + hc4] = pk.u;
  }
}

// ---------------------------------------------------------------------------
// GroupNorm stats, 2-stage coalesced. Stage 1: 64-row chunks -> 32 group
// partial (s, ss) per block. Stage 2: one block finalizes mu/rsig.
// ---------------------------------------------------------------------------
__global__ __launch_bounds__(256) void gn_part_kernel(const float* __restrict__ x,
                                                      float2* __restrict__ part) {
  const int STs[4] = {0, 4096, 5120, 5376};
  int chunk = blockIdx.x, b = blockIdx.y;
  int l, row0;
  get_chunk(chunk, l, row0);
  size_t base = ((size_t)b * LQ + STs[l] + row0) * 256;
  int t = threadIdx.x;
  int col4 = t & 63, rb = t >> 6;
  float s = 0.f, ss = 0.f;
#pragma unroll 4
  for (int i = 0; i < 16; ++i) {
    int r = rb + i * 4;
    float4 v = *(const float4*)&x[base + (size_t)r * 256 + col4 * 4];
    s += v.x + v.y + v.z + v.w;
    ss += v.x * v.x + v.y * v.y + v.z * v.z + v.w * v.w;
  }
  __shared__ float sA[256], sB[256];
  sA[t] = s;
  sB[t] = ss;
  __syncthreads();
  if (t < 64) {
    s = sA[t] + sA[t + 64] + sA[t + 128] + sA[t + 192];
    ss = sB[t] + sB[t + 64] + sB[t + 128] + sB[t + 192];
    sA[t] = s;
    sB[t] = ss;
  }
  __syncthreads();
  if (t < 32)
    part[((size_t)b * 85 + chunk) * 32 + t] =
        make_float2(sA[2 * t] + sA[2 * t + 1], sB[2 * t] + sB[2 * t + 1]);
}

__global__ void gn_finalize_kernel(const float2* __restrict__ part,
                                   float2* __restrict__ stats) {
  int t = threadIdx.x;  // 256 = 2b * 4l * 32g
  int b = t >> 7, rem = t & 127, l = rem >> 5, g = rem & 31;
  const int cnt_[4] = {64, 16, 4, 1};
  const int cb_[4] = {0, 64, 80, 84};
  const int HWs[4] = {4096, 1024, 256, 64};
  float s = 0.f, ss = 0.f;
  for (int i = 0; i < cnt_[l]; ++i) {
    float2 v = part[((size_t)b * 85 + cb_[l] + i) * 32 + g];
    s += v.x;
    ss += v.y;
  }
  float n = (float)(HWs[l] * 8);
  float mu = s / n;
  float var = ss / n - mu * mu;
  stats[(b * 4 + l) * 32 + g] = make_float2(mu, rsqrtf(var + 1e-5f));
}

// ---------------------------------------------------------------------------
__device__ __forceinline__ void get_level(int t, int& l, int& hw, int& Hl, int& Wl) {
  if (t < 4096)      { l = 0; hw = t;        Hl = 64; Wl = 64; }
  else if (t < 5120) { l = 1; hw = t - 4096; Hl = 32; Wl = 32; }
  else if (t < 5376) { l = 2; hw = t - 5120; Hl = 16; Wl = 16; }
  else               { l = 3; hw = t - 5376; Hl = 8;  Wl = 8;  }
}

// GN apply + bf16 shadow + qb = bf16(x + pos)
__global__ void gn_apply_kernel(float* __restrict__ x, __hip_bfloat16* __restrict__ xb,
                                __hip_bfloat16* __restrict__ qb,
                                const float* __restrict__ pos,
                                const float2* __restrict__ stats,
                                const float* __restrict__ gw, const float* __restrict__ gb) {
  int idx = blockIdx.x * 256 + threadIdx.x;
  if (idx >= BATCH * LQ * CDIM) return;
  int c = idx & 255;
  int tok = idx >> 8;
  int b = tok / LQ, t = tok % LQ;
  int l, hw, Hl, Wl;
  get_level(t, l, hw, Hl, Wl);
  float2 st = stats[(b * 4 + l) * 32 + (c >> 3)];
  float v = (x[idx] - st.x) * st.y * gw[l * CDIM + c] + gb[l * CDIM + c];
  x[idx] = v;
  xb[idx] = __float2bfloat16(v);
  qb[idx] = __float2bfloat16(v + pos[t * 256 + c]);
}

__global__ void pos_embed_kernel(const float* __restrict__ level_embed,
                                 float* __restrict__ pos) {
  int idx = blockIdx.x * 256 + threadIdx.x;
  if (idx >= LQ * CDIM) return;
  int t = idx >> 8, c = idx & 255;
  int l, hw, Hl, Wl;
  get_level(t, l, hw, Hl, Wl);
  int y = hw / Wl, xx = hw % Wl;
  const float twopi = 6.28318530717958647692f;
  float v; int cc;
  if (c < 128) { v = (float)(y + 1) * twopi / ((float)Hl + 1e-6f); cc = c; }
  else         { v = (float)(xx + 1) * twopi / ((float)Wl + 1e-6f); cc = c - 128; }
  int k = cc >> 1;
  float dim_t = expf((float)k * (logf(10000.0f) / 64.0f));
  float p = v / dim_t;
  float e = (cc & 1) ? cosf(p) : sinf(p);
  pos[idx] = e + level_embed[l * CDIM + c];
}

__global__ void ref_kernel(float* __restrict__ ref) {
  int t = blockIdx.x * 256 + threadIdx.x;
  if (t >= LQ) return;
  int l, hw, Hl, Wl;
  get_level(t, l, hw, Hl, Wl);
  int y = hw / Wl, xx = hw % Wl;
  ref[t * 2]     = ((float)xx + 0.5f) / (float)Wl;
  ref[t * 2 + 1] = ((float)y + 0.5f) / (float)Hl;
}

// ---------------------------------------------------------------------------
// Deformable attention: 8-lane group per (token, head); branchless bilinear.
// ---------------------------------------------------------------------------
__global__ __launch_bounds__(256) void deform_attn_kernel(
    const __hip_bfloat16* __restrict__ value, const float* __restrict__ comb,
    const float* __restrict__ ref, __hip_bfloat16* __restrict__ out) {
  const int Wl_[4] = {64, 32, 16, 8};
  const int st_[4] = {0, 4096, 5120, 5376};
  int gid = blockIdx.x * 32 + (threadIdx.x >> 3);
  int lane8 = threadIdx.x & 7;
  int h = gid & 7;
  int tok = gid >> 3;
  int b = tok / LQ;
  int qi = tok - b * LQ;

  const float4* awv = (const float4*)(comb + (size_t)tok * 384 + 256 + h * 16);
  float4 q0 = awv[0], q1 = awv[1], q2 = awv[2], q3 = awv[3];
  float logit[16] = {q0.x, q0.y, q0.z, q0.w, q1.x, q1.y, q1.z, q1.w,
                     q2.x, q2.y, q2.z, q2.w, q3.x, q3.y, q3.z, q3.w};
  float mx = -1e30f;
#pragma unroll
  for (int i = 0; i < 16; ++i) mx = fmaxf(mx, logit[i]);
  const float LOG2E = 1.4426950408889634f;
  float ssum = 0.f;
#pragma unroll
  for (int i = 0; i < 16; ++i) {
    logit[i] = exp2f((logit[i] - mx) * LOG2E);
    ssum += logit[i];
  }
  float inv = 1.0f / ssum;

  float rx = ref[qi * 2], ry = ref[qi * 2 + 1];
  const float4* offv = (const float4*)(comb + (size_t)tok * 384 + h * 32);
  float acc0 = 0.f, acc1 = 0.f, acc2 = 0.f, acc3 = 0.f;

#pragma unroll
  for (int l = 0; l < 4; ++l) {
    const int Wl = Wl_[l];
    const float fW = (float)Wl;
    const __hip_bfloat16* vbase =
        value + ((size_t)b * LQ + st_[l]) * CDIM + h * 32 + lane8 * 4;
    float bx = fmaf(rx, fW, -0.5f);
    float by = fmaf(ry, fW, -0.5f);
    float4 oa = offv[l * 2], ob = offv[l * 2 + 1];
    float oxs[4] = {oa.x, oa.z, ob.x, ob.z};
    float oys[4] = {oa.y, oa.w, ob.y, ob.w};
#pragma unroll
    for (int p = 0; p < 4; ++p) {
      float px = bx + oxs[p], py = by + oys[p];
      float wgt = logit[l * 4 + p] * inv;
      float fpx = floorf(px), fpy = floorf(py);
      int x0 = (int)fpx, y0 = (int)fpy;
      float fx = px - fpx, fy = py - fpy;
      float wx0 = (x0 >= 0 && x0 < Wl) ? (1.f - fx) : 0.f;
      float wx1 = (x0 >= -1 && x0 < Wl - 1) ? fx : 0.f;
      float wy0 = (y0 >= 0 && y0 < Wl) ? (wgt * (1.f - fy)) : 0.f;
      float wy1 = (y0 >= -1 && y0 < Wl - 1) ? (wgt * fy) : 0.f;
      int xc0 = min(max(x0, 0), Wl - 1);
      int xc1 = min(max(x0 + 1, 0), Wl - 1);
      int yc0 = min(max(y0, 0), Wl - 1);
      int yc1 = min(max(y0 + 1, 0), Wl - 1);
      const __hip_bfloat16* r0 = vbase + (size_t)(yc0 * Wl) * CDIM;
      const __hip_bfloat16* r1 = vbase + (size_t)(yc1 * Wl) * CDIM;
      ushort4 u00 = *(const ushort4*)(r0 + (size_t)xc0 * CDIM);
      ushort4 u01 = *(const ushort4*)(r0 + (size_t)xc1 * CDIM);
      ushort4 u10 = *(const ushort4*)(r1 + (size_t)xc0 * CDIM);
      ushort4 u11 = *(const ushort4*)(r1 + (size_t)xc1 * CDIM);
      float w00 = wy0 * wx0, w01 = wy0 * wx1, w10 = wy1 * wx0, w11 = wy1 * wx1;
      acc0 = fmaf(w00, __uint_as_float((unsigned)u00.x << 16), acc0);
      acc1 = fmaf(w00, __uint_as_float((unsigned)u00.y << 16), acc1);
      acc2 = fmaf(w00, __uint_as_float((unsigned)u00.z << 16), acc2);
      acc3 = fmaf(w00, __uint_as_float((unsigned)u00.w << 16), acc3);
      acc0 = fmaf(w01, __uint_as_float((unsigned)u01.x << 16), acc0);
      acc1 = fmaf(w01, __uint_as_float((unsigned)u01.y << 16), acc1);
      acc2 = fmaf(w01, __uint_as_float((unsigned)u01.z << 16), acc2);
      acc3 = fmaf(w01, __uint_as_float((unsigned)u01.w << 16), acc3);
      acc0 = fmaf(w10, __uint_as_float((unsigned)u10.x << 16), acc0);
      acc1 = fmaf(w10, __uint_as_float((unsigned)u10.y << 16), acc1);
      acc2 = fmaf(w10, __uint_as_float((unsigned)u10.z << 16), acc2);
      acc3 = fmaf(w10, __uint_as_float((unsigned)u10.w << 16), acc3);
      acc0 = fmaf(w11, __uint_as_float((unsigned)u11.x << 16), acc0);
      acc1 = fmaf(w11, __uint_as_float((unsigned)u11.y << 16), acc1);
      acc2 = fmaf(w11, __uint_as_float((unsigned)u11.z << 16), acc2);
      acc3 = fmaf(w11, __uint_as_float((unsigned)u11.w << 16), acc3);
    }
  }
  union { ushort4 u; __hip_bfloat16 hh[4]; } pk;
  pk.hh[0] = __float2bfloat16(acc0);
  pk.hh[1] = __float2bfloat16(acc1);
  pk.hh[2] = __float2bfloat16(acc2);
  pk.hh[3] = __float2bfloat16(acc3);
  *(ushort4*)(out + (size_t)tok * CDIM + h * 32 + lane8 * 4) = pk.u;
}

// x = LayerNorm(x + r); writes fp32 x, bf16 xb, optionally qb = bf16(x+pos).
template <bool EMIT_Q>
__global__ __launch_bounds__(256) void add_ln_kernel(
    float* __restrict__ x, __hip_bfloat16* __restrict__ xb,
    __hip_bfloat16* __restrict__ qb, const float* __restrict__ pos,
    const float* __restrict__ r, const float* __restrict__ w,
    const float* __restrict__ b) {
  int wid = threadIdx.x >> 6, lane = threadIdx.x & 63;
  size_t tok = (size_t)blockIdx.x * 4 + wid;
  size_t base = tok * CDIM + lane * 4;
  float4 xv = *(const float4*)&x[base];
  float4 rv = *(const float4*)&r[base];
  float v[4] = {xv.x + rv.x, xv.y + rv.y, xv.z + rv.z, xv.w + rv.w};
  float s = v[0] + v[1] + v[2] + v[3];
  float ss = v[0] * v[0] + v[1] * v[1] + v[2] * v[2] + v[3] * v[3];
#pragma unroll
  for (int o = 1; o < 64; o <<= 1) { s += __shfl_xor(s, o); ss += __shfl_xor(ss, o); }
  float mu = s * (1.0f / 256.0f);
  float var = ss * (1.0f / 256.0f) - mu * mu;
  float rsig = rsqrtf(var + 1e-5f);
  int c = lane * 4;
  float4 wv = *(const float4*)&w[c];
  float4 bv = *(const float4*)&b[c];
  float4 o4;
  o4.x = (v[0] - mu) * rsig * wv.x + bv.x;
  o4.y = (v[1] - mu) * rsig * wv.y + bv.y;
  o4.z = (v[2] - mu) * rsig * wv.z + bv.z;
  o4.w = (v[3] - mu) * rsig * wv.w + bv.w;
  *(float4*)&x[base] = o4;
  union { ushort4 u; __hip_bfloat16 h[4]; } pk;
  pk.h[0] = __float2bfloat16(o4.x);
  pk.h[1] = __float2bfloat16(o4.y);
  pk.h[2] = __float2bfloat16(o4.z);
  pk.h[3] = __float2bfloat16(o4.w);
  *(ushort4*)&xb[base] = pk.u;
  if (EMIT_Q) {
    int t = (int)(tok >= LQ ? tok - LQ : tok);
    float4 pv = *(const float4*)&pos[(size_t)t * CDIM + c];
    union { ushort4 u; __hip_bfloat16 h[4]; } pq;
    pq.h[0] = __float2bfloat16(o4.x + pv.x);
    pq.h[1] = __float2bfloat16(o4.y + pv.y);
    pq.h[2] = __float2bfloat16(o4.z + pv.z);
    pq.h[3] = __float2bfloat16(o4.w + pv.w);
    *(ushort4*)&qb[base] = pq.u;
  }
}

// conv2 NHWC split over taps: part[tap][b][pix][2]
__global__ __launch_bounds__(256) void conv2_part_kernel(
    const __hip_bfloat16* __restrict__ c1o, const float* __restrict__ w,
    float* __restrict__ part) {
  int pix = blockIdx.x * 256 + threadIdx.x;
  int tap = blockIdx.y, b = blockIdx.z;
  int y = pix >> 6, x = pix & 63;
  int dy = tap / 3 - 1, dx = tap % 3 - 1;
  int yy = y + dy, xx = x + dx;
  bool ok = (yy >= 0 && yy < 64 && xx >= 0 && xx < 64);
  float a0 = 0.f, a1 = 0.f;
  if (ok) {
    const __hip_bfloat16* row = c1o + (size_t)(b * 4096 + yy * 64 + xx) * 64;
#pragma unroll
    for (int ic4 = 0; ic4 < 16; ++ic4) {
      ushort4 u = *(const ushort4*)(row + ic4 * 4);
      float f0 = __uint_as_float((unsigned)u.x << 16);
      float f1 = __uint_as_float((unsigned)u.y << 16);
      float f2 = __uint_as_float((unsigned)u.z << 16);
      float f3 = __uint_as_float((unsigned)u.w << 16);
      int ic = ic4 * 4;
      a0 = fmaf(w[(ic + 0) * 9 + tap], f0, a0);
      a0 = fmaf(w[(ic + 1) * 9 + tap], f1, a0);
      a0 = fmaf(w[(ic + 2) * 9 + tap], f2, a0);
      a0 = fmaf(w[(ic + 3) * 9 + tap], f3, a0);
      a1 = fmaf(w[576 + (ic + 0) * 9 + tap], f0, a1);
      a1 = fmaf(w[576 + (ic + 1) * 9 + tap], f1, a1);
      a1 = fmaf(w[576 + (ic + 2) * 9 + tap], f2, a1);
      a1 = fmaf(w[576 + (ic + 3) * 9 + tap], f3, a1);
    }
  }
  float2 o = make_float2(a0, a1);
  *(float2*)&part[((size_t)(tap * BATCH + b) * 4096 + pix) * 2] = o;
}

// sum 9 taps + bias -> c2o [b][pix][2]
__global__ void conv2_reduce_kernel(const float* __restrict__ part,
                                    const float* __restrict__ bias,
                                    float* __restrict__ out) {
  int i = blockIdx.x * 256 + threadIdx.x;
  if (i >= BATCH * 4096) return;
  int b = i >> 12, pix = i & 4095;
  float s0 = bias[0], s1 = bias[1];
#pragma unroll
  for (int tap = 0; tap < 9; ++tap) {
    float2 v = *(const float2*)&part[((size_t)(tap * BATCH + b) * 4096 + pix) * 2];
    s0 += v.x; s1 += v.y;
  }
  *(float2*)&out[(size_t)i * 2] = make_float2(s0, s1);
}

// 4x bilinear upsample 64->256; input layout [b][pix][2]
__global__ void upsample_kernel(const float* __restrict__ in, float* __restrict__ out) {
  int idx = blockIdx.x * 256 + threadIdx.x;
  if (idx >= BATCH * 2 * 256 * 256) return;
  int X = idx & 255, Y = (idx >> 8) & 255, p = idx >> 16;
  int b = p >> 1, oc = p & 1;
  float tx = ((float)X + 0.5f) * 0.25f - 0.5f;
  float ty = ((float)Y + 0.5f) * 0.25f - 0.5f;
  float fxf = floorf(tx), fyf = floorf(ty);
  int x0 = (int)fxf, y0 = (int)fyf;
  float fx = tx - fxf, fy = ty - fyf;
  int x0c = min(max(x0, 0), 63), x1c = min(max(x0 + 1, 0), 63);
  int y0c = min(max(y0, 0), 63), y1c = min(max(y0 + 1, 0), 63);
  const float* ip = in + (size_t)b * 4096 * 2 + oc;
  float v = (1.f - fy) * ((1.f - fx) * ip[(y0c * 64 + x0c) * 2] + fx * ip[(y0c * 64 + x1c) * 2]) +
            fy * ((1.f - fx) * ip[(y1c * 64 + x0c) * 2] + fx * ip[(y1c * 64 + x1c) * 2]);
  out[idx] = v;
}

// ---------------------------------------------------------------------------
extern "C" void kernel_launch(void* const* d_in, const int* in_sizes, int n_in,
                              void* d_out, int out_size, void* d_ws, size_t ws_size,
                              hipStream_t stream) {
  const float* f[4] = {(const float*)d_in[0], (const float*)d_in[1],
                       (const float*)d_in[2], (const float*)d_in[3]};
  const float* proj_w = (const float*)d_in[4];
  const float* proj_b = (const float*)d_in[5];
  const float* gn_w = (const float*)d_in[6];
  const float* gn_b = (const float*)d_in[7];
  const float* level_embed = (const float*)d_in[8];
  const float* so_w = (const float*)d_in[9];
  const float* so_b = (const float*)d_in[10];
  const float* aw_w = (const float*)d_in[11];
  const float* aw_b = (const float*)d_in[12];
  const float* vp_w = (const float*)d_in[13];
  const float* vp_b = (const float*)d_in[14];
  const float* op_w = (const float*)d_in[15];
  const float* op_b = (const float*)d_in[16];
  const float* n1_w = (const float*)d_in[17];
  const float* n1_b = (const float*)d_in[18];
  const float* l1_w = (const float*)d_in[19];
  const float* l1_b = (const float*)d_in[20];
  const float* l2_w = (const float*)d_in[21];
  const float* l2_b = (const float*)d_in[22];
  const float* n2_w = (const float*)d_in[23];
  const float* n2_b = (const float*)d_in[24];
  const float* c1_w = (const float*)d_in[25];
  const float* c1_b = (const float*)d_in[26];
  const float* c2_w = (const float*)d_in[27];
  const float* c2_b = (const float*)d_in[28];
  (void)in_sizes; (void)n_in; (void)out_size; (void)ws_size;

  float* ws = (float*)d_ws;
  const size_t TOK = (size_t)BATCH * LQ * CDIM;  // 2785280
  size_t o = 0;
  float* x = ws + o;     o += TOK;
  float* tmp = ws + o;   o += TOK;
  float* comb = ws + o;  o += (size_t)BATCH * LQ * 384;
  float* pos = ws + o;   o += (size_t)LQ * CDIM;
  float* refb = ws + o;  o += 11008;
  float2* stats = (float2*)(ws + o); o += 512;
  float* zerof = ws + o; o += 256;
  float* sowa_bias = ws + o; o += 2304;
  float2* gnpart = (float2*)(ws + o); o += 11008;
  __hip_bfloat16* xb = (__hip_bfloat16*)(ws + o);    o += TOK / 2;
  __hip_bfloat16* qb = (__hip_bfloat16*)(ws + o);    o += TOK / 2;
  __hip_bfloat16* valb = (__hip_bfloat16*)(ws + o);  o += TOK / 2;
  __hip_bfloat16* attnb = (__hip_bfloat16*)(ws + o); o += TOK / 2;
  __hip_bfloat16* ftb = (__hip_bfloat16*)(ws + o);   o += TOK / 2;
  __hip_bfloat16* ff1b = (__hip_bfloat16*)(ws + o);  o += (size_t)BATCH * LQ * FFDIM / 2;
  __hip_bfloat16* sowa_wb = (__hip_bfloat16*)(ws + o); o += 294912;
  __hip_bfloat16* vp_wb = (__hip_bfloat16*)(ws + o); o += 196608;
  __hip_bfloat16* op_wb = (__hip_bfloat16*)(ws + o); o += 196608;
  __hip_bfloat16* l1_wb = (__hip_bfloat16*)(ws + o); o += 786432;
  __hip_bfloat16* l2_wb = (__hip_bfloat16*)(ws + o); o += 786432;
  __hip_bfloat16* proj_wb = (__hip_bfloat16*)(ws + o); o += 131072;
  __hip_bfloat16* wc1b = (__hip_bfloat16*)(ws + o);  o += 73728;
  // head scratch aliases ff1b region (free after encoder)
  __hip_bfloat16* c1ob = ff1b;
  float* part2 = (float*)(ff1b + 524288);
  float* c2o = part2 + 147456;

  const int HWs[4] = {4096, 1024, 256, 64};
  const int STs[4] = {0, 4096, 5120, 5376};

  // 0) staging
  hipMemsetAsync(zerof, 0, 1024, stream);
  sowa_prep_kernel<<<(589824 + 255) / 256, 256, 0, stream>>>(so_w, aw_w, sowa_wb);
  sowa_bias_prep_kernel<<<9, 256, 0, stream>>>(so_b, aw_b, sowa_bias);
  wc1_prep_kernel<<<(147456 + 255) / 256, 256, 0, stream>>>(c1_w, wc1b);
  f2b4_kernel<<<(262144 / 4 + 255) / 256, 256, 0, stream>>>(proj_w, proj_wb, 262144 / 4);
  f2b4_kernel<<<(393216 / 4 + 255) / 256, 256, 0, stream>>>(vp_w, vp_wb, 393216 / 4);
  f2b4_kernel<<<(393216 / 4 + 255) / 256, 256, 0, stream>>>(op_w, op_wb, 393216 / 4);
  f2b4_kernel<<<(1572864 / 4 + 255) / 256, 256, 0, stream>>>(l1_w, l1_wb, 1572864 / 4);
  f2b4_kernel<<<(1572864 / 4 + 255) / 256, 256, 0, stream>>>(l2_w, l2_wb, 1572864 / 4);

  // 1) input transpose+convert, then bf16 MFMA input-proj (remapped output)
  transpose_f_kernel<<<dim3(85, 4, BATCH), 256, 0, stream>>>(f[0], f[1], f[2], f[3],
                                                             ftb);
  for (int l = 0; l < 4; ++l) {
    int M2 = 2 * HWs[l];
    gemm_bf16_kernel<false, true, false, true><<<dim3(2, M2 / 128), 256, 0, stream>>>(
        ftb + (size_t)2 * STs[l] * 256, proj_wb + (size_t)l * 65536,
        proj_b + (size_t)l * 256, x, nullptr, M2, 256, 256,
        HWs[l], (long)STs[l] * 256, (long)LQ * 256);
  }
  // 2) pos embed + ref
  pos_embed_kernel<<<(LQ * CDIM + 255) / 256, 256, 0, stream>>>(level_embed, pos);
  ref_kernel<<<(LQ + 255) / 256, 256, 0, stream>>>(refb);
  // 3) GroupNorm (2-stage stats + apply)
  gn_part_kernel<<<dim3(85, BATCH), 256, 0, stream>>>(x, gnpart);
  gn_finalize_kernel<<<1, 256, 0, stream>>>(gnpart, stats);
  {
    int n = BATCH * LQ * CDIM;
    gn_apply_kernel<<<(n + 255) / 256, 256, 0, stream>>>(x, xb, qb, pos, stats,
                                                         gn_w, gn_b);
  }

  const int M = BATCH * LQ;  // 10880 = 85 * 128
  for (int i = 0; i < 6; ++i) {
    const __hip_bfloat16* sowa = sowa_wb + (size_t)i * 98304;
    const __hip_bfloat16* vw = vp_wb + (size_t)i * 65536;
    const __hip_bfloat16* ow = op_wb + (size_t)i * 65536;
    const __hip_bfloat16* w1 = l1_wb + (size_t)i * 262144;
    const __hip_bfloat16* w2 = l2_wb + (size_t)i * 262144;
    const float* vb = vp_b + (size_t)i * CDIM;
    const float* ob = op_b + (size_t)i * CDIM;
    const float* b1 = l1_b + (size_t)i * FFDIM;
    const float* b2 = l2_b + (size_t)i * CDIM;

    gemm_bf16_kernel<false, false, true, false><<<dim3(2, 85), 256, 0, stream>>>(
        xb, vw, vb, nullptr, valb, M, CDIM, CDIM, 0, 0, 0);
    gemm_bf16_kernel<false, true, false, false><<<dim3(3, 85), 256, 0, stream>>>(
        qb, sowa, sowa_bias + i * 384, comb, nullptr, M, 384, CDIM, 0, 0, 0);
    deform_attn_kernel<<<BATCH * LQ * 8 / 32, 256, 0, stream>>>(valb, comb, refb,
                                                                attnb);
    gemm_bf16_kernel<false, true, false, false><<<dim3(2, 85), 256, 0, stream>>>(
        attnb, ow, ob, tmp, nullptr, M, CDIM, CDIM, 0, 0, 0);
    add_ln_kernel<false><<<M / 4, 256, 0, stream>>>(
        x, xb, nullptr, nullptr, tmp, n1_w + (size_t)i * CDIM, n1_b + (size_t)i * CDIM);
    gemm_bf16_kernel<true, false, true, false><<<dim3(8, 85), 256, 0, stream>>>(
        xb, w1, b1, nullptr, ff1b, M, FFDIM, CDIM, 0, 0, 0);
    gemm_bf16_kernel<false, true, false, false><<<dim3(2, 85), 256, 0, stream>>>(
        ff1b, w2, b2, tmp, nullptr, M, CDIM, FFDIM, 0, 0, 0);
    add_ln_kernel<true><<<M / 4, 256, 0, stream>>>(
        x, xb, qb, pos, tmp, n2_w + (size_t)i * CDIM, n2_b + (size_t)i * CDIM);
  }

  // head
  conv1_mfma_kernel<<<64, 256, 0, stream>>>(xb, wc1b, c1_b,
                                            (const __hip_bfloat16*)zerof, c1ob);
  conv2_part_kernel<<<dim3(16, 9, BATCH), 256, 0, stream>>>(c1ob, c2_w, part2);
  conv2_reduce_kernel<<<(BATCH * 4096 + 255) / 256, 256, 0, stream>>>(part2, c2_b,
                                                                      c2o);
  {
    int n = BATCH * 2 * 256 * 256;
    upsample_kernel<<<(n + 255) / 256, 256, 0, stream>>>(c2o, (float*)d_out);
  }
}

// Round 9
// 715.183 us; speedup vs baseline: 4.5706x; 1.0235x over previous
//
#include <hip/hip_runtime.h>
#include <hip/hip_bf16.h>
#include <math.h>

#define LQ 5440
#define CDIM 256
#define BATCH 2
#define FFDIM 1024

typedef __attribute__((ext_vector_type(8))) short bf16x8;
typedef __attribute__((ext_vector_type(4))) float f32x4;

typedef __attribute__((address_space(1))) void* gas1_t;
typedef __attribute__((address_space(3))) void* las3_t;

__device__ __forceinline__ void async16(const void* g, void* l) {
  __builtin_amdgcn_global_load_lds((gas1_t)g, (las3_t)l, 16, 0, 0);
}

#define WAIT_VM5() asm volatile("s_waitcnt vmcnt(5)" ::: "memory")
#define WAIT_VM4() asm volatile("s_waitcnt vmcnt(4)" ::: "memory")
#define WAIT_VM3() asm volatile("s_waitcnt vmcnt(3)" ::: "memory")
#define WAIT_VM0() asm volatile("s_waitcnt vmcnt(0)" ::: "memory")

// chunk (0..84) -> level, row0 (64-row chunks across the 4 levels)
__device__ __forceinline__ void get_chunk(int chunk, int& l, int& row0) {
  if (chunk < 64)      { l = 0; row0 = chunk * 64; }
  else if (chunk < 80) { l = 1; row0 = (chunk - 64) * 64; }
  else if (chunk < 84) { l = 2; row0 = (chunk - 80) * 64; }
  else                 { l = 3; row0 = 0; }
}

// ---------------------------------------------------------------------------
// bf16 MFMA GEMM, 3-buffer depth-2 pipelined (counted vmcnt, 1 barrier/iter).
// ---------------------------------------------------------------------------
template <bool RELU, bool OUT_F32, bool OUT_B16, bool REMAP>
__global__ __launch_bounds__(256, 2) void gemm_bf16_kernel(
    const __hip_bfloat16* __restrict__ A, const __hip_bfloat16* __restrict__ Wt,
    const float* __restrict__ bias, float* __restrict__ C,
    __hip_bfloat16* __restrict__ Cb, int M, int N, int K,
    int mrows, long obase, long obstride) {
  __shared__ __hip_bfloat16 As[3][128 * 32];
  __shared__ __hip_bfloat16 Bs[3][128 * 32];
  const int tid = threadIdx.x;
  const int bm = blockIdx.y * 128, bn = blockIdx.x * 128;
  const int lane = tid & 63, wave = tid >> 6;
  const int wr = wave >> 1, wc = wave & 1;
  const int srow = tid >> 2;
  const int scol = (tid & 3) * 8;
  const int lo0 = srow * 32 + scol;
  const int lo1 = (64 + srow) * 32 + scol;
  const __hip_bfloat16* ga0 = A + (size_t)(bm + srow) * K + scol;
  const __hip_bfloat16* ga1 = A + (size_t)(bm + 64 + srow) * K + scol;
  const __hip_bfloat16* gb0 = Wt + (size_t)(bn + srow) * K + scol;
  const __hip_bfloat16* gb1 = Wt + (size_t)(bn + 64 + srow) * K + scol;

  const int nt = K >> 5;
  async16(ga0, &As[0][lo0]);
  async16(ga1, &As[0][lo1]);
  async16(gb0, &Bs[0][lo0]);
  async16(gb1, &Bs[0][lo1]);
  async16(ga0 + 32, &As[1][lo0]);
  async16(ga1 + 32, &As[1][lo1]);
  async16(gb0 + 32, &Bs[1][lo0]);
  async16(gb1 + 32, &Bs[1][lo1]);

  f32x4 acc[4][4] = {};
  const int fr = lane & 15;
  const int ksub = (lane >> 4) * 8;

  int cur = 0, nxt = 2;
  for (int t = 0; t < nt; ++t) {
    if (t == nt - 1) WAIT_VM0(); else WAIT_VM4();
    __builtin_amdgcn_s_barrier();
    asm volatile("" ::: "memory");
    bf16x8 af[4], bfv[4];
    const __hip_bfloat16* as = As[cur];
    const __hip_bfloat16* bs = Bs[cur];
#pragma unroll
    for (int mi = 0; mi < 4; ++mi)
      af[mi] = *(const bf16x8*)&as[(wr * 64 + mi * 16 + fr) * 32 + ksub];
#pragma unroll
    for (int nj = 0; nj < 4; ++nj)
      bfv[nj] = *(const bf16x8*)&bs[(wc * 64 + nj * 16 + fr) * 32 + ksub];
    if (t + 2 < nt) {
      const int ko = (t + 2) * 32;
      async16(ga0 + ko, &As[nxt][lo0]);
      async16(ga1 + ko, &As[nxt][lo1]);
      async16(gb0 + ko, &Bs[nxt][lo0]);
      async16(gb1 + ko, &Bs[nxt][lo1]);
    }
#pragma unroll
    for (int mi = 0; mi < 4; ++mi)
#pragma unroll
      for (int nj = 0; nj < 4; ++nj)
        acc[mi][nj] = __builtin_amdgcn_mfma_f32_16x16x32_bf16(af[mi], bfv[nj],
                                                              acc[mi][nj], 0, 0, 0);
    cur = (cur == 2) ? 0 : cur + 1;
    nxt = (nxt == 2) ? 0 : nxt + 1;
  }

  const int cc = lane & 15;
  const int rbase = (lane >> 4) * 4;
  float bcol[4];
#pragma unroll
  for (int nj = 0; nj < 4; ++nj) bcol[nj] = bias[bn + wc * 64 + nj * 16 + cc];
#pragma unroll
  for (int mi = 0; mi < 4; ++mi)
#pragma unroll
    for (int nj = 0; nj < 4; ++nj) {
      int col = bn + wc * 64 + nj * 16 + cc;
#pragma unroll
      for (int r = 0; r < 4; ++r) {
        int row = bm + wr * 64 + mi * 16 + rbase + r;
        float v = acc[mi][nj][r] + bcol[nj];
        if (RELU) v = fmaxf(v, 0.f);
        if (OUT_F32) {
          size_t oaddr;
          if (REMAP)
            oaddr = (size_t)obase +
                    (row < mrows ? (size_t)row * N
                                 : (size_t)obstride + (size_t)(row - mrows) * N) +
                    col;
          else
            oaddr = (size_t)row * N + col;
          C[oaddr] = v;
        }
        if (OUT_B16) Cb[(size_t)row * N + col] = __float2bfloat16(v);
      }
    }
}

// ---------------------------------------------------------------------------
// Fused GEMM (N=256) + residual + LayerNorm. Tile 64 rows x 256 cols, 4 waves
// side-by-side in N. Epilogue: v = acc+bias+x; rowwise LN over 256 cols via
// shfl-xor (16 cc-lanes) + 4-wave LDS reduce; writes x (f32), xb, [qb=x+pos].
// ---------------------------------------------------------------------------
template <bool EMIT_Q>
__global__ __launch_bounds__(256, 2) void gemm_ln_kernel(
    const __hip_bfloat16* __restrict__ A, const __hip_bfloat16* __restrict__ Wt,
    const float* __restrict__ bias, float* __restrict__ x,
    __hip_bfloat16* __restrict__ xb, __hip_bfloat16* __restrict__ qb,
    const float* __restrict__ pos, const float* __restrict__ lnw,
    const float* __restrict__ lnb, int K) {
  __shared__ __hip_bfloat16 As[3][64 * 32];
  __shared__ __hip_bfloat16 Bs[3][256 * 32];
  __shared__ float sred[4][64], ssred[4][64];
  const int tid = threadIdx.x;
  const int bm = blockIdx.x * 64;
  const int lane = tid & 63, wv = tid >> 6;
  const int srow = tid >> 2;
  const int scol = (tid & 3) * 8;
  const int loA = srow * 32 + scol;
  const __hip_bfloat16* ga = A + (size_t)(bm + srow) * K + scol;
  const __hip_bfloat16* gb = Wt + (size_t)srow * K + scol;

  const int nt = K >> 5;
  auto stage = [&](int t, int buf) {
    const int ko = t * 32;
    async16(ga + ko, &As[buf][loA]);
#pragma unroll
    for (int i = 0; i < 4; ++i)
      async16(gb + (size_t)(64 * i) * K + ko, &Bs[buf][(64 * i) * 32 + loA]);
  };
  stage(0, 0);
  stage(1, 1);

  f32x4 acc[4][4] = {};
  const int fr = lane & 15;
  const int ksub = (lane >> 4) * 8;

  int cur = 0, nxt = 2;
  for (int t = 0; t < nt; ++t) {
    if (t == nt - 1) WAIT_VM0(); else WAIT_VM5();
    __builtin_amdgcn_s_barrier();
    asm volatile("" ::: "memory");
    bf16x8 af[4], bfv[4];
#pragma unroll
    for (int mi = 0; mi < 4; ++mi)
      af[mi] = *(const bf16x8*)&As[cur][(mi * 16 + fr) * 32 + ksub];
#pragma unroll
    for (int nj = 0; nj < 4; ++nj)
      bfv[nj] = *(const bf16x8*)&Bs[cur][(wv * 64 + nj * 16 + fr) * 32 + ksub];
    if (t + 2 < nt) stage(t + 2, nxt);
#pragma unroll
    for (int mi = 0; mi < 4; ++mi)
#pragma unroll
      for (int nj = 0; nj < 4; ++nj)
        acc[mi][nj] = __builtin_amdgcn_mfma_f32_16x16x32_bf16(af[mi], bfv[nj],
                                                              acc[mi][nj], 0, 0, 0);
    cur = (cur == 2) ? 0 : cur + 1;
    nxt = (nxt == 2) ? 0 : nxt + 1;
  }

  const int cc = lane & 15;
  const int rbase = (lane >> 4) * 4;
  float bcol[4], wcol[4], bncol[4];
#pragma unroll
  for (int nj = 0; nj < 4; ++nj) {
    int col = wv * 64 + nj * 16 + cc;
    bcol[nj] = bias[col];
    wcol[nj] = lnw[col];
    bncol[nj] = lnb[col];
  }
  // v = acc + bias + residual
#pragma unroll
  for (int mi = 0; mi < 4; ++mi)
#pragma unroll
    for (int r = 0; r < 4; ++r) {
      int grow = bm + mi * 16 + rbase + r;
#pragma unroll
      for (int nj = 0; nj < 4; ++nj) {
        int col = wv * 64 + nj * 16 + cc;
        acc[mi][nj][r] += bcol[nj] + x[(size_t)grow * 256 + col];
      }
    }
  // rowwise partial sums over this wave's 64 cols
#pragma unroll
  for (int mi = 0; mi < 4; ++mi)
#pragma unroll
    for (int r = 0; r < 4; ++r) {
      float s = 0.f, ssq = 0.f;
#pragma unroll
      for (int nj = 0; nj < 4; ++nj) {
        float v = acc[mi][nj][r];
        s += v;
        ssq += v * v;
      }
#pragma unroll
      for (int m = 1; m < 16; m <<= 1) {
        s += __shfl_xor(s, m);
        ssq += __shfl_xor(ssq, m);
      }
      if (cc == 0) {
        int row = mi * 16 + rbase + r;
        sred[wv][row] = s;
        ssred[wv][row] = ssq;
      }
    }
  __syncthreads();
#pragma unroll
  for (int mi = 0; mi < 4; ++mi)
#pragma unroll
    for (int r = 0; r < 4; ++r) {
      int row = mi * 16 + rbase + r;
      int grow = bm + row;
      float s = sred[0][row] + sred[1][row] + sred[2][row] + sred[3][row];
      float ssq = ssred[0][row] + ssred[1][row] + ssred[2][row] + ssred[3][row];
      float mu = s * (1.0f / 256.0f);
      float var = ssq * (1.0f / 256.0f) - mu * mu;
      float rsig = rsqrtf(var + 1e-5f);
      int tokp = grow >= LQ ? grow - LQ : grow;
#pragma unroll
      for (int nj = 0; nj < 4; ++nj) {
        int col = wv * 64 + nj * 16 + cc;
        float xn = (acc[mi][nj][r] - mu) * rsig * wcol[nj] + bncol[nj];
        x[(size_t)grow * 256 + col] = xn;
        xb[(size_t)grow * 256 + col] = __float2bfloat16(xn);
        if (EMIT_Q)
          qb[(size_t)grow * 256 + col] =
              __float2bfloat16(xn + pos[(size_t)tokp * 256 + col]);
      }
    }
}

// ---------------------------------------------------------------------------
// conv1 implicit GEMM (NHWC), flattened 72-step pipelined K-loop.
// ---------------------------------------------------------------------------
__global__ __launch_bounds__(256, 2) void conv1_mfma_kernel(
    const __hip_bfloat16* __restrict__ xb, const __hip_bfloat16* __restrict__ wc1,
    const float* __restrict__ bias, const __hip_bfloat16* __restrict__ zerob,
    __hip_bfloat16* __restrict__ c1o) {
  __shared__ __hip_bfloat16 As[3][128 * 32];
  __shared__ __hip_bfloat16 Bs[3][64 * 32];
  const int tid = threadIdx.x;
  const int b = blockIdx.x >> 5;
  const int pm = (blockIdx.x & 31) * 128;
  const int lane = tid & 63, wave = tid >> 6;
  const int sr = tid >> 2;
  const int sc = (tid & 3) * 8;
  const int loA0 = sr * 32 + sc, loA1 = (64 + sr) * 32 + sc;
  f32x4 acc[2][4] = {};
  const int fr = lane & 15, ksub = (lane >> 4) * 8;

  auto stage = [&](int kt, int buf) {
    int tap = kt >> 3;
    int kk = (kt & 7) * 32;
    int dy = tap / 3 - 1, dx = tap % 3 - 1;
    int hw0 = pm + sr;
    int y0 = (hw0 >> 6) + dy, x0 = (hw0 & 63) + dx;
    bool ok0 = (y0 >= 0 && y0 < 64 && x0 >= 0 && x0 < 64);
    const __hip_bfloat16* s0 =
        xb + ((size_t)(b * LQ) + y0 * 64 + x0) * 256 + kk + sc;
    int hw1 = pm + 64 + sr;
    int y1 = (hw1 >> 6) + dy, x1 = (hw1 & 63) + dx;
    bool ok1 = (y1 >= 0 && y1 < 64 && x1 >= 0 && x1 < 64);
    const __hip_bfloat16* s1 =
        xb + ((size_t)(b * LQ) + y1 * 64 + x1) * 256 + kk + sc;
    const __hip_bfloat16* wsrc = wc1 + (size_t)sr * 2304 + tap * 256 + kk + sc;
    async16(ok0 ? s0 : zerob, &As[buf][loA0]);
    async16(ok1 ? s1 : zerob, &As[buf][loA1]);
    async16(wsrc, &Bs[buf][loA0]);
  };
  stage(0, 0);
  stage(1, 1);
  int cur = 0, nxt = 2;
  for (int kt = 0; kt < 72; ++kt) {
    if (kt == 71) WAIT_VM0(); else WAIT_VM3();
    __builtin_amdgcn_s_barrier();
    asm volatile("" ::: "memory");
    bf16x8 af[2], bfv[4];
#pragma unroll
    for (int mi = 0; mi < 2; ++mi)
      af[mi] = *(const bf16x8*)&As[cur][(wave * 32 + mi * 16 + fr) * 32 + ksub];
#pragma unroll
    for (int nj = 0; nj < 4; ++nj)
      bfv[nj] = *(const bf16x8*)&Bs[cur][(nj * 16 + fr) * 32 + ksub];
    if (kt + 2 < 72) stage(kt + 2, nxt);
#pragma unroll
    for (int mi = 0; mi < 2; ++mi)
#pragma unroll
      for (int nj = 0; nj < 4; ++nj)
        acc[mi][nj] = __builtin_amdgcn_mfma_f32_16x16x32_bf16(
            af[mi], bfv[nj], acc[mi][nj], 0, 0, 0);
    cur = (cur == 2) ? 0 : cur + 1;
    nxt = (nxt == 2) ? 0 : nxt + 1;
  }
  const int cc = lane & 15;
  const int rbase = (lane >> 4) * 4;
#pragma unroll
  for (int mi = 0; mi < 2; ++mi)
#pragma unroll
    for (int nj = 0; nj < 4; ++nj) {
      int col = nj * 16 + cc;
      float bb = bias[col];
#pragma unroll
      for (int r = 0; r < 4; ++r) {
        int row = wave * 32 + mi * 16 + rbase + r;
        float v = fmaxf(acc[mi][nj][r] + bb, 0.f);
        c1o[(size_t)(b * 4096 + pm + row) * 64 + col] = __float2bfloat16(v);
      }
    }
}

// multi-section fp32 -> bf16 convert (proj, vp, op, l1, l2), float4 granules
__global__ void f2b_multi_kernel(const float* __restrict__ p0, const float* __restrict__ p1,
                                 const float* __restrict__ p2, const float* __restrict__ p3,
                                 const float* __restrict__ p4,
                                 __hip_bfloat16* __restrict__ o0, __hip_bfloat16* __restrict__ o1,
                                 __hip_bfloat16* __restrict__ o2, __hip_bfloat16* __restrict__ o3,
                                 __hip_bfloat16* __restrict__ o4) {
  int i = blockIdx.x * 256 + threadIdx.x;  // float4 index, total 1048576
  if (i >= 1048576) return;
  const float* in;
  __hip_bfloat16* out;
  int j;
  if (i < 65536)       { in = p0; out = o0; j = i; }
  else if (i < 163840) { in = p1; out = o1; j = i - 65536; }
  else if (i < 262144) { in = p2; out = o2; j = i - 163840; }
  else if (i < 655360) { in = p3; out = o3; j = i - 262144; }
  else                 { in = p4; out = o4; j = i - 655360; }
  float4 v = ((const float4*)in)[j];
  union { ushort4 u; __hip_bfloat16 h[4]; } p;
  p.h[0] = __float2bfloat16(v.x);
  p.h[1] = __float2bfloat16(v.y);
  p.h[2] = __float2bfloat16(v.z);
  p.h[3] = __float2bfloat16(v.w);
  ((ushort4*)out)[j] = p.u;
}

// combined so+aw weight staging: [6][384][256] bf16 (+ bias at tail blocks)
__global__ void sowa_prep_kernel(const float* __restrict__ so_w,
                                 const float* __restrict__ aw_w,
                                 const float* __restrict__ so_b,
                                 const float* __restrict__ aw_b,
                                 __hip_bfloat16* __restrict__ out,
                                 float* __restrict__ bias_out) {
  int i = blockIdx.x * 256 + threadIdx.x;
  if (i < 6 * 384 * 256) {
    int il = i / (384 * 256);
    int rem = i - il * 384 * 256;
    int n = rem >> 8, k = rem & 255;
    float v = (n < 256) ? so_w[(size_t)il * 65536 + n * 256 + k]
                        : aw_w[(size_t)il * 32768 + (n - 256) * 256 + k];
    out[i] = __float2bfloat16(v);
  } else if (i < 6 * 384 * 256 + 6 * 384) {
    int j = i - 6 * 384 * 256;
    int il = j / 384, n = j % 384;
    bias_out[j] = (n < 256) ? so_b[il * 256 + n] : aw_b[il * 128 + n - 256];
  }
}

// conv1 weight staging: wc1[oc][tap*256+ic] = bf16(c1_w[oc][ic][tap])
__global__ void wc1_prep_kernel(const float* __restrict__ w,
                                __hip_bfloat16* __restrict__ out) {
  int i = blockIdx.x * 256 + threadIdx.x;
  if (i >= 64 * 2304) return;
  int oc = i / 2304, r = i % 2304;
  int tap = r >> 8, ic = r & 255;
  out[i] = __float2bfloat16(w[(size_t)oc * 2304 + ic * 9 + tap]);
}

// ---------------------------------------------------------------------------
// transpose+convert: f[l][b][c][hw] fp32 -> ft (level-major) [l][b][hw][c] bf16
// ---------------------------------------------------------------------------
__global__ __launch_bounds__(256) void transpose_f_kernel(
    const float* __restrict__ f0, const float* __restrict__ f1,
    const float* __restrict__ f2, const float* __restrict__ f3,
    __hip_bfloat16* __restrict__ ft) {
  __shared__ float tile[64][65];
  const int HWs[4] = {4096, 1024, 256, 64};
  const int STs[4] = {0, 4096, 5120, 5376};
  int chunk = blockIdx.x, c0 = blockIdx.y * 64, b = blockIdx.z;
  int l, row0;
  get_chunk(chunk, l, row0);
  const float* fin = (l == 0) ? f0 : (l == 1) ? f1 : (l == 2) ? f2 : f3;
  const int HW = HWs[l];
  int t = threadIdx.x;
  int cr = t >> 4, hc4 = (t & 15) * 4;
#pragma unroll
  for (int p = 0; p < 4; ++p) {
    int c = c0 + p * 16 + cr;
    float4 v = *(const float4*)&fin[(size_t)(b * 256 + c) * HW + row0 + hc4];
    tile[p * 16 + cr][hc4 + 0] = v.x;
    tile[p * 16 + cr][hc4 + 1] = v.y;
    tile[p * 16 + cr][hc4 + 2] = v.z;
    tile[p * 16 + cr][hc4 + 3] = v.w;
  }
  __syncthreads();
  size_t obase = (size_t)2 * STs[l] * 256 + ((size_t)b * HW + row0) * 256 + c0;
#pragma unroll
  for (int p = 0; p < 4; ++p) {
    int r = p * 16 + cr;
    union { ushort4 u; __hip_bfloat16 h[4]; } pk;
    pk.h[0] = __float2bfloat16(tile[hc4 + 0][r]);
    pk.h[1] = __float2bfloat16(tile[hc4 + 1][r]);
    pk.h[2] = __float2bfloat16(tile[hc4 + 2][r]);
    pk.h[3] = __float2bfloat16(tile[hc4 + 3][r]);
    *(ushort4*)&ft[obase + (size_t)r * 256 + hc4] = pk.u;
  }
}

// ---------------------------------------------------------------------------
// GroupNorm stats, 2-stage coalesced.
// ---------------------------------------------------------------------------
__global__ __launch_bounds__(256) void gn_part_kernel(const float* __restrict__ x,
                                                      float2* __restrict__ part) {
  const int STs[4] = {0, 4096, 5120, 5376};
  int chunk = blockIdx.x, b = blockIdx.y;
  int l, row0;
  get_chunk(chunk, l, row0);
  size_t base = ((size_t)b * LQ + STs[l] + row0) * 256;
  int t = threadIdx.x;
  int col4 = t & 63, rb = t >> 6;
  float s = 0.f, ss = 0.f;
#pragma unroll 4
  for (int i = 0; i < 16; ++i) {
    int r = rb + i * 4;
    float4 v = *(const float4*)&x[base + (size_t)r * 256 + col4 * 4];
    s += v.x + v.y + v.z + v.w;
    ss += v.x * v.x + v.y * v.y + v.z * v.z + v.w * v.w;
  }
  __shared__ float sA[256], sB[256];
  sA[t] = s;
  sB[t] = ss;
  __syncthreads();
  if (t < 64) {
    s = sA[t] + sA[t + 64] + sA[t + 128] + sA[t + 192];
    ss = sB[t] + sB[t + 64] + sB[t + 128] + sB[t + 192];
    sA[t] = s;
    sB[t] = ss;
  }
  __syncthreads();
  if (t < 32)
    part[((size_t)b * 85 + chunk) * 32 + t] =
        make_float2(sA[2 * t] + sA[2 * t + 1], sB[2 * t] + sB[2 * t + 1]);
}

__global__ void gn_finalize_kernel(const float2* __restrict__ part,
                                   float2* __restrict__ stats) {
  int t = threadIdx.x;  // 256 = 2b * 4l * 32g
  int b = t >> 7, rem = t & 127, l = rem >> 5, g = rem & 31;
  const int cnt_[4] = {64, 16, 4, 1};
  const int cb_[4] = {0, 64, 80, 84};
  const int HWs[4] = {4096, 1024, 256, 64};
  float s = 0.f, ss = 0.f;
  for (int i = 0; i < cnt_[l]; ++i) {
    float2 v = part[((size_t)b * 85 + cb_[l] + i) * 32 + g];
    s += v.x;
    ss += v.y;
  }
  float n = (float)(HWs[l] * 8);
  float mu = s / n;
  float var = ss / n - mu * mu;
  stats[(b * 4 + l) * 32 + g] = make_float2(mu, rsqrtf(var + 1e-5f));
}

// ---------------------------------------------------------------------------
__device__ __forceinline__ void get_level(int t, int& l, int& hw, int& Hl, int& Wl) {
  if (t < 4096)      { l = 0; hw = t;        Hl = 64; Wl = 64; }
  else if (t < 5120) { l = 1; hw = t - 4096; Hl = 32; Wl = 32; }
  else if (t < 5376) { l = 2; hw = t - 5120; Hl = 16; Wl = 16; }
  else               { l = 3; hw = t - 5376; Hl = 8;  Wl = 8;  }
}

// GN apply + bf16 shadow + qb = bf16(x + pos)
__global__ void gn_apply_kernel(float* __restrict__ x, __hip_bfloat16* __restrict__ xb,
                                __hip_bfloat16* __restrict__ qb,
                                const float* __restrict__ pos,
                                const float2* __restrict__ stats,
                                const float* __restrict__ gw, const float* __restrict__ gb) {
  int idx = blockIdx.x * 256 + threadIdx.x;
  if (idx >= BATCH * LQ * CDIM) return;
  int c = idx & 255;
  int tok = idx >> 8;
  int b = tok / LQ, t = tok % LQ;
  int l, hw, Hl, Wl;
  get_level(t, l, hw, Hl, Wl);
  float2 st = stats[(b * 4 + l) * 32 + (c >> 3)];
  float v = (x[idx] - st.x) * st.y * gw[l * CDIM + c] + gb[l * CDIM + c];
  x[idx] = v;
  xb[idx] = __float2bfloat16(v);
  qb[idx] = __float2bfloat16(v + pos[t * 256 + c]);
}

__global__ void pos_embed_kernel(const float* __restrict__ level_embed,
                                 float* __restrict__ pos) {
  int idx = blockIdx.x * 256 + threadIdx.x;
  if (idx >= LQ * CDIM) return;
  int t = idx >> 8, c = idx & 255;
  int l, hw, Hl, Wl;
  get_level(t, l, hw, Hl, Wl);
  int y = hw / Wl, xx = hw % Wl;
  const float twopi = 6.28318530717958647692f;
  float v; int cc;
  if (c < 128) { v = (float)(y + 1) * twopi / ((float)Hl + 1e-6f); cc = c; }
  else         { v = (float)(xx + 1) * twopi / ((float)Wl + 1e-6f); cc = c - 128; }
  int k = cc >> 1;
  float dim_t = expf((float)k * (logf(10000.0f) / 64.0f));
  float p = v / dim_t;
  float e = (cc & 1) ? cosf(p) : sinf(p);
  pos[idx] = e + level_embed[l * CDIM + c];
}

__global__ void ref_kernel(float* __restrict__ ref) {
  int t = blockIdx.x * 256 + threadIdx.x;
  if (t >= LQ) return;
  int l, hw, Hl, Wl;
  get_level(t, l, hw, Hl, Wl);
  int y = hw / Wl, xx = hw % Wl;
  ref[t * 2]     = ((float)xx + 0.5f) / (float)Wl;
  ref[t * 2 + 1] = ((float)y + 0.5f) / (float)Hl;
}

// ---------------------------------------------------------------------------
// Deformable attention: 8-lane group per (token, head); branchless bilinear.
// ---------------------------------------------------------------------------
__global__ __launch_bounds__(256) void deform_attn_kernel(
    const __hip_bfloat16* __restrict__ value, const float* __restrict__ comb,
    const float* __restrict__ ref, __hip_bfloat16* __restrict__ out) {
  const int Wl_[4] = {64, 32, 16, 8};
  const int st_[4] = {0, 4096, 5120, 5376};
  int gid = blockIdx.x * 32 + (threadIdx.x >> 3);
  int lane8 = threadIdx.x & 7;
  int h = gid & 7;
  int tok = gid >> 3;
  int b = tok / LQ;
  int qi = tok - b * LQ;

  const float4* awv = (const float4*)(comb + (size_t)tok * 384 + 256 + h * 16);
  float4 q0 = awv[0], q1 = awv[1], q2 = awv[2], q3 = awv[3];
  float logit[16] = {q0.x, q0.y, q0.z, q0.w, q1.x, q1.y, q1.z, q1.w,
                     q2.x, q2.y, q2.z, q2.w, q3.x, q3.y, q3.z, q3.w};
  float mx = -1e30f;
#pragma unroll
  for (int i = 0; i < 16; ++i) mx = fmaxf(mx, logit[i]);
  const float LOG2E = 1.4426950408889634f;
  float ssum = 0.f;
#pragma unroll
  for (int i = 0; i < 16; ++i) {
    logit[i] = exp2f((logit[i] - mx) * LOG2E);
    ssum += logit[i];
  }
  float inv = 1.0f / ssum;

  float rx = ref[qi * 2], ry = ref[qi * 2 + 1];
  const float4* offv = (const float4*)(comb + (size_t)tok * 384 + h * 32);
  float acc0 = 0.f, acc1 = 0.f, acc2 = 0.f, acc3 = 0.f;

#pragma unroll
  for (int l = 0; l < 4; ++l) {
    const int Wl = Wl_[l];
    const float fW = (float)Wl;
    const __hip_bfloat16* vbase =
        value + ((size_t)b * LQ + st_[l]) * CDIM + h * 32 + lane8 * 4;
    float bx = fmaf(rx, fW, -0.5f);
    float by = fmaf(ry, fW, -0.5f);
    float4 oa = offv[l * 2], ob = offv[l * 2 + 1];
    float oxs[4] = {oa.x, oa.z, ob.x, ob.z};
    float oys[4] = {oa.y, oa.w, ob.y, ob.w};
#pragma unroll
    for (int p = 0; p < 4; ++p) {
      float px = bx + oxs[p], py = by + oys[p];
      float wgt = logit[l * 4 + p] * inv;
      float fpx = floorf(px), fpy = floorf(py);
      int x0 = (int)fpx, y0 = (int)fpy;
      float fx = px - fpx, fy = py - fpy;
      float wx0 = (x0 >= 0 && x0 < Wl) ? (1.f - fx) : 0.f;
      float wx1 = (x0 >= -1 && x0 < Wl - 1) ? fx : 0.f;
      float wy0 = (y0 >= 0 && y0 < Wl) ? (wgt * (1.f - fy)) : 0.f;
      float wy1 = (y0 >= -1 && y0 < Wl - 1) ? (wgt * fy) : 0.f;
      int xc0 = min(max(x0, 0), Wl - 1);
      int xc1 = min(max(x0 + 1, 0), Wl - 1);
      int yc0 = min(max(y0, 0), Wl - 1);
      int yc1 = min(max(y0 + 1, 0), Wl - 1);
      const __hip_bfloat16* r0 = vbase + (size_t)(yc0 * Wl) * CDIM;
      const __hip_bfloat16* r1 = vbase + (size_t)(yc1 * Wl) * CDIM;
      ushort4 u00 = *(const ushort4*)(r0 + (size_t)xc0 * CDIM);
      ushort4 u01 = *(const ushort4*)(r0 + (size_t)xc1 * CDIM);
      ushort4 u10 = *(const ushort4*)(r1 + (size_t)xc0 * CDIM);
      ushort4 u11 = *(const ushort4*)(r1 + (size_t)xc1 * CDIM);
      float w00 = wy0 * wx0, w01 = wy0 * wx1, w10 = wy1 * wx0, w11 = wy1 * wx1;
      acc0 = fmaf(w00, __uint_as_float((unsigned)u00.x << 16), acc0);
      acc1 = fmaf(w00, __uint_as_float((unsigned)u00.y << 16), acc1);
      acc2 = fmaf(w00, __uint_as_float((unsigned)u00.z << 16), acc2);
      acc3 = fmaf(w00, __uint_as_float((unsigned)u00.w << 16), acc3);
      acc0 = fmaf(w01, __uint_as_float((unsigned)u01.x << 16), acc0);
      acc1 = fmaf(w01, __uint_as_float((unsigned)u01.y << 16), acc1);
      acc2 = fmaf(w01, __uint_as_float((unsigned)u01.z << 16), acc2);
      acc3 = fmaf(w01, __uint_as_float((unsigned)u01.w << 16), acc3);
      acc0 = fmaf(w10, __uint_as_float((unsigned)u10.x << 16), acc0);
      acc1 = fmaf(w10, __uint_as_float((unsigned)u10.y << 16), acc1);
      acc2 = fmaf(w10, __uint_as_float((unsigned)u10.z << 16), acc2);
      acc3 = fmaf(w10, __uint_as_float((unsigned)u10.w << 16), acc3);
      acc0 = fmaf(w11, __uint_as_float((unsigned)u11.x << 16), acc0);
      acc1 = fmaf(w11, __uint_as_float((unsigned)u11.y << 16), acc1);
      acc2 = fmaf(w11, __uint_as_float((unsigned)u11.z << 16), acc2);
      acc3 = fmaf(w11, __uint_as_float((unsigned)u11.w << 16), acc3);
    }
  }
  union { ushort4 u; __hip_bfloat16 hh[4]; } pk;
  pk.hh[0] = __float2bfloat16(acc0);
  pk.hh[1] = __float2bfloat16(acc1);
  pk.hh[2] = __float2bfloat16(acc2);
  pk.hh[3] = __float2bfloat16(acc3);
  *(ushort4*)(out + (size_t)tok * CDIM + h * 32 + lane8 * 4) = pk.u;
}

// conv2 NHWC split over taps: part[tap][b][pix][2]
__global__ __launch_bounds__(256) void conv2_part_kernel(
    const __hip_bfloat16* __restrict__ c1o, const float* __restrict__ w,
    float* __restrict__ part) {
  int pix = blockIdx.x * 256 + threadIdx.x;
  int tap = blockIdx.y, b = blockIdx.z;
  int y = pix >> 6, x = pix & 63;
  int dy = tap / 3 - 1, dx = tap % 3 - 1;
  int yy = y + dy, xx = x + dx;
  bool ok = (yy >= 0 && yy < 64 && xx >= 0 && xx < 64);
  float a0 = 0.f, a1 = 0.f;
  if (ok) {
    const __hip_bfloat16* row = c1o + (size_t)(b * 4096 + yy * 64 + xx) * 64;
#pragma unroll
    for (int ic4 = 0; ic4 < 16; ++ic4) {
      ushort4 u = *(const ushort4*)(row + ic4 * 4);
      float f0 = __uint_as_float((unsigned)u.x << 16);
      float f1 = __uint_as_float((unsigned)u.y << 16);
      float f2 = __uint_as_float((unsigned)u.z << 16);
      float f3 = __uint_as_float((unsigned)u.w << 16);
      int ic = ic4 * 4;
      a0 = fmaf(w[(ic + 0) * 9 + tap], f0, a0);
      a0 = fmaf(w[(ic + 1) * 9 + tap], f1, a0);
      a0 = fmaf(w[(ic + 2) * 9 + tap], f2, a0);
      a0 = fmaf(w[(ic + 3) * 9 + tap], f3, a0);
      a1 = fmaf(w[576 + (ic + 0) * 9 + tap], f0, a1);
      a1 = fmaf(w[576 + (ic + 1) * 9 + tap], f1, a1);
      a1 = fmaf(w[576 + (ic + 2) * 9 + tap], f2, a1);
      a1 = fmaf(w[576 + (ic + 3) * 9 + tap], f3, a1);
    }
  }
  float2 o = make_float2(a0, a1);
  *(float2*)&part[((size_t)(tap * BATCH + b) * 4096 + pix) * 2] = o;
}

// sum 9 taps + bias -> c2o [b][pix][2]
__global__ void conv2_reduce_kernel(const float* __restrict__ part,
                                    const float* __restrict__ bias,
                                    float* __restrict__ out) {
  int i = blockIdx.x * 256 + threadIdx.x;
  if (i >= BATCH * 4096) return;
  int b = i >> 12, pix = i & 4095;
  float s0 = bias[0], s1 = bias[1];
#pragma unroll
  for (int tap = 0; tap < 9; ++tap) {
    float2 v = *(const float2*)&part[((size_t)(tap * BATCH + b) * 4096 + pix) * 2];
    s0 += v.x; s1 += v.y;
  }
  *(float2*)&out[(size_t)i * 2] = make_float2(s0, s1);
}

// 4x bilinear upsample 64->256; input layout [b][pix][2]
__global__ void upsample_kernel(const float* __restrict__ in, float* __restrict__ out) {
  int idx = blockIdx.x * 256 + threadIdx.x;
  if (idx >= BATCH * 2 * 256 * 256) return;
  int X = idx & 255, Y = (idx >> 8) & 255, p = idx >> 16;
  int b = p >> 1, oc = p & 1;
  float tx = ((float)X + 0.5f) * 0.25f - 0.5f;
  float ty = ((float)Y + 0.5f) * 0.25f - 0.5f;
  float fxf = floorf(tx), fyf = floorf(ty);
  int x0 = (int)fxf, y0 = (int)fyf;
  float fx = tx - fxf, fy = ty - fyf;
  int x0c = min(max(x0, 0), 63), x1c = min(max(x0 + 1, 0), 63);
  int y0c = min(max(y0, 0), 63), y1c = min(max(y0 + 1, 0), 63);
  const float* ip = in + (size_t)b * 4096 * 2 + oc;
  float v = (1.f - fy) * ((1.f - fx) * ip[(y0c * 64 + x0c) * 2] + fx * ip[(y0c * 64 + x1c) * 2]) +
            fy * ((1.f - fx) * ip[(y1c * 64 + x0c) * 2] + fx * ip[(y1c * 64 + x1c) * 2]);
  out[idx] = v;
}

// ---------------------------------------------------------------------------
extern "C" void kernel_launch(void* const* d_in, const int* in_sizes, int n_in,
                              void* d_out, int out_size, void* d_ws, size_t ws_size,
                              hipStream_t stream) {
  const float* f[4] = {(const float*)d_in[0], (const float*)d_in[1],
                       (const float*)d_in[2], (const float*)d_in[3]};
  const float* proj_w = (const float*)d_in[4];
  const float* proj_b = (const float*)d_in[5];
  const float* gn_w = (const float*)d_in[6];
  const float* gn_b = (const float*)d_in[7];
  const float* level_embed = (const float*)d_in[8];
  const float* so_w = (const float*)d_in[9];
  const float* so_b = (const float*)d_in[10];
  const float* aw_w = (const float*)d_in[11];
  const float* aw_b = (const float*)d_in[12];
  const float* vp_w = (const float*)d_in[13];
  const float* vp_b = (const float*)d_in[14];
  const float* op_w = (const float*)d_in[15];
  const float* op_b = (const float*)d_in[16];
  const float* n1_w = (const float*)d_in[17];
  const float* n1_b = (const float*)d_in[18];
  const float* l1_w = (const float*)d_in[19];
  const float* l1_b = (const float*)d_in[20];
  const float* l2_w = (const float*)d_in[21];
  const float* l2_b = (const float*)d_in[22];
  const float* n2_w = (const float*)d_in[23];
  const float* n2_b = (const float*)d_in[24];
  const float* c1_w = (const float*)d_in[25];
  const float* c1_b = (const float*)d_in[26];
  const float* c2_w = (const float*)d_in[27];
  const float* c2_b = (const float*)d_in[28];
  (void)in_sizes; (void)n_in; (void)out_size; (void)ws_size;

  float* ws = (float*)d_ws;
  const size_t TOK = (size_t)BATCH * LQ * CDIM;  // 2785280
  size_t o = 0;
  float* x = ws + o;     o += TOK;
  float* comb = ws + o;  o += (size_t)BATCH * LQ * 384;
  float* pos = ws + o;   o += (size_t)LQ * CDIM;
  float* refb = ws + o;  o += 11008;
  float2* stats = (float2*)(ws + o); o += 512;
  float* zerof = ws + o; o += 256;
  float* sowa_bias = ws + o; o += 2304;
  float2* gnpart = (float2*)(ws + o); o += 11008;
  __hip_bfloat16* xb = (__hip_bfloat16*)(ws + o);    o += TOK / 2;
  __hip_bfloat16* qb = (__hip_bfloat16*)(ws + o);    o += TOK / 2;
  __hip_bfloat16* valb = (__hip_bfloat16*)(ws + o);  o += TOK / 2;
  __hip_bfloat16* attnb = (__hip_bfloat16*)(ws + o); o += TOK / 2;
  __hip_bfloat16* ftb = (__hip_bfloat16*)(ws + o);   o += TOK / 2;
  __hip_bfloat16* ff1b = (__hip_bfloat16*)(ws + o);  o += (size_t)BATCH * LQ * FFDIM / 2;
  __hip_bfloat16* sowa_wb = (__hip_bfloat16*)(ws + o); o += 294912;
  __hip_bfloat16* vp_wb = (__hip_bfloat16*)(ws + o); o += 196608;
  __hip_bfloat16* op_wb = (__hip_bfloat16*)(ws + o); o += 196608;
  __hip_bfloat16* l1_wb = (__hip_bfloat16*)(ws + o); o += 786432;
  __hip_bfloat16* l2_wb = (__hip_bfloat16*)(ws + o); o += 786432;
  __hip_bfloat16* proj_wb = (__hip_bfloat16*)(ws + o); o += 131072;
  __hip_bfloat16* wc1b = (__hip_bfloat16*)(ws + o);  o += 73728;
  // head scratch aliases ff1b region (free after encoder)
  __hip_bfloat16* c1ob = ff1b;
  float* part2 = (float*)(ff1b + 524288);
  float* c2o = part2 + 147456;

  const int HWs[4] = {4096, 1024, 256, 64};
  const int STs[4] = {0, 4096, 5120, 5376};

  // 0) staging (4 dispatches)
  hipMemsetAsync(zerof, 0, 1024, stream);
  sowa_prep_kernel<<<(6 * 384 * 256 + 6 * 384 + 255) / 256, 256, 0, stream>>>(
      so_w, aw_w, so_b, aw_b, sowa_wb, sowa_bias);
  wc1_prep_kernel<<<(147456 + 255) / 256, 256, 0, stream>>>(c1_w, wc1b);
  f2b_multi_kernel<<<(1048576 + 255) / 256, 256, 0, stream>>>(
      proj_w, vp_w, op_w, l1_w, l2_w, proj_wb, vp_wb, op_wb, l1_wb, l2_wb);

  // 1) input transpose+convert, then bf16 MFMA input-proj (remapped output)
  transpose_f_kernel<<<dim3(85, 4, BATCH), 256, 0, stream>>>(f[0], f[1], f[2], f[3],
                                                             ftb);
  for (int l = 0; l < 4; ++l) {
    int M2 = 2 * HWs[l];
    gemm_bf16_kernel<false, true, false, true><<<dim3(2, M2 / 128), 256, 0, stream>>>(
        ftb + (size_t)2 * STs[l] * 256, proj_wb + (size_t)l * 65536,
        proj_b + (size_t)l * 256, x, nullptr, M2, 256, 256,
        HWs[l], (long)STs[l] * 256, (long)LQ * 256);
  }
  // 2) pos embed + ref
  pos_embed_kernel<<<(LQ * CDIM + 255) / 256, 256, 0, stream>>>(level_embed, pos);
  ref_kernel<<<(LQ + 255) / 256, 256, 0, stream>>>(refb);
  // 3) GroupNorm (2-stage stats + apply)
  gn_part_kernel<<<dim3(85, BATCH), 256, 0, stream>>>(x, gnpart);
  gn_finalize_kernel<<<1, 256, 0, stream>>>(gnpart, stats);
  {
    int n = BATCH * LQ * CDIM;
    gn_apply_kernel<<<(n + 255) / 256, 256, 0, stream>>>(x, xb, qb, pos, stats,
                                                         gn_w, gn_b);
  }

  const int M = BATCH * LQ;  // 10880 = 85 * 128 = 170 * 64
  for (int i = 0; i < 6; ++i) {
    const __hip_bfloat16* sowa = sowa_wb + (size_t)i * 98304;
    const __hip_bfloat16* vw = vp_wb + (size_t)i * 65536;
    const __hip_bfloat16* ow = op_wb + (size_t)i * 65536;
    const __hip_bfloat16* w1 = l1_wb + (size_t)i * 262144;
    const __hip_bfloat16* w2 = l2_wb + (size_t)i * 262144;
    const float* vb = vp_b + (size_t)i * CDIM;
    const float* ob = op_b + (size_t)i * CDIM;
    const float* b1 = l1_b + (size_t)i * FFDIM;
    const float* b2 = l2_b + (size_t)i * CDIM;

    gemm_bf16_kernel<false, false, true, false><<<dim3(2, 85), 256, 0, stream>>>(
        xb, vw, vb, nullptr, valb, M, CDIM, CDIM, 0, 0, 0);
    gemm_bf16_kernel<false, true, false, false><<<dim3(3, 85), 256, 0, stream>>>(
        qb, sowa, sowa_bias + i * 384, comb, nullptr, M, 384, CDIM, 0, 0, 0);
    deform_attn_kernel<<<BATCH * LQ * 8 / 32, 256, 0, stream>>>(valb, comb, refb,
                                                                attnb);
    // fused: x = LN(x + attnb@ow^T + ob), emits xb
    gemm_ln_kernel<false><<<170, 256, 0, stream>>>(
        attnb, ow, ob, x, xb, nullptr, nullptr,
        n1_w + (size_t)i * CDIM, n1_b + (size_t)i * CDIM, CDIM);
    gemm_bf16_kernel<true, false, true, false><<<dim3(8, 85), 256, 0, stream>>>(
        xb, w1, b1, nullptr, ff1b, M, FFDIM, CDIM, 0, 0, 0);
    // fused: x = LN(x + ff1b@w2^T + b2), emits xb and qb = bf16(x+pos)
    gemm_ln_kernel<true><<<170, 256, 0, stream>>>(
        ff1b, w2, b2, x, xb, qb, pos,
        n2_w + (size_t)i * CDIM, n2_b + (size_t)i * CDIM, FFDIM);
  }

  // head
  conv1_mfma_kernel<<<64, 256, 0, stream>>>(xb, wc1b, c1_b,
                                            (const __hip_bfloat16*)zerof, c1ob);
  conv2_part_kernel<<<dim3(16, 9, BATCH), 256, 0, stream>>>(c1ob, c2_w, part2);
  conv2_reduce_kernel<<<(BATCH * 4096 + 255) / 256, 256, 0, stream>>>(part2, c2_b,
                                                                      c2o);
  {
    int n = BATCH * 2 * 256 * 256;
    upsample_kernel<<<(n + 255) / 256, 256, 0, stream>>>(c2o, (float*)d_out);
  }
}

// Round 10
// 636.789 us; speedup vs baseline: 5.1332x; 1.1231x over previous
//
#include <hip/hip_runtime.h>
#include <hip/hip_bf16.h>
#include <math.h>

#define LQ 5440
#define CDIM 256
#define BATCH 2
#define FFDIM 1024

typedef __attribute__((ext_vector_type(8))) short bf16x8;
typedef __attribute__((ext_vector_type(4))) float f32x4;

typedef __attribute__((address_space(1))) void* gas1_t;
typedef __attribute__((address_space(3))) void* las3_t;

__device__ __forceinline__ void async16(const void* g, void* l) {
  __builtin_amdgcn_global_load_lds((gas1_t)g, (las3_t)l, 16, 0, 0);
}

#define WAIT_VM5() asm volatile("s_waitcnt vmcnt(5)" ::: "memory")
#define WAIT_VM4() asm volatile("s_waitcnt vmcnt(4)" ::: "memory")
#define WAIT_VM3() asm volatile("s_waitcnt vmcnt(3)" ::: "memory")
#define WAIT_VM2() asm volatile("s_waitcnt vmcnt(2)" ::: "memory")
#define WAIT_VM0() asm volatile("s_waitcnt vmcnt(0)" ::: "memory")

// chunk (0..84) -> level, row0 (64-row chunks across the 4 levels)
__device__ __forceinline__ void get_chunk(int chunk, int& l, int& row0) {
  if (chunk < 64)      { l = 0; row0 = chunk * 64; }
  else if (chunk < 80) { l = 1; row0 = (chunk - 64) * 64; }
  else if (chunk < 84) { l = 2; row0 = (chunk - 80) * 64; }
  else                 { l = 3; row0 = 0; }
}

// ---------------------------------------------------------------------------
// bf16 MFMA GEMM, 128x128 tile, 3-buffer depth-2 pipeline (ffn1 + input proj).
// ---------------------------------------------------------------------------
template <bool RELU, bool OUT_F32, bool OUT_B16, bool REMAP>
__global__ __launch_bounds__(256, 2) void gemm_bf16_kernel(
    const __hip_bfloat16* __restrict__ A, const __hip_bfloat16* __restrict__ Wt,
    const float* __restrict__ bias, float* __restrict__ C,
    __hip_bfloat16* __restrict__ Cb, int M, int N, int K,
    int mrows, long obase, long obstride) {
  __shared__ __hip_bfloat16 As[3][128 * 32];
  __shared__ __hip_bfloat16 Bs[3][128 * 32];
  const int tid = threadIdx.x;
  const int bm = blockIdx.y * 128, bn = blockIdx.x * 128;
  const int lane = tid & 63, wave = tid >> 6;
  const int wr = wave >> 1, wc = wave & 1;
  const int srow = tid >> 2;
  const int scol = (tid & 3) * 8;
  const int lo0 = srow * 32 + scol;
  const int lo1 = (64 + srow) * 32 + scol;
  const __hip_bfloat16* ga0 = A + (size_t)(bm + srow) * K + scol;
  const __hip_bfloat16* ga1 = A + (size_t)(bm + 64 + srow) * K + scol;
  const __hip_bfloat16* gb0 = Wt + (size_t)(bn + srow) * K + scol;
  const __hip_bfloat16* gb1 = Wt + (size_t)(bn + 64 + srow) * K + scol;

  const int nt = K >> 5;
  async16(ga0, &As[0][lo0]);
  async16(ga1, &As[0][lo1]);
  async16(gb0, &Bs[0][lo0]);
  async16(gb1, &Bs[0][lo1]);
  async16(ga0 + 32, &As[1][lo0]);
  async16(ga1 + 32, &As[1][lo1]);
  async16(gb0 + 32, &Bs[1][lo0]);
  async16(gb1 + 32, &Bs[1][lo1]);

  f32x4 acc[4][4] = {};
  const int fr = lane & 15;
  const int ksub = (lane >> 4) * 8;

  int cur = 0, nxt = 2;
  for (int t = 0; t < nt; ++t) {
    if (t == nt - 1) WAIT_VM0(); else WAIT_VM4();
    __builtin_amdgcn_s_barrier();
    asm volatile("" ::: "memory");
    bf16x8 af[4], bfv[4];
    const __hip_bfloat16* as = As[cur];
    const __hip_bfloat16* bs = Bs[cur];
#pragma unroll
    for (int mi = 0; mi < 4; ++mi)
      af[mi] = *(const bf16x8*)&as[(wr * 64 + mi * 16 + fr) * 32 + ksub];
#pragma unroll
    for (int nj = 0; nj < 4; ++nj)
      bfv[nj] = *(const bf16x8*)&bs[(wc * 64 + nj * 16 + fr) * 32 + ksub];
    if (t + 2 < nt) {
      const int ko = (t + 2) * 32;
      async16(ga0 + ko, &As[nxt][lo0]);
      async16(ga1 + ko, &As[nxt][lo1]);
      async16(gb0 + ko, &Bs[nxt][lo0]);
      async16(gb1 + ko, &Bs[nxt][lo1]);
    }
#pragma unroll
    for (int mi = 0; mi < 4; ++mi)
#pragma unroll
      for (int nj = 0; nj < 4; ++nj)
        acc[mi][nj] = __builtin_amdgcn_mfma_f32_16x16x32_bf16(af[mi], bfv[nj],
                                                              acc[mi][nj], 0, 0, 0);
    cur = (cur == 2) ? 0 : cur + 1;
    nxt = (nxt == 2) ? 0 : nxt + 1;
  }

  const int cc = lane & 15;
  const int rbase = (lane >> 4) * 4;
  float bcol[4];
#pragma unroll
  for (int nj = 0; nj < 4; ++nj) bcol[nj] = bias[bn + wc * 64 + nj * 16 + cc];
#pragma unroll
  for (int mi = 0; mi < 4; ++mi)
#pragma unroll
    for (int nj = 0; nj < 4; ++nj) {
      int col = bn + wc * 64 + nj * 16 + cc;
#pragma unroll
      for (int r = 0; r < 4; ++r) {
        int row = bm + wr * 64 + mi * 16 + rbase + r;
        float v = acc[mi][nj][r] + bcol[nj];
        if (RELU) v = fmaxf(v, 0.f);
        if (OUT_F32) {
          size_t oaddr;
          if (REMAP)
            oaddr = (size_t)obase +
                    (row < mrows ? (size_t)row * N
                                 : (size_t)obstride + (size_t)(row - mrows) * N) +
                    col;
          else
            oaddr = (size_t)row * N + col;
          C[oaddr] = v;
        }
        if (OUT_B16) Cb[(size_t)row * N + col] = __float2bfloat16(v);
      }
    }
}

// ---------------------------------------------------------------------------
// 64x128-tile GEMM body (4 waves, each 64 rows x 32 cols). 3 loads/thread/stage.
// ---------------------------------------------------------------------------
template <bool OUT_F32, bool OUT_B16>
__device__ __forceinline__ void gemm64_body(
    const __hip_bfloat16* __restrict__ A, const __hip_bfloat16* __restrict__ Wt,
    const float* __restrict__ bias, float* __restrict__ C,
    __hip_bfloat16* __restrict__ Cb, int bm, int bn, int N, int K,
    __hip_bfloat16 (*As)[64 * 32], __hip_bfloat16 (*Bs)[128 * 32]) {
  const int tid = threadIdx.x;
  const int lane = tid & 63, wv = tid >> 6;
  const int srow = tid >> 2, scol = (tid & 3) * 8;
  const int loA = srow * 32 + scol;
  const int loB1 = (64 + srow) * 32 + scol;
  const __hip_bfloat16* ga = A + (size_t)(bm + srow) * K + scol;
  const __hip_bfloat16* gb0 = Wt + (size_t)(bn + srow) * K + scol;
  const __hip_bfloat16* gb1 = Wt + (size_t)(bn + 64 + srow) * K + scol;
  const int nt = K >> 5;
  async16(ga, &As[0][loA]);
  async16(gb0, &Bs[0][loA]);
  async16(gb1, &Bs[0][loB1]);
  async16(ga + 32, &As[1][loA]);
  async16(gb0 + 32, &Bs[1][loA]);
  async16(gb1 + 32, &Bs[1][loB1]);

  f32x4 acc[4][2] = {};
  const int fr = lane & 15, ksub = (lane >> 4) * 8;
  int cur = 0, nxt = 2;
  for (int t = 0; t < nt; ++t) {
    if (t == nt - 1) WAIT_VM0(); else WAIT_VM3();
    __builtin_amdgcn_s_barrier();
    asm volatile("" ::: "memory");
    bf16x8 af[4], bfv[2];
#pragma unroll
    for (int mi = 0; mi < 4; ++mi)
      af[mi] = *(const bf16x8*)&As[cur][(mi * 16 + fr) * 32 + ksub];
#pragma unroll
    for (int nj = 0; nj < 2; ++nj)
      bfv[nj] = *(const bf16x8*)&Bs[cur][(wv * 32 + nj * 16 + fr) * 32 + ksub];
    if (t + 2 < nt) {
      const int ko = (t + 2) * 32;
      async16(ga + ko, &As[nxt][loA]);
      async16(gb0 + ko, &Bs[nxt][loA]);
      async16(gb1 + ko, &Bs[nxt][loB1]);
    }
#pragma unroll
    for (int mi = 0; mi < 4; ++mi)
#pragma unroll
      for (int nj = 0; nj < 2; ++nj)
        acc[mi][nj] = __builtin_amdgcn_mfma_f32_16x16x32_bf16(af[mi], bfv[nj],
                                                              acc[mi][nj], 0, 0, 0);
    cur = (cur == 2) ? 0 : cur + 1;
    nxt = (nxt == 2) ? 0 : nxt + 1;
  }
  const int cc = lane & 15;
  const int rbase = (lane >> 4) * 4;
#pragma unroll
  for (int nj = 0; nj < 2; ++nj) {
    int col = bn + wv * 32 + nj * 16 + cc;
    float bb = bias[col];
#pragma unroll
    for (int mi = 0; mi < 4; ++mi)
#pragma unroll
      for (int r = 0; r < 4; ++r) {
        int row = bm + mi * 16 + rbase + r;
        float v = acc[mi][nj][r] + bb;
        if (OUT_F32) C[(size_t)row * N + col] = v;
        if (OUT_B16) Cb[(size_t)row * N + col] = __float2bfloat16(v);
      }
  }
}

// Dual GEMM: blocks [0,340) -> value proj (xb @ vw^T -> valb bf16, N=256);
// blocks [340,850) -> sampling offsets+weights (qb @ sowa^T -> comb f32, N=384)
__global__ __launch_bounds__(256, 4) void gemm_dual_kernel(
    const __hip_bfloat16* __restrict__ xb, const __hip_bfloat16* __restrict__ vw,
    const float* __restrict__ vb, __hip_bfloat16* __restrict__ valb,
    const __hip_bfloat16* __restrict__ qb, const __hip_bfloat16* __restrict__ sowa,
    const float* __restrict__ sbias, float* __restrict__ comb) {
  __shared__ __hip_bfloat16 As[3][64 * 32];
  __shared__ __hip_bfloat16 Bs[3][128 * 32];
  if (blockIdx.x < 340) {
    int i = blockIdx.x;
    gemm64_body<false, true>(xb, vw, vb, nullptr, valb, (i >> 1) * 64,
                             (i & 1) * 128, 256, 256, As, Bs);
  } else {
    int j = blockIdx.x - 340;
    gemm64_body<true, false>(qb, sowa, sbias, comb, nullptr, (j / 3) * 64,
                             (j % 3) * 128, 384, 256, As, Bs);
  }
}

// ---------------------------------------------------------------------------
// Fused GEMM (N=256) + residual + LayerNorm, 32-row tiles (grid 340).
// 4 waves side-by-side in N (each 32 rows x 64 cols). 5 loads/thread/stage.
// ---------------------------------------------------------------------------
template <bool EMIT_Q>
__global__ __launch_bounds__(256, 2) void gemm_ln_kernel(
    const __hip_bfloat16* __restrict__ A, const __hip_bfloat16* __restrict__ Wt,
    const float* __restrict__ bias, float* __restrict__ x,
    __hip_bfloat16* __restrict__ xb, __hip_bfloat16* __restrict__ qb,
    const float* __restrict__ pos, const float* __restrict__ lnw,
    const float* __restrict__ lnb, int K) {
  __shared__ __hip_bfloat16 As[3][32 * 32];
  __shared__ __hip_bfloat16 Bs[3][256 * 32];
  __shared__ float sred[4][32], ssred[4][32];
  const int tid = threadIdx.x;
  const int bm = blockIdx.x * 32;
  const int lane = tid & 63, wv = tid >> 6;
  const int srow = tid >> 2;             // 0..63 (B rows)
  const int arow = srow & 31;            // duplicated A rows
  const int scol = (tid & 3) * 8;
  const int loA = arow * 32 + scol;
  const __hip_bfloat16* ga = A + (size_t)(bm + arow) * K + scol;
  const __hip_bfloat16* gb = Wt + (size_t)srow * K + scol;

  const int nt = K >> 5;
  auto stage = [&](int t, int buf) {
    const int ko = t * 32;
    async16(ga + ko, &As[buf][loA]);
#pragma unroll
    for (int i = 0; i < 4; ++i)
      async16(gb + (size_t)(64 * i) * K + ko, &Bs[buf][(64 * i + srow) * 32 + scol]);
  };
  stage(0, 0);
  stage(1, 1);

  f32x4 acc[2][4] = {};
  const int fr = lane & 15;
  const int ksub = (lane >> 4) * 8;

  int cur = 0, nxt = 2;
  for (int t = 0; t < nt; ++t) {
    if (t == nt - 1) WAIT_VM0(); else WAIT_VM5();
    __builtin_amdgcn_s_barrier();
    asm volatile("" ::: "memory");
    bf16x8 af[2], bfv[4];
#pragma unroll
    for (int mi = 0; mi < 2; ++mi)
      af[mi] = *(const bf16x8*)&As[cur][(mi * 16 + fr) * 32 + ksub];
#pragma unroll
    for (int nj = 0; nj < 4; ++nj)
      bfv[nj] = *(const bf16x8*)&Bs[cur][(wv * 64 + nj * 16 + fr) * 32 + ksub];
    if (t + 2 < nt) stage(t + 2, nxt);
#pragma unroll
    for (int mi = 0; mi < 2; ++mi)
#pragma unroll
      for (int nj = 0; nj < 4; ++nj)
        acc[mi][nj] = __builtin_amdgcn_mfma_f32_16x16x32_bf16(af[mi], bfv[nj],
                                                              acc[mi][nj], 0, 0, 0);
    cur = (cur == 2) ? 0 : cur + 1;
    nxt = (nxt == 2) ? 0 : nxt + 1;
  }

  const int cc = lane & 15;
  const int rbase = (lane >> 4) * 4;
  float bcol[4], wcol[4], bncol[4];
#pragma unroll
  for (int nj = 0; nj < 4; ++nj) {
    int col = wv * 64 + nj * 16 + cc;
    bcol[nj] = bias[col];
    wcol[nj] = lnw[col];
    bncol[nj] = lnb[col];
  }
#pragma unroll
  for (int mi = 0; mi < 2; ++mi)
#pragma unroll
    for (int r = 0; r < 4; ++r) {
      int grow = bm + mi * 16 + rbase + r;
#pragma unroll
      for (int nj = 0; nj < 4; ++nj) {
        int col = wv * 64 + nj * 16 + cc;
        acc[mi][nj][r] += bcol[nj] + x[(size_t)grow * 256 + col];
      }
    }
#pragma unroll
  for (int mi = 0; mi < 2; ++mi)
#pragma unroll
    for (int r = 0; r < 4; ++r) {
      float s = 0.f, ssq = 0.f;
#pragma unroll
      for (int nj = 0; nj < 4; ++nj) {
        float v = acc[mi][nj][r];
        s += v;
        ssq += v * v;
      }
#pragma unroll
      for (int m = 1; m < 16; m <<= 1) {
        s += __shfl_xor(s, m);
        ssq += __shfl_xor(ssq, m);
      }
      if (cc == 0) {
        int row = mi * 16 + rbase + r;
        sred[wv][row] = s;
        ssred[wv][row] = ssq;
      }
    }
  __syncthreads();
#pragma unroll
  for (int mi = 0; mi < 2; ++mi)
#pragma unroll
    for (int r = 0; r < 4; ++r) {
      int row = mi * 16 + rbase + r;
      int grow = bm + row;
      float s = sred[0][row] + sred[1][row] + sred[2][row] + sred[3][row];
      float ssq = ssred[0][row] + ssred[1][row] + ssred[2][row] + ssred[3][row];
      float mu = s * (1.0f / 256.0f);
      float var = ssq * (1.0f / 256.0f) - mu * mu;
      float rsig = rsqrtf(var + 1e-5f);
      int tokp = grow >= LQ ? grow - LQ : grow;
#pragma unroll
      for (int nj = 0; nj < 4; ++nj) {
        int col = wv * 64 + nj * 16 + cc;
        float xn = (acc[mi][nj][r] - mu) * rsig * wcol[nj] + bncol[nj];
        x[(size_t)grow * 256 + col] = xn;
        xb[(size_t)grow * 256 + col] = __float2bfloat16(xn);
        if (EMIT_Q)
          qb[(size_t)grow * 256 + col] =
              __float2bfloat16(xn + pos[(size_t)tokp * 256 + col]);
      }
    }
}

// ---------------------------------------------------------------------------
// conv1 implicit GEMM (NHWC), 64-pixel tiles, 72-step pipelined K-loop.
// grid = 128 (64 tiles x B), 4 waves each 16 rows x 64 cols.
// ---------------------------------------------------------------------------
__global__ __launch_bounds__(256, 4) void conv1_mfma_kernel(
    const __hip_bfloat16* __restrict__ xb, const __hip_bfloat16* __restrict__ wc1,
    const float* __restrict__ bias, const __hip_bfloat16* __restrict__ zerob,
    __hip_bfloat16* __restrict__ c1o) {
  __shared__ __hip_bfloat16 As[3][64 * 32];
  __shared__ __hip_bfloat16 Bs[3][64 * 32];
  const int tid = threadIdx.x;
  const int b = blockIdx.x >> 6;
  const int pm = (blockIdx.x & 63) * 64;
  const int lane = tid & 63, wave = tid >> 6;
  const int sr = tid >> 2;
  const int sc = (tid & 3) * 8;
  const int lo = sr * 32 + sc;
  f32x4 acc[4] = {};
  const int fr = lane & 15, ksub = (lane >> 4) * 8;

  auto stage = [&](int kt, int buf) {
    int tap = kt >> 3;
    int kk = (kt & 7) * 32;
    int dy = tap / 3 - 1, dx = tap % 3 - 1;
    int hw = pm + sr;
    int y = (hw >> 6) + dy, x = (hw & 63) + dx;
    bool ok = (y >= 0 && y < 64 && x >= 0 && x < 64);
    const __hip_bfloat16* s =
        xb + ((size_t)(b * LQ) + y * 64 + x) * 256 + kk + sc;
    const __hip_bfloat16* wsrc = wc1 + (size_t)sr * 2304 + tap * 256 + kk + sc;
    async16(ok ? s : zerob, &As[buf][lo]);
    async16(wsrc, &Bs[buf][lo]);
  };
  stage(0, 0);
  stage(1, 1);
  int cur = 0, nxt = 2;
  for (int kt = 0; kt < 72; ++kt) {
    if (kt == 71) WAIT_VM0(); else WAIT_VM2();
    __builtin_amdgcn_s_barrier();
    asm volatile("" ::: "memory");
    bf16x8 af;
    bf16x8 bfv[4];
    af = *(const bf16x8*)&As[cur][(wave * 16 + fr) * 32 + ksub];
#pragma unroll
    for (int nj = 0; nj < 4; ++nj)
      bfv[nj] = *(const bf16x8*)&Bs[cur][(nj * 16 + fr) * 32 + ksub];
    if (kt + 2 < 72) stage(kt + 2, nxt);
#pragma unroll
    for (int nj = 0; nj < 4; ++nj)
      acc[nj] = __builtin_amdgcn_mfma_f32_16x16x32_bf16(af, bfv[nj], acc[nj], 0, 0, 0);
    cur = (cur == 2) ? 0 : cur + 1;
    nxt = (nxt == 2) ? 0 : nxt + 1;
  }
  const int cc = lane & 15;
  const int rbase = (lane >> 4) * 4;
#pragma unroll
  for (int nj = 0; nj < 4; ++nj) {
    int col = nj * 16 + cc;
    float bb = bias[col];
#pragma unroll
    for (int r = 0; r < 4; ++r) {
      int row = wave * 16 + rbase + r;
      float v = fmaxf(acc[nj][r] + bb, 0.f);
      c1o[(size_t)(b * 4096 + pm + row) * 64 + col] = __float2bfloat16(v);
    }
  }
}

// multi-section fp32 -> bf16 convert (proj, vp, op, l1, l2), float4 granules
__global__ void f2b_multi_kernel(const float* __restrict__ p0, const float* __restrict__ p1,
                                 const float* __restrict__ p2, const float* __restrict__ p3,
                                 const float* __restrict__ p4,
                                 __hip_bfloat16* __restrict__ o0, __hip_bfloat16* __restrict__ o1,
                                 __hip_bfloat16* __restrict__ o2, __hip_bfloat16* __restrict__ o3,
                                 __hip_bfloat16* __restrict__ o4) {
  int i = blockIdx.x * 256 + threadIdx.x;  // float4 index, total 1048576
  if (i >= 1048576) return;
  const float* in;
  __hip_bfloat16* out;
  int j;
  if (i < 65536)       { in = p0; out = o0; j = i; }
  else if (i < 163840) { in = p1; out = o1; j = i - 65536; }
  else if (i < 262144) { in = p2; out = o2; j = i - 163840; }
  else if (i < 655360) { in = p3; out = o3; j = i - 262144; }
  else                 { in = p4; out = o4; j = i - 655360; }
  float4 v = ((const float4*)in)[j];
  union { ushort4 u; __hip_bfloat16 h[4]; } p;
  p.h[0] = __float2bfloat16(v.x);
  p.h[1] = __float2bfloat16(v.y);
  p.h[2] = __float2bfloat16(v.z);
  p.h[3] = __float2bfloat16(v.w);
  ((ushort4*)out)[j] = p.u;
}

// combined so+aw weight staging: [6][384][256] bf16 (+ bias at tail blocks)
__global__ void sowa_prep_kernel(const float* __restrict__ so_w,
                                 const float* __restrict__ aw_w,
                                 const float* __restrict__ so_b,
                                 const float* __restrict__ aw_b,
                                 __hip_bfloat16* __restrict__ out,
                                 float* __restrict__ bias_out) {
  int i = blockIdx.x * 256 + threadIdx.x;
  if (i < 6 * 384 * 256) {
    int il = i / (384 * 256);
    int rem = i - il * 384 * 256;
    int n = rem >> 8, k = rem & 255;
    float v = (n < 256) ? so_w[(size_t)il * 65536 + n * 256 + k]
                        : aw_w[(size_t)il * 32768 + (n - 256) * 256 + k];
    out[i] = __float2bfloat16(v);
  } else if (i < 6 * 384 * 256 + 6 * 384) {
    int j = i - 6 * 384 * 256;
    int il = j / 384, n = j % 384;
    bias_out[j] = (n < 256) ? so_b[il * 256 + n] : aw_b[il * 128 + n - 256];
  }
}

// conv1 weight staging: wc1[oc][tap*256+ic] = bf16(c1_w[oc][ic][tap])
__global__ void wc1_prep_kernel(const float* __restrict__ w,
                                __hip_bfloat16* __restrict__ out) {
  int i = blockIdx.x * 256 + threadIdx.x;
  if (i >= 64 * 2304) return;
  int oc = i / 2304, r = i % 2304;
  int tap = r >> 8, ic = r & 255;
  out[i] = __float2bfloat16(w[(size_t)oc * 2304 + ic * 9 + tap]);
}

// ---------------------------------------------------------------------------
// transpose+convert: f[l][b][c][hw] fp32 -> ft (level-major) [l][b][hw][c] bf16
// ---------------------------------------------------------------------------
__global__ __launch_bounds__(256) void transpose_f_kernel(
    const float* __restrict__ f0, const float* __restrict__ f1,
    const float* __restrict__ f2, const float* __restrict__ f3,
    __hip_bfloat16* __restrict__ ft) {
  __shared__ float tile[64][65];
  const int HWs[4] = {4096, 1024, 256, 64};
  const int STs[4] = {0, 4096, 5120, 5376};
  int chunk = blockIdx.x, c0 = blockIdx.y * 64, b = blockIdx.z;
  int l, row0;
  get_chunk(chunk, l, row0);
  const float* fin = (l == 0) ? f0 : (l == 1) ? f1 : (l == 2) ? f2 : f3;
  const int HW = HWs[l];
  int t = threadIdx.x;
  int cr = t >> 4, hc4 = (t & 15) * 4;
#pragma unroll
  for (int p = 0; p < 4; ++p) {
    int c = c0 + p * 16 + cr;
    float4 v = *(const float4*)&fin[(size_t)(b * 256 + c) * HW + row0 + hc4];
    tile[p * 16 + cr][hc4 + 0] = v.x;
    tile[p * 16 + cr][hc4 + 1] = v.y;
    tile[p * 16 + cr][hc4 + 2] = v.z;
    tile[p * 16 + cr][hc4 + 3] = v.w;
  }
  __syncthreads();
  size_t obase = (size_t)2 * STs[l] * 256 + ((size_t)b * HW + row0) * 256 + c0;
#pragma unroll
  for (int p = 0; p < 4; ++p) {
    int r = p * 16 + cr;
    union { ushort4 u; __hip_bfloat16 h[4]; } pk;
    pk.h[0] = __float2bfloat16(tile[hc4 + 0][r]);
    pk.h[1] = __float2bfloat16(tile[hc4 + 1][r]);
    pk.h[2] = __float2bfloat16(tile[hc4 + 2][r]);
    pk.h[3] = __float2bfloat16(tile[hc4 + 3][r]);
    *(ushort4*)&ft[obase + (size_t)r * 256 + hc4] = pk.u;
  }
}

// ---------------------------------------------------------------------------
// GroupNorm stats, 2-stage coalesced.
// ---------------------------------------------------------------------------
__global__ __launch_bounds__(256) void gn_part_kernel(const float* __restrict__ x,
                                                      float2* __restrict__ part) {
  const int STs[4] = {0, 4096, 5120, 5376};
  int chunk = blockIdx.x, b = blockIdx.y;
  int l, row0;
  get_chunk(chunk, l, row0);
  size_t base = ((size_t)b * LQ + STs[l] + row0) * 256;
  int t = threadIdx.x;
  int col4 = t & 63, rb = t >> 6;
  float s = 0.f, ss = 0.f;
#pragma unroll 4
  for (int i = 0; i < 16; ++i) {
    int r = rb + i * 4;
    float4 v = *(const float4*)&x[base + (size_t)r * 256 + col4 * 4];
    s += v.x + v.y + v.z + v.w;
    ss += v.x * v.x + v.y * v.y + v.z * v.z + v.w * v.w;
  }
  __shared__ float sA[256], sB[256];
  sA[t] = s;
  sB[t] = ss;
  __syncthreads();
  if (t < 64) {
    s = sA[t] + sA[t + 64] + sA[t + 128] + sA[t + 192];
    ss = sB[t] + sB[t + 64] + sB[t + 128] + sB[t + 192];
    sA[t] = s;
    sB[t] = ss;
  }
  __syncthreads();
  if (t < 32)
    part[((size_t)b * 85 + chunk) * 32 + t] =
        make_float2(sA[2 * t] + sA[2 * t + 1], sB[2 * t] + sB[2 * t + 1]);
}

__global__ void gn_finalize_kernel(const float2* __restrict__ part,
                                   float2* __restrict__ stats) {
  int t = threadIdx.x;  // 256 = 2b * 4l * 32g
  int b = t >> 7, rem = t & 127, l = rem >> 5, g = rem & 31;
  const int cnt_[4] = {64, 16, 4, 1};
  const int cb_[4] = {0, 64, 80, 84};
  const int HWs[4] = {4096, 1024, 256, 64};
  float s = 0.f, ss = 0.f;
  for (int i = 0; i < cnt_[l]; ++i) {
    float2 v = part[((size_t)b * 85 + cb_[l] + i) * 32 + g];
    s += v.x;
    ss += v.y;
  }
  float n = (float)(HWs[l] * 8);
  float mu = s / n;
  float var = ss / n - mu * mu;
  stats[(b * 4 + l) * 32 + g] = make_float2(mu, rsqrtf(var + 1e-5f));
}

// ---------------------------------------------------------------------------
__device__ __forceinline__ void get_level(int t, int& l, int& hw, int& Hl, int& Wl) {
  if (t < 4096)      { l = 0; hw = t;        Hl = 64; Wl = 64; }
  else if (t < 5120) { l = 1; hw = t - 4096; Hl = 32; Wl = 32; }
  else if (t < 5376) { l = 2; hw = t - 5120; Hl = 16; Wl = 16; }
  else               { l = 3; hw = t - 5376; Hl = 8;  Wl = 8;  }
}

// GN apply + bf16 shadow + qb = bf16(x + pos)
__global__ void gn_apply_kernel(float* __restrict__ x, __hip_bfloat16* __restrict__ xb,
                                __hip_bfloat16* __restrict__ qb,
                                const float* __restrict__ pos,
                                const float2* __restrict__ stats,
                                const float* __restrict__ gw, const float* __restrict__ gb) {
  int idx = blockIdx.x * 256 + threadIdx.x;
  if (idx >= BATCH * LQ * CDIM) return;
  int c = idx & 255;
  int tok = idx >> 8;
  int b = tok / LQ, t = tok % LQ;
  int l, hw, Hl, Wl;
  get_level(t, l, hw, Hl, Wl);
  float2 st = stats[(b * 4 + l) * 32 + (c >> 3)];
  float v = (x[idx] - st.x) * st.y * gw[l * CDIM + c] + gb[l * CDIM + c];
  x[idx] = v;
  xb[idx] = __float2bfloat16(v);
  qb[idx] = __float2bfloat16(v + pos[t * 256 + c]);
}

__global__ void pos_embed_kernel(const float* __restrict__ level_embed,
                                 float* __restrict__ pos) {
  int idx = blockIdx.x * 256 + threadIdx.x;
  if (idx >= LQ * CDIM) return;
  int t = idx >> 8, c = idx & 255;
  int l, hw, Hl, Wl;
  get_level(t, l, hw, Hl, Wl);
  int y = hw / Wl, xx = hw % Wl;
  const float twopi = 6.28318530717958647692f;
  float v; int cc;
  if (c < 128) { v = (float)(y + 1) * twopi / ((float)Hl + 1e-6f); cc = c; }
  else         { v = (float)(xx + 1) * twopi / ((float)Wl + 1e-6f); cc = c - 128; }
  int k = cc >> 1;
  float dim_t = expf((float)k * (logf(10000.0f) / 64.0f));
  float p = v / dim_t;
  float e = (cc & 1) ? cosf(p) : sinf(p);
  pos[idx] = e + level_embed[l * CDIM + c];
}

__global__ void ref_kernel(float* __restrict__ ref) {
  int t = blockIdx.x * 256 + threadIdx.x;
  if (t >= LQ) return;
  int l, hw, Hl, Wl;
  get_level(t, l, hw, Hl, Wl);
  int y = hw / Wl, xx = hw % Wl;
  ref[t * 2]     = ((float)xx + 0.5f) / (float)Wl;
  ref[t * 2 + 1] = ((float)y + 0.5f) / (float)Hl;
}

// ---------------------------------------------------------------------------
// Deformable attention: 4-lane group per (token, head), 8 channels/lane,
// 16B bf16x8 gathers, branchless bilinear. grid = B*LQ*8/64 blocks of 256.
// ---------------------------------------------------------------------------
__global__ __launch_bounds__(256) void deform_attn_kernel(
    const __hip_bfloat16* __restrict__ value, const float* __restrict__ comb,
    const float* __restrict__ ref, __hip_bfloat16* __restrict__ out) {
  const int Wl_[4] = {64, 32, 16, 8};
  const int st_[4] = {0, 4096, 5120, 5376};
  int gid = blockIdx.x * 64 + (threadIdx.x >> 2);
  int lane4 = threadIdx.x & 3;
  int h = gid & 7;
  int tok = gid >> 3;
  int b = tok / LQ;
  int qi = tok - b * LQ;

  const float4* awv = (const float4*)(comb + (size_t)tok * 384 + 256 + h * 16);
  float4 q0 = awv[0], q1 = awv[1], q2 = awv[2], q3 = awv[3];
  float logit[16] = {q0.x, q0.y, q0.z, q0.w, q1.x, q1.y, q1.z, q1.w,
                     q2.x, q2.y, q2.z, q2.w, q3.x, q3.y, q3.z, q3.w};
  float mx = -1e30f;
#pragma unroll
  for (int i = 0; i < 16; ++i) mx = fmaxf(mx, logit[i]);
  const float LOG2E = 1.4426950408889634f;
  float ssum = 0.f;
#pragma unroll
  for (int i = 0; i < 16; ++i) {
    logit[i] = exp2f((logit[i] - mx) * LOG2E);
    ssum += logit[i];
  }
  float inv = 1.0f / ssum;

  float rx = ref[qi * 2], ry = ref[qi * 2 + 1];
  const float4* offv = (const float4*)(comb + (size_t)tok * 384 + h * 32);
  float acc[8] = {};

#pragma unroll
  for (int l = 0; l < 4; ++l) {
    const int Wl = Wl_[l];
    const float fW = (float)Wl;
    const __hip_bfloat16* vbase =
        value + ((size_t)b * LQ + st_[l]) * CDIM + h * 32 + lane4 * 8;
    float bx = fmaf(rx, fW, -0.5f);
    float by = fmaf(ry, fW, -0.5f);
    float4 oa = offv[l * 2], ob = offv[l * 2 + 1];
    float oxs[4] = {oa.x, oa.z, ob.x, ob.z};
    float oys[4] = {oa.y, oa.w, ob.y, ob.w};
#pragma unroll
    for (int p = 0; p < 4; ++p) {
      float px = bx + oxs[p], py = by + oys[p];
      float wgt = logit[l * 4 + p] * inv;
      float fpx = floorf(px), fpy = floorf(py);
      int x0 = (int)fpx, y0 = (int)fpy;
      float fx = px - fpx, fy = py - fpy;
      float wx0 = (x0 >= 0 && x0 < Wl) ? (1.f - fx) : 0.f;
      float wx1 = (x0 >= -1 && x0 < Wl - 1) ? fx : 0.f;
      float wy0 = (y0 >= 0 && y0 < Wl) ? (wgt * (1.f - fy)) : 0.f;
      float wy1 = (y0 >= -1 && y0 < Wl - 1) ? (wgt * fy) : 0.f;
      int xc0 = min(max(x0, 0), Wl - 1);
      int xc1 = min(max(x0 + 1, 0), Wl - 1);
      int yc0 = min(max(y0, 0), Wl - 1);
      int yc1 = min(max(y0 + 1, 0), Wl - 1);
      const __hip_bfloat16* r0 = vbase + (size_t)(yc0 * Wl) * CDIM;
      const __hip_bfloat16* r1 = vbase + (size_t)(yc1 * Wl) * CDIM;
      bf16x8 u00 = *(const bf16x8*)(r0 + (size_t)xc0 * CDIM);
      bf16x8 u01 = *(const bf16x8*)(r0 + (size_t)xc1 * CDIM);
      bf16x8 u10 = *(const bf16x8*)(r1 + (size_t)xc0 * CDIM);
      bf16x8 u11 = *(const bf16x8*)(r1 + (size_t)xc1 * CDIM);
      float w00 = wy0 * wx0, w01 = wy0 * wx1, w10 = wy1 * wx0, w11 = wy1 * wx1;
#pragma unroll
      for (int k = 0; k < 8; ++k) {
        float v00 = __uint_as_float((unsigned)(unsigned short)u00[k] << 16);
        float v01 = __uint_as_float((unsigned)(unsigned short)u01[k] << 16);
        float v10 = __uint_as_float((unsigned)(unsigned short)u10[k] << 16);
        float v11 = __uint_as_float((unsigned)(unsigned short)u11[k] << 16);
        acc[k] = fmaf(w00, v00, acc[k]);
        acc[k] = fmaf(w01, v01, acc[k]);
        acc[k] = fmaf(w10, v10, acc[k]);
        acc[k] = fmaf(w11, v11, acc[k]);
      }
    }
  }
  union { bf16x8 u; __hip_bfloat16 hh[8]; } pk;
#pragma unroll
  for (int k = 0; k < 8; ++k) pk.hh[k] = __float2bfloat16(acc[k]);
  *(bf16x8*)(out + (size_t)tok * CDIM + h * 32 + lane4 * 8) = pk.u;
}

// conv2 NHWC split over taps: part[tap][b][pix][2]
__global__ __launch_bounds__(256) void conv2_part_kernel(
    const __hip_bfloat16* __restrict__ c1o, const float* __restrict__ w,
    float* __restrict__ part) {
  int pix = blockIdx.x * 256 + threadIdx.x;
  int tap = blockIdx.y, b = blockIdx.z;
  int y = pix >> 6, x = pix & 63;
  int dy = tap / 3 - 1, dx = tap % 3 - 1;
  int yy = y + dy, xx = x + dx;
  bool ok = (yy >= 0 && yy < 64 && xx >= 0 && xx < 64);
  float a0 = 0.f, a1 = 0.f;
  if (ok) {
    const __hip_bfloat16* row = c1o + (size_t)(b * 4096 + yy * 64 + xx) * 64;
#pragma unroll
    for (int ic4 = 0; ic4 < 16; ++ic4) {
      ushort4 u = *(const ushort4*)(row + ic4 * 4);
      float f0 = __uint_as_float((unsigned)u.x << 16);
      float f1 = __uint_as_float((unsigned)u.y << 16);
      float f2 = __uint_as_float((unsigned)u.z << 16);
      float f3 = __uint_as_float((unsigned)u.w << 16);
      int ic = ic4 * 4;
      a0 = fmaf(w[(ic + 0) * 9 + tap], f0, a0);
      a0 = fmaf(w[(ic + 1) * 9 + tap], f1, a0);
      a0 = fmaf(w[(ic + 2) * 9 + tap], f2, a0);
      a0 = fmaf(w[(ic + 3) * 9 + tap], f3, a0);
      a1 = fmaf(w[576 + (ic + 0) * 9 + tap], f0, a1);
      a1 = fmaf(w[576 + (ic + 1) * 9 + tap], f1, a1);
      a1 = fmaf(w[576 + (ic + 2) * 9 + tap], f2, a1);
      a1 = fmaf(w[576 + (ic + 3) * 9 + tap], f3, a1);
    }
  }
  float2 o = make_float2(a0, a1);
  *(float2*)&part[((size_t)(tap * BATCH + b) * 4096 + pix) * 2] = o;
}

// sum 9 taps + bias -> c2o [b][pix][2]
__global__ void conv2_reduce_kernel(const float* __restrict__ part,
                                    const float* __restrict__ bias,
                                    float* __restrict__ out) {
  int i = blockIdx.x * 256 + threadIdx.x;
  if (i >= BATCH * 4096) return;
  int b = i >> 12, pix = i & 4095;
  float s0 = bias[0], s1 = bias[1];
#pragma unroll
  for (int tap = 0; tap < 9; ++tap) {
    float2 v = *(const float2*)&part[((size_t)(tap * BATCH + b) * 4096 + pix) * 2];
    s0 += v.x; s1 += v.y;
  }
  *(float2*)&out[(size_t)i * 2] = make_float2(s0, s1);
}

// 4x bilinear upsample 64->256; input layout [b][pix][2]
__global__ void upsample_kernel(const float* __restrict__ in, float* __restrict__ out) {
  int idx = blockIdx.x * 256 + threadIdx.x;
  if (idx >= BATCH * 2 * 256 * 256) return;
  int X = idx & 255, Y = (idx >> 8) & 255, p = idx >> 16;
  int b = p >> 1, oc = p & 1;
  float tx = ((float)X + 0.5f) * 0.25f - 0.5f;
  float ty = ((float)Y + 0.5f) * 0.25f - 0.5f;
  float fxf = floorf(tx), fyf = floorf(ty);
  int x0 = (int)fxf, y0 = (int)fyf;
  float fx = tx - fxf, fy = ty - fyf;
  int x0c = min(max(x0, 0), 63), x1c = min(max(x0 + 1, 0), 63);
  int y0c = min(max(y0, 0), 63), y1c = min(max(y0 + 1, 0), 63);
  const float* ip = in + (size_t)b * 4096 * 2 + oc;
  float v = (1.f - fy) * ((1.f - fx) * ip[(y0c * 64 + x0c) * 2] + fx * ip[(y0c * 64 + x1c) * 2]) +
            fy * ((1.f - fx) * ip[(y1c * 64 + x0c) * 2] + fx * ip[(y1c * 64 + x1c) * 2]);
  out[idx] = v;
}

// ---------------------------------------------------------------------------
extern "C" void kernel_launch(void* const* d_in, const int* in_sizes, int n_in,
                              void* d_out, int out_size, void* d_ws, size_t ws_size,
                              hipStream_t stream) {
  const float* f[4] = {(const float*)d_in[0], (const float*)d_in[1],
                       (const float*)d_in[2], (const float*)d_in[3]};
  const float* proj_w = (const float*)d_in[4];
  const float* proj_b = (const float*)d_in[5];
  const float* gn_w = (const float*)d_in[6];
  const float* gn_b = (const float*)d_in[7];
  const float* level_embed = (const float*)d_in[8];
  const float* so_w = (const float*)d_in[9];
  const float* so_b = (const float*)d_in[10];
  const float* aw_w = (const float*)d_in[11];
  const float* aw_b = (const float*)d_in[12];
  const float* vp_w = (const float*)d_in[13];
  const float* vp_b = (const float*)d_in[14];
  const float* op_w = (const float*)d_in[15];
  const float* op_b = (const float*)d_in[16];
  const float* n1_w = (const float*)d_in[17];
  const float* n1_b = (const float*)d_in[18];
  const float* l1_w = (const float*)d_in[19];
  const float* l1_b = (const float*)d_in[20];
  const float* l2_w = (const float*)d_in[21];
  const float* l2_b = (const float*)d_in[22];
  const float* n2_w = (const float*)d_in[23];
  const float* n2_b = (const float*)d_in[24];
  const float* c1_w = (const float*)d_in[25];
  const float* c1_b = (const float*)d_in[26];
  const float* c2_w = (const float*)d_in[27];
  const float* c2_b = (const float*)d_in[28];
  (void)in_sizes; (void)n_in; (void)out_size; (void)ws_size;

  float* ws = (float*)d_ws;
  const size_t TOK = (size_t)BATCH * LQ * CDIM;  // 2785280
  size_t o = 0;
  float* x = ws + o;     o += TOK;
  float* comb = ws + o;  o += (size_t)BATCH * LQ * 384;
  float* pos = ws + o;   o += (size_t)LQ * CDIM;
  float* refb = ws + o;  o += 11008;
  float2* stats = (float2*)(ws + o); o += 512;
  float* zerof = ws + o; o += 256;
  float* sowa_bias = ws + o; o += 2304;
  float2* gnpart = (float2*)(ws + o); o += 11008;
  __hip_bfloat16* xb = (__hip_bfloat16*)(ws + o);    o += TOK / 2;
  __hip_bfloat16* qb = (__hip_bfloat16*)(ws + o);    o += TOK / 2;
  __hip_bfloat16* valb = (__hip_bfloat16*)(ws + o);  o += TOK / 2;
  __hip_bfloat16* attnb = (__hip_bfloat16*)(ws + o); o += TOK / 2;
  __hip_bfloat16* ftb = (__hip_bfloat16*)(ws + o);   o += TOK / 2;
  __hip_bfloat16* ff1b = (__hip_bfloat16*)(ws + o);  o += (size_t)BATCH * LQ * FFDIM / 2;
  __hip_bfloat16* sowa_wb = (__hip_bfloat16*)(ws + o); o += 294912;
  __hip_bfloat16* vp_wb = (__hip_bfloat16*)(ws + o); o += 196608;
  __hip_bfloat16* op_wb = (__hip_bfloat16*)(ws + o); o += 196608;
  __hip_bfloat16* l1_wb = (__hip_bfloat16*)(ws + o); o += 786432;
  __hip_bfloat16* l2_wb = (__hip_bfloat16*)(ws + o); o += 786432;
  __hip_bfloat16* proj_wb = (__hip_bfloat16*)(ws + o); o += 131072;
  __hip_bfloat16* wc1b = (__hip_bfloat16*)(ws + o);  o += 73728;
  // head scratch aliases ff1b region (free after encoder)
  __hip_bfloat16* c1ob = ff1b;
  float* part2 = (float*)(ff1b + 524288);
  float* c2o = part2 + 147456;

  const int HWs[4] = {4096, 1024, 256, 64};
  const int STs[4] = {0, 4096, 5120, 5376};

  // 0) staging (4 dispatches)
  hipMemsetAsync(zerof, 0, 1024, stream);
  sowa_prep_kernel<<<(6 * 384 * 256 + 6 * 384 + 255) / 256, 256, 0, stream>>>(
      so_w, aw_w, so_b, aw_b, sowa_wb, sowa_bias);
  wc1_prep_kernel<<<(147456 + 255) / 256, 256, 0, stream>>>(c1_w, wc1b);
  f2b_multi_kernel<<<(1048576 + 255) / 256, 256, 0, stream>>>(
      proj_w, vp_w, op_w, l1_w, l2_w, proj_wb, vp_wb, op_wb, l1_wb, l2_wb);

  // 1) input transpose+convert, then bf16 MFMA input-proj (remapped output)
  transpose_f_kernel<<<dim3(85, 4, BATCH), 256, 0, stream>>>(f[0], f[1], f[2], f[3],
                                                             ftb);
  for (int l = 0; l < 4; ++l) {
    int M2 = 2 * HWs[l];
    gemm_bf16_kernel<false, true, false, true><<<dim3(2, M2 / 128), 256, 0, stream>>>(
        ftb + (size_t)2 * STs[l] * 256, proj_wb + (size_t)l * 65536,
        proj_b + (size_t)l * 256, x, nullptr, M2, 256, 256,
        HWs[l], (long)STs[l] * 256, (long)LQ * 256);
  }
  // 2) pos embed + ref
  pos_embed_kernel<<<(LQ * CDIM + 255) / 256, 256, 0, stream>>>(level_embed, pos);
  ref_kernel<<<(LQ + 255) / 256, 256, 0, stream>>>(refb);
  // 3) GroupNorm (2-stage stats + apply)
  gn_part_kernel<<<dim3(85, BATCH), 256, 0, stream>>>(x, gnpart);
  gn_finalize_kernel<<<1, 256, 0, stream>>>(gnpart, stats);
  {
    int n = BATCH * LQ * CDIM;
    gn_apply_kernel<<<(n + 255) / 256, 256, 0, stream>>>(x, xb, qb, pos, stats,
                                                         gn_w, gn_b);
  }

  const int M = BATCH * LQ;  // 10880 = 85*128 = 170*64 = 340*32
  for (int i = 0; i < 6; ++i) {
    const __hip_bfloat16* sowa = sowa_wb + (size_t)i * 98304;
    const __hip_bfloat16* vw = vp_wb + (size_t)i * 65536;
    const __hip_bfloat16* ow = op_wb + (size_t)i * 65536;
    const __hip_bfloat16* w1 = l1_wb + (size_t)i * 262144;
    const __hip_bfloat16* w2 = l2_wb + (size_t)i * 262144;
    const float* vb = vp_b + (size_t)i * CDIM;
    const float* ob = op_b + (size_t)i * CDIM;
    const float* b1 = l1_b + (size_t)i * FFDIM;
    const float* b2 = l2_b + (size_t)i * CDIM;

    // value proj + sampling proj in one launch (850 blocks)
    gemm_dual_kernel<<<850, 256, 0, stream>>>(xb, vw, vb, valb, qb, sowa,
                                              sowa_bias + i * 384, comb);
    deform_attn_kernel<<<BATCH * LQ * 8 / 64, 256, 0, stream>>>(valb, comb, refb,
                                                                attnb);
    // fused: x = LN(x + attnb@ow^T + ob), emits xb
    gemm_ln_kernel<false><<<340, 256, 0, stream>>>(
        attnb, ow, ob, x, xb, nullptr, nullptr,
        n1_w + (size_t)i * CDIM, n1_b + (size_t)i * CDIM, CDIM);
    gemm_bf16_kernel<true, false, true, false><<<dim3(8, 85), 256, 0, stream>>>(
        xb, w1, b1, nullptr, ff1b, M, FFDIM, CDIM, 0, 0, 0);
    // fused: x = LN(x + ff1b@w2^T + b2), emits xb and qb = bf16(x+pos)
    gemm_ln_kernel<true><<<340, 256, 0, stream>>>(
        ff1b, w2, b2, x, xb, qb, pos,
        n2_w + (size_t)i * CDIM, n2_b + (size_t)i * CDIM, FFDIM);
  }

  // head
  conv1_mfma_kernel<<<128, 256, 0, stream>>>(xb, wc1b, c1_b,
                                             (const __hip_bfloat16*)zerof, c1ob);
  conv2_part_kernel<<<dim3(16, 9, BATCH), 256, 0, stream>>>(c1ob, c2_w, part2);
  conv2_reduce_kernel<<<(BATCH * 4096 + 255) / 256, 256, 0, stream>>>(part2, c2_b,
                                                                      c2o);
  {
    int n = BATCH * 2 * 256 * 256;
    upsample_kernel<<<(n + 255) / 256, 256, 0, stream>>>(c2o, (float*)d_out);
  }
}

// Round 11
// 621.037 us; speedup vs baseline: 5.2634x; 1.0254x over previous
//
#include <hip/hip_runtime.h>
#include <hip/hip_bf16.h>
#include <math.h>

#define LQ 5440
#define CDIM 256
#define BATCH 2
#define FFDIM 1024

typedef __attribute__((ext_vector_type(8))) short bf16x8;
typedef __attribute__((ext_vector_type(4))) float f32x4;

typedef __attribute__((address_space(1))) void* gas1_t;
typedef __attribute__((address_space(3))) void* las3_t;

__device__ __forceinline__ void async16(const void* g, void* l) {
  __builtin_amdgcn_global_load_lds((gas1_t)g, (las3_t)l, 16, 0, 0);
}

#define WAIT_VM5() asm volatile("s_waitcnt vmcnt(5)" ::: "memory")
#define WAIT_VM4() asm volatile("s_waitcnt vmcnt(4)" ::: "memory")
#define WAIT_VM3() asm volatile("s_waitcnt vmcnt(3)" ::: "memory")
#define WAIT_VM2() asm volatile("s_waitcnt vmcnt(2)" ::: "memory")
#define WAIT_VM0() asm volatile("s_waitcnt vmcnt(0)" ::: "memory")

// chunk (0..84) -> level, row0 (64-row chunks across the 4 levels)
__device__ __forceinline__ void get_chunk(int chunk, int& l, int& row0) {
  if (chunk < 64)      { l = 0; row0 = chunk * 64; }
  else if (chunk < 80) { l = 1; row0 = (chunk - 64) * 64; }
  else if (chunk < 84) { l = 2; row0 = (chunk - 80) * 64; }
  else                 { l = 3; row0 = 0; }
}

// ---------------------------------------------------------------------------
// Input proj: all 4 levels in ONE launch. 128x128 tiles, 3-buffer pipeline,
// REMAP epilogue writes token-major x. grid = 170 blocks.
// ---------------------------------------------------------------------------
__global__ __launch_bounds__(256, 2) void input_proj_kernel(
    const __hip_bfloat16* __restrict__ ftb, const __hip_bfloat16* __restrict__ proj_wb,
    const float* __restrict__ proj_b, float* __restrict__ x) {
  const int HWs[4] = {4096, 1024, 256, 64};
  const int STs[4] = {0, 4096, 5120, 5376};
  int i = blockIdx.x, l, j;
  if (i < 128)      { l = 0; j = i; }
  else if (i < 160) { l = 1; j = i - 128; }
  else if (i < 168) { l = 2; j = i - 160; }
  else              { l = 3; j = i - 168; }
  const int bm = (j >> 1) * 128, bn = (j & 1) * 128;
  const int mrows = HWs[l];
  const long obase = (long)STs[l] * 256;
  const long obstride = (long)LQ * 256;
  const __hip_bfloat16* A = ftb + (size_t)2 * STs[l] * 256;
  const __hip_bfloat16* Wt = proj_wb + (size_t)l * 65536;
  const float* bias = proj_b + l * 256;
  const int K = 256, N = 256;

  __shared__ __hip_bfloat16 As[3][128 * 32];
  __shared__ __hip_bfloat16 Bs[3][128 * 32];
  const int tid = threadIdx.x;
  const int lane = tid & 63, wave = tid >> 6;
  const int wr = wave >> 1, wc = wave & 1;
  const int srow = tid >> 2;
  const int scol = (tid & 3) * 8;
  const int lo0 = srow * 32 + scol;
  const int lo1 = (64 + srow) * 32 + scol;
  const __hip_bfloat16* ga0 = A + (size_t)(bm + srow) * K + scol;
  const __hip_bfloat16* ga1 = A + (size_t)(bm + 64 + srow) * K + scol;
  const __hip_bfloat16* gb0 = Wt + (size_t)(bn + srow) * K + scol;
  const __hip_bfloat16* gb1 = Wt + (size_t)(bn + 64 + srow) * K + scol;

  const int nt = K >> 5;
  async16(ga0, &As[0][lo0]);
  async16(ga1, &As[0][lo1]);
  async16(gb0, &Bs[0][lo0]);
  async16(gb1, &Bs[0][lo1]);
  async16(ga0 + 32, &As[1][lo0]);
  async16(ga1 + 32, &As[1][lo1]);
  async16(gb0 + 32, &Bs[1][lo0]);
  async16(gb1 + 32, &Bs[1][lo1]);

  f32x4 acc[4][4] = {};
  const int fr = lane & 15;
  const int ksub = (lane >> 4) * 8;
  int cur = 0, nxt = 2;
  for (int t = 0; t < nt; ++t) {
    if (t == nt - 1) WAIT_VM0(); else WAIT_VM4();
    __builtin_amdgcn_s_barrier();
    asm volatile("" ::: "memory");
    bf16x8 af[4], bfv[4];
#pragma unroll
    for (int mi = 0; mi < 4; ++mi)
      af[mi] = *(const bf16x8*)&As[cur][(wr * 64 + mi * 16 + fr) * 32 + ksub];
#pragma unroll
    for (int nj = 0; nj < 4; ++nj)
      bfv[nj] = *(const bf16x8*)&Bs[cur][(wc * 64 + nj * 16 + fr) * 32 + ksub];
    if (t + 2 < nt) {
      const int ko = (t + 2) * 32;
      async16(ga0 + ko, &As[nxt][lo0]);
      async16(ga1 + ko, &As[nxt][lo1]);
      async16(gb0 + ko, &Bs[nxt][lo0]);
      async16(gb1 + ko, &Bs[nxt][lo1]);
    }
#pragma unroll
    for (int mi = 0; mi < 4; ++mi)
#pragma unroll
      for (int nj = 0; nj < 4; ++nj)
        acc[mi][nj] = __builtin_amdgcn_mfma_f32_16x16x32_bf16(af[mi], bfv[nj],
                                                              acc[mi][nj], 0, 0, 0);
    cur = (cur == 2) ? 0 : cur + 1;
    nxt = (nxt == 2) ? 0 : nxt + 1;
  }

  const int cc = lane & 15;
  const int rbase = (lane >> 4) * 4;
  float bcol[4];
#pragma unroll
  for (int nj = 0; nj < 4; ++nj) bcol[nj] = bias[bn + wc * 64 + nj * 16 + cc];
#pragma unroll
  for (int mi = 0; mi < 4; ++mi)
#pragma unroll
    for (int nj = 0; nj < 4; ++nj) {
      int col = bn + wc * 64 + nj * 16 + cc;
#pragma unroll
      for (int r = 0; r < 4; ++r) {
        int row = bm + wr * 64 + mi * 16 + rbase + r;
        size_t oaddr = (size_t)obase +
                       (row < mrows ? (size_t)row * N
                                    : (size_t)obstride + (size_t)(row - mrows) * N) +
                       col;
        x[oaddr] = acc[mi][nj][r] + bcol[nj];
      }
    }
}

// ---------------------------------------------------------------------------
// 64x128-tile GEMM body (4 waves, each 64 rows x 32 cols). 3 loads/thread/stage.
// ---------------------------------------------------------------------------
template <bool RELU, bool OUT_F32, bool OUT_B16>
__device__ __forceinline__ void gemm64_body(
    const __hip_bfloat16* __restrict__ A, const __hip_bfloat16* __restrict__ Wt,
    const float* __restrict__ bias, float* __restrict__ C,
    __hip_bfloat16* __restrict__ Cb, int bm, int bn, int N, int K,
    __hip_bfloat16 (*As)[64 * 32], __hip_bfloat16 (*Bs)[128 * 32]) {
  const int tid = threadIdx.x;
  const int lane = tid & 63, wv = tid >> 6;
  const int srow = tid >> 2, scol = (tid & 3) * 8;
  const int loA = srow * 32 + scol;
  const int loB1 = (64 + srow) * 32 + scol;
  const __hip_bfloat16* ga = A + (size_t)(bm + srow) * K + scol;
  const __hip_bfloat16* gb0 = Wt + (size_t)(bn + srow) * K + scol;
  const __hip_bfloat16* gb1 = Wt + (size_t)(bn + 64 + srow) * K + scol;
  const int nt = K >> 5;
  async16(ga, &As[0][loA]);
  async16(gb0, &Bs[0][loA]);
  async16(gb1, &Bs[0][loB1]);
  async16(ga + 32, &As[1][loA]);
  async16(gb0 + 32, &Bs[1][loA]);
  async16(gb1 + 32, &Bs[1][loB1]);

  f32x4 acc[4][2] = {};
  const int fr = lane & 15, ksub = (lane >> 4) * 8;
  int cur = 0, nxt = 2;
  for (int t = 0; t < nt; ++t) {
    if (t == nt - 1) WAIT_VM0(); else WAIT_VM3();
    __builtin_amdgcn_s_barrier();
    asm volatile("" ::: "memory");
    bf16x8 af[4], bfv[2];
#pragma unroll
    for (int mi = 0; mi < 4; ++mi)
      af[mi] = *(const bf16x8*)&As[cur][(mi * 16 + fr) * 32 + ksub];
#pragma unroll
    for (int nj = 0; nj < 2; ++nj)
      bfv[nj] = *(const bf16x8*)&Bs[cur][(wv * 32 + nj * 16 + fr) * 32 + ksub];
    if (t + 2 < nt) {
      const int ko = (t + 2) * 32;
      async16(ga + ko, &As[nxt][loA]);
      async16(gb0 + ko, &Bs[nxt][loA]);
      async16(gb1 + ko, &Bs[nxt][loB1]);
    }
#pragma unroll
    for (int mi = 0; mi < 4; ++mi)
#pragma unroll
      for (int nj = 0; nj < 2; ++nj)
        acc[mi][nj] = __builtin_amdgcn_mfma_f32_16x16x32_bf16(af[mi], bfv[nj],
                                                              acc[mi][nj], 0, 0, 0);
    cur = (cur == 2) ? 0 : cur + 1;
    nxt = (nxt == 2) ? 0 : nxt + 1;
  }
  const int cc = lane & 15;
  const int rbase = (lane >> 4) * 4;
#pragma unroll
  for (int nj = 0; nj < 2; ++nj) {
    int col = bn + wv * 32 + nj * 16 + cc;
    float bb = bias[col];
#pragma unroll
    for (int mi = 0; mi < 4; ++mi)
#pragma unroll
      for (int r = 0; r < 4; ++r) {
        int row = bm + mi * 16 + rbase + r;
        float v = acc[mi][nj][r] + bb;
        if (RELU) v = fmaxf(v, 0.f);
        if (OUT_F32) C[(size_t)row * N + col] = v;
        if (OUT_B16) Cb[(size_t)row * N + col] = __float2bfloat16(v);
      }
  }
}

// Dual GEMM: blocks [0,340) -> value proj (xb @ vw^T -> valb bf16, N=256);
// blocks [340,850) -> sampling offsets+weights (qb @ sowa^T -> comb f32, N=384)
__global__ __launch_bounds__(256, 4) void gemm_dual_kernel(
    const __hip_bfloat16* __restrict__ xb, const __hip_bfloat16* __restrict__ vw,
    const float* __restrict__ vb, __hip_bfloat16* __restrict__ valb,
    const __hip_bfloat16* __restrict__ qb, const __hip_bfloat16* __restrict__ sowa,
    const float* __restrict__ sbias, float* __restrict__ comb) {
  __shared__ __hip_bfloat16 As[3][64 * 32];
  __shared__ __hip_bfloat16 Bs[3][128 * 32];
  if (blockIdx.x < 340) {
    int i = blockIdx.x;
    gemm64_body<false, false, true>(xb, vw, vb, nullptr, valb, (i >> 1) * 64,
                                    (i & 1) * 128, 256, 256, As, Bs);
  } else {
    int j = blockIdx.x - 340;
    gemm64_body<false, true, false>(qb, sowa, sbias, comb, nullptr, (j / 3) * 64,
                                    (j % 3) * 128, 384, 256, As, Bs);
  }
}

// ffn1: relu(xb @ w1^T + b1) -> ff1b bf16. grid = 170*8 = 1360 blocks.
__global__ __launch_bounds__(256, 4) void ffn1_kernel(
    const __hip_bfloat16* __restrict__ xb, const __hip_bfloat16* __restrict__ w1,
    const float* __restrict__ b1, __hip_bfloat16* __restrict__ ff1b) {
  __shared__ __hip_bfloat16 As[3][64 * 32];
  __shared__ __hip_bfloat16 Bs[3][128 * 32];
  int i = blockIdx.x;
  gemm64_body<true, false, true>(xb, w1, b1, nullptr, ff1b, (i >> 3) * 64,
                                 (i & 7) * 128, 1024, 256, As, Bs);
}

// ---------------------------------------------------------------------------
// Fused GEMM (N=256) + residual + LayerNorm, 32-row tiles (grid 340).
// ---------------------------------------------------------------------------
template <bool EMIT_Q>
__global__ __launch_bounds__(256, 2) void gemm_ln_kernel(
    const __hip_bfloat16* __restrict__ A, const __hip_bfloat16* __restrict__ Wt,
    const float* __restrict__ bias, float* __restrict__ x,
    __hip_bfloat16* __restrict__ xb, __hip_bfloat16* __restrict__ qb,
    const float* __restrict__ pos, const float* __restrict__ lnw,
    const float* __restrict__ lnb, int K) {
  __shared__ __hip_bfloat16 As[3][32 * 32];
  __shared__ __hip_bfloat16 Bs[3][256 * 32];
  __shared__ float sred[4][32], ssred[4][32];
  const int tid = threadIdx.x;
  const int bm = blockIdx.x * 32;
  const int lane = tid & 63, wv = tid >> 6;
  const int srow = tid >> 2;             // 0..63 (B rows)
  const int arow = srow & 31;            // duplicated A rows
  const int scol = (tid & 3) * 8;
  const int loA = arow * 32 + scol;
  const __hip_bfloat16* ga = A + (size_t)(bm + arow) * K + scol;
  const __hip_bfloat16* gb = Wt + (size_t)srow * K + scol;

  const int nt = K >> 5;
  auto stage = [&](int t, int buf) {
    const int ko = t * 32;
    async16(ga + ko, &As[buf][loA]);
#pragma unroll
    for (int i = 0; i < 4; ++i)
      async16(gb + (size_t)(64 * i) * K + ko, &Bs[buf][(64 * i + srow) * 32 + scol]);
  };
  stage(0, 0);
  stage(1, 1);

  f32x4 acc[2][4] = {};
  const int fr = lane & 15;
  const int ksub = (lane >> 4) * 8;

  int cur = 0, nxt = 2;
  for (int t = 0; t < nt; ++t) {
    if (t == nt - 1) WAIT_VM0(); else WAIT_VM5();
    __builtin_amdgcn_s_barrier();
    asm volatile("" ::: "memory");
    bf16x8 af[2], bfv[4];
#pragma unroll
    for (int mi = 0; mi < 2; ++mi)
      af[mi] = *(const bf16x8*)&As[cur][(mi * 16 + fr) * 32 + ksub];
#pragma unroll
    for (int nj = 0; nj < 4; ++nj)
      bfv[nj] = *(const bf16x8*)&Bs[cur][(wv * 64 + nj * 16 + fr) * 32 + ksub];
    if (t + 2 < nt) stage(t + 2, nxt);
#pragma unroll
    for (int mi = 0; mi < 2; ++mi)
#pragma unroll
      for (int nj = 0; nj < 4; ++nj)
        acc[mi][nj] = __builtin_amdgcn_mfma_f32_16x16x32_bf16(af[mi], bfv[nj],
                                                              acc[mi][nj], 0, 0, 0);
    cur = (cur == 2) ? 0 : cur + 1;
    nxt = (nxt == 2) ? 0 : nxt + 1;
  }

  const int cc = lane & 15;
  const int rbase = (lane >> 4) * 4;
  float bcol[4], wcol[4], bncol[4];
#pragma unroll
  for (int nj = 0; nj < 4; ++nj) {
    int col = wv * 64 + nj * 16 + cc;
    bcol[nj] = bias[col];
    wcol[nj] = lnw[col];
    bncol[nj] = lnb[col];
  }
#pragma unroll
  for (int mi = 0; mi < 2; ++mi)
#pragma unroll
    for (int r = 0; r < 4; ++r) {
      int grow = bm + mi * 16 + rbase + r;
#pragma unroll
      for (int nj = 0; nj < 4; ++nj) {
        int col = wv * 64 + nj * 16 + cc;
        acc[mi][nj][r] += bcol[nj] + x[(size_t)grow * 256 + col];
      }
    }
#pragma unroll
  for (int mi = 0; mi < 2; ++mi)
#pragma unroll
    for (int r = 0; r < 4; ++r) {
      float s = 0.f, ssq = 0.f;
#pragma unroll
      for (int nj = 0; nj < 4; ++nj) {
        float v = acc[mi][nj][r];
        s += v;
        ssq += v * v;
      }
#pragma unroll
      for (int m = 1; m < 16; m <<= 1) {
        s += __shfl_xor(s, m);
        ssq += __shfl_xor(ssq, m);
      }
      if (cc == 0) {
        int row = mi * 16 + rbase + r;
        sred[wv][row] = s;
        ssred[wv][row] = ssq;
      }
    }
  __syncthreads();
#pragma unroll
  for (int mi = 0; mi < 2; ++mi)
#pragma unroll
    for (int r = 0; r < 4; ++r) {
      int row = mi * 16 + rbase + r;
      int grow = bm + row;
      float s = sred[0][row] + sred[1][row] + sred[2][row] + sred[3][row];
      float ssq = ssred[0][row] + ssred[1][row] + ssred[2][row] + ssred[3][row];
      float mu = s * (1.0f / 256.0f);
      float var = ssq * (1.0f / 256.0f) - mu * mu;
      float rsig = rsqrtf(var + 1e-5f);
      int tokp = grow >= LQ ? grow - LQ : grow;
#pragma unroll
      for (int nj = 0; nj < 4; ++nj) {
        int col = wv * 64 + nj * 16 + cc;
        float xn = (acc[mi][nj][r] - mu) * rsig * wcol[nj] + bncol[nj];
        x[(size_t)grow * 256 + col] = xn;
        xb[(size_t)grow * 256 + col] = __float2bfloat16(xn);
        if (EMIT_Q)
          qb[(size_t)grow * 256 + col] =
              __float2bfloat16(xn + pos[(size_t)tokp * 256 + col]);
      }
    }
}

// ---------------------------------------------------------------------------
// conv1 implicit GEMM (NHWC), 64-pixel tiles, 72-step pipelined K-loop.
// ---------------------------------------------------------------------------
__global__ __launch_bounds__(256, 4) void conv1_mfma_kernel(
    const __hip_bfloat16* __restrict__ xb, const __hip_bfloat16* __restrict__ wc1,
    const float* __restrict__ bias, const __hip_bfloat16* __restrict__ zerob,
    __hip_bfloat16* __restrict__ c1o) {
  __shared__ __hip_bfloat16 As[3][64 * 32];
  __shared__ __hip_bfloat16 Bs[3][64 * 32];
  const int tid = threadIdx.x;
  const int b = blockIdx.x >> 6;
  const int pm = (blockIdx.x & 63) * 64;
  const int lane = tid & 63, wave = tid >> 6;
  const int sr = tid >> 2;
  const int sc = (tid & 3) * 8;
  const int lo = sr * 32 + sc;
  f32x4 acc[4] = {};
  const int fr = lane & 15, ksub = (lane >> 4) * 8;

  auto stage = [&](int kt, int buf) {
    int tap = kt >> 3;
    int kk = (kt & 7) * 32;
    int dy = tap / 3 - 1, dx = tap % 3 - 1;
    int hw = pm + sr;
    int y = (hw >> 6) + dy, x = (hw & 63) + dx;
    bool ok = (y >= 0 && y < 64 && x >= 0 && x < 64);
    const __hip_bfloat16* s =
        xb + ((size_t)(b * LQ) + y * 64 + x) * 256 + kk + sc;
    const __hip_bfloat16* wsrc = wc1 + (size_t)sr * 2304 + tap * 256 + kk + sc;
    async16(ok ? s : zerob, &As[buf][lo]);
    async16(wsrc, &Bs[buf][lo]);
  };
  stage(0, 0);
  stage(1, 1);
  int cur = 0, nxt = 2;
  for (int kt = 0; kt < 72; ++kt) {
    if (kt == 71) WAIT_VM0(); else WAIT_VM2();
    __builtin_amdgcn_s_barrier();
    asm volatile("" ::: "memory");
    bf16x8 af;
    bf16x8 bfv[4];
    af = *(const bf16x8*)&As[cur][(wave * 16 + fr) * 32 + ksub];
#pragma unroll
    for (int nj = 0; nj < 4; ++nj)
      bfv[nj] = *(const bf16x8*)&Bs[cur][(nj * 16 + fr) * 32 + ksub];
    if (kt + 2 < 72) stage(kt + 2, nxt);
#pragma unroll
    for (int nj = 0; nj < 4; ++nj)
      acc[nj] = __builtin_amdgcn_mfma_f32_16x16x32_bf16(af, bfv[nj], acc[nj], 0, 0, 0);
    cur = (cur == 2) ? 0 : cur + 1;
    nxt = (nxt == 2) ? 0 : nxt + 1;
  }
  const int cc = lane & 15;
  const int rbase = (lane >> 4) * 4;
#pragma unroll
  for (int nj = 0; nj < 4; ++nj) {
    int col = nj * 16 + cc;
    float bb = bias[col];
#pragma unroll
    for (int r = 0; r < 4; ++r) {
      int row = wave * 16 + rbase + r;
      float v = fmaxf(acc[nj][r] + bb, 0.f);
      c1o[(size_t)(b * 4096 + pm + row) * 64 + col] = __float2bfloat16(v);
    }
  }
}

// multi-section fp32 -> bf16 convert (proj, vp, op, l1, l2), float4 granules
__global__ void f2b_multi_kernel(const float* __restrict__ p0, const float* __restrict__ p1,
                                 const float* __restrict__ p2, const float* __restrict__ p3,
                                 const float* __restrict__ p4,
                                 __hip_bfloat16* __restrict__ o0, __hip_bfloat16* __restrict__ o1,
                                 __hip_bfloat16* __restrict__ o2, __hip_bfloat16* __restrict__ o3,
                                 __hip_bfloat16* __restrict__ o4) {
  int i = blockIdx.x * 256 + threadIdx.x;  // float4 index, total 1048576
  if (i >= 1048576) return;
  const float* in;
  __hip_bfloat16* out;
  int j;
  if (i < 65536)       { in = p0; out = o0; j = i; }
  else if (i < 163840) { in = p1; out = o1; j = i - 65536; }
  else if (i < 262144) { in = p2; out = o2; j = i - 163840; }
  else if (i < 655360) { in = p3; out = o3; j = i - 262144; }
  else                 { in = p4; out = o4; j = i - 655360; }
  float4 v = ((const float4*)in)[j];
  union { ushort4 u; __hip_bfloat16 h[4]; } p;
  p.h[0] = __float2bfloat16(v.x);
  p.h[1] = __float2bfloat16(v.y);
  p.h[2] = __float2bfloat16(v.z);
  p.h[3] = __float2bfloat16(v.w);
  ((ushort4*)out)[j] = p.u;
}

// combined so+aw weight staging: [6][384][256] bf16 (+ bias at tail blocks)
__global__ void sowa_prep_kernel(const float* __restrict__ so_w,
                                 const float* __restrict__ aw_w,
                                 const float* __restrict__ so_b,
                                 const float* __restrict__ aw_b,
                                 __hip_bfloat16* __restrict__ out,
                                 float* __restrict__ bias_out) {
  int i = blockIdx.x * 256 + threadIdx.x;
  if (i < 6 * 384 * 256) {
    int il = i / (384 * 256);
    int rem = i - il * 384 * 256;
    int n = rem >> 8, k = rem & 255;
    float v = (n < 256) ? so_w[(size_t)il * 65536 + n * 256 + k]
                        : aw_w[(size_t)il * 32768 + (n - 256) * 256 + k];
    out[i] = __float2bfloat16(v);
  } else if (i < 6 * 384 * 256 + 6 * 384) {
    int j = i - 6 * 384 * 256;
    int il = j / 384, n = j % 384;
    bias_out[j] = (n < 256) ? so_b[il * 256 + n] : aw_b[il * 128 + n - 256];
  }
}

// conv1 weight staging: wc1[oc][tap*256+ic] = bf16(c1_w[oc][ic][tap])
__global__ void wc1_prep_kernel(const float* __restrict__ w,
                                __hip_bfloat16* __restrict__ out) {
  int i = blockIdx.x * 256 + threadIdx.x;
  if (i >= 64 * 2304) return;
  int oc = i / 2304, r = i % 2304;
  int tap = r >> 8, ic = r & 255;
  out[i] = __float2bfloat16(w[(size_t)oc * 2304 + ic * 9 + tap]);
}

// ---------------------------------------------------------------------------
// transpose+convert: f[l][b][c][hw] fp32 -> ft (level-major) [l][b][hw][c] bf16
// ---------------------------------------------------------------------------
__global__ __launch_bounds__(256) void transpose_f_kernel(
    const float* __restrict__ f0, const float* __restrict__ f1,
    const float* __restrict__ f2, const float* __restrict__ f3,
    __hip_bfloat16* __restrict__ ft) {
  __shared__ float tile[64][65];
  const int HWs[4] = {4096, 1024, 256, 64};
  const int STs[4] = {0, 4096, 5120, 5376};
  int chunk = blockIdx.x, c0 = blockIdx.y * 64, b = blockIdx.z;
  int l, row0;
  get_chunk(chunk, l, row0);
  const float* fin = (l == 0) ? f0 : (l == 1) ? f1 : (l == 2) ? f2 : f3;
  const int HW = HWs[l];
  int t = threadIdx.x;
  int cr = t >> 4, hc4 = (t & 15) * 4;
#pragma unroll
  for (int p = 0; p < 4; ++p) {
    int c = c0 + p * 16 + cr;
    float4 v = *(const float4*)&fin[(size_t)(b * 256 + c) * HW + row0 + hc4];
    tile[p * 16 + cr][hc4 + 0] = v.x;
    tile[p * 16 + cr][hc4 + 1] = v.y;
    tile[p * 16 + cr][hc4 + 2] = v.z;
    tile[p * 16 + cr][hc4 + 3] = v.w;
  }
  __syncthreads();
  size_t obase = (size_t)2 * STs[l] * 256 + ((size_t)b * HW + row0) * 256 + c0;
#pragma unroll
  for (int p = 0; p < 4; ++p) {
    int r = p * 16 + cr;
    union { ushort4 u; __hip_bfloat16 h[4]; } pk;
    pk.h[0] = __float2bfloat16(tile[hc4 + 0][r]);
    pk.h[1] = __float2bfloat16(tile[hc4 + 1][r]);
    pk.h[2] = __float2bfloat16(tile[hc4 + 2][r]);
    pk.h[3] = __float2bfloat16(tile[hc4 + 3][r]);
    *(ushort4*)&ft[obase + (size_t)r * 256 + hc4] = pk.u;
  }
}

// ---------------------------------------------------------------------------
// GroupNorm stats, 2-stage coalesced.
// ---------------------------------------------------------------------------
__global__ __launch_bounds__(256) void gn_part_kernel(const float* __restrict__ x,
                                                      float2* __restrict__ part) {
  const int STs[4] = {0, 4096, 5120, 5376};
  int chunk = blockIdx.x, b = blockIdx.y;
  int l, row0;
  get_chunk(chunk, l, row0);
  size_t base = ((size_t)b * LQ + STs[l] + row0) * 256;
  int t = threadIdx.x;
  int col4 = t & 63, rb = t >> 6;
  float s = 0.f, ss = 0.f;
#pragma unroll 4
  for (int i = 0; i < 16; ++i) {
    int r = rb + i * 4;
    float4 v = *(const float4*)&x[base + (size_t)r * 256 + col4 * 4];
    s += v.x + v.y + v.z + v.w;
    ss += v.x * v.x + v.y * v.y + v.z * v.z + v.w * v.w;
  }
  __shared__ float sA[256], sB[256];
  sA[t] = s;
  sB[t] = ss;
  __syncthreads();
  if (t < 64) {
    s = sA[t] + sA[t + 64] + sA[t + 128] + sA[t + 192];
    ss = sB[t] + sB[t + 64] + sB[t + 128] + sB[t + 192];
    sA[t] = s;
    sB[t] = ss;
  }
  __syncthreads();
  if (t < 32)
    part[((size_t)b * 85 + chunk) * 32 + t] =
        make_float2(sA[2 * t] + sA[2 * t + 1], sB[2 * t] + sB[2 * t + 1]);
}

__global__ void gn_finalize_kernel(const float2* __restrict__ part,
                                   float2* __restrict__ stats) {
  int t = threadIdx.x;  // 256 = 2b * 4l * 32g
  int b = t >> 7, rem = t & 127, l = rem >> 5, g = rem & 31;
  const int cnt_[4] = {64, 16, 4, 1};
  const int cb_[4] = {0, 64, 80, 84};
  const int HWs[4] = {4096, 1024, 256, 64};
  float s = 0.f, ss = 0.f;
  for (int i = 0; i < cnt_[l]; ++i) {
    float2 v = part[((size_t)b * 85 + cb_[l] + i) * 32 + g];
    s += v.x;
    ss += v.y;
  }
  float n = (float)(HWs[l] * 8);
  float mu = s / n;
  float var = ss / n - mu * mu;
  stats[(b * 4 + l) * 32 + g] = make_float2(mu, rsqrtf(var + 1e-5f));
}

// ---------------------------------------------------------------------------
__device__ __forceinline__ void get_level(int t, int& l, int& hw, int& Hl, int& Wl) {
  if (t < 4096)      { l = 0; hw = t;        Hl = 64; Wl = 64; }
  else if (t < 5120) { l = 1; hw = t - 4096; Hl = 32; Wl = 32; }
  else if (t < 5376) { l = 2; hw = t - 5120; Hl = 16; Wl = 16; }
  else               { l = 3; hw = t - 5376; Hl = 8;  Wl = 8;  }
}

// GN apply + bf16 shadow + qb = bf16(x + pos)
__global__ void gn_apply_kernel(float* __restrict__ x, __hip_bfloat16* __restrict__ xb,
                                __hip_bfloat16* __restrict__ qb,
                                const float* __restrict__ pos,
                                const float2* __restrict__ stats,
                                const float* __restrict__ gw, const float* __restrict__ gb) {
  int idx = blockIdx.x * 256 + threadIdx.x;
  if (idx >= BATCH * LQ * CDIM) return;
  int c = idx & 255;
  int tok = idx >> 8;
  int b = tok / LQ, t = tok % LQ;
  int l, hw, Hl, Wl;
  get_level(t, l, hw, Hl, Wl);
  float2 st = stats[(b * 4 + l) * 32 + (c >> 3)];
  float v = (x[idx] - st.x) * st.y * gw[l * CDIM + c] + gb[l * CDIM + c];
  x[idx] = v;
  xb[idx] = __float2bfloat16(v);
  qb[idx] = __float2bfloat16(v + pos[t * 256 + c]);
}

// pos embed + reference points in one launch
__global__ void pos_ref_kernel(const float* __restrict__ level_embed,
                               float* __restrict__ pos, float* __restrict__ ref) {
  int idx = blockIdx.x * 256 + threadIdx.x;
  if (idx >= LQ * CDIM) return;
  int t = idx >> 8, c = idx & 255;
  int l, hw, Hl, Wl;
  get_level(t, l, hw, Hl, Wl);
  int y = hw / Wl, xx = hw % Wl;
  const float twopi = 6.28318530717958647692f;
  float v; int cc;
  if (c < 128) { v = (float)(y + 1) * twopi / ((float)Hl + 1e-6f); cc = c; }
  else         { v = (float)(xx + 1) * twopi / ((float)Wl + 1e-6f); cc = c - 128; }
  int k = cc >> 1;
  float dim_t = expf((float)k * (logf(10000.0f) / 64.0f));
  float p = v / dim_t;
  float e = (cc & 1) ? cosf(p) : sinf(p);
  pos[idx] = e + level_embed[l * CDIM + c];
  if (c == 0) {
    ref[t * 2]     = ((float)xx + 0.5f) / (float)Wl;
    ref[t * 2 + 1] = ((float)y + 0.5f) / (float)Hl;
  }
}

// ---------------------------------------------------------------------------
// Deformable attention: 4-lane group per (token, head), 8 channels/lane,
// 16B bf16x8 gathers, branchless bilinear. grid = B*LQ*8/64 blocks of 256.
// ---------------------------------------------------------------------------
__global__ __launch_bounds__(256) void deform_attn_kernel(
    const __hip_bfloat16* __restrict__ value, const float* __restrict__ comb,
    const float* __restrict__ ref, __hip_bfloat16* __restrict__ out) {
  const int Wl_[4] = {64, 32, 16, 8};
  const int st_[4] = {0, 4096, 5120, 5376};
  int gid = blockIdx.x * 64 + (threadIdx.x >> 2);
  int lane4 = threadIdx.x & 3;
  int h = gid & 7;
  int tok = gid >> 3;
  int b = tok / LQ;
  int qi = tok - b * LQ;

  const float4* awv = (const float4*)(comb + (size_t)tok * 384 + 256 + h * 16);
  float4 q0 = awv[0], q1 = awv[1], q2 = awv[2], q3 = awv[3];
  float logit[16] = {q0.x, q0.y, q0.z, q0.w, q1.x, q1.y, q1.z, q1.w,
                     q2.x, q2.y, q2.z, q2.w, q3.x, q3.y, q3.z, q3.w};
  float mx = -1e30f;
#pragma unroll
  for (int i = 0; i < 16; ++i) mx = fmaxf(mx, logit[i]);
  const float LOG2E = 1.4426950408889634f;
  float ssum = 0.f;
#pragma unroll
  for (int i = 0; i < 16; ++i) {
    logit[i] = exp2f((logit[i] - mx) * LOG2E);
    ssum += logit[i];
  }
  float inv = 1.0f / ssum;

  float rx = ref[qi * 2], ry = ref[qi * 2 + 1];
  const float4* offv = (const float4*)(comb + (size_t)tok * 384 + h * 32);
  float acc[8] = {};

#pragma unroll
  for (int l = 0; l < 4; ++l) {
    const int Wl = Wl_[l];
    const float fW = (float)Wl;
    const __hip_bfloat16* vbase =
        value + ((size_t)b * LQ + st_[l]) * CDIM + h * 32 + lane4 * 8;
    float bx = fmaf(rx, fW, -0.5f);
    float by = fmaf(ry, fW, -0.5f);
    float4 oa = offv[l * 2], ob = offv[l * 2 + 1];
    float oxs[4] = {oa.x, oa.z, ob.x, ob.z};
    float oys[4] = {oa.y, oa.w, ob.y, ob.w};
#pragma unroll
    for (int p = 0; p < 4; ++p) {
      float px = bx + oxs[p], py = by + oys[p];
      float wgt = logit[l * 4 + p] * inv;
      float fpx = floorf(px), fpy = floorf(py);
      int x0 = (int)fpx, y0 = (int)fpy;
      float fx = px - fpx, fy = py - fpy;
      float wx0 = (x0 >= 0 && x0 < Wl) ? (1.f - fx) : 0.f;
      float wx1 = (x0 >= -1 && x0 < Wl - 1) ? fx : 0.f;
      float wy0 = (y0 >= 0 && y0 < Wl) ? (wgt * (1.f - fy)) : 0.f;
      float wy1 = (y0 >= -1 && y0 < Wl - 1) ? (wgt * fy) : 0.f;
      int xc0 = min(max(x0, 0), Wl - 1);
      int xc1 = min(max(x0 + 1, 0), Wl - 1);
      int yc0 = min(max(y0, 0), Wl - 1);
      int yc1 = min(max(y0 + 1, 0), Wl - 1);
      const __hip_bfloat16* r0 = vbase + (size_t)(yc0 * Wl) * CDIM;
      const __hip_bfloat16* r1 = vbase + (size_t)(yc1 * Wl) * CDIM;
      bf16x8 u00 = *(const bf16x8*)(r0 + (size_t)xc0 * CDIM);
      bf16x8 u01 = *(const bf16x8*)(r0 + (size_t)xc1 * CDIM);
      bf16x8 u10 = *(const bf16x8*)(r1 + (size_t)xc0 * CDIM);
      bf16x8 u11 = *(const bf16x8*)(r1 + (size_t)xc1 * CDIM);
      float w00 = wy0 * wx0, w01 = wy0 * wx1, w10 = wy1 * wx0, w11 = wy1 * wx1;
#pragma unroll
      for (int k = 0; k < 8; ++k) {
        float v00 = __uint_as_float((unsigned)(unsigned short)u00[k] << 16);
        float v01 = __uint_as_float((unsigned)(unsigned short)u01[k] << 16);
        float v10 = __uint_as_float((unsigned)(unsigned short)u10[k] << 16);
        float v11 = __uint_as_float((unsigned)(unsigned short)u11[k] << 16);
        acc[k] = fmaf(w00, v00, acc[k]);
        acc[k] = fmaf(w01, v01, acc[k]);
        acc[k] = fmaf(w10, v10, acc[k]);
        acc[k] = fmaf(w11, v11, acc[k]);
      }
    }
  }
  union { bf16x8 u; __hip_bfloat16 hh[8]; } pk;
#pragma unroll
  for (int k = 0; k < 8; ++k) pk.hh[k] = __float2bfloat16(acc[k]);
  *(bf16x8*)(out + (size_t)tok * CDIM + h * 32 + lane4 * 8) = pk.u;
}

// conv2 NHWC split over taps: part[tap][b][pix][2]
__global__ __launch_bounds__(256) void conv2_part_kernel(
    const __hip_bfloat16* __restrict__ c1o, const float* __restrict__ w,
    float* __restrict__ part) {
  int pix = blockIdx.x * 256 + threadIdx.x;
  int tap = blockIdx.y, b = blockIdx.z;
  int y = pix >> 6, x = pix & 63;
  int dy = tap / 3 - 1, dx = tap % 3 - 1;
  int yy = y + dy, xx = x + dx;
  bool ok = (yy >= 0 && yy < 64 && xx >= 0 && xx < 64);
  float a0 = 0.f, a1 = 0.f;
  if (ok) {
    const __hip_bfloat16* row = c1o + (size_t)(b * 4096 + yy * 64 + xx) * 64;
#pragma unroll
    for (int ic4 = 0; ic4 < 16; ++ic4) {
      ushort4 u = *(const ushort4*)(row + ic4 * 4);
      float f0 = __uint_as_float((unsigned)u.x << 16);
      float f1 = __uint_as_float((unsigned)u.y << 16);
      float f2 = __uint_as_float((unsigned)u.z << 16);
      float f3 = __uint_as_float((unsigned)u.w << 16);
      int ic = ic4 * 4;
      a0 = fmaf(w[(ic + 0) * 9 + tap], f0, a0);
      a0 = fmaf(w[(ic + 1) * 9 + tap], f1, a0);
      a0 = fmaf(w[(ic + 2) * 9 + tap], f2, a0);
      a0 = fmaf(w[(ic + 3) * 9 + tap], f3, a0);
      a1 = fmaf(w[576 + (ic + 0) * 9 + tap], f0, a1);
      a1 = fmaf(w[576 + (ic + 1) * 9 + tap], f1, a1);
      a1 = fmaf(w[576 + (ic + 2) * 9 + tap], f2, a1);
      a1 = fmaf(w[576 + (ic + 3) * 9 + tap], f3, a1);
    }
  }
  float2 o = make_float2(a0, a1);
  *(float2*)&part[((size_t)(tap * BATCH + b) * 4096 + pix) * 2] = o;
}

// sum 9 taps + bias -> c2o [b][pix][2]
__global__ void conv2_reduce_kernel(const float* __restrict__ part,
                                    const float* __restrict__ bias,
                                    float* __restrict__ out) {
  int i = blockIdx.x * 256 + threadIdx.x;
  if (i >= BATCH * 4096) return;
  int b = i >> 12, pix = i & 4095;
  float s0 = bias[0], s1 = bias[1];
#pragma unroll
  for (int tap = 0; tap < 9; ++tap) {
    float2 v = *(const float2*)&part[((size_t)(tap * BATCH + b) * 4096 + pix) * 2];
    s0 += v.x; s1 += v.y;
  }
  *(float2*)&out[(size_t)i * 2] = make_float2(s0, s1);
}

// 4x bilinear upsample 64->256; input layout [b][pix][2]
__global__ void upsample_kernel(const float* __restrict__ in, float* __restrict__ out) {
  int idx = blockIdx.x * 256 + threadIdx.x;
  if (idx >= BATCH * 2 * 256 * 256) return;
  int X = idx & 255, Y = (idx >> 8) & 255, p = idx >> 16;
  int b = p >> 1, oc = p & 1;
  float tx = ((float)X + 0.5f) * 0.25f - 0.5f;
  float ty = ((float)Y + 0.5f) * 0.25f - 0.5f;
  float fxf = floorf(tx), fyf = floorf(ty);
  int x0 = (int)fxf, y0 = (int)fyf;
  float fx = tx - fxf, fy = ty - fyf;
  int x0c = min(max(x0, 0), 63), x1c = min(max(x0 + 1, 0), 63);
  int y0c = min(max(y0, 0), 63), y1c = min(max(y0 + 1, 0), 63);
  const float* ip = in + (size_t)b * 4096 * 2 + oc;
  float v = (1.f - fy) * ((1.f - fx) * ip[(y0c * 64 + x0c) * 2] + fx * ip[(y0c * 64 + x1c) * 2]) +
            fy * ((1.f - fx) * ip[(y1c * 64 + x0c) * 2] + fx * ip[(y1c * 64 + x1c) * 2]);
  out[idx] = v;
}

// ---------------------------------------------------------------------------
extern "C" void kernel_launch(void* const* d_in, const int* in_sizes, int n_in,
                              void* d_out, int out_size, void* d_ws, size_t ws_size,
                              hipStream_t stream) {
  const float* f[4] = {(const float*)d_in[0], (const float*)d_in[1],
                       (const float*)d_in[2], (const float*)d_in[3]};
  const float* proj_w = (const float*)d_in[4];
  const float* proj_b = (const float*)d_in[5];
  const float* gn_w = (const float*)d_in[6];
  const float* gn_b = (const float*)d_in[7];
  const float* level_embed = (const float*)d_in[8];
  const float* so_w = (const float*)d_in[9];
  const float* so_b = (const float*)d_in[10];
  const float* aw_w = (const float*)d_in[11];
  const float* aw_b = (const float*)d_in[12];
  const float* vp_w = (const float*)d_in[13];
  const float* vp_b = (const float*)d_in[14];
  const float* op_w = (const float*)d_in[15];
  const float* op_b = (const float*)d_in[16];
  const float* n1_w = (const float*)d_in[17];
  const float* n1_b = (const float*)d_in[18];
  const float* l1_w = (const float*)d_in[19];
  const float* l1_b = (const float*)d_in[20];
  const float* l2_w = (const float*)d_in[21];
  const float* l2_b = (const float*)d_in[22];
  const float* n2_w = (const float*)d_in[23];
  const float* n2_b = (const float*)d_in[24];
  const float* c1_w = (const float*)d_in[25];
  const float* c1_b = (const float*)d_in[26];
  const float* c2_w = (const float*)d_in[27];
  const float* c2_b = (const float*)d_in[28];
  (void)in_sizes; (void)n_in; (void)out_size; (void)ws_size;

  float* ws = (float*)d_ws;
  const size_t TOK = (size_t)BATCH * LQ * CDIM;  // 2785280
  size_t o = 0;
  float* x = ws + o;     o += TOK;
  float* comb = ws + o;  o += (size_t)BATCH * LQ * 384;
  float* pos = ws + o;   o += (size_t)LQ * CDIM;
  float* refb = ws + o;  o += 11008;
  float2* stats = (float2*)(ws + o); o += 512;
  float* zerof = ws + o; o += 256;
  float* sowa_bias = ws + o; o += 2304;
  float2* gnpart = (float2*)(ws + o); o += 11008;
  __hip_bfloat16* xb = (__hip_bfloat16*)(ws + o);    o += TOK / 2;
  __hip_bfloat16* qb = (__hip_bfloat16*)(ws + o);    o += TOK / 2;
  __hip_bfloat16* valb = (__hip_bfloat16*)(ws + o);  o += TOK / 2;
  __hip_bfloat16* attnb = (__hip_bfloat16*)(ws + o); o += TOK / 2;
  __hip_bfloat16* ftb = (__hip_bfloat16*)(ws + o);   o += TOK / 2;
  __hip_bfloat16* ff1b = (__hip_bfloat16*)(ws + o);  o += (size_t)BATCH * LQ * FFDIM / 2;
  __hip_bfloat16* sowa_wb = (__hip_bfloat16*)(ws + o); o += 294912;
  __hip_bfloat16* vp_wb = (__hip_bfloat16*)(ws + o); o += 196608;
  __hip_bfloat16* op_wb = (__hip_bfloat16*)(ws + o); o += 196608;
  __hip_bfloat16* l1_wb = (__hip_bfloat16*)(ws + o); o += 786432;
  __hip_bfloat16* l2_wb = (__hip_bfloat16*)(ws + o); o += 786432;
  __hip_bfloat16* proj_wb = (__hip_bfloat16*)(ws + o); o += 131072;
  __hip_bfloat16* wc1b = (__hip_bfloat16*)(ws + o);  o += 73728;
  // head scratch aliases ff1b region (free after encoder)
  __hip_bfloat16* c1ob = ff1b;
  float* part2 = (float*)(ff1b + 524288);
  float* c2o = part2 + 147456;

  // 0) staging (4 dispatches)
  hipMemsetAsync(zerof, 0, 1024, stream);
  sowa_prep_kernel<<<(6 * 384 * 256 + 6 * 384 + 255) / 256, 256, 0, stream>>>(
      so_w, aw_w, so_b, aw_b, sowa_wb, sowa_bias);
  wc1_prep_kernel<<<(147456 + 255) / 256, 256, 0, stream>>>(c1_w, wc1b);
  f2b_multi_kernel<<<(1048576 + 255) / 256, 256, 0, stream>>>(
      proj_w, vp_w, op_w, l1_w, l2_w, proj_wb, vp_wb, op_wb, l1_wb, l2_wb);

  // 1) input transpose+convert, then single-launch bf16 MFMA input-proj
  transpose_f_kernel<<<dim3(85, 4, BATCH), 256, 0, stream>>>(f[0], f[1], f[2], f[3],
                                                             ftb);
  input_proj_kernel<<<170, 256, 0, stream>>>(ftb, proj_wb, proj_b, x);
  // 2) pos embed + ref (one launch)
  pos_ref_kernel<<<(LQ * CDIM + 255) / 256, 256, 0, stream>>>(level_embed, pos, refb);
  // 3) GroupNorm (2-stage stats + apply)
  gn_part_kernel<<<dim3(85, BATCH), 256, 0, stream>>>(x, gnpart);
  gn_finalize_kernel<<<1, 256, 0, stream>>>(gnpart, stats);
  {
    int n = BATCH * LQ * CDIM;
    gn_apply_kernel<<<(n + 255) / 256, 256, 0, stream>>>(x, xb, qb, pos, stats,
                                                         gn_w, gn_b);
  }

  for (int i = 0; i < 6; ++i) {
    const __hip_bfloat16* sowa = sowa_wb + (size_t)i * 98304;
    const __hip_bfloat16* vw = vp_wb + (size_t)i * 65536;
    const __hip_bfloat16* ow = op_wb + (size_t)i * 65536;
    const __hip_bfloat16* w1 = l1_wb + (size_t)i * 262144;
    const __hip_bfloat16* w2 = l2_wb + (size_t)i * 262144;
    const float* vb = vp_b + (size_t)i * CDIM;
    const float* ob = op_b + (size_t)i * CDIM;
    const float* b1 = l1_b + (size_t)i * FFDIM;
    const float* b2 = l2_b + (size_t)i * CDIM;

    // value proj + sampling proj in one launch (850 blocks)
    gemm_dual_kernel<<<850, 256, 0, stream>>>(xb, vw, vb, valb, qb, sowa,
                                              sowa_bias + i * 384, comb);
    deform_attn_kernel<<<BATCH * LQ * 8 / 64, 256, 0, stream>>>(valb, comb, refb,
                                                                attnb);
    // fused: x = LN(x + attnb@ow^T + ob), emits xb
    gemm_ln_kernel<false><<<340, 256, 0, stream>>>(
        attnb, ow, ob, x, xb, nullptr, nullptr,
        n1_w + (size_t)i * CDIM, n1_b + (size_t)i * CDIM, CDIM);
    // ffn1 at 4 blocks/CU (1360 blocks)
    ffn1_kernel<<<1360, 256, 0, stream>>>(xb, w1, b1, ff1b);
    // fused: x = LN(x + ff1b@w2^T + b2), emits xb and qb = bf16(x+pos)
    gemm_ln_kernel<true><<<340, 256, 0, stream>>>(
        ff1b, w2, b2, x, xb, qb, pos,
        n2_w + (size_t)i * CDIM, n2_b + (size_t)i * CDIM, FFDIM);
  }

  // head
  conv1_mfma_kernel<<<128, 256, 0, stream>>>(xb, wc1b, c1_b,
                                             (const __hip_bfloat16*)zerof, c1ob);
  conv2_part_kernel<<<dim3(16, 9, BATCH), 256, 0, stream>>>(c1ob, c2_w, part2);
  conv2_reduce_kernel<<<(BATCH * 4096 + 255) / 256, 256, 0, stream>>>(part2, c2_b,
                                                                      c2o);
  {
    int n = BATCH * 2 * 256 * 256;
    upsample_kernel<<<(n + 255) / 256, 256, 0, stream>>>(c2o, (float*)d_out);
  }
}

// Round 12
// 586.642 us; speedup vs baseline: 5.5720x; 1.0586x over previous
//
#include <hip/hip_runtime.h>
#include <hip/hip_bf16.h>
#include <math.h>

#define LQ 5440
#define CDIM 256
#define BATCH 2
#define FFDIM 1024

typedef __attribute__((ext_vector_type(8))) short bf16x8;
typedef __attribute__((ext_vector_type(4))) float f32x4;

typedef __attribute__((address_space(1))) void* gas1_t;
typedef __attribute__((address_space(3))) void* las3_t;

__device__ __forceinline__ void async16(const void* g, void* l) {
  __builtin_amdgcn_global_load_lds((gas1_t)g, (las3_t)l, 16, 0, 0);
}

#define WAIT_VM5() asm volatile("s_waitcnt vmcnt(5)" ::: "memory")
#define WAIT_VM4() asm volatile("s_waitcnt vmcnt(4)" ::: "memory")
#define WAIT_VM3() asm volatile("s_waitcnt vmcnt(3)" ::: "memory")
#define WAIT_VM2() asm volatile("s_waitcnt vmcnt(2)" ::: "memory")
#define WAIT_VM0() asm volatile("s_waitcnt vmcnt(0)" ::: "memory")

// chunk (0..84) -> level, row0 (64-row chunks across the 4 levels)
__device__ __forceinline__ void get_chunk(int chunk, int& l, int& row0) {
  if (chunk < 64)      { l = 0; row0 = chunk * 64; }
  else if (chunk < 80) { l = 1; row0 = (chunk - 64) * 64; }
  else if (chunk < 84) { l = 2; row0 = (chunk - 80) * 64; }
  else                 { l = 3; row0 = 0; }
}

// ---------------------------------------------------------------------------
// Input proj: all 4 levels in ONE launch. 128x128 tiles, 3-buffer pipeline,
// REMAP epilogue writes token-major x (fp32, consumed by GN only). grid=170.
// ---------------------------------------------------------------------------
__global__ __launch_bounds__(256, 2) void input_proj_kernel(
    const __hip_bfloat16* __restrict__ ftb, const __hip_bfloat16* __restrict__ proj_wb,
    const float* __restrict__ proj_b, float* __restrict__ x) {
  const int HWs[4] = {4096, 1024, 256, 64};
  const int STs[4] = {0, 4096, 5120, 5376};
  int i = blockIdx.x, l, j;
  if (i < 128)      { l = 0; j = i; }
  else if (i < 160) { l = 1; j = i - 128; }
  else if (i < 168) { l = 2; j = i - 160; }
  else              { l = 3; j = i - 168; }
  const int bm = (j >> 1) * 128, bn = (j & 1) * 128;
  const int mrows = HWs[l];
  const long obase = (long)STs[l] * 256;
  const long obstride = (long)LQ * 256;
  const __hip_bfloat16* A = ftb + (size_t)2 * STs[l] * 256;
  const __hip_bfloat16* Wt = proj_wb + (size_t)l * 65536;
  const float* bias = proj_b + l * 256;
  const int K = 256, N = 256;

  __shared__ __hip_bfloat16 As[3][128 * 32];
  __shared__ __hip_bfloat16 Bs[3][128 * 32];
  const int tid = threadIdx.x;
  const int lane = tid & 63, wave = tid >> 6;
  const int wr = wave >> 1, wc = wave & 1;
  const int srow = tid >> 2;
  const int scol = (tid & 3) * 8;
  const int lo0 = srow * 32 + scol;
  const int lo1 = (64 + srow) * 32 + scol;
  const __hip_bfloat16* ga0 = A + (size_t)(bm + srow) * K + scol;
  const __hip_bfloat16* ga1 = A + (size_t)(bm + 64 + srow) * K + scol;
  const __hip_bfloat16* gb0 = Wt + (size_t)(bn + srow) * K + scol;
  const __hip_bfloat16* gb1 = Wt + (size_t)(bn + 64 + srow) * K + scol;

  const int nt = K >> 5;
  async16(ga0, &As[0][lo0]);
  async16(ga1, &As[0][lo1]);
  async16(gb0, &Bs[0][lo0]);
  async16(gb1, &Bs[0][lo1]);
  async16(ga0 + 32, &As[1][lo0]);
  async16(ga1 + 32, &As[1][lo1]);
  async16(gb0 + 32, &Bs[1][lo0]);
  async16(gb1 + 32, &Bs[1][lo1]);

  f32x4 acc[4][4] = {};
  const int fr = lane & 15;
  const int ksub = (lane >> 4) * 8;
  int cur = 0, nxt = 2;
  for (int t = 0; t < nt; ++t) {
    if (t == nt - 1) WAIT_VM0(); else WAIT_VM4();
    __builtin_amdgcn_s_barrier();
    asm volatile("" ::: "memory");
    bf16x8 af[4], bfv[4];
#pragma unroll
    for (int mi = 0; mi < 4; ++mi)
      af[mi] = *(const bf16x8*)&As[cur][(wr * 64 + mi * 16 + fr) * 32 + ksub];
#pragma unroll
    for (int nj = 0; nj < 4; ++nj)
      bfv[nj] = *(const bf16x8*)&Bs[cur][(wc * 64 + nj * 16 + fr) * 32 + ksub];
    if (t + 2 < nt) {
      const int ko = (t + 2) * 32;
      async16(ga0 + ko, &As[nxt][lo0]);
      async16(ga1 + ko, &As[nxt][lo1]);
      async16(gb0 + ko, &Bs[nxt][lo0]);
      async16(gb1 + ko, &Bs[nxt][lo1]);
    }
#pragma unroll
    for (int mi = 0; mi < 4; ++mi)
#pragma unroll
      for (int nj = 0; nj < 4; ++nj)
        acc[mi][nj] = __builtin_amdgcn_mfma_f32_16x16x32_bf16(af[mi], bfv[nj],
                                                              acc[mi][nj], 0, 0, 0);
    cur = (cur == 2) ? 0 : cur + 1;
    nxt = (nxt == 2) ? 0 : nxt + 1;
  }

  const int cc = lane & 15;
  const int rbase = (lane >> 4) * 4;
  float bcol[4];
#pragma unroll
  for (int nj = 0; nj < 4; ++nj) bcol[nj] = bias[bn + wc * 64 + nj * 16 + cc];
#pragma unroll
  for (int mi = 0; mi < 4; ++mi)
#pragma unroll
    for (int nj = 0; nj < 4; ++nj) {
      int col = bn + wc * 64 + nj * 16 + cc;
#pragma unroll
      for (int r = 0; r < 4; ++r) {
        int row = bm + wr * 64 + mi * 16 + rbase + r;
        size_t oaddr = (size_t)obase +
                       (row < mrows ? (size_t)row * N
                                    : (size_t)obstride + (size_t)(row - mrows) * N) +
                       col;
        x[oaddr] = acc[mi][nj][r] + bcol[nj];
      }
    }
}

// ---------------------------------------------------------------------------
// 64x128-tile GEMM body (4 waves, each 64 rows x 32 cols). 3 loads/thread/stage.
// ---------------------------------------------------------------------------
template <bool RELU, bool OUT_F32, bool OUT_B16>
__device__ __forceinline__ void gemm64_body(
    const __hip_bfloat16* __restrict__ A, const __hip_bfloat16* __restrict__ Wt,
    const float* __restrict__ bias, float* __restrict__ C,
    __hip_bfloat16* __restrict__ Cb, int bm, int bn, int N, int K,
    __hip_bfloat16 (*As)[64 * 32], __hip_bfloat16 (*Bs)[128 * 32]) {
  const int tid = threadIdx.x;
  const int lane = tid & 63, wv = tid >> 6;
  const int srow = tid >> 2, scol = (tid & 3) * 8;
  const int loA = srow * 32 + scol;
  const int loB1 = (64 + srow) * 32 + scol;
  const __hip_bfloat16* ga = A + (size_t)(bm + srow) * K + scol;
  const __hip_bfloat16* gb0 = Wt + (size_t)(bn + srow) * K + scol;
  const __hip_bfloat16* gb1 = Wt + (size_t)(bn + 64 + srow) * K + scol;
  const int nt = K >> 5;
  async16(ga, &As[0][loA]);
  async16(gb0, &Bs[0][loA]);
  async16(gb1, &Bs[0][loB1]);
  async16(ga + 32, &As[1][loA]);
  async16(gb0 + 32, &Bs[1][loA]);
  async16(gb1 + 32, &Bs[1][loB1]);

  f32x4 acc[4][2] = {};
  const int fr = lane & 15, ksub = (lane >> 4) * 8;
  int cur = 0, nxt = 2;
  for (int t = 0; t < nt; ++t) {
    if (t == nt - 1) WAIT_VM0(); else WAIT_VM3();
    __builtin_amdgcn_s_barrier();
    asm volatile("" ::: "memory");
    bf16x8 af[4], bfv[2];
#pragma unroll
    for (int mi = 0; mi < 4; ++mi)
      af[mi] = *(const bf16x8*)&As[cur][(mi * 16 + fr) * 32 + ksub];
#pragma unroll
    for (int nj = 0; nj < 2; ++nj)
      bfv[nj] = *(const bf16x8*)&Bs[cur][(wv * 32 + nj * 16 + fr) * 32 + ksub];
    if (t + 2 < nt) {
      const int ko = (t + 2) * 32;
      async16(ga + ko, &As[nxt][loA]);
      async16(gb0 + ko, &Bs[nxt][loA]);
      async16(gb1 + ko, &Bs[nxt][loB1]);
    }
#pragma unroll
    for (int mi = 0; mi < 4; ++mi)
#pragma unroll
      for (int nj = 0; nj < 2; ++nj)
        acc[mi][nj] = __builtin_amdgcn_mfma_f32_16x16x32_bf16(af[mi], bfv[nj],
                                                              acc[mi][nj], 0, 0, 0);
    cur = (cur == 2) ? 0 : cur + 1;
    nxt = (nxt == 2) ? 0 : nxt + 1;
  }
  const int cc = lane & 15;
  const int rbase = (lane >> 4) * 4;
#pragma unroll
  for (int nj = 0; nj < 2; ++nj) {
    int col = bn + wv * 32 + nj * 16 + cc;
    float bb = bias[col];
#pragma unroll
    for (int mi = 0; mi < 4; ++mi)
#pragma unroll
      for (int r = 0; r < 4; ++r) {
        int row = bm + mi * 16 + rbase + r;
        float v = acc[mi][nj][r] + bb;
        if (RELU) v = fmaxf(v, 0.f);
        if (OUT_F32) C[(size_t)row * N + col] = v;
        if (OUT_B16) Cb[(size_t)row * N + col] = __float2bfloat16(v);
      }
  }
}

// Dual GEMM: blocks [0,340) -> value proj; [340,850) -> sampling proj (N=384)
__global__ __launch_bounds__(256, 4) void gemm_dual_kernel(
    const __hip_bfloat16* __restrict__ xb, const __hip_bfloat16* __restrict__ vw,
    const float* __restrict__ vb, __hip_bfloat16* __restrict__ valb,
    const __hip_bfloat16* __restrict__ qb, const __hip_bfloat16* __restrict__ sowa,
    const float* __restrict__ sbias, float* __restrict__ comb) {
  __shared__ __hip_bfloat16 As[3][64 * 32];
  __shared__ __hip_bfloat16 Bs[3][128 * 32];
  if (blockIdx.x < 340) {
    int i = blockIdx.x;
    gemm64_body<false, false, true>(xb, vw, vb, nullptr, valb, (i >> 1) * 64,
                                    (i & 1) * 128, 256, 256, As, Bs);
  } else {
    int j = blockIdx.x - 340;
    gemm64_body<false, true, false>(qb, sowa, sbias, comb, nullptr, (j / 3) * 64,
                                    (j % 3) * 128, 384, 256, As, Bs);
  }
}

// ffn1: relu(xb @ w1^T + b1) -> ff1b bf16. grid = 1360 blocks.
__global__ __launch_bounds__(256, 4) void ffn1_kernel(
    const __hip_bfloat16* __restrict__ xb, const __hip_bfloat16* __restrict__ w1,
    const float* __restrict__ b1, __hip_bfloat16* __restrict__ ff1b) {
  __shared__ __hip_bfloat16 As[3][64 * 32];
  __shared__ __hip_bfloat16 Bs[3][128 * 32];
  int i = blockIdx.x;
  gemm64_body<true, false, true>(xb, w1, b1, nullptr, ff1b, (i >> 3) * 64,
                                 (i & 7) * 128, 1024, 256, As, Bs);
}

// ---------------------------------------------------------------------------
// Fused GEMM (N=256) + residual(bf16 xb) + LayerNorm, 32-row tiles (grid 340).
// Writes xb (and qb = bf16(ln+pos) when EMIT_Q). No fp32 master.
// ---------------------------------------------------------------------------
template <bool EMIT_Q>
__global__ __launch_bounds__(256, 2) void gemm_ln_kernel(
    const __hip_bfloat16* __restrict__ A, const __hip_bfloat16* __restrict__ Wt,
    const float* __restrict__ bias, __hip_bfloat16* xb,
    __hip_bfloat16* __restrict__ qb, const float* __restrict__ pos,
    const float* __restrict__ lnw, const float* __restrict__ lnb, int K) {
  __shared__ __hip_bfloat16 As[3][32 * 32];
  __shared__ __hip_bfloat16 Bs[3][256 * 32];
  __shared__ float sred[4][32], ssred[4][32];
  const int tid = threadIdx.x;
  const int bm = blockIdx.x * 32;
  const int lane = tid & 63, wv = tid >> 6;
  const int srow = tid >> 2;             // 0..63 (B rows)
  const int arow = srow & 31;            // duplicated A rows
  const int scol = (tid & 3) * 8;
  const int loA = arow * 32 + scol;
  const __hip_bfloat16* ga = A + (size_t)(bm + arow) * K + scol;
  const __hip_bfloat16* gb = Wt + (size_t)srow * K + scol;

  const int nt = K >> 5;
  auto stage = [&](int t, int buf) {
    const int ko = t * 32;
    async16(ga + ko, &As[buf][loA]);
#pragma unroll
    for (int i = 0; i < 4; ++i)
      async16(gb + (size_t)(64 * i) * K + ko, &Bs[buf][(64 * i + srow) * 32 + scol]);
  };
  stage(0, 0);
  stage(1, 1);

  f32x4 acc[2][4] = {};
  const int fr = lane & 15;
  const int ksub = (lane >> 4) * 8;

  int cur = 0, nxt = 2;
  for (int t = 0; t < nt; ++t) {
    if (t == nt - 1) WAIT_VM0(); else WAIT_VM5();
    __builtin_amdgcn_s_barrier();
    asm volatile("" ::: "memory");
    bf16x8 af[2], bfv[4];
#pragma unroll
    for (int mi = 0; mi < 2; ++mi)
      af[mi] = *(const bf16x8*)&As[cur][(mi * 16 + fr) * 32 + ksub];
#pragma unroll
    for (int nj = 0; nj < 4; ++nj)
      bfv[nj] = *(const bf16x8*)&Bs[cur][(wv * 64 + nj * 16 + fr) * 32 + ksub];
    if (t + 2 < nt) stage(t + 2, nxt);
#pragma unroll
    for (int mi = 0; mi < 2; ++mi)
#pragma unroll
      for (int nj = 0; nj < 4; ++nj)
        acc[mi][nj] = __builtin_amdgcn_mfma_f32_16x16x32_bf16(af[mi], bfv[nj],
                                                              acc[mi][nj], 0, 0, 0);
    cur = (cur == 2) ? 0 : cur + 1;
    nxt = (nxt == 2) ? 0 : nxt + 1;
  }

  const int cc = lane & 15;
  const int rbase = (lane >> 4) * 4;
  float bcol[4], wcol[4], bncol[4];
#pragma unroll
  for (int nj = 0; nj < 4; ++nj) {
    int col = wv * 64 + nj * 16 + cc;
    bcol[nj] = bias[col];
    wcol[nj] = lnw[col];
    bncol[nj] = lnb[col];
  }
  // v = acc + bias + residual (bf16 xb)
#pragma unroll
  for (int mi = 0; mi < 2; ++mi)
#pragma unroll
    for (int r = 0; r < 4; ++r) {
      int grow = bm + mi * 16 + rbase + r;
#pragma unroll
      for (int nj = 0; nj < 4; ++nj) {
        int col = wv * 64 + nj * 16 + cc;
        acc[mi][nj][r] += bcol[nj] + __bfloat162float(xb[(size_t)grow * 256 + col]);
      }
    }
#pragma unroll
  for (int mi = 0; mi < 2; ++mi)
#pragma unroll
    for (int r = 0; r < 4; ++r) {
      float s = 0.f, ssq = 0.f;
#pragma unroll
      for (int nj = 0; nj < 4; ++nj) {
        float v = acc[mi][nj][r];
        s += v;
        ssq += v * v;
      }
#pragma unroll
      for (int m = 1; m < 16; m <<= 1) {
        s += __shfl_xor(s, m);
        ssq += __shfl_xor(ssq, m);
      }
      if (cc == 0) {
        int row = mi * 16 + rbase + r;
        sred[wv][row] = s;
        ssred[wv][row] = ssq;
      }
    }
  __syncthreads();
#pragma unroll
  for (int mi = 0; mi < 2; ++mi)
#pragma unroll
    for (int r = 0; r < 4; ++r) {
      int row = mi * 16 + rbase + r;
      int grow = bm + row;
      float s = sred[0][row] + sred[1][row] + sred[2][row] + sred[3][row];
      float ssq = ssred[0][row] + ssred[1][row] + ssred[2][row] + ssred[3][row];
      float mu = s * (1.0f / 256.0f);
      float var = ssq * (1.0f / 256.0f) - mu * mu;
      float rsig = rsqrtf(var + 1e-5f);
      int tokp = grow >= LQ ? grow - LQ : grow;
#pragma unroll
      for (int nj = 0; nj < 4; ++nj) {
        int col = wv * 64 + nj * 16 + cc;
        float xn = (acc[mi][nj][r] - mu) * rsig * wcol[nj] + bncol[nj];
        xb[(size_t)grow * 256 + col] = __float2bfloat16(xn);
        if (EMIT_Q)
          qb[(size_t)grow * 256 + col] =
              __float2bfloat16(xn + pos[(size_t)tokp * 256 + col]);
      }
    }
}

// ---------------------------------------------------------------------------
// conv1 implicit GEMM (NHWC), 64-pixel tiles, 72-step pipelined K-loop.
// ---------------------------------------------------------------------------
__global__ __launch_bounds__(256, 4) void conv1_mfma_kernel(
    const __hip_bfloat16* __restrict__ xb, const __hip_bfloat16* __restrict__ wc1,
    const float* __restrict__ bias, const __hip_bfloat16* __restrict__ zerob,
    __hip_bfloat16* __restrict__ c1o) {
  __shared__ __hip_bfloat16 As[3][64 * 32];
  __shared__ __hip_bfloat16 Bs[3][64 * 32];
  const int tid = threadIdx.x;
  const int b = blockIdx.x >> 6;
  const int pm = (blockIdx.x & 63) * 64;
  const int lane = tid & 63, wave = tid >> 6;
  const int sr = tid >> 2;
  const int sc = (tid & 3) * 8;
  const int lo = sr * 32 + sc;
  f32x4 acc[4] = {};
  const int fr = lane & 15, ksub = (lane >> 4) * 8;

  auto stage = [&](int kt, int buf) {
    int tap = kt >> 3;
    int kk = (kt & 7) * 32;
    int dy = tap / 3 - 1, dx = tap % 3 - 1;
    int hw = pm + sr;
    int y = (hw >> 6) + dy, x = (hw & 63) + dx;
    bool ok = (y >= 0 && y < 64 && x >= 0 && x < 64);
    const __hip_bfloat16* s =
        xb + ((size_t)(b * LQ) + y * 64 + x) * 256 + kk + sc;
    const __hip_bfloat16* wsrc = wc1 + (size_t)sr * 2304 + tap * 256 + kk + sc;
    async16(ok ? s : zerob, &As[buf][lo]);
    async16(wsrc, &Bs[buf][lo]);
  };
  stage(0, 0);
  stage(1, 1);
  int cur = 0, nxt = 2;
  for (int kt = 0; kt < 72; ++kt) {
    if (kt == 71) WAIT_VM0(); else WAIT_VM2();
    __builtin_amdgcn_s_barrier();
    asm volatile("" ::: "memory");
    bf16x8 af;
    bf16x8 bfv[4];
    af = *(const bf16x8*)&As[cur][(wave * 16 + fr) * 32 + ksub];
#pragma unroll
    for (int nj = 0; nj < 4; ++nj)
      bfv[nj] = *(const bf16x8*)&Bs[cur][(nj * 16 + fr) * 32 + ksub];
    if (kt + 2 < 72) stage(kt + 2, nxt);
#pragma unroll
    for (int nj = 0; nj < 4; ++nj)
      acc[nj] = __builtin_amdgcn_mfma_f32_16x16x32_bf16(af, bfv[nj], acc[nj], 0, 0, 0);
    cur = (cur == 2) ? 0 : cur + 1;
    nxt = (nxt == 2) ? 0 : nxt + 1;
  }
  const int cc = lane & 15;
  const int rbase = (lane >> 4) * 4;
#pragma unroll
  for (int nj = 0; nj < 4; ++nj) {
    int col = nj * 16 + cc;
    float bb = bias[col];
#pragma unroll
    for (int r = 0; r < 4; ++r) {
      int row = wave * 16 + rbase + r;
      float v = fmaxf(acc[nj][r] + bb, 0.f);
      c1o[(size_t)(b * 4096 + pm + row) * 64 + col] = __float2bfloat16(v);
    }
  }
}

// ---------------------------------------------------------------------------
// ONE prep kernel: f2b (proj,vp,op,l1,l2) + sowa weights/bias + wc1 + zero page
// Ranges: [0,1048576) f4 | [.,1638400) sowa w | [.,1640704) sowa b |
//         [.,1788160) wc1 | [.,1788416) zero
// ---------------------------------------------------------------------------
__global__ void prep_all_kernel(
    const float* __restrict__ proj_w, const float* __restrict__ vp_w,
    const float* __restrict__ op_w, const float* __restrict__ l1_w,
    const float* __restrict__ l2_w, const float* __restrict__ so_w,
    const float* __restrict__ aw_w, const float* __restrict__ so_b,
    const float* __restrict__ aw_b, const float* __restrict__ c1_w,
    __hip_bfloat16* __restrict__ proj_wb, __hip_bfloat16* __restrict__ vp_wb,
    __hip_bfloat16* __restrict__ op_wb, __hip_bfloat16* __restrict__ l1_wb,
    __hip_bfloat16* __restrict__ l2_wb, __hip_bfloat16* __restrict__ sowa_wb,
    float* __restrict__ sowa_bias, __hip_bfloat16* __restrict__ wc1b,
    float* __restrict__ zerof) {
  int i = blockIdx.x * 256 + threadIdx.x;
  if (i < 1048576) {
    const float* in;
    __hip_bfloat16* out;
    int j;
    if (i < 65536)       { in = proj_w; out = proj_wb; j = i; }
    else if (i < 163840) { in = vp_w;   out = vp_wb;   j = i - 65536; }
    else if (i < 262144) { in = op_w;   out = op_wb;   j = i - 163840; }
    else if (i < 655360) { in = l1_w;   out = l1_wb;   j = i - 262144; }
    else                 { in = l2_w;   out = l2_wb;   j = i - 655360; }
    float4 v = ((const float4*)in)[j];
    union { ushort4 u; __hip_bfloat16 h[4]; } p;
    p.h[0] = __float2bfloat16(v.x);
    p.h[1] = __float2bfloat16(v.y);
    p.h[2] = __float2bfloat16(v.z);
    p.h[3] = __float2bfloat16(v.w);
    ((ushort4*)out)[j] = p.u;
  } else if (i < 1638400) {
    int j = i - 1048576;
    int il = j / (384 * 256);
    int rem = j - il * 384 * 256;
    int n = rem >> 8, k = rem & 255;
    float v = (n < 256) ? so_w[(size_t)il * 65536 + n * 256 + k]
                        : aw_w[(size_t)il * 32768 + (n - 256) * 256 + k];
    sowa_wb[j] = __float2bfloat16(v);
  } else if (i < 1640704) {
    int j = i - 1638400;
    int il = j / 384, n = j % 384;
    sowa_bias[j] = (n < 256) ? so_b[il * 256 + n] : aw_b[il * 128 + n - 256];
  } else if (i < 1788160) {
    int j = i - 1640704;
    int oc = j / 2304, r = j % 2304;
    int tap = r >> 8, ic = r & 255;
    wc1b[j] = __float2bfloat16(c1_w[(size_t)oc * 2304 + ic * 9 + tap]);
  } else if (i < 1788416) {
    zerof[i - 1788160] = 0.f;
  }
}

// ---------------------------------------------------------------------------
// transpose+convert: f[l][b][c][hw] fp32 -> ft (level-major) [l][b][hw][c] bf16
// ---------------------------------------------------------------------------
__global__ __launch_bounds__(256) void transpose_f_kernel(
    const float* __restrict__ f0, const float* __restrict__ f1,
    const float* __restrict__ f2, const float* __restrict__ f3,
    __hip_bfloat16* __restrict__ ft) {
  __shared__ float tile[64][65];
  const int HWs[4] = {4096, 1024, 256, 64};
  const int STs[4] = {0, 4096, 5120, 5376};
  int chunk = blockIdx.x, c0 = blockIdx.y * 64, b = blockIdx.z;
  int l, row0;
  get_chunk(chunk, l, row0);
  const float* fin = (l == 0) ? f0 : (l == 1) ? f1 : (l == 2) ? f2 : f3;
  const int HW = HWs[l];
  int t = threadIdx.x;
  int cr = t >> 4, hc4 = (t & 15) * 4;
#pragma unroll
  for (int p = 0; p < 4; ++p) {
    int c = c0 + p * 16 + cr;
    float4 v = *(const float4*)&fin[(size_t)(b * 256 + c) * HW + row0 + hc4];
    tile[p * 16 + cr][hc4 + 0] = v.x;
    tile[p * 16 + cr][hc4 + 1] = v.y;
    tile[p * 16 + cr][hc4 + 2] = v.z;
    tile[p * 16 + cr][hc4 + 3] = v.w;
  }
  __syncthreads();
  size_t obase = (size_t)2 * STs[l] * 256 + ((size_t)b * HW + row0) * 256 + c0;
#pragma unroll
  for (int p = 0; p < 4; ++p) {
    int r = p * 16 + cr;
    union { ushort4 u; __hip_bfloat16 h[4]; } pk;
    pk.h[0] = __float2bfloat16(tile[hc4 + 0][r]);
    pk.h[1] = __float2bfloat16(tile[hc4 + 1][r]);
    pk.h[2] = __float2bfloat16(tile[hc4 + 2][r]);
    pk.h[3] = __float2bfloat16(tile[hc4 + 3][r]);
    *(ushort4*)&ft[obase + (size_t)r * 256 + hc4] = pk.u;
  }
}

// ---------------------------------------------------------------------------
// GroupNorm stats stage 1 (coalesced 64-row chunks).
// ---------------------------------------------------------------------------
__global__ __launch_bounds__(256) void gn_part_kernel(const float* __restrict__ x,
                                                      float2* __restrict__ part) {
  const int STs[4] = {0, 4096, 5120, 5376};
  int chunk = blockIdx.x, b = blockIdx.y;
  int l, row0;
  get_chunk(chunk, l, row0);
  size_t base = ((size_t)b * LQ + STs[l] + row0) * 256;
  int t = threadIdx.x;
  int col4 = t & 63, rb = t >> 6;
  float s = 0.f, ss = 0.f;
#pragma unroll 4
  for (int i = 0; i < 16; ++i) {
    int r = rb + i * 4;
    float4 v = *(const float4*)&x[base + (size_t)r * 256 + col4 * 4];
    s += v.x + v.y + v.z + v.w;
    ss += v.x * v.x + v.y * v.y + v.z * v.z + v.w * v.w;
  }
  __shared__ float sA[256], sB[256];
  sA[t] = s;
  sB[t] = ss;
  __syncthreads();
  if (t < 64) {
    s = sA[t] + sA[t + 64] + sA[t + 128] + sA[t + 192];
    ss = sB[t] + sB[t + 64] + sB[t + 128] + sB[t + 192];
    sA[t] = s;
    sB[t] = ss;
  }
  __syncthreads();
  if (t < 32)
    part[((size_t)b * 85 + chunk) * 32 + t] =
        make_float2(sA[2 * t] + sA[2 * t + 1], sB[2 * t] + sB[2 * t + 1]);
}

// ---------------------------------------------------------------------------
__device__ __forceinline__ void get_level(int t, int& l, int& hw, int& Hl, int& Wl) {
  if (t < 4096)      { l = 0; hw = t;        Hl = 64; Wl = 64; }
  else if (t < 5120) { l = 1; hw = t - 4096; Hl = 32; Wl = 32; }
  else if (t < 5376) { l = 2; hw = t - 5120; Hl = 16; Wl = 16; }
  else               { l = 3; hw = t - 5376; Hl = 8;  Wl = 8;  }
}

// pos embed + reference points + GN finalize (last block). grid = 5441.
__global__ void pos_ref_fin_kernel(const float* __restrict__ level_embed,
                                   float* __restrict__ pos, float* __restrict__ ref,
                                   const float2* __restrict__ part,
                                   float2* __restrict__ stats) {
  if (blockIdx.x == 5440) {
    int t = threadIdx.x;  // 256 = 2b * 4l * 32g
    int b = t >> 7, rem = t & 127, l = rem >> 5, g = rem & 31;
    const int cnt_[4] = {64, 16, 4, 1};
    const int cb_[4] = {0, 64, 80, 84};
    const int HWs[4] = {4096, 1024, 256, 64};
    float s = 0.f, ss = 0.f;
    for (int i = 0; i < cnt_[l]; ++i) {
      float2 v = part[((size_t)b * 85 + cb_[l] + i) * 32 + g];
      s += v.x;
      ss += v.y;
    }
    float n = (float)(HWs[l] * 8);
    float mu = s / n;
    float var = ss / n - mu * mu;
    stats[(b * 4 + l) * 32 + g] = make_float2(mu, rsqrtf(var + 1e-5f));
    return;
  }
  int idx = blockIdx.x * 256 + threadIdx.x;  // < LQ*CDIM exactly
  int t = idx >> 8, c = idx & 255;
  int l, hw, Hl, Wl;
  get_level(t, l, hw, Hl, Wl);
  int y = hw / Wl, xx = hw % Wl;
  const float twopi = 6.28318530717958647692f;
  float v; int cc;
  if (c < 128) { v = (float)(y + 1) * twopi / ((float)Hl + 1e-6f); cc = c; }
  else         { v = (float)(xx + 1) * twopi / ((float)Wl + 1e-6f); cc = c - 128; }
  int k = cc >> 1;
  float dim_t = expf((float)k * (logf(10000.0f) / 64.0f));
  float p = v / dim_t;
  float e = (cc & 1) ? cosf(p) : sinf(p);
  pos[idx] = e + level_embed[l * CDIM + c];
  if (c == 0) {
    ref[t * 2]     = ((float)xx + 0.5f) / (float)Wl;
    ref[t * 2 + 1] = ((float)y + 0.5f) / (float)Hl;
  }
}

// GN apply: emits xb + qb = bf16(x + pos) (no fp32 master write)
__global__ void gn_apply_kernel(const float* __restrict__ x,
                                __hip_bfloat16* __restrict__ xb,
                                __hip_bfloat16* __restrict__ qb,
                                const float* __restrict__ pos,
                                const float2* __restrict__ stats,
                                const float* __restrict__ gw, const float* __restrict__ gb) {
  int idx = blockIdx.x * 256 + threadIdx.x;
  if (idx >= BATCH * LQ * CDIM) return;
  int c = idx & 255;
  int tok = idx >> 8;
  int b = tok / LQ, t = tok % LQ;
  int l, hw, Hl, Wl;
  get_level(t, l, hw, Hl, Wl);
  float2 st = stats[(b * 4 + l) * 32 + (c >> 3)];
  float v = (x[idx] - st.x) * st.y * gw[l * CDIM + c] + gb[l * CDIM + c];
  xb[idx] = __float2bfloat16(v);
  qb[idx] = __float2bfloat16(v + pos[t * 256 + c]);
}

// ---------------------------------------------------------------------------
// Deformable attention: 4-lane group per (token, head), 8 channels/lane,
// 16B bf16x8 gathers, branchless bilinear. grid = B*LQ*8/64 blocks of 256.
// ---------------------------------------------------------------------------
__global__ __launch_bounds__(256) void deform_attn_kernel(
    const __hip_bfloat16* __restrict__ value, const float* __restrict__ comb,
    const float* __restrict__ ref, __hip_bfloat16* __restrict__ out) {
  const int Wl_[4] = {64, 32, 16, 8};
  const int st_[4] = {0, 4096, 5120, 5376};
  int gid = blockIdx.x * 64 + (threadIdx.x >> 2);
  int lane4 = threadIdx.x & 3;
  int h = gid & 7;
  int tok = gid >> 3;
  int b = tok / LQ;
  int qi = tok - b * LQ;

  const float4* awv = (const float4*)(comb + (size_t)tok * 384 + 256 + h * 16);
  float4 q0 = awv[0], q1 = awv[1], q2 = awv[2], q3 = awv[3];
  float logit[16] = {q0.x, q0.y, q0.z, q0.w, q1.x, q1.y, q1.z, q1.w,
                     q2.x, q2.y, q2.z, q2.w, q3.x, q3.y, q3.z, q3.w};
  float mx = -1e30f;
#pragma unroll
  for (int i = 0; i < 16; ++i) mx = fmaxf(mx, logit[i]);
  const float LOG2E = 1.4426950408889634f;
  float ssum = 0.f;
#pragma unroll
  for (int i = 0; i < 16; ++i) {
    logit[i] = exp2f((logit[i] - mx) * LOG2E);
    ssum += logit[i];
  }
  float inv = 1.0f / ssum;

  float rx = ref[qi * 2], ry = ref[qi * 2 + 1];
  const float4* offv = (const float4*)(comb + (size_t)tok * 384 + h * 32);
  float acc[8] = {};

#pragma unroll
  for (int l = 0; l < 4; ++l) {
    const int Wl = Wl_[l];
    const float fW = (float)Wl;
    const __hip_bfloat16* vbase =
        value + ((size_t)b * LQ + st_[l]) * CDIM + h * 32 + lane4 * 8;
    float bx = fmaf(rx, fW, -0.5f);
    float by = fmaf(ry, fW, -0.5f);
    float4 oa = offv[l * 2], ob = offv[l * 2 + 1];
    float oxs[4] = {oa.x, oa.z, ob.x, ob.z};
    float oys[4] = {oa.y, oa.w, ob.y, ob.w};
#pragma unroll
    for (int p = 0; p < 4; ++p) {
      float px = bx + oxs[p], py = by + oys[p];
      float wgt = logit[l * 4 + p] * inv;
      float fpx = floorf(px), fpy = floorf(py);
      int x0 = (int)fpx, y0 = (int)fpy;
      float fx = px - fpx, fy = py - fpy;
      float wx0 = (x0 >= 0 && x0 < Wl) ? (1.f - fx) : 0.f;
      float wx1 = (x0 >= -1 && x0 < Wl - 1) ? fx : 0.f;
      float wy0 = (y0 >= 0 && y0 < Wl) ? (wgt * (1.f - fy)) : 0.f;
      float wy1 = (y0 >= -1 && y0 < Wl - 1) ? (wgt * fy) : 0.f;
      int xc0 = min(max(x0, 0), Wl - 1);
      int xc1 = min(max(x0 + 1, 0), Wl - 1);
      int yc0 = min(max(y0, 0), Wl - 1);
      int yc1 = min(max(y0 + 1, 0), Wl - 1);
      const __hip_bfloat16* r0 = vbase + (size_t)(yc0 * Wl) * CDIM;
      const __hip_bfloat16* r1 = vbase + (size_t)(yc1 * Wl) * CDIM;
      bf16x8 u00 = *(const bf16x8*)(r0 + (size_t)xc0 * CDIM);
      bf16x8 u01 = *(const bf16x8*)(r0 + (size_t)xc1 * CDIM);
      bf16x8 u10 = *(const bf16x8*)(r1 + (size_t)xc0 * CDIM);
      bf16x8 u11 = *(const bf16x8*)(r1 + (size_t)xc1 * CDIM);
      float w00 = wy0 * wx0, w01 = wy0 * wx1, w10 = wy1 * wx0, w11 = wy1 * wx1;
#pragma unroll
      for (int k = 0; k < 8; ++k) {
        float v00 = __uint_as_float((unsigned)(unsigned short)u00[k] << 16);
        float v01 = __uint_as_float((unsigned)(unsigned short)u01[k] << 16);
        float v10 = __uint_as_float((unsigned)(unsigned short)u10[k] << 16);
        float v11 = __uint_as_float((unsigned)(unsigned short)u11[k] << 16);
        acc[k] = fmaf(w00, v00, acc[k]);
        acc[k] = fmaf(w01, v01, acc[k]);
        acc[k] = fmaf(w10, v10, acc[k]);
        acc[k] = fmaf(w11, v11, acc[k]);
      }
    }
  }
  union { bf16x8 u; __hip_bfloat16 hh[8]; } pk;
#pragma unroll
  for (int k = 0; k < 8; ++k) pk.hh[k] = __float2bfloat16(acc[k]);
  *(bf16x8*)(out + (size_t)tok * CDIM + h * 32 + lane4 * 8) = pk.u;
}

// conv2 NHWC split over taps: part[tap][b][pix][2]
__global__ __launch_bounds__(256) void conv2_part_kernel(
    const __hip_bfloat16* __restrict__ c1o, const float* __restrict__ w,
    float* __restrict__ part) {
  int pix = blockIdx.x * 256 + threadIdx.x;
  int tap = blockIdx.y, b = blockIdx.z;
  int y = pix >> 6, x = pix & 63;
  int dy = tap / 3 - 1, dx = tap % 3 - 1;
  int yy = y + dy, xx = x + dx;
  bool ok = (yy >= 0 && yy < 64 && xx >= 0 && xx < 64);
  float a0 = 0.f, a1 = 0.f;
  if (ok) {
    const __hip_bfloat16* row = c1o + (size_t)(b * 4096 + yy * 64 + xx) * 64;
#pragma unroll
    for (int ic4 = 0; ic4 < 16; ++ic4) {
      ushort4 u = *(const ushort4*)(row + ic4 * 4);
      float f0 = __uint_as_float((unsigned)u.x << 16);
      float f1 = __uint_as_float((unsigned)u.y << 16);
      float f2 = __uint_as_float((unsigned)u.z << 16);
      float f3 = __uint_as_float((unsigned)u.w << 16);
      int ic = ic4 * 4;
      a0 = fmaf(w[(ic + 0) * 9 + tap], f0, a0);
      a0 = fmaf(w[(ic + 1) * 9 + tap], f1, a0);
      a0 = fmaf(w[(ic + 2) * 9 + tap], f2, a0);
      a0 = fmaf(w[(ic + 3) * 9 + tap], f3, a0);
      a1 = fmaf(w[576 + (ic + 0) * 9 + tap], f0, a1);
      a1 = fmaf(w[576 + (ic + 1) * 9 + tap], f1, a1);
      a1 = fmaf(w[576 + (ic + 2) * 9 + tap], f2, a1);
      a1 = fmaf(w[576 + (ic + 3) * 9 + tap], f3, a1);
    }
  }
  float2 o = make_float2(a0, a1);
  *(float2*)&part[((size_t)(tap * BATCH + b) * 4096 + pix) * 2] = o;
}

// tap-sum + bias + 4x bilinear upsample in one pass. One thread per (b,Y,X),
// writes both output channels. grid = B*65536/256 = 512 blocks.
__global__ void upsample2_kernel(const float* __restrict__ part,
                                 const float* __restrict__ bias,
                                 float* __restrict__ out) {
  int idx = blockIdx.x * 256 + threadIdx.x;
  if (idx >= BATCH * 65536) return;
  int X = idx & 255, Y = (idx >> 8) & 255, b = idx >> 16;
  float tx = ((float)X + 0.5f) * 0.25f - 0.5f;
  float ty = ((float)Y + 0.5f) * 0.25f - 0.5f;
  float fxf = floorf(tx), fyf = floorf(ty);
  int x0 = (int)fxf, y0 = (int)fyf;
  float fx = tx - fxf, fy = ty - fyf;
  int x0c = min(max(x0, 0), 63), x1c = min(max(x0 + 1, 0), 63);
  int y0c = min(max(y0, 0), 63), y1c = min(max(y0 + 1, 0), 63);
  int p00 = y0c * 64 + x0c, p01 = y0c * 64 + x1c;
  int p10 = y1c * 64 + x0c, p11 = y1c * 64 + x1c;
  float c00x = 0.f, c00y = 0.f, c01x = 0.f, c01y = 0.f;
  float c10x = 0.f, c10y = 0.f, c11x = 0.f, c11y = 0.f;
#pragma unroll
  for (int tap = 0; tap < 9; ++tap) {
    const float* pp = part + ((size_t)(tap * BATCH + b) * 4096) * 2;
    float2 v00 = *(const float2*)&pp[p00 * 2];
    float2 v01 = *(const float2*)&pp[p01 * 2];
    float2 v10 = *(const float2*)&pp[p10 * 2];
    float2 v11 = *(const float2*)&pp[p11 * 2];
    c00x += v00.x; c00y += v00.y;
    c01x += v01.x; c01y += v01.y;
    c10x += v10.x; c10y += v10.y;
    c11x += v11.x; c11y += v11.y;
  }
  float b0 = bias[0], b1 = bias[1];
  float w00 = (1.f - fy) * (1.f - fx), w01 = (1.f - fy) * fx;
  float w10 = fy * (1.f - fx), w11 = fy * fx;
  float o0 = w00 * (c00x + b0) + w01 * (c01x + b0) + w10 * (c10x + b0) + w11 * (c11x + b0);
  float o1 = w00 * (c00y + b1) + w01 * (c01y + b1) + w10 * (c10y + b1) + w11 * (c11y + b1);
  size_t obase = (size_t)b * 2 * 65536 + (Y << 8) + X;
  out[obase] = o0;
  out[obase + 65536] = o1;
}

// ---------------------------------------------------------------------------
extern "C" void kernel_launch(void* const* d_in, const int* in_sizes, int n_in,
                              void* d_out, int out_size, void* d_ws, size_t ws_size,
                              hipStream_t stream) {
  const float* f[4] = {(const float*)d_in[0], (const float*)d_in[1],
                       (const float*)d_in[2], (const float*)d_in[3]};
  const float* proj_w = (const float*)d_in[4];
  const float* proj_b = (const float*)d_in[5];
  const float* gn_w = (const float*)d_in[6];
  const float* gn_b = (const float*)d_in[7];
  const float* level_embed = (const float*)d_in[8];
  const float* so_w = (const float*)d_in[9];
  const float* so_b = (const float*)d_in[10];
  const float* aw_w = (const float*)d_in[11];
  const float* aw_b = (const float*)d_in[12];
  const float* vp_w = (const float*)d_in[13];
  const float* vp_b = (const float*)d_in[14];
  const float* op_w = (const float*)d_in[15];
  const float* op_b = (const float*)d_in[16];
  const float* n1_w = (const float*)d_in[17];
  const float* n1_b = (const float*)d_in[18];
  const float* l1_w = (const float*)d_in[19];
  const float* l1_b = (const float*)d_in[20];
  const float* l2_w = (const float*)d_in[21];
  const float* l2_b = (const float*)d_in[22];
  const float* n2_w = (const float*)d_in[23];
  const float* n2_b = (const float*)d_in[24];
  const float* c1_w = (const float*)d_in[25];
  const float* c1_b = (const float*)d_in[26];
  const float* c2_w = (const float*)d_in[27];
  const float* c2_b = (const float*)d_in[28];
  (void)in_sizes; (void)n_in; (void)out_size; (void)ws_size;

  float* ws = (float*)d_ws;
  const size_t TOK = (size_t)BATCH * LQ * CDIM;  // 2785280
  size_t o = 0;
  float* x = ws + o;     o += TOK;
  float* comb = ws + o;  o += (size_t)BATCH * LQ * 384;
  float* pos = ws + o;   o += (size_t)LQ * CDIM;
  float* refb = ws + o;  o += 11008;
  float2* stats = (float2*)(ws + o); o += 512;
  float* zerof = ws + o; o += 256;
  float* sowa_bias = ws + o; o += 2304;
  float2* gnpart = (float2*)(ws + o); o += 11008;
  __hip_bfloat16* xb = (__hip_bfloat16*)(ws + o);    o += TOK / 2;
  __hip_bfloat16* qb = (__hip_bfloat16*)(ws + o);    o += TOK / 2;
  __hip_bfloat16* valb = (__hip_bfloat16*)(ws + o);  o += TOK / 2;
  __hip_bfloat16* attnb = (__hip_bfloat16*)(ws + o); o += TOK / 2;
  __hip_bfloat16* ftb = (__hip_bfloat16*)(ws + o);   o += TOK / 2;
  __hip_bfloat16* ff1b = (__hip_bfloat16*)(ws + o);  o += (size_t)BATCH * LQ * FFDIM / 2;
  __hip_bfloat16* sowa_wb = (__hip_bfloat16*)(ws + o); o += 294912;
  __hip_bfloat16* vp_wb = (__hip_bfloat16*)(ws + o); o += 196608;
  __hip_bfloat16* op_wb = (__hip_bfloat16*)(ws + o); o += 196608;
  __hip_bfloat16* l1_wb = (__hip_bfloat16*)(ws + o); o += 786432;
  __hip_bfloat16* l2_wb = (__hip_bfloat16*)(ws + o); o += 786432;
  __hip_bfloat16* proj_wb = (__hip_bfloat16*)(ws + o); o += 131072;
  __hip_bfloat16* wc1b = (__hip_bfloat16*)(ws + o);  o += 73728;
  // head scratch aliases ff1b region (free after encoder)
  __hip_bfloat16* c1ob = ff1b;
  float* part2 = (float*)(ff1b + 524288);

  // 0) all weight prep in one launch
  prep_all_kernel<<<(1788416 + 255) / 256, 256, 0, stream>>>(
      proj_w, vp_w, op_w, l1_w, l2_w, so_w, aw_w, so_b, aw_b, c1_w,
      proj_wb, vp_wb, op_wb, l1_wb, l2_wb, sowa_wb, sowa_bias, wc1b, zerof);

  // 1) input transpose+convert, single-launch input-proj, GN stats
  transpose_f_kernel<<<dim3(85, 4, BATCH), 256, 0, stream>>>(f[0], f[1], f[2], f[3],
                                                             ftb);
  input_proj_kernel<<<170, 256, 0, stream>>>(ftb, proj_wb, proj_b, x);
  gn_part_kernel<<<dim3(85, BATCH), 256, 0, stream>>>(x, gnpart);
  // 2) pos embed + ref + GN finalize (one launch)
  pos_ref_fin_kernel<<<5441, 256, 0, stream>>>(level_embed, pos, refb, gnpart, stats);
  // 3) GN apply -> xb, qb
  {
    int n = BATCH * LQ * CDIM;
    gn_apply_kernel<<<(n + 255) / 256, 256, 0, stream>>>(x, xb, qb, pos, stats,
                                                         gn_w, gn_b);
  }

  for (int i = 0; i < 6; ++i) {
    const __hip_bfloat16* sowa = sowa_wb + (size_t)i * 98304;
    const __hip_bfloat16* vw = vp_wb + (size_t)i * 65536;
    const __hip_bfloat16* ow = op_wb + (size_t)i * 65536;
    const __hip_bfloat16* w1 = l1_wb + (size_t)i * 262144;
    const __hip_bfloat16* w2 = l2_wb + (size_t)i * 262144;
    const float* vb = vp_b + (size_t)i * CDIM;
    const float* ob = op_b + (size_t)i * CDIM;
    const float* b1 = l1_b + (size_t)i * FFDIM;
    const float* b2 = l2_b + (size_t)i * CDIM;

    gemm_dual_kernel<<<850, 256, 0, stream>>>(xb, vw, vb, valb, qb, sowa,
                                              sowa_bias + i * 384, comb);
    deform_attn_kernel<<<BATCH * LQ * 8 / 64, 256, 0, stream>>>(valb, comb, refb,
                                                                attnb);
    // fused: xb = bf16(LN(xb + attnb@ow^T + ob))
    gemm_ln_kernel<false><<<340, 256, 0, stream>>>(
        attnb, ow, ob, xb, nullptr, nullptr,
        n1_w + (size_t)i * CDIM, n1_b + (size_t)i * CDIM, CDIM);
    ffn1_kernel<<<1360, 256, 0, stream>>>(xb, w1, b1, ff1b);
    // fused: xb = bf16(LN(xb + ff1b@w2^T + b2)); qb = bf16(ln + pos)
    gemm_ln_kernel<true><<<340, 256, 0, stream>>>(
        ff1b, w2, b2, xb, qb, pos,
        n2_w + (size_t)i * CDIM, n2_b + (size_t)i * CDIM, FFDIM);
  }

  // head
  conv1_mfma_kernel<<<128, 256, 0, stream>>>(xb, wc1b, c1_b,
                                             (const __hip_bfloat16*)zerof, c1ob);
  conv2_part_kernel<<<dim3(16, 9, BATCH), 256, 0, stream>>>(c1ob, c2_w, part2);
  upsample2_kernel<<<(BATCH * 65536 + 255) / 256, 256, 0, stream>>>(part2, c2_b,
                                                                    (float*)d_out);
}